// Round 1
// baseline (5146.978 us; speedup 1.0000x reference)
//
#include <hip/hip_runtime.h>
#include <math.h>

#define TPB 256

__device__ __forceinline__ float gelu_exact(float x) {
    return 0.5f * x * (1.0f + erff(x * 0.70710678118654752f));
}

// ---------------------------------------------------------------------------
// Instance-norm stats, channel-major source. If x1 != null: stage-A mode,
// 2048 channels (cam 0..1023, lid 1024..2047), value = x + pos (broadcast).
// Else: plain mode over gridDim.x channels of x0 (each P contiguous floats).
// ---------------------------------------------------------------------------
__global__ void k_stats_cm(const float* __restrict__ x0, const float* __restrict__ x1,
                           const float* __restrict__ pos, float* __restrict__ mean,
                           float* __restrict__ rstd, int P) {
    int gc = blockIdx.x;
    const float* src;
    const float* posr = nullptr;
    if (x1 != nullptr) {
        src = ((gc < 1024) ? x0 : x1) + (size_t)(gc & 1023) * P;
        posr = pos + (size_t)(gc & 127) * P;
    } else {
        src = x0 + (size_t)gc * P;
    }
    float s = 0.f, s2 = 0.f;
    for (int p = threadIdx.x; p < P; p += TPB) {
        float v = src[p];
        if (posr) v += posr[p];
        s += v; s2 += v * v;
    }
#pragma unroll
    for (int m = 32; m; m >>= 1) { s += __shfl_xor(s, m); s2 += __shfl_xor(s2, m); }
    __shared__ float ls[4], ls2[4];
    int w = threadIdx.x >> 6;
    if ((threadIdx.x & 63) == 0) { ls[w] = s; ls2[w] = s2; }
    __syncthreads();
    if (threadIdx.x == 0) {
        s = ls[0] + ls[1] + ls[2] + ls[3];
        s2 = ls2[0] + ls2[1] + ls2[2] + ls2[3];
        float mu = s / (float)P;
        float var = s2 / (float)P - mu * mu;
        mean[gc] = mu;
        rstd[gc] = rsqrtf(var + 1e-5f);
    }
}

// ---------------------------------------------------------------------------
// Token-major stats: z is (8, 2048, 128) row-major; stats per (bn, d) over 2048.
// One block per bn.
// ---------------------------------------------------------------------------
__global__ void k_stats_tm(const float* __restrict__ z, float* __restrict__ mean,
                           float* __restrict__ rstd) {
    int b = blockIdx.x;
    int d = threadIdx.x & 127, half = threadIdx.x >> 7;
    float s = 0.f, s2 = 0.f;
    for (int t = half; t < 2048; t += 2) {
        float v = z[((size_t)b * 2048 + t) * 128 + d];
        s += v; s2 += v * v;
    }
    __shared__ float ls[256], ls2[256];
    ls[threadIdx.x] = s; ls2[threadIdx.x] = s2;
    __syncthreads();
    if (threadIdx.x < 128) {
        s = ls[threadIdx.x] + ls[threadIdx.x + 128];
        s2 = ls2[threadIdx.x] + ls2[threadIdx.x + 128];
        float mu = s / 2048.f;
        float var = s2 / 2048.f - mu * mu;
        mean[b * 128 + d] = mu;
        rstd[b * 128 + d] = rsqrtf(var + 1e-5f);
    }
}

// ---------------------------------------------------------------------------
// Conv2x2 stride2 as GEMM: out[b][o][p] = sum_k w[o][k] * xcol[k][p],
// k = c*4 + a*2 + d, p over 32x32. Normalize+ReLU applied on the fly.
// grid (4 pgroups, 8 ogroups, 8 bn), 256 threads. K-chunks of 32 (8 channels).
// ---------------------------------------------------------------------------
__global__ void k_conv(const float* __restrict__ x, const float* __restrict__ pos,
                       const float* __restrict__ mean, const float* __restrict__ rstd,
                       const float* __restrict__ w, float* __restrict__ out, int stat_off) {
    __shared__ float Xs[32][256];
    __shared__ float Ws[32][17];
    int tid = threadIdx.x;
    int pg = blockIdx.x, og = blockIdx.y, b = blockIdx.z;
    int h0 = pg * 8;
    float acc[16];
#pragma unroll
    for (int i = 0; i < 16; i++) acc[i] = 0.f;
    for (int c0 = 0; c0 < 128; c0 += 8) {
        for (int i = tid; i < 512; i += TPB) {
            int ol = i >> 5, kc = i & 31;
            Ws[kc][ol] = w[(og * 16 + ol) * 512 + c0 * 4 + kc];
        }
        for (int i = tid; i < 8192; i += TPB) {
            int kc = i >> 8, p = i & 255;
            int cl = kc >> 2, a = (kc >> 1) & 1, dd = kc & 1;
            int c = c0 + cl;
            int hh = h0 + (p >> 5), ww = p & 31;
            int y = 2 * hh + a, xx = 2 * ww + dd;
            int ch = b * 128 + c;
            float v = x[(size_t)ch * 4096 + y * 64 + xx] + pos[c * 4096 + y * 64 + xx];
            v = (v - mean[stat_off + ch]) * rstd[stat_off + ch];
            Xs[kc][p] = fmaxf(v, 0.f);
        }
        __syncthreads();
#pragma unroll 8
        for (int kc = 0; kc < 32; kc++) {
            float xv = Xs[kc][tid];
#pragma unroll
            for (int o = 0; o < 16; o++) acc[o] += Ws[kc][o] * xv;
        }
        __syncthreads();
    }
    int p = pg * 256 + tid;
#pragma unroll
    for (int o = 0; o < 16; o++)
        out[((size_t)b * 128 + og * 16 + o) * 1024 + p] = acc[o];
}

// ---------------------------------------------------------------------------
// Transpose e (8,128,1024) channel-major into token-major rows (b, t, 128).
// mode 0: qin  (T=2048): t<1024 -> cam_e, else lid_e (token order)
// mode 1: kin  (T=1024): single source e0
// mode 2: skip (T=2048): s=(H,W) with W<32 -> cam_e[H*32+W], else lid_e
// grid (8, T/64)
// ---------------------------------------------------------------------------
__global__ void k_transpose(const float* __restrict__ e0, const float* __restrict__ e1,
                            float* __restrict__ out, int T, int mode) {
    __shared__ float tile[128][65];
    int b = blockIdx.x, tb = blockIdx.y;
    int t0 = tb * 64;
    int tid = threadIdx.x;
    for (int i = tid; i < 8192; i += TPB) {
        int d = i >> 6, j = i & 63;
        const float* src; int tt;
        if (mode == 0)      { src = (t0 < 1024) ? e0 : e1; tt = (t0 & 1023) + j; }
        else if (mode == 1) { src = e0; tt = t0 + j; }
        else                { src = (j < 32) ? e0 : e1; tt = tb * 32 + (j & 31); }
        tile[d][j] = src[((size_t)b * 128 + d) * 1024 + tt];
    }
    __syncthreads();
    for (int i = tid; i < 8192; i += TPB) {
        int j = i >> 7, d = i & 127;
        out[((size_t)b * T + t0 + j) * 128 + d] = tile[d][j];
    }
}

// ---------------------------------------------------------------------------
// Row LayerNorm (128 cols). One wave per row, 4 rows per block.
// ---------------------------------------------------------------------------
__global__ void k_rowln(const float* __restrict__ in, float* __restrict__ out,
                        const float* __restrict__ g, const float* __restrict__ bb) {
    int r = blockIdx.x * 4 + (threadIdx.x >> 6);
    int lane = threadIdx.x & 63;
    const float* row = in + (size_t)r * 128;
    float v0 = row[lane], v1 = row[lane + 64];
    float s = v0 + v1, s2 = v0 * v0 + v1 * v1;
#pragma unroll
    for (int m = 32; m; m >>= 1) { s += __shfl_xor(s, m); s2 += __shfl_xor(s2, m); }
    float mu = s * (1.f / 128.f);
    float var = s2 * (1.f / 128.f) - mu * mu;
    float rs = rsqrtf(var + 1e-5f);
    out[(size_t)r * 128 + lane]      = (v0 - mu) * rs * g[lane] + bb[lane];
    out[(size_t)r * 128 + lane + 64] = (v1 - mu) * rs * g[lane + 64] + bb[lane + 64];
}

// ---------------------------------------------------------------------------
// Generic fp32 GEMM: C[M,N] = A[M,K] @ B[K,N], 64x64 tile, Kc=32, 4x4/thread.
// mode 0: plain; 1: +bias; 2: +bias+aux[row,col]; 3: +bias then exact GELU.
// ---------------------------------------------------------------------------
__global__ void k_gemm(const float* __restrict__ A, const float* __restrict__ B,
                       float* __restrict__ C, int M, int N, int K, int mode,
                       const float* __restrict__ bias, const float* __restrict__ aux) {
    __shared__ __align__(16) float As[32][68];
    __shared__ __align__(16) float Bs[32][68];
    int tid = threadIdx.x;
    int m0 = blockIdx.y * 64, n0 = blockIdx.x * 64;
    int ty = tid >> 4, tx = tid & 15;
    float acc[4][4];
#pragma unroll
    for (int i = 0; i < 4; i++)
#pragma unroll
        for (int j = 0; j < 4; j++) acc[i][j] = 0.f;
    for (int k0 = 0; k0 < K; k0 += 32) {
        for (int i = tid; i < 512; i += TPB) {
            int row = i >> 3, k4 = i & 7;
            float4 va = *(const float4*)&A[(size_t)(m0 + row) * K + k0 + k4 * 4];
            As[k4 * 4 + 0][row] = va.x; As[k4 * 4 + 1][row] = va.y;
            As[k4 * 4 + 2][row] = va.z; As[k4 * 4 + 3][row] = va.w;
        }
        for (int i = tid; i < 512; i += TPB) {
            int row = i >> 4, n4 = i & 15;
            *(float4*)&Bs[row][n4 * 4] = *(const float4*)&B[(size_t)(k0 + row) * N + n0 + n4 * 4];
        }
        __syncthreads();
#pragma unroll
        for (int kk = 0; kk < 32; kk++) {
            float4 a4 = *(const float4*)&As[kk][ty * 4];
            float4 b4 = *(const float4*)&Bs[kk][tx * 4];
            float av[4] = {a4.x, a4.y, a4.z, a4.w};
            float bv[4] = {b4.x, b4.y, b4.z, b4.w};
#pragma unroll
            for (int i = 0; i < 4; i++)
#pragma unroll
                for (int j = 0; j < 4; j++) acc[i][j] += av[i] * bv[j];
        }
        __syncthreads();
    }
#pragma unroll
    for (int i = 0; i < 4; i++) {
        int row = m0 + ty * 4 + i;
#pragma unroll
        for (int j = 0; j < 4; j++) {
            int col = n0 + tx * 4 + j;
            float v = acc[i][j];
            if (mode >= 1) v += bias[col];
            if (mode == 2) v += aux[(size_t)row * N + col];
            if (mode == 3) v = gelu_exact(v);
            C[(size_t)row * N + col] = v;
        }
    }
}

// ---------------------------------------------------------------------------
// Flash attention (fp32). One block = (bn, head, 16-query tile); online softmax
// over 32-key chunks. q is pre-projected (16384,512); k,v are (8192,512).
// ---------------------------------------------------------------------------
__global__ void k_attn(const float* __restrict__ q, const float* __restrict__ k,
                       const float* __restrict__ v, float* __restrict__ aout) {
    __shared__ float Qs[16][128];
    __shared__ float Kc[32][129];
    __shared__ __align__(16) float Vc[32][132];
    __shared__ float Sc[16][33];
    __shared__ float m_s[16], l_s[16], f_s[16];
    int qt = blockIdx.x, h = blockIdx.y, b = blockIdx.z;
    int tid = threadIdx.x;
    const float scale = 0.08838834764831845f;  // 1/sqrt(128)

    for (int i = tid; i < 2048; i += TPB) {
        int r = i >> 7, d = i & 127;
        Qs[r][d] = q[((size_t)(b * 2048 + qt * 16 + r)) * 512 + h * 128 + d] * scale;
    }
    if (tid < 16) { m_s[tid] = -1e30f; l_s[tid] = 0.f; }
    float4 accA = {0, 0, 0, 0}, accB = {0, 0, 0, 0};
    int r_pv = tid >> 4, dl = tid & 15;
    int kk_sc = tid & 31, rg = tid >> 5;
    __syncthreads();

    for (int c0 = 0; c0 < 1024; c0 += 32) {
        for (int i = tid; i < 4096; i += TPB) {
            int row = i >> 7, d = i & 127;
            size_t base = ((size_t)(b * 1024 + c0 + row)) * 512 + h * 128 + d;
            Kc[row][d] = k[base];
            Vc[row][d] = v[base];
        }
        __syncthreads();
        // scores: 16x32, 2 rows per thread
        {
            float a0 = 0.f, a1 = 0.f;
            int r0 = rg * 2;
#pragma unroll 8
            for (int d = 0; d < 128; d++) {
                float kv = Kc[kk_sc][d];
                a0 += Qs[r0][d] * kv;
                a1 += Qs[r0 + 1][d] * kv;
            }
            Sc[r0][kk_sc] = a0;
            Sc[r0 + 1][kk_sc] = a1;
        }
        __syncthreads();
        // per-row running max
        if (tid < 16) {
            float mo = m_s[tid], mn = mo;
#pragma unroll
            for (int kk = 0; kk < 32; kk++) mn = fmaxf(mn, Sc[tid][kk]);
            f_s[tid] = expf(mo - mn);
            m_s[tid] = mn;
        }
        __syncthreads();
        // exponentiate + l update
        {
            int r = tid >> 4, k2 = tid & 15;
            float mn = m_s[r];
            float e0 = expf(Sc[r][k2] - mn);
            float e1 = expf(Sc[r][k2 + 16] - mn);
            Sc[r][k2] = e0; Sc[r][k2 + 16] = e1;
            float ps = e0 + e1;
            ps += __shfl_xor(ps, 1); ps += __shfl_xor(ps, 2);
            ps += __shfl_xor(ps, 4); ps += __shfl_xor(ps, 8);
            if (k2 == 0) l_s[r] = l_s[r] * f_s[r] + ps;
        }
        __syncthreads();
        // PV accumulate: thread (r, dl) owns d = dl*8 .. dl*8+7
        {
            float f = f_s[r_pv];
            accA.x *= f; accA.y *= f; accA.z *= f; accA.w *= f;
            accB.x *= f; accB.y *= f; accB.z *= f; accB.w *= f;
#pragma unroll 8
            for (int kk = 0; kk < 32; kk++) {
                float p = Sc[r_pv][kk];
                float4 va = *(const float4*)&Vc[kk][dl * 8];
                float4 vb = *(const float4*)&Vc[kk][dl * 8 + 4];
                accA.x += p * va.x; accA.y += p * va.y; accA.z += p * va.z; accA.w += p * va.w;
                accB.x += p * vb.x; accB.y += p * vb.y; accB.z += p * vb.z; accB.w += p * vb.w;
            }
        }
        __syncthreads();
    }
    float linv = 1.f / l_s[r_pv];
    size_t ob = ((size_t)(b * 2048 + qt * 16 + r_pv)) * 512 + h * 128 + dl * 8;
    float4 oA = {accA.x * linv, accA.y * linv, accA.z * linv, accA.w * linv};
    float4 oB = {accB.x * linv, accB.y * linv, accB.z * linv, accB.w * linv};
    *(float4*)&aout[ob] = oA;
    *(float4*)&aout[ob + 4] = oB;
}

// ---------------------------------------------------------------------------
// fused_s[b][d][p] = sum over {cam,lid} x {m=0,1} of z[b][m*1024+p][d]
// ---------------------------------------------------------------------------
__global__ void k_fused_sum(const float* __restrict__ zc, const float* __restrict__ zl,
                            float* __restrict__ fs) {
    int idx = blockIdx.x * TPB + threadIdx.x;  // 1,048,576 total
    int d = idx & 127, p = (idx >> 7) & 1023, b = idx >> 17;
    size_t r0 = ((size_t)b * 2048 + p) * 128 + d;
    size_t r1 = ((size_t)b * 2048 + 1024 + p) * 128 + d;
    float v = zc[r0] + zc[r1] + zl[r0] + zl[r1];
    fs[((size_t)b * 128 + d) * 1024 + p] = v;
}

// ---------------------------------------------------------------------------
// ConvTranspose2x2 stride2 as GEMM: out[(o,a,d)][p] = sum_i xn[i][p]*wT[i][o,a,d]
// layout 0: src channel-major (b,128,P); layout 1: src token-major z (b,P,128).
// grid (P/64, 16 ogroups of 8, 8 bn).
// ---------------------------------------------------------------------------
__global__ void k_convt(const float* __restrict__ src, int layout,
                        const float* __restrict__ mean, const float* __restrict__ rstd,
                        const float* __restrict__ wT, float* __restrict__ out,
                        int Hin, int Win) {
    __shared__ float Xs[128][66];
    __shared__ float Ws[128][32];
    int tid = threadIdx.x;
    int pg = blockIdx.x, og = blockIdx.y, b = blockIdx.z;
    int P = Hin * Win;
    int p0 = pg * 64;
    for (int i = tid; i < 4096; i += TPB) {
        int ii = i >> 5, col = i & 31;
        Ws[ii][col] = wT[ii * 512 + og * 32 + col];
    }
    if (layout == 0) {
        for (int idx = tid; idx < 8192; idx += TPB) {
            int ii = idx >> 6, pr = idx & 63;
            int ch = b * 128 + ii;
            float vv = src[(size_t)ch * P + p0 + pr];
            Xs[ii][pr] = fmaxf((vv - mean[ch]) * rstd[ch], 0.f);
        }
    } else {
        for (int idx = tid; idx < 8192; idx += TPB) {
            int pr = idx >> 7, ii = idx & 127;
            int ch = b * 128 + ii;
            float vv = src[((size_t)b * P + p0 + pr) * 128 + ii];
            Xs[ii][pr] = fmaxf((vv - mean[ch]) * rstd[ch], 0.f);
        }
    }
    __syncthreads();
    int p = tid >> 2, ad = tid & 3;
    float acc[8];
#pragma unroll
    for (int o = 0; o < 8; o++) acc[o] = 0.f;
#pragma unroll 4
    for (int i = 0; i < 128; i++) {
        float xv = Xs[i][p];
#pragma unroll
        for (int o = 0; o < 8; o++) acc[o] += xv * Ws[i][o * 4 + ad];
    }
    int pp = p0 + p;
    int hin = pp / Win, win = pp % Win;
    int a = ad >> 1, dd = ad & 1;
    int Ho = 2 * Hin, Wo = 2 * Win;
#pragma unroll
    for (int o = 0; o < 8; o++) {
        int oc = og * 8 + o;
        out[(((size_t)b * 128 + oc) * Ho + 2 * hin + a) * Wo + 2 * win + dd] = acc[o];
    }
}

// ---------------------------------------------------------------------------
extern "C" void kernel_launch(void* const* d_in, const int* in_sizes, int n_in,
                              void* d_out, int out_size, void* d_ws, size_t ws_size,
                              hipStream_t stream) {
    const float* cam_feat = (const float*)d_in[0];
    const float* lid_feat = (const float*)d_in[1];
    const float* pos      = (const float*)d_in[2];
    const float* conv_w   = (const float*)d_in[3];
    const float* convT_w  = (const float*)d_in[4];
    const float* lnq_g = (const float*)d_in[5];
    const float* lnq_b = (const float*)d_in[6];
    const float* wq    = (const float*)d_in[7];
    const float* lnk_g = (const float*)d_in[8];
    const float* lnk_b = (const float*)d_in[9];
    const float* wk    = (const float*)d_in[10];
    const float* lnv_g = (const float*)d_in[11];
    const float* lnv_b = (const float*)d_in[12];
    const float* wv    = (const float*)d_in[13];
    const float* proj_w = (const float*)d_in[14];
    const float* proj_b = (const float*)d_in[15];
    const float* pre_g = (const float*)d_in[16];
    const float* pre_b = (const float*)d_in[17];
    const float* mlp_w1 = (const float*)d_in[18];
    const float* mlp_b1 = (const float*)d_in[19];
    const float* mlp_w2 = (const float*)d_in[20];
    const float* mlp_b2 = (const float*)d_in[21];
    const float* post_g = (const float*)d_in[22];
    const float* post_b = (const float*)d_in[23];

    float* ws = (float*)d_ws;
    float* outp = (float*)d_out;

    // workspace layout (floats)
    float* cam_e   = ws + 0;               // 1,048,576
    float* lid_e   = ws + 1048576;         // 1,048,576
    float* qbuf    = ws + 2097152;         // 8,388,608
    float* skip    = ws + 10485760;        // 2,097,152
    float* z_cam   = ws + 12582912;        // 2,097,152
    float* z_lid   = ws + 14680064;        // 2,097,152
    float* fused_s = ws + 16777216;        // 1,048,576
    float* stats   = ws + 17825792;        // 16,384
    float* pool    = ws + 17842176;        // 19,922,944   (total 37,765,120 f = 151 MB)

    float* meanA = stats + 0,    *rstdA = stats + 2048;
    float* meanF = stats + 4096, *rstdF = stats + 5120;
    float* meanC = stats + 6144, *rstdC = stats + 7168;
    float* meanL = stats + 8192, *rstdL = stats + 9216;

    float* qin   = pool + 0;
    float* lnqb  = pool + 2097152;
    float* kin   = pool + 0;
    float* lnkb  = pool + 1048576;
    float* lnvb  = pool + 2097152;
    float* kbuf  = pool + 3145728;
    float* vbuf  = pool + 7340032;
    float* abuf  = pool + 11534336;
    float* z1    = pool + 0;
    float* h1    = pool + 3145728;
    float* z2    = pool + 7340032;
    float* z3    = pool + 9437184;

    // Stage A: instance-norm stats + conv encoders
    k_stats_cm<<<2048, TPB, 0, stream>>>(cam_feat, lid_feat, pos, meanA, rstdA, 4096);
    k_conv<<<dim3(4, 8, 8), TPB, 0, stream>>>(cam_feat, pos, meanA, rstdA, conv_w, cam_e, 0);
    k_conv<<<dim3(4, 8, 8), TPB, 0, stream>>>(lid_feat, pos, meanA, rstdA, conv_w, lid_e, 1024);

    // Shared Q and skip
    k_transpose<<<dim3(8, 32), TPB, 0, stream>>>(cam_e, lid_e, qin, 2048, 0);
    k_rowln<<<4096, TPB, 0, stream>>>(qin, lnqb, lnq_g, lnq_b);
    k_gemm<<<dim3(8, 256), TPB, 0, stream>>>(lnqb, wq, qbuf, 16384, 512, 128, 0, nullptr, nullptr);
    k_transpose<<<dim3(8, 32), TPB, 0, stream>>>(cam_e, lid_e, skip, 2048, 2);

    for (int cross = 0; cross < 2; cross++) {
        const float* e = cross ? lid_e : cam_e;
        float* zout = cross ? z_lid : z_cam;
        k_transpose<<<dim3(8, 16), TPB, 0, stream>>>(e, nullptr, kin, 1024, 1);
        k_rowln<<<2048, TPB, 0, stream>>>(kin, lnkb, lnk_g, lnk_b);
        k_rowln<<<2048, TPB, 0, stream>>>(kin, lnvb, lnv_g, lnv_b);
        k_gemm<<<dim3(8, 128), TPB, 0, stream>>>(lnkb, wk, kbuf, 8192, 512, 128, 0, nullptr, nullptr);
        k_gemm<<<dim3(8, 128), TPB, 0, stream>>>(lnvb, wv, vbuf, 8192, 512, 128, 0, nullptr, nullptr);
        k_attn<<<dim3(128, 4, 8), TPB, 0, stream>>>(qbuf, kbuf, vbuf, abuf);
        k_gemm<<<dim3(2, 256), TPB, 0, stream>>>(abuf, proj_w, z1, 16384, 128, 512, 2, proj_b, skip);
        k_rowln<<<4096, TPB, 0, stream>>>(z1, z2, pre_g, pre_b);
        k_gemm<<<dim3(4, 256), TPB, 0, stream>>>(z2, mlp_w1, h1, 16384, 256, 128, 3, mlp_b1, nullptr);
        k_gemm<<<dim3(2, 256), TPB, 0, stream>>>(h1, mlp_w2, z3, 16384, 128, 256, 2, mlp_b2, z2);
        k_rowln<<<4096, TPB, 0, stream>>>(z3, zout, post_g, post_b);
    }

    // Outputs
    k_fused_sum<<<4096, TPB, 0, stream>>>(z_cam, z_lid, fused_s);
    k_stats_cm<<<1024, TPB, 0, stream>>>(fused_s, nullptr, nullptr, meanF, rstdF, 1024);
    k_stats_tm<<<8, TPB, 0, stream>>>(z_cam, meanC, rstdC);
    k_stats_tm<<<8, TPB, 0, stream>>>(z_lid, meanL, rstdL);
    k_convt<<<dim3(16, 16, 8), TPB, 0, stream>>>(fused_s, 0, meanF, rstdF, convT_w, outp, 32, 32);
    k_convt<<<dim3(32, 16, 8), TPB, 0, stream>>>(z_cam, 1, meanC, rstdC, convT_w, outp + 4194304, 64, 32);
    k_convt<<<dim3(32, 16, 8), TPB, 0, stream>>>(z_lid, 1, meanL, rstdL, convT_w, outp + 12582912, 64, 32);
}

// Round 2
// 1837.278 us; speedup vs baseline: 2.8014x; 2.8014x over previous
//
#include <hip/hip_runtime.h>
#include <math.h>

#define TPB 256

typedef __attribute__((ext_vector_type(8))) short bf16x8;
typedef __attribute__((ext_vector_type(4))) float f32x4;

__device__ __forceinline__ float gelu_exact(float x) {
    return 0.5f * x * (1.0f + erff(x * 0.70710678118654752f));
}

__device__ __forceinline__ unsigned short f2bf(float x) {
    unsigned u = __float_as_uint(x);
    return (unsigned short)((u + 0x7fffu + ((u >> 16) & 1u)) >> 16);
}

// ---------------------------------------------------------------------------
// Instance-norm stats, channel-major source. If x1 != null: stage-A mode,
// 2048 channels (cam 0..1023, lid 1024..2047), value = x + pos (broadcast).
// Else: plain mode over gridDim.x channels of x0 (each P contiguous floats).
// ---------------------------------------------------------------------------
__global__ void k_stats_cm(const float* __restrict__ x0, const float* __restrict__ x1,
                           const float* __restrict__ pos, float* __restrict__ mean,
                           float* __restrict__ rstd, int P) {
    int gc = blockIdx.x;
    const float* src;
    const float* posr = nullptr;
    if (x1 != nullptr) {
        src = ((gc < 1024) ? x0 : x1) + (size_t)(gc & 1023) * P;
        posr = pos + (size_t)(gc & 127) * P;
    } else {
        src = x0 + (size_t)gc * P;
    }
    float s = 0.f, s2 = 0.f;
    for (int p = threadIdx.x; p < P; p += TPB) {
        float v = src[p];
        if (posr) v += posr[p];
        s += v; s2 += v * v;
    }
#pragma unroll
    for (int m = 32; m; m >>= 1) { s += __shfl_xor(s, m); s2 += __shfl_xor(s2, m); }
    __shared__ float ls[4], ls2[4];
    int w = threadIdx.x >> 6;
    if ((threadIdx.x & 63) == 0) { ls[w] = s; ls2[w] = s2; }
    __syncthreads();
    if (threadIdx.x == 0) {
        s = ls[0] + ls[1] + ls[2] + ls[3];
        s2 = ls2[0] + ls2[1] + ls2[2] + ls2[3];
        float mu = s / (float)P;
        float var = s2 / (float)P - mu * mu;
        mean[gc] = mu;
        rstd[gc] = rsqrtf(var + 1e-5f);
    }
}

// ---------------------------------------------------------------------------
// Token-major stats: z is (8, 2048, 128) row-major; stats per (bn, d) over 2048.
// ---------------------------------------------------------------------------
__global__ void k_stats_tm(const float* __restrict__ z, float* __restrict__ mean,
                           float* __restrict__ rstd) {
    int b = blockIdx.x;
    int d = threadIdx.x & 127, half = threadIdx.x >> 7;
    float s = 0.f, s2 = 0.f;
    for (int t = half; t < 2048; t += 2) {
        float v = z[((size_t)b * 2048 + t) * 128 + d];
        s += v; s2 += v * v;
    }
    __shared__ float ls[256], ls2[256];
    ls[threadIdx.x] = s; ls2[threadIdx.x] = s2;
    __syncthreads();
    if (threadIdx.x < 128) {
        s = ls[threadIdx.x] + ls[threadIdx.x + 128];
        s2 = ls2[threadIdx.x] + ls2[threadIdx.x + 128];
        float mu = s / 2048.f;
        float var = s2 / 2048.f - mu * mu;
        mean[b * 128 + d] = mu;
        rstd[b * 128 + d] = rsqrtf(var + 1e-5f);
    }
}

// ---------------------------------------------------------------------------
// Conv2x2 stride2 as GEMM (see round 0 comments).
// ---------------------------------------------------------------------------
__global__ void k_conv(const float* __restrict__ x, const float* __restrict__ pos,
                       const float* __restrict__ mean, const float* __restrict__ rstd,
                       const float* __restrict__ w, float* __restrict__ out, int stat_off) {
    __shared__ float Xs[32][256];
    __shared__ float Ws[32][17];
    int tid = threadIdx.x;
    int pg = blockIdx.x, og = blockIdx.y, b = blockIdx.z;
    int h0 = pg * 8;
    float acc[16];
#pragma unroll
    for (int i = 0; i < 16; i++) acc[i] = 0.f;
    for (int c0 = 0; c0 < 128; c0 += 8) {
        for (int i = tid; i < 512; i += TPB) {
            int ol = i >> 5, kc = i & 31;
            Ws[kc][ol] = w[(og * 16 + ol) * 512 + c0 * 4 + kc];
        }
        for (int i = tid; i < 8192; i += TPB) {
            int kc = i >> 8, p = i & 255;
            int cl = kc >> 2, a = (kc >> 1) & 1, dd = kc & 1;
            int c = c0 + cl;
            int hh = h0 + (p >> 5), ww = p & 31;
            int y = 2 * hh + a, xx = 2 * ww + dd;
            int ch = b * 128 + c;
            float v = x[(size_t)ch * 4096 + y * 64 + xx] + pos[c * 4096 + y * 64 + xx];
            v = (v - mean[stat_off + ch]) * rstd[stat_off + ch];
            Xs[kc][p] = fmaxf(v, 0.f);
        }
        __syncthreads();
#pragma unroll 8
        for (int kc = 0; kc < 32; kc++) {
            float xv = Xs[kc][tid];
#pragma unroll
            for (int o = 0; o < 16; o++) acc[o] += Ws[kc][o] * xv;
        }
        __syncthreads();
    }
    int p = pg * 256 + tid;
#pragma unroll
    for (int o = 0; o < 16; o++)
        out[((size_t)b * 128 + og * 16 + o) * 1024 + p] = acc[o];
}

// ---------------------------------------------------------------------------
// Transpose e (8,128,1024) channel-major into token-major rows (b, t, 128).
// ---------------------------------------------------------------------------
__global__ void k_transpose(const float* __restrict__ e0, const float* __restrict__ e1,
                            float* __restrict__ out, int T, int mode) {
    __shared__ float tile[128][65];
    int b = blockIdx.x, tb = blockIdx.y;
    int t0 = tb * 64;
    int tid = threadIdx.x;
    for (int i = tid; i < 8192; i += TPB) {
        int d = i >> 6, j = i & 63;
        const float* src; int tt;
        if (mode == 0)      { src = (t0 < 1024) ? e0 : e1; tt = (t0 & 1023) + j; }
        else if (mode == 1) { src = e0; tt = t0 + j; }
        else                { src = (j < 32) ? e0 : e1; tt = tb * 32 + (j & 31); }
        tile[d][j] = src[((size_t)b * 128 + d) * 1024 + tt];
    }
    __syncthreads();
    for (int i = tid; i < 8192; i += TPB) {
        int j = i >> 7, d = i & 127;
        out[((size_t)b * T + t0 + j) * 128 + d] = tile[d][j];
    }
}

// ---------------------------------------------------------------------------
// Row LayerNorm (128 cols). One wave per row, 4 rows per block.
// ---------------------------------------------------------------------------
__global__ void k_rowln(const float* __restrict__ in, float* __restrict__ out,
                        const float* __restrict__ g, const float* __restrict__ bb) {
    int r = blockIdx.x * 4 + (threadIdx.x >> 6);
    int lane = threadIdx.x & 63;
    const float* row = in + (size_t)r * 128;
    float v0 = row[lane], v1 = row[lane + 64];
    float s = v0 + v1, s2 = v0 * v0 + v1 * v1;
#pragma unroll
    for (int m = 32; m; m >>= 1) { s += __shfl_xor(s, m); s2 += __shfl_xor(s2, m); }
    float mu = s * (1.f / 128.f);
    float var = s2 * (1.f / 128.f) - mu * mu;
    float rs = rsqrtf(var + 1e-5f);
    out[(size_t)r * 128 + lane]      = (v0 - mu) * rs * g[lane] + bb[lane];
    out[(size_t)r * 128 + lane + 64] = (v1 - mu) * rs * g[lane + 64] + bb[lane + 64];
}

// ---------------------------------------------------------------------------
// Generic fp32 GEMM (round 0).
// ---------------------------------------------------------------------------
__global__ void k_gemm(const float* __restrict__ A, const float* __restrict__ B,
                       float* __restrict__ C, int M, int N, int K, int mode,
                       const float* __restrict__ bias, const float* __restrict__ aux) {
    __shared__ __align__(16) float As[32][68];
    __shared__ __align__(16) float Bs[32][68];
    int tid = threadIdx.x;
    int m0 = blockIdx.y * 64, n0 = blockIdx.x * 64;
    int ty = tid >> 4, tx = tid & 15;
    float acc[4][4];
#pragma unroll
    for (int i = 0; i < 4; i++)
#pragma unroll
        for (int j = 0; j < 4; j++) acc[i][j] = 0.f;
    for (int k0 = 0; k0 < K; k0 += 32) {
        for (int i = tid; i < 512; i += TPB) {
            int row = i >> 3, k4 = i & 7;
            float4 va = *(const float4*)&A[(size_t)(m0 + row) * K + k0 + k4 * 4];
            As[k4 * 4 + 0][row] = va.x; As[k4 * 4 + 1][row] = va.y;
            As[k4 * 4 + 2][row] = va.z; As[k4 * 4 + 3][row] = va.w;
        }
        for (int i = tid; i < 512; i += TPB) {
            int row = i >> 4, n4 = i & 15;
            *(float4*)&Bs[row][n4 * 4] = *(const float4*)&B[(size_t)(k0 + row) * N + n0 + n4 * 4];
        }
        __syncthreads();
#pragma unroll
        for (int kk = 0; kk < 32; kk++) {
            float4 a4 = *(const float4*)&As[kk][ty * 4];
            float4 b4 = *(const float4*)&Bs[kk][tx * 4];
            float av[4] = {a4.x, a4.y, a4.z, a4.w};
            float bv[4] = {b4.x, b4.y, b4.z, b4.w};
#pragma unroll
            for (int i = 0; i < 4; i++)
#pragma unroll
                for (int j = 0; j < 4; j++) acc[i][j] += av[i] * bv[j];
        }
        __syncthreads();
    }
#pragma unroll
    for (int i = 0; i < 4; i++) {
        int row = m0 + ty * 4 + i;
#pragma unroll
        for (int j = 0; j < 4; j++) {
            int col = n0 + tx * 4 + j;
            float v = acc[i][j];
            if (mode >= 1) v += bias[col];
            if (mode == 2) v += aux[(size_t)row * N + col];
            if (mode == 3) v = gelu_exact(v);
            C[(size_t)row * N + col] = v;
        }
    }
}

// ---------------------------------------------------------------------------
// MFMA flash attention (bf16 inputs, fp32 accum).
// Block = 256 threads = 4 waves; 128 q-rows/block (32/wave as 2 m-tiles).
// Per 32-kv chunk: K staged row-major swizzled bf16; V staged transposed
// Vt[128][40]; QK^T via mfma_16x16x32_bf16; shfl-based online softmax
// (C-layout: row r lives in one 16-lane group); P -> per-wave LDS -> A-frag;
// PV with V-frags shared across m-tiles. grid (16, 4, 8).
// ---------------------------------------------------------------------------
__global__ __launch_bounds__(256, 2) void k_attn_mfma(
        const float* __restrict__ q, const float* __restrict__ k,
        const float* __restrict__ v, float* __restrict__ aout) {
    __shared__ __align__(16) unsigned short smem[16384];  // 32 KB
    unsigned short* Ks = smem;            // [32][128] swizzled
    unsigned short* Vt = smem + 4096;     // [128][40]
    unsigned short* Ps = smem + 9216;     // 4 waves x [32][40]
    int tid = threadIdx.x;
    int lane = tid & 63, w = tid >> 6;
    int l16 = lane & 15, lhi = lane >> 4;
    int qt = blockIdx.x, h = blockIdx.y, b = blockIdx.z;
    const float scale = 0.08838834764831845f;  // 1/sqrt(128)

    // ---- stage Q (scaled, bf16, swizzled) then pull frags to registers ----
    const float* qg = q + ((size_t)(b * 2048 + qt * 128)) * 512 + h * 128;
    for (int i = tid; i < 4096; i += TPB) {
        int row = i >> 5, c4 = (i & 31) * 4;
        float4 va = *(const float4*)&qg[(size_t)row * 512 + c4];
        ushort4 u;
        u.x = f2bf(va.x * scale); u.y = f2bf(va.y * scale);
        u.z = f2bf(va.z * scale); u.w = f2bf(va.w * scale);
        *(ushort4*)&smem[(row * 128 + c4) ^ ((row & 7) << 3)] = u;
    }
    __syncthreads();
    bf16x8 qa[2][4];
#pragma unroll
    for (int mt = 0; mt < 2; mt++) {
        int r = w * 32 + mt * 16 + l16;
#pragma unroll
        for (int ks = 0; ks < 4; ks++)
            qa[mt][ks] = *(bf16x8*)&smem[(r * 128 + ks * 32 + lhi * 8) ^ ((r & 7) << 3)];
    }
    __syncthreads();

    f32x4 acc[2][8];
#pragma unroll
    for (int mt = 0; mt < 2; mt++)
#pragma unroll
        for (int dt = 0; dt < 8; dt++) acc[mt][dt] = (f32x4){0.f, 0.f, 0.f, 0.f};
    float m_r[2][4], l_r[2][4];
#pragma unroll
    for (int mt = 0; mt < 2; mt++)
#pragma unroll
        for (int rg = 0; rg < 4; rg++) { m_r[mt][rg] = -1e30f; l_r[mt][rg] = 0.f; }

    const float* kg = k + ((size_t)(b * 1024)) * 512 + h * 128;
    const float* vg = v + ((size_t)(b * 1024)) * 512 + h * 128;
    unsigned short* Pw = Ps + w * 1280;

    for (int c0 = 0; c0 < 1024; c0 += 32) {
        // stage K chunk (bf16, swizzled rows)
        for (int i = tid; i < 1024; i += TPB) {
            int row = i >> 5, c4 = (i & 31) * 4;
            float4 va = *(const float4*)&kg[(size_t)(c0 + row) * 512 + c4];
            ushort4 u;
            u.x = f2bf(va.x); u.y = f2bf(va.y); u.z = f2bf(va.z); u.w = f2bf(va.w);
            *(ushort4*)&Ks[(row * 128 + c4) ^ ((row & 7) << 3)] = u;
        }
        // stage V transposed: Vt[d][kk]
        for (int i = tid; i < 4096; i += TPB) {
            int kk = i >> 7, d = i & 127;
            Vt[d * 40 + kk] = f2bf(vg[(size_t)(c0 + kk) * 512 + d]);
        }
        __syncthreads();

        // ---- QK^T : S[2 m-tiles][2 n-tiles], K-frags reused across m ----
        f32x4 s[2][2];
        s[0][0] = s[0][1] = s[1][0] = s[1][1] = (f32x4){0.f, 0.f, 0.f, 0.f};
#pragma unroll
        for (int nt = 0; nt < 2; nt++) {
            int r = nt * 16 + l16;
#pragma unroll
            for (int ks = 0; ks < 4; ks++) {
                bf16x8 kb = *(bf16x8*)&Ks[(r * 128 + ks * 32 + lhi * 8) ^ ((r & 7) << 3)];
                s[0][nt] = __builtin_amdgcn_mfma_f32_16x16x32_bf16(qa[0][ks], kb, s[0][nt], 0, 0, 0);
                s[1][nt] = __builtin_amdgcn_mfma_f32_16x16x32_bf16(qa[1][ks], kb, s[1][nt], 0, 0, 0);
            }
        }

        // ---- online softmax (row r of a 16x16 D-tile lives in lane group) ----
#pragma unroll
        for (int mt = 0; mt < 2; mt++) {
#pragma unroll
            for (int rg = 0; rg < 4; rg++) {
                float s0 = s[mt][0][rg], s1 = s[mt][1][rg];
                float mx = fmaxf(s0, s1);
                mx = fmaxf(mx, __shfl_xor(mx, 1));
                mx = fmaxf(mx, __shfl_xor(mx, 2));
                mx = fmaxf(mx, __shfl_xor(mx, 4));
                mx = fmaxf(mx, __shfl_xor(mx, 8));
                float mo = m_r[mt][rg];
                float mn = fmaxf(mo, mx);
                float f = __expf(mo - mn);
                m_r[mt][rg] = mn;
                float p0 = __expf(s0 - mn), p1 = __expf(s1 - mn);
                float ps = p0 + p1;
                ps += __shfl_xor(ps, 1);
                ps += __shfl_xor(ps, 2);
                ps += __shfl_xor(ps, 4);
                ps += __shfl_xor(ps, 8);
                l_r[mt][rg] = l_r[mt][rg] * f + ps;
#pragma unroll
                for (int dt = 0; dt < 8; dt++) acc[mt][dt][rg] *= f;
                int row = mt * 16 + lhi * 4 + rg;
                Pw[row * 40 + l16] = f2bf(p0);
                Pw[row * 40 + 16 + l16] = f2bf(p1);
            }
        }
        asm volatile("s_waitcnt lgkmcnt(0)" ::: "memory");

        // ---- PV : V-frags shared across m-tiles ----
        bf16x8 pa0 = *(bf16x8*)&Pw[l16 * 40 + lhi * 8];
        bf16x8 pa1 = *(bf16x8*)&Pw[(16 + l16) * 40 + lhi * 8];
#pragma unroll
        for (int dt = 0; dt < 8; dt++) {
            bf16x8 vb = *(bf16x8*)&Vt[(dt * 16 + l16) * 40 + lhi * 8];
            acc[0][dt] = __builtin_amdgcn_mfma_f32_16x16x32_bf16(pa0, vb, acc[0][dt], 0, 0, 0);
            acc[1][dt] = __builtin_amdgcn_mfma_f32_16x16x32_bf16(pa1, vb, acc[1][dt], 0, 0, 0);
        }
        __syncthreads();
    }

    // ---- epilogue ----
#pragma unroll
    for (int mt = 0; mt < 2; mt++)
#pragma unroll
        for (int rg = 0; rg < 4; rg++) {
            float linv = 1.f / l_r[mt][rg];
            int qrow = qt * 128 + w * 32 + mt * 16 + lhi * 4 + rg;
            float* orow = aout + ((size_t)(b * 2048 + qrow)) * 512 + h * 128;
#pragma unroll
            for (int dt = 0; dt < 8; dt++)
                orow[dt * 16 + l16] = acc[mt][dt][rg] * linv;
        }
}

// ---------------------------------------------------------------------------
__global__ void k_fused_sum(const float* __restrict__ zc, const float* __restrict__ zl,
                            float* __restrict__ fs) {
    int idx = blockIdx.x * TPB + threadIdx.x;
    int d = idx & 127, p = (idx >> 7) & 1023, b = idx >> 17;
    size_t r0 = ((size_t)b * 2048 + p) * 128 + d;
    size_t r1 = ((size_t)b * 2048 + 1024 + p) * 128 + d;
    float v = zc[r0] + zc[r1] + zl[r0] + zl[r1];
    fs[((size_t)b * 128 + d) * 1024 + p] = v;
}

// ---------------------------------------------------------------------------
// ConvTranspose2x2 stride2 as GEMM (round 0).
// ---------------------------------------------------------------------------
__global__ void k_convt(const float* __restrict__ src, int layout,
                        const float* __restrict__ mean, const float* __restrict__ rstd,
                        const float* __restrict__ wT, float* __restrict__ out,
                        int Hin, int Win) {
    __shared__ float Xs[128][66];
    __shared__ float Ws[128][32];
    int tid = threadIdx.x;
    int pg = blockIdx.x, og = blockIdx.y, b = blockIdx.z;
    int P = Hin * Win;
    int p0 = pg * 64;
    for (int i = tid; i < 4096; i += TPB) {
        int ii = i >> 5, col = i & 31;
        Ws[ii][col] = wT[ii * 512 + og * 32 + col];
    }
    if (layout == 0) {
        for (int idx = tid; idx < 8192; idx += TPB) {
            int ii = idx >> 6, pr = idx & 63;
            int ch = b * 128 + ii;
            float vv = src[(size_t)ch * P + p0 + pr];
            Xs[ii][pr] = fmaxf((vv - mean[ch]) * rstd[ch], 0.f);
        }
    } else {
        for (int idx = tid; idx < 8192; idx += TPB) {
            int pr = idx >> 7, ii = idx & 127;
            int ch = b * 128 + ii;
            float vv = src[((size_t)b * P + p0 + pr) * 128 + ii];
            Xs[ii][pr] = fmaxf((vv - mean[ch]) * rstd[ch], 0.f);
        }
    }
    __syncthreads();
    int p = tid >> 2, ad = tid & 3;
    float acc[8];
#pragma unroll
    for (int o = 0; o < 8; o++) acc[o] = 0.f;
#pragma unroll 4
    for (int i = 0; i < 128; i++) {
        float xv = Xs[i][p];
#pragma unroll
        for (int o = 0; o < 8; o++) acc[o] += xv * Ws[i][o * 4 + ad];
    }
    int pp = p0 + p;
    int hin = pp / Win, win = pp % Win;
    int a = ad >> 1, dd = ad & 1;
    int Ho = 2 * Hin, Wo = 2 * Win;
#pragma unroll
    for (int o = 0; o < 8; o++) {
        int oc = og * 8 + o;
        out[(((size_t)b * 128 + oc) * Ho + 2 * hin + a) * Wo + 2 * win + dd] = acc[o];
    }
}

// ---------------------------------------------------------------------------
extern "C" void kernel_launch(void* const* d_in, const int* in_sizes, int n_in,
                              void* d_out, int out_size, void* d_ws, size_t ws_size,
                              hipStream_t stream) {
    const float* cam_feat = (const float*)d_in[0];
    const float* lid_feat = (const float*)d_in[1];
    const float* pos      = (const float*)d_in[2];
    const float* conv_w   = (const float*)d_in[3];
    const float* convT_w  = (const float*)d_in[4];
    const float* lnq_g = (const float*)d_in[5];
    const float* lnq_b = (const float*)d_in[6];
    const float* wq    = (const float*)d_in[7];
    const float* lnk_g = (const float*)d_in[8];
    const float* lnk_b = (const float*)d_in[9];
    const float* wk    = (const float*)d_in[10];
    const float* lnv_g = (const float*)d_in[11];
    const float* lnv_b = (const float*)d_in[12];
    const float* wv    = (const float*)d_in[13];
    const float* proj_w = (const float*)d_in[14];
    const float* proj_b = (const float*)d_in[15];
    const float* pre_g = (const float*)d_in[16];
    const float* pre_b = (const float*)d_in[17];
    const float* mlp_w1 = (const float*)d_in[18];
    const float* mlp_b1 = (const float*)d_in[19];
    const float* mlp_w2 = (const float*)d_in[20];
    const float* mlp_b2 = (const float*)d_in[21];
    const float* post_g = (const float*)d_in[22];
    const float* post_b = (const float*)d_in[23];

    float* ws = (float*)d_ws;
    float* outp = (float*)d_out;

    // workspace layout (floats)
    float* cam_e   = ws + 0;               // 1,048,576
    float* lid_e   = ws + 1048576;         // 1,048,576
    float* qbuf    = ws + 2097152;         // 8,388,608
    float* skip    = ws + 10485760;        // 2,097,152
    float* z_cam   = ws + 12582912;        // 2,097,152
    float* z_lid   = ws + 14680064;        // 2,097,152
    float* fused_s = ws + 16777216;        // 1,048,576
    float* stats   = ws + 17825792;        // 16,384
    float* pool    = ws + 17842176;        // 19,922,944

    float* meanA = stats + 0,    *rstdA = stats + 2048;
    float* meanF = stats + 4096, *rstdF = stats + 5120;
    float* meanC = stats + 6144, *rstdC = stats + 7168;
    float* meanL = stats + 8192, *rstdL = stats + 9216;

    float* qin   = pool + 0;
    float* lnqb  = pool + 2097152;
    float* kin   = pool + 0;
    float* lnkb  = pool + 1048576;
    float* lnvb  = pool + 2097152;
    float* kbuf  = pool + 3145728;
    float* vbuf  = pool + 7340032;
    float* abuf  = pool + 11534336;
    float* z1    = pool + 0;
    float* h1    = pool + 3145728;
    float* z2    = pool + 7340032;
    float* z3    = pool + 9437184;

    // Stage A: instance-norm stats + conv encoders
    k_stats_cm<<<2048, TPB, 0, stream>>>(cam_feat, lid_feat, pos, meanA, rstdA, 4096);
    k_conv<<<dim3(4, 8, 8), TPB, 0, stream>>>(cam_feat, pos, meanA, rstdA, conv_w, cam_e, 0);
    k_conv<<<dim3(4, 8, 8), TPB, 0, stream>>>(lid_feat, pos, meanA, rstdA, conv_w, lid_e, 1024);

    // Shared Q and skip
    k_transpose<<<dim3(8, 32), TPB, 0, stream>>>(cam_e, lid_e, qin, 2048, 0);
    k_rowln<<<4096, TPB, 0, stream>>>(qin, lnqb, lnq_g, lnq_b);
    k_gemm<<<dim3(8, 256), TPB, 0, stream>>>(lnqb, wq, qbuf, 16384, 512, 128, 0, nullptr, nullptr);
    k_transpose<<<dim3(8, 32), TPB, 0, stream>>>(cam_e, lid_e, skip, 2048, 2);

    for (int cross = 0; cross < 2; cross++) {
        const float* e = cross ? lid_e : cam_e;
        float* zout = cross ? z_lid : z_cam;
        k_transpose<<<dim3(8, 16), TPB, 0, stream>>>(e, nullptr, kin, 1024, 1);
        k_rowln<<<2048, TPB, 0, stream>>>(kin, lnkb, lnk_g, lnk_b);
        k_rowln<<<2048, TPB, 0, stream>>>(kin, lnvb, lnv_g, lnv_b);
        k_gemm<<<dim3(8, 128), TPB, 0, stream>>>(lnkb, wk, kbuf, 8192, 512, 128, 0, nullptr, nullptr);
        k_gemm<<<dim3(8, 128), TPB, 0, stream>>>(lnvb, wv, vbuf, 8192, 512, 128, 0, nullptr, nullptr);
        k_attn_mfma<<<dim3(16, 4, 8), TPB, 0, stream>>>(qbuf, kbuf, vbuf, abuf);
        k_gemm<<<dim3(2, 256), TPB, 0, stream>>>(abuf, proj_w, z1, 16384, 128, 512, 2, proj_b, skip);
        k_rowln<<<4096, TPB, 0, stream>>>(z1, z2, pre_g, pre_b);
        k_gemm<<<dim3(4, 256), TPB, 0, stream>>>(z2, mlp_w1, h1, 16384, 256, 128, 3, mlp_b1, nullptr);
        k_gemm<<<dim3(2, 256), TPB, 0, stream>>>(h1, mlp_w2, z3, 16384, 128, 256, 2, mlp_b2, z2);
        k_rowln<<<4096, TPB, 0, stream>>>(z3, zout, post_g, post_b);
    }

    // Outputs
    k_fused_sum<<<4096, TPB, 0, stream>>>(z_cam, z_lid, fused_s);
    k_stats_cm<<<1024, TPB, 0, stream>>>(fused_s, nullptr, nullptr, meanF, rstdF, 1024);
    k_stats_tm<<<8, TPB, 0, stream>>>(z_cam, meanC, rstdC);
    k_stats_tm<<<8, TPB, 0, stream>>>(z_lid, meanL, rstdL);
    k_convt<<<dim3(16, 16, 8), TPB, 0, stream>>>(fused_s, 0, meanF, rstdF, convT_w, outp, 32, 32);
    k_convt<<<dim3(32, 16, 8), TPB, 0, stream>>>(z_cam, 1, meanC, rstdC, convT_w, outp + 4194304, 64, 32);
    k_convt<<<dim3(32, 16, 8), TPB, 0, stream>>>(z_lid, 1, meanL, rstdL, convT_w, outp + 12582912, 64, 32);
}

// Round 3
// 1288.906 us; speedup vs baseline: 3.9933x; 1.4255x over previous
//
#include <hip/hip_runtime.h>
#include <math.h>

#define TPB 256

typedef __attribute__((ext_vector_type(8))) short bf16x8;
typedef __attribute__((ext_vector_type(4))) float f32x4;

__device__ __forceinline__ float gelu_exact(float x) {
    return 0.5f * x * (1.0f + erff(x * 0.70710678118654752f));
}

__device__ __forceinline__ unsigned short f2bf(float x) {
    unsigned u = __float_as_uint(x);
    return (unsigned short)((u + 0x7fffu + ((u >> 16) & 1u)) >> 16);
}

// ---------------------------------------------------------------------------
// Instance-norm stats, channel-major source. If x1 != null: stage-A mode,
// 2048 channels (cam 0..1023, lid 1024..2047), value = x + pos (broadcast).
// Else: plain mode over gridDim.x channels of x0.
// ---------------------------------------------------------------------------
__global__ void k_stats_cm(const float* __restrict__ x0, const float* __restrict__ x1,
                           const float* __restrict__ pos, float* __restrict__ mean,
                           float* __restrict__ rstd, int P) {
    int gc = blockIdx.x;
    const float* src;
    const float* posr = nullptr;
    if (x1 != nullptr) {
        src = ((gc < 1024) ? x0 : x1) + (size_t)(gc & 1023) * P;
        posr = pos + (size_t)(gc & 127) * P;
    } else {
        src = x0 + (size_t)gc * P;
    }
    float s = 0.f, s2 = 0.f;
    for (int p = threadIdx.x; p < P; p += TPB) {
        float v = src[p];
        if (posr) v += posr[p];
        s += v; s2 += v * v;
    }
#pragma unroll
    for (int m = 32; m; m >>= 1) { s += __shfl_xor(s, m); s2 += __shfl_xor(s2, m); }
    __shared__ float ls[4], ls2[4];
    int w = threadIdx.x >> 6;
    if ((threadIdx.x & 63) == 0) { ls[w] = s; ls2[w] = s2; }
    __syncthreads();
    if (threadIdx.x == 0) {
        s = ls[0] + ls[1] + ls[2] + ls[3];
        s2 = ls2[0] + ls2[1] + ls2[2] + ls2[3];
        float mu = s / (float)P;
        float var = s2 / (float)P - mu * mu;
        mean[gc] = mu;
        rstd[gc] = rsqrtf(var + 1e-5f);
    }
}

// ---------------------------------------------------------------------------
// Token-major stats, two-phase. Phase 1: grid (32 chunks, 8 bn), 64 tokens each.
// part[b][c][2][128] = {sum, sumsq}. Phase 2: grid 8 x 128 threads.
// ---------------------------------------------------------------------------
__global__ void k_stats_part(const float* __restrict__ z, float* __restrict__ part) {
    int c = blockIdx.x, b = blockIdx.y;
    int tid = threadIdx.x;
    int d = tid & 127, half = tid >> 7;
    const float* base = z + ((size_t)b * 2048 + c * 64) * 128;
    float s = 0.f, s2 = 0.f;
    for (int t = half; t < 64; t += 2) {
        float v = base[t * 128 + d];
        s += v; s2 += v * v;
    }
    __shared__ float ls[256], ls2[256];
    ls[tid] = s; ls2[tid] = s2;
    __syncthreads();
    if (tid < 128) {
        s = ls[tid] + ls[tid + 128];
        s2 = ls2[tid] + ls2[tid + 128];
        float* p = part + ((size_t)(b * 32 + c) * 2) * 128;
        p[d] = s; p[128 + d] = s2;
    }
}

__global__ void k_stats_red(const float* __restrict__ part, float* __restrict__ mean,
                            float* __restrict__ rstd) {
    int b = blockIdx.x, d = threadIdx.x;  // 128 threads
    float s = 0.f, s2 = 0.f;
    for (int c = 0; c < 32; c++) {
        const float* p = part + ((size_t)(b * 32 + c) * 2) * 128;
        s += p[d]; s2 += p[128 + d];
    }
    float mu = s / 2048.f;
    float var = s2 / 2048.f - mu * mu;
    mean[b * 128 + d] = mu;
    rstd[b * 128 + d] = rsqrtf(var + 1e-5f);
}

// ---------------------------------------------------------------------------
// Conv2x2 stride2 as GEMM (see round 0 comments).
// ---------------------------------------------------------------------------
__global__ void k_conv(const float* __restrict__ x, const float* __restrict__ pos,
                       const float* __restrict__ mean, const float* __restrict__ rstd,
                       const float* __restrict__ w, float* __restrict__ out, int stat_off) {
    __shared__ float Xs[32][256];
    __shared__ float Ws[32][17];
    int tid = threadIdx.x;
    int pg = blockIdx.x, og = blockIdx.y, b = blockIdx.z;
    int h0 = pg * 8;
    float acc[16];
#pragma unroll
    for (int i = 0; i < 16; i++) acc[i] = 0.f;
    for (int c0 = 0; c0 < 128; c0 += 8) {
        for (int i = tid; i < 512; i += TPB) {
            int ol = i >> 5, kc = i & 31;
            Ws[kc][ol] = w[(og * 16 + ol) * 512 + c0 * 4 + kc];
        }
        for (int i = tid; i < 8192; i += TPB) {
            int kc = i >> 8, p = i & 255;
            int cl = kc >> 2, a = (kc >> 1) & 1, dd = kc & 1;
            int c = c0 + cl;
            int hh = h0 + (p >> 5), ww = p & 31;
            int y = 2 * hh + a, xx = 2 * ww + dd;
            int ch = b * 128 + c;
            float v = x[(size_t)ch * 4096 + y * 64 + xx] + pos[c * 4096 + y * 64 + xx];
            v = (v - mean[stat_off + ch]) * rstd[stat_off + ch];
            Xs[kc][p] = fmaxf(v, 0.f);
        }
        __syncthreads();
#pragma unroll 8
        for (int kc = 0; kc < 32; kc++) {
            float xv = Xs[kc][tid];
#pragma unroll
            for (int o = 0; o < 16; o++) acc[o] += Ws[kc][o] * xv;
        }
        __syncthreads();
    }
    int p = pg * 256 + tid;
#pragma unroll
    for (int o = 0; o < 16; o++)
        out[((size_t)b * 128 + og * 16 + o) * 1024 + p] = acc[o];
}

// ---------------------------------------------------------------------------
// Transpose e (8,128,1024) channel-major into token-major rows (b, t, 128).
// ---------------------------------------------------------------------------
__global__ void k_transpose(const float* __restrict__ e0, const float* __restrict__ e1,
                            float* __restrict__ out, int T, int mode) {
    __shared__ float tile[128][65];
    int b = blockIdx.x, tb = blockIdx.y;
    int t0 = tb * 64;
    int tid = threadIdx.x;
    for (int i = tid; i < 8192; i += TPB) {
        int d = i >> 6, j = i & 63;
        const float* src; int tt;
        if (mode == 0)      { src = (t0 < 1024) ? e0 : e1; tt = (t0 & 1023) + j; }
        else if (mode == 1) { src = e0; tt = t0 + j; }
        else                { src = (j < 32) ? e0 : e1; tt = tb * 32 + (j & 31); }
        tile[d][j] = src[((size_t)b * 128 + d) * 1024 + tt];
    }
    __syncthreads();
    for (int i = tid; i < 8192; i += TPB) {
        int j = i >> 7, d = i & 127;
        out[((size_t)b * T + t0 + j) * 128 + d] = tile[d][j];
    }
}

// ---------------------------------------------------------------------------
// Row LayerNorm (128 cols). One wave per row, 4 rows per block.
// ---------------------------------------------------------------------------
__global__ void k_rowln(const float* __restrict__ in, float* __restrict__ out,
                        const float* __restrict__ g, const float* __restrict__ bb) {
    int r = blockIdx.x * 4 + (threadIdx.x >> 6);
    int lane = threadIdx.x & 63;
    const float* row = in + (size_t)r * 128;
    float v0 = row[lane], v1 = row[lane + 64];
    float s = v0 + v1, s2 = v0 * v0 + v1 * v1;
#pragma unroll
    for (int m = 32; m; m >>= 1) { s += __shfl_xor(s, m); s2 += __shfl_xor(s2, m); }
    float mu = s * (1.f / 128.f);
    float var = s2 * (1.f / 128.f) - mu * mu;
    float rs = rsqrtf(var + 1e-5f);
    out[(size_t)r * 128 + lane]      = (v0 - mu) * rs * g[lane] + bb[lane];
    out[(size_t)r * 128 + lane + 64] = (v1 - mu) * rs * g[lane + 64] + bb[lane + 64];
}

// ---------------------------------------------------------------------------
// Weight transpose+convert: W[K][N] fp32 -> WT[N][K] bf16. grid (N/32, K/32).
// ---------------------------------------------------------------------------
__global__ void k_wtrans(const float* __restrict__ W, unsigned short* __restrict__ WT,
                         int K, int N) {
    __shared__ float t[32][33];
    int n0 = blockIdx.x * 32, k0 = blockIdx.y * 32;
    int tid = threadIdx.x;
    for (int i = tid; i < 1024; i += TPB) {
        int r = i >> 5, c = i & 31;
        t[r][c] = W[(size_t)(k0 + r) * N + n0 + c];
    }
    __syncthreads();
    for (int i = tid; i < 1024; i += TPB) {
        int r = i >> 5, c = i & 31;
        WT[(size_t)(n0 + r) * K + k0 + c] = f2bf(t[c][r]);
    }
}

// ---------------------------------------------------------------------------
// MFMA bf16 GEMM: C[M,N] = A[M,K](fp32, converted) @ BT[N,K](bf16).
// 256 threads = 4 waves in WM x WN grid; tiles BM x BN, BK=32.
// LDS rows stride 40 shorts (80 B): 16B-aligned b128 reads, worst 2-way bank
// aliasing (free). mode 0: plain; 2: +bias+aux; 3: +bias, exact GELU.
// ---------------------------------------------------------------------------
template <int BM, int BN, int WM, int WN>
__global__ __launch_bounds__(256, 2) void k_gemm_mfma(
        const float* __restrict__ A, const unsigned short* __restrict__ BT,
        float* __restrict__ C, int M, int N, int K, int mode,
        const float* __restrict__ bias, const float* __restrict__ aux) {
    constexpr int MI = BM / WM / 16;
    constexpr int NI = BN / WN / 16;
    __shared__ __align__(16) unsigned short As[BM * 40];
    __shared__ __align__(16) unsigned short Bs[BN * 40];
    int tid = threadIdx.x, lane = tid & 63, w = tid >> 6;
    int l16 = lane & 15, lhi = lane >> 4;
    int wm = w / WN, wn = w % WN;
    int m0 = blockIdx.y * BM, n0 = blockIdx.x * BN;

    f32x4 acc[MI][NI];
#pragma unroll
    for (int mi = 0; mi < MI; mi++)
#pragma unroll
        for (int ni = 0; ni < NI; ni++) acc[mi][ni] = (f32x4){0.f, 0.f, 0.f, 0.f};

    for (int k0 = 0; k0 < K; k0 += 32) {
        // stage A (fp32 -> bf16)
        for (int i = tid; i < BM * 8; i += TPB) {
            int row = i >> 3, kc = (i & 7) * 4;
            float4 va = *(const float4*)&A[(size_t)(m0 + row) * K + k0 + kc];
            ushort4 u;
            u.x = f2bf(va.x); u.y = f2bf(va.y); u.z = f2bf(va.z); u.w = f2bf(va.w);
            *(ushort4*)&As[row * 40 + kc] = u;
        }
        // stage B (already bf16, [N][K])
        for (int i = tid; i < BN * 4; i += TPB) {
            int n = i >> 2, kc = (i & 3) * 8;
            bf16x8 bv = *(const bf16x8*)&BT[(size_t)(n0 + n) * K + k0 + kc];
            *(bf16x8*)&Bs[n * 40 + kc] = bv;
        }
        __syncthreads();
        bf16x8 af[MI], bfr[NI];
#pragma unroll
        for (int mi = 0; mi < MI; mi++)
            af[mi] = *(bf16x8*)&As[(wm * (BM / WM) + mi * 16 + l16) * 40 + lhi * 8];
#pragma unroll
        for (int ni = 0; ni < NI; ni++)
            bfr[ni] = *(bf16x8*)&Bs[(wn * (BN / WN) + ni * 16 + l16) * 40 + lhi * 8];
#pragma unroll
        for (int mi = 0; mi < MI; mi++)
#pragma unroll
            for (int ni = 0; ni < NI; ni++)
                acc[mi][ni] = __builtin_amdgcn_mfma_f32_16x16x32_bf16(af[mi], bfr[ni], acc[mi][ni], 0, 0, 0);
        __syncthreads();
    }
    // epilogue: C row = (lhi*4+rg), col = l16 within each 16x16 tile
#pragma unroll
    for (int mi = 0; mi < MI; mi++) {
#pragma unroll
        for (int ni = 0; ni < NI; ni++) {
            int col = n0 + wn * (BN / WN) + ni * 16 + l16;
#pragma unroll
            for (int rg = 0; rg < 4; rg++) {
                int row = m0 + wm * (BM / WM) + mi * 16 + lhi * 4 + rg;
                float v = acc[mi][ni][rg];
                if (mode >= 2) v += bias[col];
                if (mode == 2) v += aux[(size_t)row * N + col];
                if (mode == 3) v = gelu_exact(v);
                C[(size_t)row * N + col] = v;
            }
        }
    }
}

// ---------------------------------------------------------------------------
// MFMA flash attention (round 1, unchanged).
// ---------------------------------------------------------------------------
__global__ __launch_bounds__(256, 2) void k_attn_mfma(
        const float* __restrict__ q, const float* __restrict__ k,
        const float* __restrict__ v, float* __restrict__ aout) {
    __shared__ __align__(16) unsigned short smem[16384];  // 32 KB
    unsigned short* Ks = smem;            // [32][128] swizzled
    unsigned short* Vt = smem + 4096;     // [128][40]
    unsigned short* Ps = smem + 9216;     // 4 waves x [32][40]
    int tid = threadIdx.x;
    int lane = tid & 63, w = tid >> 6;
    int l16 = lane & 15, lhi = lane >> 4;
    int qt = blockIdx.x, h = blockIdx.y, b = blockIdx.z;
    const float scale = 0.08838834764831845f;  // 1/sqrt(128)

    const float* qg = q + ((size_t)(b * 2048 + qt * 128)) * 512 + h * 128;
    for (int i = tid; i < 4096; i += TPB) {
        int row = i >> 5, c4 = (i & 31) * 4;
        float4 va = *(const float4*)&qg[(size_t)row * 512 + c4];
        ushort4 u;
        u.x = f2bf(va.x * scale); u.y = f2bf(va.y * scale);
        u.z = f2bf(va.z * scale); u.w = f2bf(va.w * scale);
        *(ushort4*)&smem[(row * 128 + c4) ^ ((row & 7) << 3)] = u;
    }
    __syncthreads();
    bf16x8 qa[2][4];
#pragma unroll
    for (int mt = 0; mt < 2; mt++) {
        int r = w * 32 + mt * 16 + l16;
#pragma unroll
        for (int ks = 0; ks < 4; ks++)
            qa[mt][ks] = *(bf16x8*)&smem[(r * 128 + ks * 32 + lhi * 8) ^ ((r & 7) << 3)];
    }
    __syncthreads();

    f32x4 acc[2][8];
#pragma unroll
    for (int mt = 0; mt < 2; mt++)
#pragma unroll
        for (int dt = 0; dt < 8; dt++) acc[mt][dt] = (f32x4){0.f, 0.f, 0.f, 0.f};
    float m_r[2][4], l_r[2][4];
#pragma unroll
    for (int mt = 0; mt < 2; mt++)
#pragma unroll
        for (int rg = 0; rg < 4; rg++) { m_r[mt][rg] = -1e30f; l_r[mt][rg] = 0.f; }

    const float* kg = k + ((size_t)(b * 1024)) * 512 + h * 128;
    const float* vg = v + ((size_t)(b * 1024)) * 512 + h * 128;
    unsigned short* Pw = Ps + w * 1280;

    for (int c0 = 0; c0 < 1024; c0 += 32) {
        for (int i = tid; i < 1024; i += TPB) {
            int row = i >> 5, c4 = (i & 31) * 4;
            float4 va = *(const float4*)&kg[(size_t)(c0 + row) * 512 + c4];
            ushort4 u;
            u.x = f2bf(va.x); u.y = f2bf(va.y); u.z = f2bf(va.z); u.w = f2bf(va.w);
            *(ushort4*)&Ks[(row * 128 + c4) ^ ((row & 7) << 3)] = u;
        }
        for (int i = tid; i < 4096; i += TPB) {
            int kk = i >> 7, d = i & 127;
            Vt[d * 40 + kk] = f2bf(vg[(size_t)(c0 + kk) * 512 + d]);
        }
        __syncthreads();

        f32x4 s[2][2];
        s[0][0] = s[0][1] = s[1][0] = s[1][1] = (f32x4){0.f, 0.f, 0.f, 0.f};
#pragma unroll
        for (int nt = 0; nt < 2; nt++) {
            int r = nt * 16 + l16;
#pragma unroll
            for (int ks = 0; ks < 4; ks++) {
                bf16x8 kb = *(bf16x8*)&Ks[(r * 128 + ks * 32 + lhi * 8) ^ ((r & 7) << 3)];
                s[0][nt] = __builtin_amdgcn_mfma_f32_16x16x32_bf16(qa[0][ks], kb, s[0][nt], 0, 0, 0);
                s[1][nt] = __builtin_amdgcn_mfma_f32_16x16x32_bf16(qa[1][ks], kb, s[1][nt], 0, 0, 0);
            }
        }

#pragma unroll
        for (int mt = 0; mt < 2; mt++) {
#pragma unroll
            for (int rg = 0; rg < 4; rg++) {
                float s0 = s[mt][0][rg], s1 = s[mt][1][rg];
                float mx = fmaxf(s0, s1);
                mx = fmaxf(mx, __shfl_xor(mx, 1));
                mx = fmaxf(mx, __shfl_xor(mx, 2));
                mx = fmaxf(mx, __shfl_xor(mx, 4));
                mx = fmaxf(mx, __shfl_xor(mx, 8));
                float mo = m_r[mt][rg];
                float mn = fmaxf(mo, mx);
                float f = __expf(mo - mn);
                m_r[mt][rg] = mn;
                float p0 = __expf(s0 - mn), p1 = __expf(s1 - mn);
                float ps = p0 + p1;
                ps += __shfl_xor(ps, 1);
                ps += __shfl_xor(ps, 2);
                ps += __shfl_xor(ps, 4);
                ps += __shfl_xor(ps, 8);
                l_r[mt][rg] = l_r[mt][rg] * f + ps;
#pragma unroll
                for (int dt = 0; dt < 8; dt++) acc[mt][dt][rg] *= f;
                int row = mt * 16 + lhi * 4 + rg;
                Pw[row * 40 + l16] = f2bf(p0);
                Pw[row * 40 + 16 + l16] = f2bf(p1);
            }
        }
        asm volatile("s_waitcnt lgkmcnt(0)" ::: "memory");

        bf16x8 pa0 = *(bf16x8*)&Pw[l16 * 40 + lhi * 8];
        bf16x8 pa1 = *(bf16x8*)&Pw[(16 + l16) * 40 + lhi * 8];
#pragma unroll
        for (int dt = 0; dt < 8; dt++) {
            bf16x8 vb = *(bf16x8*)&Vt[(dt * 16 + l16) * 40 + lhi * 8];
            acc[0][dt] = __builtin_amdgcn_mfma_f32_16x16x32_bf16(pa0, vb, acc[0][dt], 0, 0, 0);
            acc[1][dt] = __builtin_amdgcn_mfma_f32_16x16x32_bf16(pa1, vb, acc[1][dt], 0, 0, 0);
        }
        __syncthreads();
    }

#pragma unroll
    for (int mt = 0; mt < 2; mt++)
#pragma unroll
        for (int rg = 0; rg < 4; rg++) {
            float linv = 1.f / l_r[mt][rg];
            int qrow = qt * 128 + w * 32 + mt * 16 + lhi * 4 + rg;
            float* orow = aout + ((size_t)(b * 2048 + qrow)) * 512 + h * 128;
#pragma unroll
            for (int dt = 0; dt < 8; dt++)
                orow[dt * 16 + l16] = acc[mt][dt][rg] * linv;
        }
}

// ---------------------------------------------------------------------------
__global__ void k_fused_sum(const float* __restrict__ zc, const float* __restrict__ zl,
                            float* __restrict__ fs) {
    int idx = blockIdx.x * TPB + threadIdx.x;
    int d = idx & 127, p = (idx >> 7) & 1023, b = idx >> 17;
    size_t r0 = ((size_t)b * 2048 + p) * 128 + d;
    size_t r1 = ((size_t)b * 2048 + 1024 + p) * 128 + d;
    float v = zc[r0] + zc[r1] + zl[r0] + zl[r1];
    fs[((size_t)b * 128 + d) * 1024 + p] = v;
}

// ---------------------------------------------------------------------------
// ConvTranspose2x2 stride2 as GEMM (round 0).
// ---------------------------------------------------------------------------
__global__ void k_convt(const float* __restrict__ src, int layout,
                        const float* __restrict__ mean, const float* __restrict__ rstd,
                        const float* __restrict__ wT, float* __restrict__ out,
                        int Hin, int Win) {
    __shared__ float Xs[128][66];
    __shared__ float Ws[128][32];
    int tid = threadIdx.x;
    int pg = blockIdx.x, og = blockIdx.y, b = blockIdx.z;
    int P = Hin * Win;
    int p0 = pg * 64;
    for (int i = tid; i < 4096; i += TPB) {
        int ii = i >> 5, col = i & 31;
        Ws[ii][col] = wT[ii * 512 + og * 32 + col];
    }
    if (layout == 0) {
        for (int idx = tid; idx < 8192; idx += TPB) {
            int ii = idx >> 6, pr = idx & 63;
            int ch = b * 128 + ii;
            float vv = src[(size_t)ch * P + p0 + pr];
            Xs[ii][pr] = fmaxf((vv - mean[ch]) * rstd[ch], 0.f);
        }
    } else {
        for (int idx = tid; idx < 8192; idx += TPB) {
            int pr = idx >> 7, ii = idx & 127;
            int ch = b * 128 + ii;
            float vv = src[((size_t)b * P + p0 + pr) * 128 + ii];
            Xs[ii][pr] = fmaxf((vv - mean[ch]) * rstd[ch], 0.f);
        }
    }
    __syncthreads();
    int p = tid >> 2, ad = tid & 3;
    float acc[8];
#pragma unroll
    for (int o = 0; o < 8; o++) acc[o] = 0.f;
#pragma unroll 4
    for (int i = 0; i < 128; i++) {
        float xv = Xs[i][p];
#pragma unroll
        for (int o = 0; o < 8; o++) acc[o] += xv * Ws[i][o * 4 + ad];
    }
    int pp = p0 + p;
    int hin = pp / Win, win = pp % Win;
    int a = ad >> 1, dd = ad & 1;
    int Ho = 2 * Hin, Wo = 2 * Win;
#pragma unroll
    for (int o = 0; o < 8; o++) {
        int oc = og * 8 + o;
        out[(((size_t)b * 128 + oc) * Ho + 2 * hin + a) * Wo + 2 * win + dd] = acc[o];
    }
}

// ---------------------------------------------------------------------------
extern "C" void kernel_launch(void* const* d_in, const int* in_sizes, int n_in,
                              void* d_out, int out_size, void* d_ws, size_t ws_size,
                              hipStream_t stream) {
    const float* cam_feat = (const float*)d_in[0];
    const float* lid_feat = (const float*)d_in[1];
    const float* pos      = (const float*)d_in[2];
    const float* conv_w   = (const float*)d_in[3];
    const float* convT_w  = (const float*)d_in[4];
    const float* lnq_g = (const float*)d_in[5];
    const float* lnq_b = (const float*)d_in[6];
    const float* wq    = (const float*)d_in[7];
    const float* lnk_g = (const float*)d_in[8];
    const float* lnk_b = (const float*)d_in[9];
    const float* wk    = (const float*)d_in[10];
    const float* lnv_g = (const float*)d_in[11];
    const float* lnv_b = (const float*)d_in[12];
    const float* wv    = (const float*)d_in[13];
    const float* proj_w = (const float*)d_in[14];
    const float* proj_b = (const float*)d_in[15];
    const float* pre_g = (const float*)d_in[16];
    const float* pre_b = (const float*)d_in[17];
    const float* mlp_w1 = (const float*)d_in[18];
    const float* mlp_b1 = (const float*)d_in[19];
    const float* mlp_w2 = (const float*)d_in[20];
    const float* mlp_b2 = (const float*)d_in[21];
    const float* post_g = (const float*)d_in[22];
    const float* post_b = (const float*)d_in[23];

    float* ws = (float*)d_ws;
    float* outp = (float*)d_out;

    // workspace layout (floats)
    float* cam_e   = ws + 0;               // 1,048,576
    float* lid_e   = ws + 1048576;         // 1,048,576
    float* qbuf    = ws + 2097152;         // 8,388,608
    float* skip    = ws + 10485760;        // 2,097,152
    float* z_cam   = ws + 12582912;        // 2,097,152
    float* z_lid   = ws + 14680064;        // 2,097,152
    float* fused_s = ws + 16777216;        // 1,048,576
    float* stats   = ws + 17825792;        // 16,384
    float* pool    = ws + 17842176;        // 19,922,944
    // new: bf16 weights (327,680 u16 = 163,840 f) + stats partials (65,536 f)
    unsigned short* wbuf = (unsigned short*)(ws + 37765120);
    float* part = ws + 37765120 + 163840;  // total 37,994,496 f = 152.0 MB

    unsigned short* wqT   = wbuf + 0;        // 512x128
    unsigned short* wkT   = wbuf + 65536;    // 512x128
    unsigned short* wvT   = wbuf + 131072;   // 512x128
    unsigned short* projT = wbuf + 196608;   // 128x512
    unsigned short* m1T   = wbuf + 262144;   // 256x128
    unsigned short* m2T   = wbuf + 294912;   // 128x256

    float* meanA = stats + 0,    *rstdA = stats + 2048;
    float* meanF = stats + 4096, *rstdF = stats + 5120;
    float* meanC = stats + 6144, *rstdC = stats + 7168;
    float* meanL = stats + 8192, *rstdL = stats + 9216;

    float* qin   = pool + 0;
    float* lnqb  = pool + 2097152;
    float* kin   = pool + 0;
    float* lnkb  = pool + 1048576;
    float* lnvb  = pool + 2097152;
    float* kbuf  = pool + 3145728;
    float* vbuf  = pool + 7340032;
    float* abuf  = pool + 11534336;
    float* z1    = pool + 0;
    float* h1    = pool + 3145728;
    float* z2    = pool + 7340032;
    float* z3    = pool + 9437184;

    // Weight prep (bf16, transposed [N][K])
    k_wtrans<<<dim3(16, 4), TPB, 0, stream>>>(wq, wqT, 128, 512);
    k_wtrans<<<dim3(16, 4), TPB, 0, stream>>>(wk, wkT, 128, 512);
    k_wtrans<<<dim3(16, 4), TPB, 0, stream>>>(wv, wvT, 128, 512);
    k_wtrans<<<dim3(4, 16), TPB, 0, stream>>>(proj_w, projT, 512, 128);
    k_wtrans<<<dim3(8, 4), TPB, 0, stream>>>(mlp_w1, m1T, 128, 256);
    k_wtrans<<<dim3(4, 8), TPB, 0, stream>>>(mlp_w2, m2T, 256, 128);

    // Stage A: instance-norm stats + conv encoders
    k_stats_cm<<<2048, TPB, 0, stream>>>(cam_feat, lid_feat, pos, meanA, rstdA, 4096);
    k_conv<<<dim3(4, 8, 8), TPB, 0, stream>>>(cam_feat, pos, meanA, rstdA, conv_w, cam_e, 0);
    k_conv<<<dim3(4, 8, 8), TPB, 0, stream>>>(lid_feat, pos, meanA, rstdA, conv_w, lid_e, 1024);

    // Shared Q and skip
    k_transpose<<<dim3(8, 32), TPB, 0, stream>>>(cam_e, lid_e, qin, 2048, 0);
    k_rowln<<<4096, TPB, 0, stream>>>(qin, lnqb, lnq_g, lnq_b);
    k_gemm_mfma<128, 128, 2, 2><<<dim3(4, 128), TPB, 0, stream>>>(
        lnqb, wqT, qbuf, 16384, 512, 128, 0, nullptr, nullptr);
    k_transpose<<<dim3(8, 32), TPB, 0, stream>>>(cam_e, lid_e, skip, 2048, 2);

    for (int cross = 0; cross < 2; cross++) {
        const float* e = cross ? lid_e : cam_e;
        float* zout = cross ? z_lid : z_cam;
        k_transpose<<<dim3(8, 16), TPB, 0, stream>>>(e, nullptr, kin, 1024, 1);
        k_rowln<<<2048, TPB, 0, stream>>>(kin, lnkb, lnk_g, lnk_b);
        k_rowln<<<2048, TPB, 0, stream>>>(kin, lnvb, lnv_g, lnv_b);
        k_gemm_mfma<128, 128, 2, 2><<<dim3(4, 64), TPB, 0, stream>>>(
            lnkb, wkT, kbuf, 8192, 512, 128, 0, nullptr, nullptr);
        k_gemm_mfma<128, 128, 2, 2><<<dim3(4, 64), TPB, 0, stream>>>(
            lnvb, wvT, vbuf, 8192, 512, 128, 0, nullptr, nullptr);
        k_attn_mfma<<<dim3(16, 4, 8), TPB, 0, stream>>>(qbuf, kbuf, vbuf, abuf);
        k_gemm_mfma<64, 128, 1, 4><<<dim3(1, 256), TPB, 0, stream>>>(
            abuf, projT, z1, 16384, 128, 512, 2, proj_b, skip);
        k_rowln<<<4096, TPB, 0, stream>>>(z1, z2, pre_g, pre_b);
        k_gemm_mfma<128, 128, 2, 2><<<dim3(2, 128), TPB, 0, stream>>>(
            z2, m1T, h1, 16384, 256, 128, 3, mlp_b1, nullptr);
        k_gemm_mfma<64, 128, 1, 4><<<dim3(1, 256), TPB, 0, stream>>>(
            h1, m2T, z3, 16384, 128, 256, 2, mlp_b2, z2);
        k_rowln<<<4096, TPB, 0, stream>>>(z3, zout, post_g, post_b);
    }

    // Outputs
    k_fused_sum<<<4096, TPB, 0, stream>>>(z_cam, z_lid, fused_s);
    k_stats_cm<<<1024, TPB, 0, stream>>>(fused_s, nullptr, nullptr, meanF, rstdF, 1024);
    k_stats_part<<<dim3(32, 8), TPB, 0, stream>>>(z_cam, part);
    k_stats_red<<<8, 128, 0, stream>>>(part, meanC, rstdC);
    k_stats_part<<<dim3(32, 8), TPB, 0, stream>>>(z_lid, part);
    k_stats_red<<<8, 128, 0, stream>>>(part, meanL, rstdL);
    k_convt<<<dim3(16, 16, 8), TPB, 0, stream>>>(fused_s, 0, meanF, rstdF, convT_w, outp, 32, 32);
    k_convt<<<dim3(32, 16, 8), TPB, 0, stream>>>(z_cam, 1, meanC, rstdC, convT_w, outp + 4194304, 64, 32);
    k_convt<<<dim3(32, 16, 8), TPB, 0, stream>>>(z_lid, 1, meanL, rstdL, convT_w, outp + 12582912, 64, 32);
}

// Round 4
// 1154.560 us; speedup vs baseline: 4.4580x; 1.1164x over previous
//
#include <hip/hip_runtime.h>
#include <math.h>

#define TPB 256

typedef __attribute__((ext_vector_type(8))) short bf16x8;
typedef __attribute__((ext_vector_type(4))) float f32x4;

__device__ __forceinline__ float gelu_exact(float x) {
    return 0.5f * x * (1.0f + erff(x * 0.70710678118654752f));
}

__device__ __forceinline__ unsigned short f2bf(float x) {
    unsigned u = __float_as_uint(x);
    return (unsigned short)((u + 0x7fffu + ((u >> 16) & 1u)) >> 16);
}

// ---------------------------------------------------------------------------
// Instance-norm stats, channel-major source (round 0).
// ---------------------------------------------------------------------------
__global__ void k_stats_cm(const float* __restrict__ x0, const float* __restrict__ x1,
                           const float* __restrict__ pos, float* __restrict__ mean,
                           float* __restrict__ rstd, int P) {
    int gc = blockIdx.x;
    const float* src;
    const float* posr = nullptr;
    if (x1 != nullptr) {
        src = ((gc < 1024) ? x0 : x1) + (size_t)(gc & 1023) * P;
        posr = pos + (size_t)(gc & 127) * P;
    } else {
        src = x0 + (size_t)gc * P;
    }
    float s = 0.f, s2 = 0.f;
    for (int p = threadIdx.x; p < P; p += TPB) {
        float v = src[p];
        if (posr) v += posr[p];
        s += v; s2 += v * v;
    }
#pragma unroll
    for (int m = 32; m; m >>= 1) { s += __shfl_xor(s, m); s2 += __shfl_xor(s2, m); }
    __shared__ float ls[4], ls2[4];
    int w = threadIdx.x >> 6;
    if ((threadIdx.x & 63) == 0) { ls[w] = s; ls2[w] = s2; }
    __syncthreads();
    if (threadIdx.x == 0) {
        s = ls[0] + ls[1] + ls[2] + ls[3];
        s2 = ls2[0] + ls2[1] + ls2[2] + ls2[3];
        float mu = s / (float)P;
        float var = s2 / (float)P - mu * mu;
        mean[gc] = mu;
        rstd[gc] = rsqrtf(var + 1e-5f);
    }
}

// ---------------------------------------------------------------------------
// Token-major stats, two-phase (round 2).
// ---------------------------------------------------------------------------
__global__ void k_stats_part(const float* __restrict__ z, float* __restrict__ part) {
    int c = blockIdx.x, b = blockIdx.y;
    int tid = threadIdx.x;
    int d = tid & 127, half = tid >> 7;
    const float* base = z + ((size_t)b * 2048 + c * 64) * 128;
    float s = 0.f, s2 = 0.f;
    for (int t = half; t < 64; t += 2) {
        float v = base[t * 128 + d];
        s += v; s2 += v * v;
    }
    __shared__ float ls[256], ls2[256];
    ls[tid] = s; ls2[tid] = s2;
    __syncthreads();
    if (tid < 128) {
        s = ls[tid] + ls[tid + 128];
        s2 = ls2[tid] + ls2[tid + 128];
        float* p = part + ((size_t)(b * 32 + c) * 2) * 128;
        p[d] = s; p[128 + d] = s2;
    }
}

__global__ void k_stats_red(const float* __restrict__ part, float* __restrict__ mean,
                            float* __restrict__ rstd) {
    int b = blockIdx.x, d = threadIdx.x;  // 128 threads
    float s = 0.f, s2 = 0.f;
    for (int c = 0; c < 32; c++) {
        const float* p = part + ((size_t)(b * 32 + c) * 2) * 128;
        s += p[d]; s2 += p[128 + d];
    }
    float mu = s / 2048.f;
    float var = s2 / 2048.f - mu * mu;
    mean[b * 128 + d] = mu;
    rstd[b * 128 + d] = rsqrtf(var + 1e-5f);
}

// ---------------------------------------------------------------------------
// Conv2x2 stride2 as GEMM (round 0).
// ---------------------------------------------------------------------------
__global__ void k_conv(const float* __restrict__ x, const float* __restrict__ pos,
                       const float* __restrict__ mean, const float* __restrict__ rstd,
                       const float* __restrict__ w, float* __restrict__ out, int stat_off) {
    __shared__ float Xs[32][256];
    __shared__ float Ws[32][17];
    int tid = threadIdx.x;
    int pg = blockIdx.x, og = blockIdx.y, b = blockIdx.z;
    int h0 = pg * 8;
    float acc[16];
#pragma unroll
    for (int i = 0; i < 16; i++) acc[i] = 0.f;
    for (int c0 = 0; c0 < 128; c0 += 8) {
        for (int i = tid; i < 512; i += TPB) {
            int ol = i >> 5, kc = i & 31;
            Ws[kc][ol] = w[(og * 16 + ol) * 512 + c0 * 4 + kc];
        }
        for (int i = tid; i < 8192; i += TPB) {
            int kc = i >> 8, p = i & 255;
            int cl = kc >> 2, a = (kc >> 1) & 1, dd = kc & 1;
            int c = c0 + cl;
            int hh = h0 + (p >> 5), ww = p & 31;
            int y = 2 * hh + a, xx = 2 * ww + dd;
            int ch = b * 128 + c;
            float v = x[(size_t)ch * 4096 + y * 64 + xx] + pos[c * 4096 + y * 64 + xx];
            v = (v - mean[stat_off + ch]) * rstd[stat_off + ch];
            Xs[kc][p] = fmaxf(v, 0.f);
        }
        __syncthreads();
#pragma unroll 8
        for (int kc = 0; kc < 32; kc++) {
            float xv = Xs[kc][tid];
#pragma unroll
            for (int o = 0; o < 16; o++) acc[o] += Ws[kc][o] * xv;
        }
        __syncthreads();
    }
    int p = pg * 256 + tid;
#pragma unroll
    for (int o = 0; o < 16; o++)
        out[((size_t)b * 128 + og * 16 + o) * 1024 + p] = acc[o];
}

// ---------------------------------------------------------------------------
// Transpose e (8,128,1024) channel-major into token-major rows (round 0).
// ---------------------------------------------------------------------------
__global__ void k_transpose(const float* __restrict__ e0, const float* __restrict__ e1,
                            float* __restrict__ out, int T, int mode) {
    __shared__ float tile[128][65];
    int b = blockIdx.x, tb = blockIdx.y;
    int t0 = tb * 64;
    int tid = threadIdx.x;
    for (int i = tid; i < 8192; i += TPB) {
        int d = i >> 6, j = i & 63;
        const float* src; int tt;
        if (mode == 0)      { src = (t0 < 1024) ? e0 : e1; tt = (t0 & 1023) + j; }
        else if (mode == 1) { src = e0; tt = t0 + j; }
        else                { src = (j < 32) ? e0 : e1; tt = tb * 32 + (j & 31); }
        tile[d][j] = src[((size_t)b * 128 + d) * 1024 + tt];
    }
    __syncthreads();
    for (int i = tid; i < 8192; i += TPB) {
        int j = i >> 7, d = i & 127;
        out[((size_t)b * T + t0 + j) * 128 + d] = tile[d][j];
    }
}

// ---------------------------------------------------------------------------
// Row LayerNorm (128 cols). One wave per row, 4 rows per block.
// ---------------------------------------------------------------------------
__global__ void k_rowln(const float* __restrict__ in, float* __restrict__ out,
                        const float* __restrict__ g, const float* __restrict__ bb) {
    int r = blockIdx.x * 4 + (threadIdx.x >> 6);
    int lane = threadIdx.x & 63;
    const float* row = in + (size_t)r * 128;
    float v0 = row[lane], v1 = row[lane + 64];
    float s = v0 + v1, s2 = v0 * v0 + v1 * v1;
#pragma unroll
    for (int m = 32; m; m >>= 1) { s += __shfl_xor(s, m); s2 += __shfl_xor(s2, m); }
    float mu = s * (1.f / 128.f);
    float var = s2 * (1.f / 128.f) - mu * mu;
    float rs = rsqrtf(var + 1e-5f);
    out[(size_t)r * 128 + lane]      = (v0 - mu) * rs * g[lane] + bb[lane];
    out[(size_t)r * 128 + lane + 64] = (v1 - mu) * rs * g[lane + 64] + bb[lane + 64];
}

// ---------------------------------------------------------------------------
// Weight transpose+convert: W[K][N] fp32 -> WT[N][K] bf16. grid (N/32, K/32).
// ---------------------------------------------------------------------------
__global__ void k_wtrans(const float* __restrict__ W, unsigned short* __restrict__ WT,
                         int K, int N) {
    __shared__ float t[32][33];
    int n0 = blockIdx.x * 32, k0 = blockIdx.y * 32;
    int tid = threadIdx.x;
    for (int i = tid; i < 1024; i += TPB) {
        int r = i >> 5, c = i & 31;
        t[r][c] = W[(size_t)(k0 + r) * N + n0 + c];
    }
    __syncthreads();
    for (int i = tid; i < 1024; i += TPB) {
        int r = i >> 5, c = i & 31;
        WT[(size_t)(n0 + r) * K + k0 + c] = f2bf(t[c][r]);
    }
}

// ---------------------------------------------------------------------------
// MFMA bf16 GEMM: C[M,N] = A[M,K](fp32, converted) @ BT[N,K](bf16).
// mode 0: fp32 C; 2: +bias+aux; 3: +bias, exact GELU;
// mode 4: bf16 head-major write to C16: [b][h=col>>7][t][d=col&127], t = row
//         within batch (1<<sT tokens per b), value scaled by `scale`.
// ---------------------------------------------------------------------------
template <int BM, int BN, int WM, int WN>
__global__ __launch_bounds__(256, 2) void k_gemm_mfma(
        const float* __restrict__ A, const unsigned short* __restrict__ BT,
        float* __restrict__ C, unsigned short* __restrict__ C16,
        int M, int N, int K, int mode,
        const float* __restrict__ bias, const float* __restrict__ aux,
        int sT, float scale) {
    constexpr int MI = BM / WM / 16;
    constexpr int NI = BN / WN / 16;
    __shared__ __align__(16) unsigned short As[BM * 40];
    __shared__ __align__(16) unsigned short Bs[BN * 40];
    int tid = threadIdx.x, lane = tid & 63, w = tid >> 6;
    int l16 = lane & 15, lhi = lane >> 4;
    int wm = w / WN, wn = w % WN;
    int m0 = blockIdx.y * BM, n0 = blockIdx.x * BN;

    f32x4 acc[MI][NI];
#pragma unroll
    for (int mi = 0; mi < MI; mi++)
#pragma unroll
        for (int ni = 0; ni < NI; ni++) acc[mi][ni] = (f32x4){0.f, 0.f, 0.f, 0.f};

    for (int k0 = 0; k0 < K; k0 += 32) {
        for (int i = tid; i < BM * 8; i += TPB) {
            int row = i >> 3, kc = (i & 7) * 4;
            float4 va = *(const float4*)&A[(size_t)(m0 + row) * K + k0 + kc];
            ushort4 u;
            u.x = f2bf(va.x); u.y = f2bf(va.y); u.z = f2bf(va.z); u.w = f2bf(va.w);
            *(ushort4*)&As[row * 40 + kc] = u;
        }
        for (int i = tid; i < BN * 4; i += TPB) {
            int n = i >> 2, kc = (i & 3) * 8;
            bf16x8 bv = *(const bf16x8*)&BT[(size_t)(n0 + n) * K + k0 + kc];
            *(bf16x8*)&Bs[n * 40 + kc] = bv;
        }
        __syncthreads();
        bf16x8 af[MI], bfr[NI];
#pragma unroll
        for (int mi = 0; mi < MI; mi++)
            af[mi] = *(bf16x8*)&As[(wm * (BM / WM) + mi * 16 + l16) * 40 + lhi * 8];
#pragma unroll
        for (int ni = 0; ni < NI; ni++)
            bfr[ni] = *(bf16x8*)&Bs[(wn * (BN / WN) + ni * 16 + l16) * 40 + lhi * 8];
#pragma unroll
        for (int mi = 0; mi < MI; mi++)
#pragma unroll
            for (int ni = 0; ni < NI; ni++)
                acc[mi][ni] = __builtin_amdgcn_mfma_f32_16x16x32_bf16(af[mi], bfr[ni], acc[mi][ni], 0, 0, 0);
        __syncthreads();
    }
#pragma unroll
    for (int mi = 0; mi < MI; mi++) {
#pragma unroll
        for (int ni = 0; ni < NI; ni++) {
            int col = n0 + wn * (BN / WN) + ni * 16 + l16;
#pragma unroll
            for (int rg = 0; rg < 4; rg++) {
                int row = m0 + wm * (BM / WM) + mi * 16 + lhi * 4 + rg;
                float v = acc[mi][ni][rg];
                if (mode == 4) {
                    int bb = row >> sT, t = row & ((1 << sT) - 1);
                    size_t oa = ((((size_t)bb * 4 + (col >> 7)) << sT) + t) * 128 + (col & 127);
                    C16[oa] = f2bf(v * scale);
                } else {
                    if (mode >= 2) v += bias[col];
                    if (mode == 2) v += aux[(size_t)row * N + col];
                    if (mode == 3) v = gelu_exact(v);
                    C[(size_t)row * N + col] = v;
                }
            }
        }
    }
}

// ---------------------------------------------------------------------------
// V transpose: vbuf fp32 (b*1024+t, h*128+d) -> vbfT bf16 [b][h][d][1024].
// grid (16 t-tiles, 4 h, 8 b).
// ---------------------------------------------------------------------------
__global__ void k_vtrans(const float* __restrict__ vbuf, unsigned short* __restrict__ vt) {
    __shared__ unsigned short tile[64][140];
    int t0 = blockIdx.x * 64, h = blockIdx.y, b = blockIdx.z;
    int tid = threadIdx.x;
    for (int i = tid; i < 2048; i += TPB) {
        int tt = i >> 5, d4 = (i & 31) * 4;
        float4 va = *(const float4*)&vbuf[((size_t)(b * 1024 + t0 + tt)) * 512 + h * 128 + d4];
        ushort4 u;
        u.x = f2bf(va.x); u.y = f2bf(va.y); u.z = f2bf(va.z); u.w = f2bf(va.w);
        *(ushort4*)&tile[tt][d4] = u;
    }
    __syncthreads();
    for (int i = tid; i < 8192; i += TPB) {
        int d = i >> 6, tt = i & 63;
        vt[((size_t)(b * 4 + h) * 128 + d) * 1024 + t0 + tt] = tile[tt][d];
    }
}

// ---------------------------------------------------------------------------
// bf16 flash attention. Inputs pre-laid-out: qb [b][h][2048][128] (pre-scaled),
// kb [b][h][1024][128], vt [b][h][128][1024] (transposed). 64 q-rows/block
// (16/wave), 32-kv chunks. grid (32, 4, 8) = 1024 blocks.
// ---------------------------------------------------------------------------
__global__ __launch_bounds__(256, 4) void k_attn_bf16(
        const unsigned short* __restrict__ qb, const unsigned short* __restrict__ kb,
        const unsigned short* __restrict__ vt, float* __restrict__ aout) {
    __shared__ __align__(16) unsigned short smem[11776];  // 23.5 KB
    unsigned short* Ks = smem;            // [32][128] swizzled
    unsigned short* Vt = smem + 4096;     // [128][40]
    unsigned short* Ps = smem + 9216;     // 4 waves x [16][40]
    int tid = threadIdx.x;
    int lane = tid & 63, w = tid >> 6;
    int l16 = lane & 15, lhi = lane >> 4;
    int qt = blockIdx.x, h = blockIdx.y, b = blockIdx.z;
    int bh = b * 4 + h;

    // Q fragments straight from global (row-major bf16, rows stride 128)
    const unsigned short* qg = qb + ((size_t)bh * 2048 + qt * 64) * 128;
    bf16x8 qa[4];
    {
        int r = w * 16 + l16;
#pragma unroll
        for (int ks = 0; ks < 4; ks++)
            qa[ks] = *(const bf16x8*)&qg[(size_t)r * 128 + ks * 32 + lhi * 8];
    }

    f32x4 acc[8];
#pragma unroll
    for (int dt = 0; dt < 8; dt++) acc[dt] = (f32x4){0.f, 0.f, 0.f, 0.f};
    float m_r[4], l_r[4];
#pragma unroll
    for (int rg = 0; rg < 4; rg++) { m_r[rg] = -1e30f; l_r[rg] = 0.f; }

    const unsigned short* kg = kb + (size_t)bh * 1024 * 128;
    const unsigned short* vg = vt + (size_t)bh * 128 * 1024;
    unsigned short* Pw = Ps + w * 640;

    for (int c0 = 0; c0 < 1024; c0 += 32) {
        // stage K chunk: 32 rows x 128 bf16, XOR-swizzled, 16B copies
        for (int i = tid; i < 512; i += TPB) {
            int row = i >> 4, c8 = (i & 15) * 8;
            *(bf16x8*)&Ks[(row * 128 + c8) ^ ((row & 7) << 3)] =
                *(const bf16x8*)&kg[(size_t)(c0 + row) * 128 + c8];
        }
        // stage V^T chunk: 128 rows(d) x 32 bf16
        for (int i = tid; i < 512; i += TPB) {
            int d = i >> 2, k8 = (i & 3) * 8;
            *(bf16x8*)&Vt[d * 40 + k8] =
                *(const bf16x8*)&vg[(size_t)d * 1024 + c0 + k8];
        }
        __syncthreads();

        // QK^T: 16 rows x 32 cols per wave
        f32x4 s[2];
        s[0] = s[1] = (f32x4){0.f, 0.f, 0.f, 0.f};
#pragma unroll
        for (int nt = 0; nt < 2; nt++) {
            int r = nt * 16 + l16;
#pragma unroll
            for (int ks = 0; ks < 4; ks++) {
                bf16x8 kbf = *(bf16x8*)&Ks[(r * 128 + ks * 32 + lhi * 8) ^ ((r & 7) << 3)];
                s[nt] = __builtin_amdgcn_mfma_f32_16x16x32_bf16(qa[ks], kbf, s[nt], 0, 0, 0);
            }
        }

        // online softmax; row r = lhi*4+rg lives in the 16-lane group
#pragma unroll
        for (int rg = 0; rg < 4; rg++) {
            float s0 = s[0][rg], s1 = s[1][rg];
            float mx = fmaxf(s0, s1);
            mx = fmaxf(mx, __shfl_xor(mx, 1));
            mx = fmaxf(mx, __shfl_xor(mx, 2));
            mx = fmaxf(mx, __shfl_xor(mx, 4));
            mx = fmaxf(mx, __shfl_xor(mx, 8));
            float mo = m_r[rg];
            float mn = fmaxf(mo, mx);
            float f = __expf(mo - mn);
            m_r[rg] = mn;
            float p0 = __expf(s0 - mn), p1 = __expf(s1 - mn);
            float ps = p0 + p1;
            ps += __shfl_xor(ps, 1);
            ps += __shfl_xor(ps, 2);
            ps += __shfl_xor(ps, 4);
            ps += __shfl_xor(ps, 8);
            l_r[rg] = l_r[rg] * f + ps;
#pragma unroll
            for (int dt = 0; dt < 8; dt++) acc[dt][rg] *= f;
            int row = lhi * 4 + rg;
            Pw[row * 40 + l16] = f2bf(p0);
            Pw[row * 40 + 16 + l16] = f2bf(p1);
        }
        asm volatile("s_waitcnt lgkmcnt(0)" ::: "memory");

        // PV
        bf16x8 pa = *(bf16x8*)&Pw[l16 * 40 + lhi * 8];
#pragma unroll
        for (int dt = 0; dt < 8; dt++) {
            bf16x8 vb = *(bf16x8*)&Vt[(dt * 16 + l16) * 40 + lhi * 8];
            acc[dt] = __builtin_amdgcn_mfma_f32_16x16x32_bf16(pa, vb, acc[dt], 0, 0, 0);
        }
        __syncthreads();
    }

#pragma unroll
    for (int rg = 0; rg < 4; rg++) {
        float linv = 1.f / l_r[rg];
        int qrow = qt * 64 + w * 16 + lhi * 4 + rg;
        float* orow = aout + ((size_t)(b * 2048 + qrow)) * 512 + h * 128;
#pragma unroll
        for (int dt = 0; dt < 8; dt++)
            orow[dt * 16 + l16] = acc[dt][rg] * linv;
    }
}

// ---------------------------------------------------------------------------
__global__ void k_fused_sum(const float* __restrict__ zc, const float* __restrict__ zl,
                            float* __restrict__ fs) {
    int idx = blockIdx.x * TPB + threadIdx.x;
    int d = idx & 127, p = (idx >> 7) & 1023, b = idx >> 17;
    size_t r0 = ((size_t)b * 2048 + p) * 128 + d;
    size_t r1 = ((size_t)b * 2048 + 1024 + p) * 128 + d;
    float v = zc[r0] + zc[r1] + zl[r0] + zl[r1];
    fs[((size_t)b * 128 + d) * 1024 + p] = v;
}

// ---------------------------------------------------------------------------
// ConvTranspose2x2 stride2 as GEMM (round 0).
// ---------------------------------------------------------------------------
__global__ void k_convt(const float* __restrict__ src, int layout,
                        const float* __restrict__ mean, const float* __restrict__ rstd,
                        const float* __restrict__ wT, float* __restrict__ out,
                        int Hin, int Win) {
    __shared__ float Xs[128][66];
    __shared__ float Ws[128][32];
    int tid = threadIdx.x;
    int pg = blockIdx.x, og = blockIdx.y, b = blockIdx.z;
    int P = Hin * Win;
    int p0 = pg * 64;
    for (int i = tid; i < 4096; i += TPB) {
        int ii = i >> 5, col = i & 31;
        Ws[ii][col] = wT[ii * 512 + og * 32 + col];
    }
    if (layout == 0) {
        for (int idx = tid; idx < 8192; idx += TPB) {
            int ii = idx >> 6, pr = idx & 63;
            int ch = b * 128 + ii;
            float vv = src[(size_t)ch * P + p0 + pr];
            Xs[ii][pr] = fmaxf((vv - mean[ch]) * rstd[ch], 0.f);
        }
    } else {
        for (int idx = tid; idx < 8192; idx += TPB) {
            int pr = idx >> 7, ii = idx & 127;
            int ch = b * 128 + ii;
            float vv = src[((size_t)b * P + p0 + pr) * 128 + ii];
            Xs[ii][pr] = fmaxf((vv - mean[ch]) * rstd[ch], 0.f);
        }
    }
    __syncthreads();
    int p = tid >> 2, ad = tid & 3;
    float acc[8];
#pragma unroll
    for (int o = 0; o < 8; o++) acc[o] = 0.f;
#pragma unroll 4
    for (int i = 0; i < 128; i++) {
        float xv = Xs[i][p];
#pragma unroll
        for (int o = 0; o < 8; o++) acc[o] += xv * Ws[i][o * 4 + ad];
    }
    int pp = p0 + p;
    int hin = pp / Win, win = pp % Win;
    int a = ad >> 1, dd = ad & 1;
    int Ho = 2 * Hin, Wo = 2 * Win;
#pragma unroll
    for (int o = 0; o < 8; o++) {
        int oc = og * 8 + o;
        out[(((size_t)b * 128 + oc) * Ho + 2 * hin + a) * Wo + 2 * win + dd] = acc[o];
    }
}

// ---------------------------------------------------------------------------
extern "C" void kernel_launch(void* const* d_in, const int* in_sizes, int n_in,
                              void* d_out, int out_size, void* d_ws, size_t ws_size,
                              hipStream_t stream) {
    const float* cam_feat = (const float*)d_in[0];
    const float* lid_feat = (const float*)d_in[1];
    const float* pos      = (const float*)d_in[2];
    const float* conv_w   = (const float*)d_in[3];
    const float* convT_w  = (const float*)d_in[4];
    const float* lnq_g = (const float*)d_in[5];
    const float* lnq_b = (const float*)d_in[6];
    const float* wq    = (const float*)d_in[7];
    const float* lnk_g = (const float*)d_in[8];
    const float* lnk_b = (const float*)d_in[9];
    const float* wk    = (const float*)d_in[10];
    const float* lnv_g = (const float*)d_in[11];
    const float* lnv_b = (const float*)d_in[12];
    const float* wv    = (const float*)d_in[13];
    const float* proj_w = (const float*)d_in[14];
    const float* proj_b = (const float*)d_in[15];
    const float* pre_g = (const float*)d_in[16];
    const float* pre_b = (const float*)d_in[17];
    const float* mlp_w1 = (const float*)d_in[18];
    const float* mlp_b1 = (const float*)d_in[19];
    const float* mlp_w2 = (const float*)d_in[20];
    const float* mlp_b2 = (const float*)d_in[21];
    const float* post_g = (const float*)d_in[22];
    const float* post_b = (const float*)d_in[23];

    float* ws = (float*)d_ws;
    float* outp = (float*)d_out;

    // persistent workspace
    float* cam_e   = ws + 0;               // 1,048,576
    float* lid_e   = ws + 1048576;         // 1,048,576
    unsigned short* qbf16 = (unsigned short*)(ws + 2097152);  // 8,388,608 u16 (uses 4,194,304 f of 8,388,608)
    float* skip    = ws + 10485760;        // 2,097,152
    float* z_cam   = ws + 12582912;        // 2,097,152
    float* z_lid   = ws + 14680064;        // 2,097,152
    float* fused_s = ws + 16777216;        // 1,048,576
    float* stats   = ws + 17825792;        // 16,384
    float* pool    = ws + 17842176;        // 19,922,944
    unsigned short* wbuf = (unsigned short*)(ws + 37765120);  // 327,680 u16
    float* part = ws + 37765120 + 163840;  // 65,536 f

    unsigned short* wqT   = wbuf + 0;        // 512x128
    unsigned short* wkT   = wbuf + 65536;    // 512x128
    unsigned short* wvT   = wbuf + 131072;   // 512x128
    unsigned short* projT = wbuf + 196608;   // 128x512
    unsigned short* m1T   = wbuf + 262144;   // 256x128
    unsigned short* m2T   = wbuf + 294912;   // 128x256

    float* meanA = stats + 0,    *rstdA = stats + 2048;
    float* meanF = stats + 4096, *rstdF = stats + 5120;
    float* meanC = stats + 6144, *rstdC = stats + 7168;
    float* meanL = stats + 8192, *rstdL = stats + 9216;

    // pool layout (timeline-overlapped)
    float* qin   = pool + 0;                 // 2,097,152 (Q path: 16384x128)
    float* lnqb  = pool + 2097152;           // 2,097,152
    float* kin   = pool + 0;                 // 1,048,576
    float* lnkb  = pool + 1048576;           // 1,048,576
    float* lnvb  = pool + 2097152;           // 1,048,576
    float* vbuf  = pool + 3145728;           // 4,194,304 (8192x512 fp32)
    unsigned short* kbf16 = (unsigned short*)(pool + 7340032);  // 4,194,304 u16
    unsigned short* vbfT  = (unsigned short*)(pool + 9437184);  // 4,194,304 u16
    float* abuf  = pool + 11534336;          // 8,388,608
    float* z1    = pool + 0;                 // 2,097,152
    float* z2    = pool + 3145728;           // 2,097,152
    float* h1    = pool + 5242880;           // 4,194,304
    float* z3    = pool + 9437184;           // 2,097,152

    const float qscale = 0.08838834764831845f;  // 1/sqrt(128)

    // Weight prep (bf16, transposed [N][K])
    k_wtrans<<<dim3(16, 4), TPB, 0, stream>>>(wq, wqT, 128, 512);
    k_wtrans<<<dim3(16, 4), TPB, 0, stream>>>(wk, wkT, 128, 512);
    k_wtrans<<<dim3(16, 4), TPB, 0, stream>>>(wv, wvT, 128, 512);
    k_wtrans<<<dim3(4, 16), TPB, 0, stream>>>(proj_w, projT, 512, 128);
    k_wtrans<<<dim3(8, 4), TPB, 0, stream>>>(mlp_w1, m1T, 128, 256);
    k_wtrans<<<dim3(4, 8), TPB, 0, stream>>>(mlp_w2, m2T, 256, 128);

    // Stage A: instance-norm stats + conv encoders
    k_stats_cm<<<2048, TPB, 0, stream>>>(cam_feat, lid_feat, pos, meanA, rstdA, 4096);
    k_conv<<<dim3(4, 8, 8), TPB, 0, stream>>>(cam_feat, pos, meanA, rstdA, conv_w, cam_e, 0);
    k_conv<<<dim3(4, 8, 8), TPB, 0, stream>>>(lid_feat, pos, meanA, rstdA, conv_w, lid_e, 1024);

    // Shared Q (bf16, head-major, pre-scaled) and skip
    k_transpose<<<dim3(8, 32), TPB, 0, stream>>>(cam_e, lid_e, qin, 2048, 0);
    k_rowln<<<4096, TPB, 0, stream>>>(qin, lnqb, lnq_g, lnq_b);
    k_gemm_mfma<128, 128, 2, 2><<<dim3(4, 128), TPB, 0, stream>>>(
        lnqb, wqT, nullptr, qbf16, 16384, 512, 128, 4, nullptr, nullptr, 11, qscale);
    k_transpose<<<dim3(8, 32), TPB, 0, stream>>>(cam_e, lid_e, skip, 2048, 2);

    for (int cross = 0; cross < 2; cross++) {
        const float* e = cross ? lid_e : cam_e;
        float* zout = cross ? z_lid : z_cam;
        k_transpose<<<dim3(8, 16), TPB, 0, stream>>>(e, nullptr, kin, 1024, 1);
        k_rowln<<<2048, TPB, 0, stream>>>(kin, lnkb, lnk_g, lnk_b);
        k_rowln<<<2048, TPB, 0, stream>>>(kin, lnvb, lnv_g, lnv_b);
        k_gemm_mfma<128, 128, 2, 2><<<dim3(4, 64), TPB, 0, stream>>>(
            lnkb, wkT, nullptr, kbf16, 8192, 512, 128, 4, nullptr, nullptr, 10, 1.f);
        k_gemm_mfma<128, 128, 2, 2><<<dim3(4, 64), TPB, 0, stream>>>(
            lnvb, wvT, vbuf, nullptr, 8192, 512, 128, 0, nullptr, nullptr, 0, 1.f);
        k_vtrans<<<dim3(16, 4, 8), TPB, 0, stream>>>(vbuf, vbfT);
        k_attn_bf16<<<dim3(32, 4, 8), TPB, 0, stream>>>(qbf16, kbf16, vbfT, abuf);
        k_gemm_mfma<64, 128, 1, 4><<<dim3(1, 256), TPB, 0, stream>>>(
            abuf, projT, z1, nullptr, 16384, 128, 512, 2, proj_b, skip, 0, 1.f);
        k_rowln<<<4096, TPB, 0, stream>>>(z1, z2, pre_g, pre_b);
        k_gemm_mfma<128, 128, 2, 2><<<dim3(2, 128), TPB, 0, stream>>>(
            z2, m1T, h1, nullptr, 16384, 256, 128, 3, mlp_b1, nullptr, 0, 1.f);
        k_gemm_mfma<64, 128, 1, 4><<<dim3(1, 256), TPB, 0, stream>>>(
            h1, m2T, z3, nullptr, 16384, 128, 256, 2, mlp_b2, z2, 0, 1.f);
        k_rowln<<<4096, TPB, 0, stream>>>(z3, zout, post_g, post_b);
    }

    // Outputs
    k_fused_sum<<<4096, TPB, 0, stream>>>(z_cam, z_lid, fused_s);
    k_stats_cm<<<1024, TPB, 0, stream>>>(fused_s, nullptr, nullptr, meanF, rstdF, 1024);
    k_stats_part<<<dim3(32, 8), TPB, 0, stream>>>(z_cam, part);
    k_stats_red<<<8, 128, 0, stream>>>(part, meanC, rstdC);
    k_stats_part<<<dim3(32, 8), TPB, 0, stream>>>(z_lid, part);
    k_stats_red<<<8, 128, 0, stream>>>(part, meanL, rstdL);
    k_convt<<<dim3(16, 16, 8), TPB, 0, stream>>>(fused_s, 0, meanF, rstdF, convT_w, outp, 32, 32);
    k_convt<<<dim3(32, 16, 8), TPB, 0, stream>>>(z_cam, 1, meanC, rstdC, convT_w, outp + 4194304, 64, 32);
    k_convt<<<dim3(32, 16, 8), TPB, 0, stream>>>(z_lid, 1, meanL, rstdL, convT_w, outp + 12582912, 64, 32);
}

// Round 5
// 785.931 us; speedup vs baseline: 6.5489x; 1.4690x over previous
//
#include <hip/hip_runtime.h>
#include <math.h>

#define TPB 256

typedef __attribute__((ext_vector_type(8))) short bf16x8;
typedef __attribute__((ext_vector_type(4))) float f32x4;

__device__ __forceinline__ float gelu_exact(float x) {
    return 0.5f * x * (1.0f + erff(x * 0.70710678118654752f));
}

__device__ __forceinline__ unsigned short f2bf(float x) {
    unsigned u = __float_as_uint(x);
    return (unsigned short)((u + 0x7fffu + ((u >> 16) & 1u)) >> 16);
}

// ---------------------------------------------------------------------------
// Stage-A instance-norm stats (x + pos broadcast), 2048 channels.
// ---------------------------------------------------------------------------
__global__ void k_stats_cm(const float* __restrict__ x0, const float* __restrict__ x1,
                           const float* __restrict__ pos, float* __restrict__ mean,
                           float* __restrict__ rstd) {
    int gc = blockIdx.x;
    const float* src = ((gc < 1024) ? x0 : x1) + (size_t)(gc & 1023) * 4096;
    const float* posr = pos + (size_t)(gc & 127) * 4096;
    float s = 0.f, s2 = 0.f;
    for (int p = threadIdx.x; p < 4096; p += TPB) {
        float v = src[p] + posr[p];
        s += v; s2 += v * v;
    }
#pragma unroll
    for (int m = 32; m; m >>= 1) { s += __shfl_xor(s, m); s2 += __shfl_xor(s2, m); }
    __shared__ float ls[4], ls2[4];
    int w = threadIdx.x >> 6;
    if ((threadIdx.x & 63) == 0) { ls[w] = s; ls2[w] = s2; }
    __syncthreads();
    if (threadIdx.x == 0) {
        s = ls[0] + ls[1] + ls[2] + ls[3];
        s2 = ls2[0] + ls2[1] + ls2[2] + ls2[3];
        float mu = s / 4096.f;
        float var = s2 / 4096.f - mu * mu;
        mean[gc] = mu;
        rstd[gc] = rsqrtf(var + 1e-5f);
    }
}

// ---------------------------------------------------------------------------
// Token-major stats, two-phase. z is [8][T][128]; grid (T/64, 8).
// ---------------------------------------------------------------------------
__global__ void k_stats_part(const float* __restrict__ z, float* __restrict__ part, int T) {
    int c = blockIdx.x, b = blockIdx.y;
    int tid = threadIdx.x;
    int d = tid & 127, half = tid >> 7;
    const float* base = z + ((size_t)b * T + c * 64) * 128;
    float s = 0.f, s2 = 0.f;
    for (int t = half; t < 64; t += 2) {
        float v = base[t * 128 + d];
        s += v; s2 += v * v;
    }
    __shared__ float ls[256], ls2[256];
    ls[tid] = s; ls2[tid] = s2;
    __syncthreads();
    if (tid < 128) {
        s = ls[tid] + ls[tid + 128];
        s2 = ls2[tid] + ls2[tid + 128];
        float* p = part + ((size_t)(b * gridDim.x + c) * 2) * 128;
        p[d] = s; p[128 + d] = s2;
    }
}

__global__ void k_stats_red(const float* __restrict__ part, float* __restrict__ mean,
                            float* __restrict__ rstd, int nc, int T) {
    int b = blockIdx.x, d = threadIdx.x;  // 128 threads
    float s = 0.f, s2 = 0.f;
    for (int c = 0; c < nc; c++) {
        const float* p = part + ((size_t)(b * nc + c) * 2) * 128;
        s += p[d]; s2 += p[128 + d];
    }
    float mu = s / (float)T;
    float var = s2 / (float)T - mu * mu;
    mean[b * 128 + d] = mu;
    rstd[b * 128 + d] = rsqrtf(var + 1e-5f);
}

// ---------------------------------------------------------------------------
// Conv prep: normalize+ReLU+im2col -> bf16 xcolT[b][p=h*32+w][k=c*4+a*2+d].
// grid (32 h, 8 b). LDS-retiled so global writes are contiguous 16B.
// ---------------------------------------------------------------------------
__global__ void k_prep(const float* __restrict__ x, const float* __restrict__ pos,
                       const float* __restrict__ mean, const float* __restrict__ rstd,
                       unsigned short* __restrict__ xcolT, int stat_off) {
    __shared__ unsigned short T[32 * 520];
    int h = blockIdx.x, b = blockIdx.y;
    int tid = threadIdx.x;
    for (int i = tid; i < 4096; i += TPB) {
        int c = i >> 5, w = i & 31;
        int ch = b * 128 + c;
        const float* xr = x + (size_t)ch * 4096 + (2 * h) * 64 + 2 * w;
        const float* pr = pos + (size_t)c * 4096 + (2 * h) * 64 + 2 * w;
        float mu = mean[stat_off + ch], rs = rstd[stat_off + ch];
        float2 x0 = *(const float2*)xr;
        float2 x1 = *(const float2*)(xr + 64);
        float2 p0 = *(const float2*)pr;
        float2 p1 = *(const float2*)(pr + 64);
        ushort4 u;
        u.x = f2bf(fmaxf((x0.x + p0.x - mu) * rs, 0.f));
        u.y = f2bf(fmaxf((x0.y + p0.y - mu) * rs, 0.f));
        u.z = f2bf(fmaxf((x1.x + p1.x - mu) * rs, 0.f));
        u.w = f2bf(fmaxf((x1.y + p1.y - mu) * rs, 0.f));
        *(ushort4*)&T[w * 520 + c * 4] = u;
    }
    __syncthreads();
    unsigned short* dst = xcolT + ((size_t)b * 1024 + h * 32) * 512;
    for (int i = tid; i < 2048; i += TPB) {
        int w = i >> 6, kk = (i & 63) * 8;
        *(bf16x8*)&dst[(size_t)w * 512 + kk] = *(bf16x8*)&T[w * 520 + kk];
    }
}

// ---------------------------------------------------------------------------
// Conv as batched MFMA GEMM: eT[b][p][oc] = sum_k conv_w[oc][k] * xcolT[b][p][k].
// BM=128 (all oc), BN=64; 4 waves (WM=4). grid (16, 1, 8).
// ---------------------------------------------------------------------------
__global__ __launch_bounds__(256, 2) void k_conv_gemm(
        const float* __restrict__ W, const unsigned short* __restrict__ xcolT,
        float* __restrict__ eT) {
    __shared__ __align__(16) unsigned short As[128 * 40];
    __shared__ __align__(16) unsigned short Bs[64 * 40];
    int tid = threadIdx.x, lane = tid & 63, w = tid >> 6;
    int l16 = lane & 15, lhi = lane >> 4;
    int n0 = blockIdx.x * 64, b = blockIdx.z;
    const unsigned short* BT = xcolT + (size_t)b * 524288;

    f32x4 acc[2][4];
#pragma unroll
    for (int mi = 0; mi < 2; mi++)
#pragma unroll
        for (int ni = 0; ni < 4; ni++) acc[mi][ni] = (f32x4){0.f, 0.f, 0.f, 0.f};

    for (int k0 = 0; k0 < 512; k0 += 32) {
        for (int i = tid; i < 1024; i += TPB) {
            int row = i >> 3, kc = (i & 7) * 4;
            float4 va = *(const float4*)&W[(size_t)row * 512 + k0 + kc];
            ushort4 u;
            u.x = f2bf(va.x); u.y = f2bf(va.y); u.z = f2bf(va.z); u.w = f2bf(va.w);
            *(ushort4*)&As[row * 40 + kc] = u;
        }
        for (int i = tid; i < 256; i += TPB) {
            int n = i >> 2, kc = (i & 3) * 8;
            *(bf16x8*)&Bs[n * 40 + kc] = *(const bf16x8*)&BT[(size_t)(n0 + n) * 512 + k0 + kc];
        }
        __syncthreads();
        bf16x8 af[2], bfr[4];
#pragma unroll
        for (int mi = 0; mi < 2; mi++)
            af[mi] = *(bf16x8*)&As[(w * 32 + mi * 16 + l16) * 40 + lhi * 8];
#pragma unroll
        for (int ni = 0; ni < 4; ni++)
            bfr[ni] = *(bf16x8*)&Bs[(ni * 16 + l16) * 40 + lhi * 8];
#pragma unroll
        for (int mi = 0; mi < 2; mi++)
#pragma unroll
            for (int ni = 0; ni < 4; ni++)
                acc[mi][ni] = __builtin_amdgcn_mfma_f32_16x16x32_bf16(af[mi], bfr[ni], acc[mi][ni], 0, 0, 0);
        __syncthreads();
    }
    // token-major write: eT[b][p=col][oc] ; 4 consecutive oc per lane
#pragma unroll
    for (int mi = 0; mi < 2; mi++)
#pragma unroll
        for (int ni = 0; ni < 4; ni++) {
            int col = n0 + ni * 16 + l16;
            int rowb = w * 32 + mi * 16 + lhi * 4;
            *(float4*)&eT[((size_t)b * 1024 + col) * 128 + rowb] = *(float4*)&acc[mi][ni];
        }
}

// ---------------------------------------------------------------------------
// Row LayerNorm (128 cols), token-major input rows. 4 rows/block.
// ---------------------------------------------------------------------------
__global__ void k_rowln(const float* __restrict__ in, float* __restrict__ out,
                        const float* __restrict__ g, const float* __restrict__ bb) {
    int r = blockIdx.x * 4 + (threadIdx.x >> 6);
    int lane = threadIdx.x & 63;
    const float* row = in + (size_t)r * 128;
    float v0 = row[lane], v1 = row[lane + 64];
    float s = v0 + v1, s2 = v0 * v0 + v1 * v1;
#pragma unroll
    for (int m = 32; m; m >>= 1) { s += __shfl_xor(s, m); s2 += __shfl_xor(s2, m); }
    float mu = s * (1.f / 128.f);
    float var = s2 * (1.f / 128.f) - mu * mu;
    float rs = rsqrtf(var + 1e-5f);
    out[(size_t)r * 128 + lane]      = (v0 - mu) * rs * g[lane] + bb[lane];
    out[(size_t)r * 128 + lane + 64] = (v1 - mu) * rs * g[lane + 64] + bb[lane + 64];
}

// Q-path LN reading the concat [camT | lidT] along tokens.
__global__ void k_rowln2(const float* __restrict__ camT, const float* __restrict__ lidT,
                         float* __restrict__ out, const float* __restrict__ g,
                         const float* __restrict__ bb) {
    int r = blockIdx.x * 4 + (threadIdx.x >> 6);
    int lane = threadIdx.x & 63;
    int b = r >> 11, t = r & 2047;
    const float* row = ((t < 1024) ? camT : lidT) + ((size_t)(b * 1024 + (t & 1023))) * 128;
    float v0 = row[lane], v1 = row[lane + 64];
    float s = v0 + v1, s2 = v0 * v0 + v1 * v1;
#pragma unroll
    for (int m = 32; m; m >>= 1) { s += __shfl_xor(s, m); s2 += __shfl_xor(s2, m); }
    float mu = s * (1.f / 128.f);
    float var = s2 * (1.f / 128.f) - mu * mu;
    float rs = rsqrtf(var + 1e-5f);
    out[(size_t)r * 128 + lane]      = (v0 - mu) * rs * g[lane] + bb[lane];
    out[(size_t)r * 128 + lane + 64] = (v1 - mu) * rs * g[lane + 64] + bb[lane + 64];
}

// ---------------------------------------------------------------------------
// Weight transpose+convert: W[K][N] fp32 -> WT[N][K] bf16. grid (N/32, K/32).
// ---------------------------------------------------------------------------
__global__ void k_wtrans(const float* __restrict__ W, unsigned short* __restrict__ WT,
                         int K, int N) {
    __shared__ float t[32][33];
    int n0 = blockIdx.x * 32, k0 = blockIdx.y * 32;
    int tid = threadIdx.x;
    for (int i = tid; i < 1024; i += TPB) {
        int r = i >> 5, c = i & 31;
        t[r][c] = W[(size_t)(k0 + r) * N + n0 + c];
    }
    __syncthreads();
    for (int i = tid; i < 1024; i += TPB) {
        int r = i >> 5, c = i & 31;
        WT[(size_t)(n0 + r) * K + k0 + c] = f2bf(t[c][r]);
    }
}

// ---------------------------------------------------------------------------
// MFMA bf16 GEMM: C[M,N] = A[M,K](fp32) @ BT[N,K](bf16).
// mode 0: fp32 C; 2: +bias+aux; 3: +bias, exact GELU;
// mode 4: bf16 head-major write (C16), scaled; mode 5: +bias + skip from
// [camT|lidT] width-concat (aux=camT, aux2=lidT).
// ---------------------------------------------------------------------------
template <int BM, int BN, int WM, int WN>
__global__ __launch_bounds__(256, 2) void k_gemm_mfma(
        const float* __restrict__ A, const unsigned short* __restrict__ BT,
        float* __restrict__ C, unsigned short* __restrict__ C16,
        int M, int N, int K, int mode,
        const float* __restrict__ bias, const float* __restrict__ aux,
        const float* __restrict__ aux2, int sT, float scale) {
    constexpr int MI = BM / WM / 16;
    constexpr int NI = BN / WN / 16;
    __shared__ __align__(16) unsigned short As[BM * 40];
    __shared__ __align__(16) unsigned short Bs[BN * 40];
    int tid = threadIdx.x, lane = tid & 63, w = tid >> 6;
    int l16 = lane & 15, lhi = lane >> 4;
    int wm = w / WN, wn = w % WN;
    int m0 = blockIdx.y * BM, n0 = blockIdx.x * BN;

    f32x4 acc[MI][NI];
#pragma unroll
    for (int mi = 0; mi < MI; mi++)
#pragma unroll
        for (int ni = 0; ni < NI; ni++) acc[mi][ni] = (f32x4){0.f, 0.f, 0.f, 0.f};

    for (int k0 = 0; k0 < K; k0 += 32) {
        for (int i = tid; i < BM * 8; i += TPB) {
            int row = i >> 3, kc = (i & 7) * 4;
            float4 va = *(const float4*)&A[(size_t)(m0 + row) * K + k0 + kc];
            ushort4 u;
            u.x = f2bf(va.x); u.y = f2bf(va.y); u.z = f2bf(va.z); u.w = f2bf(va.w);
            *(ushort4*)&As[row * 40 + kc] = u;
        }
        for (int i = tid; i < BN * 4; i += TPB) {
            int n = i >> 2, kc = (i & 3) * 8;
            *(bf16x8*)&Bs[n * 40 + kc] = *(const bf16x8*)&BT[(size_t)(n0 + n) * K + k0 + kc];
        }
        __syncthreads();
        bf16x8 af[MI], bfr[NI];
#pragma unroll
        for (int mi = 0; mi < MI; mi++)
            af[mi] = *(bf16x8*)&As[(wm * (BM / WM) + mi * 16 + l16) * 40 + lhi * 8];
#pragma unroll
        for (int ni = 0; ni < NI; ni++)
            bfr[ni] = *(bf16x8*)&Bs[(wn * (BN / WN) + ni * 16 + l16) * 40 + lhi * 8];
#pragma unroll
        for (int mi = 0; mi < MI; mi++)
#pragma unroll
            for (int ni = 0; ni < NI; ni++)
                acc[mi][ni] = __builtin_amdgcn_mfma_f32_16x16x32_bf16(af[mi], bfr[ni], acc[mi][ni], 0, 0, 0);
        __syncthreads();
    }
#pragma unroll
    for (int mi = 0; mi < MI; mi++) {
#pragma unroll
        for (int ni = 0; ni < NI; ni++) {
            int col = n0 + wn * (BN / WN) + ni * 16 + l16;
#pragma unroll
            for (int rg = 0; rg < 4; rg++) {
                int row = m0 + wm * (BM / WM) + mi * 16 + lhi * 4 + rg;
                float v = acc[mi][ni][rg];
                if (mode == 4) {
                    int bb = row >> sT, t = row & ((1 << sT) - 1);
                    size_t oa = ((((size_t)bb * 4 + (col >> 7)) << sT) + t) * 128 + (col & 127);
                    C16[oa] = f2bf(v * scale);
                } else if (mode == 5) {
                    int bb = row >> 11, s = row & 2047;
                    int H = s >> 6, W = s & 63;
                    const float* sp = (W < 32) ? aux : aux2;
                    v += bias[col] + sp[((size_t)(bb * 1024 + H * 32 + (W & 31))) * 128 + col];
                    C[(size_t)row * N + col] = v;
                } else {
                    if (mode >= 2) v += bias[col];
                    if (mode == 2) v += aux[(size_t)row * N + col];
                    if (mode == 3) v = gelu_exact(v);
                    C[(size_t)row * N + col] = v;
                }
            }
        }
    }
}

// ---------------------------------------------------------------------------
// ConvTranspose as batched MFMA GEMM with fused instance-norm+ReLU on A.
// A = src[b][p][i] token-major fp32 (M rows per b); BT = ctT[512][128] bf16.
// out[b][oc][2hin+a][2win+d], col=(oc,a,d), Win=32. grid (4, M/128, 8).
// ---------------------------------------------------------------------------
__global__ __launch_bounds__(256, 2) void k_convt_gemm(
        const float* __restrict__ src, const float* __restrict__ mean,
        const float* __restrict__ rstd, const unsigned short* __restrict__ ctT,
        float* __restrict__ out, int M, int Hin) {
    __shared__ __align__(16) unsigned short As[128 * 40];
    __shared__ __align__(16) unsigned short Bs[128 * 40];
    int tid = threadIdx.x, lane = tid & 63, w = tid >> 6;
    int l16 = lane & 15, lhi = lane >> 4;
    int wm = w >> 1, wn = w & 1;
    int m0 = blockIdx.y * 128, n0 = blockIdx.x * 128, b = blockIdx.z;
    const float* Ab = src + (size_t)b * M * 128;
    const float* mb = mean + b * 128;
    const float* rb = rstd + b * 128;

    f32x4 acc[4][4];
#pragma unroll
    for (int mi = 0; mi < 4; mi++)
#pragma unroll
        for (int ni = 0; ni < 4; ni++) acc[mi][ni] = (f32x4){0.f, 0.f, 0.f, 0.f};

    for (int k0 = 0; k0 < 128; k0 += 32) {
        for (int i = tid; i < 1024; i += TPB) {
            int row = i >> 3, kc = (i & 7) * 4;
            float4 va = *(const float4*)&Ab[(size_t)(m0 + row) * 128 + k0 + kc];
            float4 mn = *(const float4*)&mb[k0 + kc];
            float4 rs = *(const float4*)&rb[k0 + kc];
            ushort4 u;
            u.x = f2bf(fmaxf((va.x - mn.x) * rs.x, 0.f));
            u.y = f2bf(fmaxf((va.y - mn.y) * rs.y, 0.f));
            u.z = f2bf(fmaxf((va.z - mn.z) * rs.z, 0.f));
            u.w = f2bf(fmaxf((va.w - mn.w) * rs.w, 0.f));
            *(ushort4*)&As[row * 40 + kc] = u;
        }
        for (int i = tid; i < 512; i += TPB) {
            int n = i >> 2, kc = (i & 3) * 8;
            *(bf16x8*)&Bs[n * 40 + kc] = *(const bf16x8*)&ctT[(size_t)(n0 + n) * 128 + k0 + kc];
        }
        __syncthreads();
        bf16x8 af[4], bfr[4];
#pragma unroll
        for (int mi = 0; mi < 4; mi++)
            af[mi] = *(bf16x8*)&As[(wm * 64 + mi * 16 + l16) * 40 + lhi * 8];
#pragma unroll
        for (int ni = 0; ni < 4; ni++)
            bfr[ni] = *(bf16x8*)&Bs[(wn * 64 + ni * 16 + l16) * 40 + lhi * 8];
#pragma unroll
        for (int mi = 0; mi < 4; mi++)
#pragma unroll
            for (int ni = 0; ni < 4; ni++)
                acc[mi][ni] = __builtin_amdgcn_mfma_f32_16x16x32_bf16(af[mi], bfr[ni], acc[mi][ni], 0, 0, 0);
        __syncthreads();
    }
    int Ho = 2 * Hin, Wo = 64;
#pragma unroll
    for (int mi = 0; mi < 4; mi++) {
#pragma unroll
        for (int ni = 0; ni < 4; ni++) {
            int col = n0 + wn * 64 + ni * 16 + l16;
            int oc = col >> 2, aa = (col >> 1) & 1, dd = col & 1;
#pragma unroll
            for (int rg = 0; rg < 4; rg++) {
                int p = m0 + wm * 64 + mi * 16 + lhi * 4 + rg;
                int hin = p >> 5, win = p & 31;
                out[(((size_t)b * 128 + oc) * Ho + 2 * hin + aa) * Wo + 2 * win + dd] =
                    acc[mi][ni][rg];
            }
        }
    }
}

// ---------------------------------------------------------------------------
// V transpose: vbuf fp32 (b*1024+t, h*128+d) -> vbfT bf16 [b][h][d][1024].
// ---------------------------------------------------------------------------
__global__ void k_vtrans(const float* __restrict__ vbuf, unsigned short* __restrict__ vt) {
    __shared__ unsigned short tile[64][140];
    int t0 = blockIdx.x * 64, h = blockIdx.y, b = blockIdx.z;
    int tid = threadIdx.x;
    for (int i = tid; i < 2048; i += TPB) {
        int tt = i >> 5, d4 = (i & 31) * 4;
        float4 va = *(const float4*)&vbuf[((size_t)(b * 1024 + t0 + tt)) * 512 + h * 128 + d4];
        ushort4 u;
        u.x = f2bf(va.x); u.y = f2bf(va.y); u.z = f2bf(va.z); u.w = f2bf(va.w);
        *(ushort4*)&tile[tt][d4] = u;
    }
    __syncthreads();
    for (int i = tid; i < 8192; i += TPB) {
        int d = i >> 6, tt = i & 63;
        vt[((size_t)(b * 4 + h) * 128 + d) * 1024 + t0 + tt] = tile[tt][d];
    }
}

// ---------------------------------------------------------------------------
// bf16 flash attention (round 3). grid (32, 4, 8).
// ---------------------------------------------------------------------------
__global__ __launch_bounds__(256, 4) void k_attn_bf16(
        const unsigned short* __restrict__ qb, const unsigned short* __restrict__ kb,
        const unsigned short* __restrict__ vt, float* __restrict__ aout) {
    __shared__ __align__(16) unsigned short smem[11776];
    unsigned short* Ks = smem;            // [32][128] swizzled
    unsigned short* Vt = smem + 4096;     // [128][40]
    unsigned short* Ps = smem + 9216;     // 4 waves x [16][40]
    int tid = threadIdx.x;
    int lane = tid & 63, w = tid >> 6;
    int l16 = lane & 15, lhi = lane >> 4;
    int qt = blockIdx.x, h = blockIdx.y, b = blockIdx.z;
    int bh = b * 4 + h;

    const unsigned short* qg = qb + ((size_t)bh * 2048 + qt * 64) * 128;
    bf16x8 qa[4];
    {
        int r = w * 16 + l16;
#pragma unroll
        for (int ks = 0; ks < 4; ks++)
            qa[ks] = *(const bf16x8*)&qg[(size_t)r * 128 + ks * 32 + lhi * 8];
    }

    f32x4 acc[8];
#pragma unroll
    for (int dt = 0; dt < 8; dt++) acc[dt] = (f32x4){0.f, 0.f, 0.f, 0.f};
    float m_r[4], l_r[4];
#pragma unroll
    for (int rg = 0; rg < 4; rg++) { m_r[rg] = -1e30f; l_r[rg] = 0.f; }

    const unsigned short* kg = kb + (size_t)bh * 1024 * 128;
    const unsigned short* vg = vt + (size_t)bh * 128 * 1024;
    unsigned short* Pw = Ps + w * 640;

    for (int c0 = 0; c0 < 1024; c0 += 32) {
        for (int i = tid; i < 512; i += TPB) {
            int row = i >> 4, c8 = (i & 15) * 8;
            *(bf16x8*)&Ks[(row * 128 + c8) ^ ((row & 7) << 3)] =
                *(const bf16x8*)&kg[(size_t)(c0 + row) * 128 + c8];
        }
        for (int i = tid; i < 512; i += TPB) {
            int d = i >> 2, k8 = (i & 3) * 8;
            *(bf16x8*)&Vt[d * 40 + k8] =
                *(const bf16x8*)&vg[(size_t)d * 1024 + c0 + k8];
        }
        __syncthreads();

        f32x4 s[2];
        s[0] = s[1] = (f32x4){0.f, 0.f, 0.f, 0.f};
#pragma unroll
        for (int nt = 0; nt < 2; nt++) {
            int r = nt * 16 + l16;
#pragma unroll
            for (int ks = 0; ks < 4; ks++) {
                bf16x8 kbf = *(bf16x8*)&Ks[(r * 128 + ks * 32 + lhi * 8) ^ ((r & 7) << 3)];
                s[nt] = __builtin_amdgcn_mfma_f32_16x16x32_bf16(qa[ks], kbf, s[nt], 0, 0, 0);
            }
        }

#pragma unroll
        for (int rg = 0; rg < 4; rg++) {
            float s0 = s[0][rg], s1 = s[1][rg];
            float mx = fmaxf(s0, s1);
            mx = fmaxf(mx, __shfl_xor(mx, 1));
            mx = fmaxf(mx, __shfl_xor(mx, 2));
            mx = fmaxf(mx, __shfl_xor(mx, 4));
            mx = fmaxf(mx, __shfl_xor(mx, 8));
            float mo = m_r[rg];
            float mn = fmaxf(mo, mx);
            float f = __expf(mo - mn);
            m_r[rg] = mn;
            float p0 = __expf(s0 - mn), p1 = __expf(s1 - mn);
            float ps = p0 + p1;
            ps += __shfl_xor(ps, 1);
            ps += __shfl_xor(ps, 2);
            ps += __shfl_xor(ps, 4);
            ps += __shfl_xor(ps, 8);
            l_r[rg] = l_r[rg] * f + ps;
#pragma unroll
            for (int dt = 0; dt < 8; dt++) acc[dt][rg] *= f;
            int row = lhi * 4 + rg;
            Pw[row * 40 + l16] = f2bf(p0);
            Pw[row * 40 + 16 + l16] = f2bf(p1);
        }
        asm volatile("s_waitcnt lgkmcnt(0)" ::: "memory");

        bf16x8 pa = *(bf16x8*)&Pw[l16 * 40 + lhi * 8];
#pragma unroll
        for (int dt = 0; dt < 8; dt++) {
            bf16x8 vb = *(bf16x8*)&Vt[(dt * 16 + l16) * 40 + lhi * 8];
            acc[dt] = __builtin_amdgcn_mfma_f32_16x16x32_bf16(pa, vb, acc[dt], 0, 0, 0);
        }
        __syncthreads();
    }

#pragma unroll
    for (int rg = 0; rg < 4; rg++) {
        float linv = 1.f / l_r[rg];
        int qrow = qt * 64 + w * 16 + lhi * 4 + rg;
        float* orow = aout + ((size_t)(b * 2048 + qrow)) * 512 + h * 128;
#pragma unroll
        for (int dt = 0; dt < 8; dt++)
            orow[dt * 16 + l16] = acc[dt][rg] * linv;
    }
}

// ---------------------------------------------------------------------------
// fused_s[b][p][d] (token-major) = zc[b][p]+zc[b][1024+p]+zl[b][p]+zl[b][1024+p]
// ---------------------------------------------------------------------------
__global__ void k_fused_sum(const float* __restrict__ zc, const float* __restrict__ zl,
                            float* __restrict__ fs) {
    int idx = blockIdx.x * TPB + threadIdx.x;
    int d = idx & 127, p = (idx >> 7) & 1023, b = idx >> 17;
    size_t r0 = ((size_t)b * 2048 + p) * 128 + d;
    size_t r1 = ((size_t)b * 2048 + 1024 + p) * 128 + d;
    fs[((size_t)b * 1024 + p) * 128 + d] = zc[r0] + zc[r1] + zl[r0] + zl[r1];
}

// ---------------------------------------------------------------------------
extern "C" void kernel_launch(void* const* d_in, const int* in_sizes, int n_in,
                              void* d_out, int out_size, void* d_ws, size_t ws_size,
                              hipStream_t stream) {
    const float* cam_feat = (const float*)d_in[0];
    const float* lid_feat = (const float*)d_in[1];
    const float* pos      = (const float*)d_in[2];
    const float* conv_w   = (const float*)d_in[3];
    const float* convT_w  = (const float*)d_in[4];
    const float* lnq_g = (const float*)d_in[5];
    const float* lnq_b = (const float*)d_in[6];
    const float* wq    = (const float*)d_in[7];
    const float* lnk_g = (const float*)d_in[8];
    const float* lnk_b = (const float*)d_in[9];
    const float* wk    = (const float*)d_in[10];
    const float* lnv_g = (const float*)d_in[11];
    const float* lnv_b = (const float*)d_in[12];
    const float* wv    = (const float*)d_in[13];
    const float* proj_w = (const float*)d_in[14];
    const float* proj_b = (const float*)d_in[15];
    const float* pre_g = (const float*)d_in[16];
    const float* pre_b = (const float*)d_in[17];
    const float* mlp_w1 = (const float*)d_in[18];
    const float* mlp_b1 = (const float*)d_in[19];
    const float* mlp_w2 = (const float*)d_in[20];
    const float* mlp_b2 = (const float*)d_in[21];
    const float* post_g = (const float*)d_in[22];
    const float* post_b = (const float*)d_in[23];

    float* ws = (float*)d_ws;
    float* outp = (float*)d_out;

    // persistent buffers (floats)
    float* cam_eT  = ws + 0;               // 1,048,576  [8][1024][128]
    float* lid_eT  = ws + 1048576;         // 1,048,576
    unsigned short* qbf16 = (unsigned short*)(ws + 2097152);  // 4,194,304 f
    float* z_cam   = ws + 6291456;         // 2,097,152
    float* z_lid   = ws + 8388608;         // 2,097,152
    float* fused_s = ws + 10485760;        // 1,048,576  [8][1024][128]
    float* stats   = ws + 11534336;        // 16,384
    unsigned short* wbuf = (unsigned short*)(ws + 11550720);  // 196,608 f
    float* part    = ws + 11747328;        // 65,536
    unsigned short* xcolT = (unsigned short*)(ws + 11812864); // 2,097,152 f
    float* pool    = ws + 13910016;        // 18,874,368  (total ~131 MB)

    unsigned short* wqT   = wbuf + 0;        // 512x128
    unsigned short* wkT   = wbuf + 65536;    // 512x128
    unsigned short* wvT   = wbuf + 131072;   // 512x128
    unsigned short* projT = wbuf + 196608;   // 128x512
    unsigned short* m1T   = wbuf + 262144;   // 256x128
    unsigned short* m2T   = wbuf + 294912;   // 128x256
    unsigned short* ctT   = wbuf + 327680;   // 512x128

    float* meanA = stats + 0,    *rstdA = stats + 2048;
    float* meanF = stats + 4096, *rstdF = stats + 5120;
    float* meanC = stats + 6144, *rstdC = stats + 7168;
    float* meanL = stats + 8192, *rstdL = stats + 9216;

    // pool (timeline-overlapped)
    float* lnqb  = pool + 0;                 // 2,097,152 (dead after Q gemm)
    float* lnkb  = pool + 0;                 // 1,048,576
    float* lnvb  = pool + 1048576;           // 1,048,576
    unsigned short* kbf16 = (unsigned short*)(pool + 2097152);  // 2,097,152 f
    float* vbuf  = pool + 4194304;           // 4,194,304
    unsigned short* vbfT  = (unsigned short*)(pool + 8388608);  // 2,097,152 f
    float* abuf  = pool + 10485760;          // 8,388,608
    float* z1    = pool + 0;                 // 2,097,152
    float* z2    = pool + 2097152;           // 2,097,152 (over dead kbf16)
    float* h1    = pool + 4194304;           // 4,194,304 (over dead vbuf)
    float* z3    = pool + 8388608;           // 2,097,152 (over dead vbfT)

    const float qscale = 0.08838834764831845f;  // 1/sqrt(128)

    // Weight prep (bf16, transposed [N][K])
    k_wtrans<<<dim3(16, 4), TPB, 0, stream>>>(wq, wqT, 128, 512);
    k_wtrans<<<dim3(16, 4), TPB, 0, stream>>>(wk, wkT, 128, 512);
    k_wtrans<<<dim3(16, 4), TPB, 0, stream>>>(wv, wvT, 128, 512);
    k_wtrans<<<dim3(4, 16), TPB, 0, stream>>>(proj_w, projT, 512, 128);
    k_wtrans<<<dim3(8, 4), TPB, 0, stream>>>(mlp_w1, m1T, 128, 256);
    k_wtrans<<<dim3(4, 8), TPB, 0, stream>>>(mlp_w2, m2T, 256, 128);
    k_wtrans<<<dim3(16, 4), TPB, 0, stream>>>(convT_w, ctT, 128, 512);

    // Stage A: stats + conv encoders (token-major outputs)
    k_stats_cm<<<2048, TPB, 0, stream>>>(cam_feat, lid_feat, pos, meanA, rstdA);
    k_prep<<<dim3(32, 8), TPB, 0, stream>>>(cam_feat, pos, meanA, rstdA, xcolT, 0);
    k_conv_gemm<<<dim3(16, 1, 8), TPB, 0, stream>>>(conv_w, xcolT, cam_eT);
    k_prep<<<dim3(32, 8), TPB, 0, stream>>>(lid_feat, pos, meanA, rstdA, xcolT, 1024);
    k_conv_gemm<<<dim3(16, 1, 8), TPB, 0, stream>>>(conv_w, xcolT, lid_eT);

    // Shared Q (bf16, head-major, pre-scaled)
    k_rowln2<<<4096, TPB, 0, stream>>>(cam_eT, lid_eT, lnqb, lnq_g, lnq_b);
    k_gemm_mfma<128, 128, 2, 2><<<dim3(4, 128), TPB, 0, stream>>>(
        lnqb, wqT, nullptr, qbf16, 16384, 512, 128, 4, nullptr, nullptr, nullptr, 11, qscale);

    for (int cross = 0; cross < 2; cross++) {
        const float* eT = cross ? lid_eT : cam_eT;
        float* zout = cross ? z_lid : z_cam;
        k_rowln<<<2048, TPB, 0, stream>>>(eT, lnkb, lnk_g, lnk_b);
        k_rowln<<<2048, TPB, 0, stream>>>(eT, lnvb, lnv_g, lnv_b);
        k_gemm_mfma<128, 128, 2, 2><<<dim3(4, 64), TPB, 0, stream>>>(
            lnkb, wkT, nullptr, kbf16, 8192, 512, 128, 4, nullptr, nullptr, nullptr, 10, 1.f);
        k_gemm_mfma<128, 128, 2, 2><<<dim3(4, 64), TPB, 0, stream>>>(
            lnvb, wvT, vbuf, nullptr, 8192, 512, 128, 0, nullptr, nullptr, nullptr, 0, 1.f);
        k_vtrans<<<dim3(16, 4, 8), TPB, 0, stream>>>(vbuf, vbfT);
        k_attn_bf16<<<dim3(32, 4, 8), TPB, 0, stream>>>(qbf16, kbf16, vbfT, abuf);
        k_gemm_mfma<64, 128, 1, 4><<<dim3(1, 256), TPB, 0, stream>>>(
            abuf, projT, z1, nullptr, 16384, 128, 512, 5, proj_b, cam_eT, lid_eT, 0, 1.f);
        k_rowln<<<4096, TPB, 0, stream>>>(z1, z2, pre_g, pre_b);
        k_gemm_mfma<128, 128, 2, 2><<<dim3(2, 128), TPB, 0, stream>>>(
            z2, m1T, h1, nullptr, 16384, 256, 128, 3, mlp_b1, nullptr, nullptr, 0, 1.f);
        k_gemm_mfma<64, 128, 1, 4><<<dim3(1, 256), TPB, 0, stream>>>(
            h1, m2T, z3, nullptr, 16384, 128, 256, 2, mlp_b2, z2, nullptr, 0, 1.f);
        k_rowln<<<4096, TPB, 0, stream>>>(z3, zout, post_g, post_b);
    }

    // Outputs
    k_fused_sum<<<4096, TPB, 0, stream>>>(z_cam, z_lid, fused_s);
    k_stats_part<<<dim3(16, 8), TPB, 0, stream>>>(fused_s, part, 1024);
    k_stats_red<<<8, 128, 0, stream>>>(part, meanF, rstdF, 16, 1024);
    k_stats_part<<<dim3(32, 8), TPB, 0, stream>>>(z_cam, part, 2048);
    k_stats_red<<<8, 128, 0, stream>>>(part, meanC, rstdC, 32, 2048);
    k_stats_part<<<dim3(32, 8), TPB, 0, stream>>>(z_lid, part, 2048);
    k_stats_red<<<8, 128, 0, stream>>>(part, meanL, rstdL, 32, 2048);
    k_convt_gemm<<<dim3(4, 8, 8), TPB, 0, stream>>>(fused_s, meanF, rstdF, ctT, outp, 1024, 32);
    k_convt_gemm<<<dim3(4, 16, 8), TPB, 0, stream>>>(z_cam, meanC, rstdC, ctT, outp + 4194304, 2048, 64);
    k_convt_gemm<<<dim3(4, 16, 8), TPB, 0, stream>>>(z_lid, meanL, rstdL, ctT, outp + 12582912, 2048, 64);
}

// Round 6
// 605.391 us; speedup vs baseline: 8.5019x; 1.2982x over previous
//
#include <hip/hip_runtime.h>
#include <math.h>

#define TPB 256

typedef __attribute__((ext_vector_type(8))) short bf16x8;
typedef __attribute__((ext_vector_type(4))) float f32x4;

__device__ __forceinline__ float gelu_exact(float x) {
    return 0.5f * x * (1.0f + erff(x * 0.70710678118654752f));
}

__device__ __forceinline__ unsigned short f2bf(float x) {
    unsigned u = __float_as_uint(x);
    return (unsigned short)((u + 0x7fffu + ((u >> 16) & 1u)) >> 16);
}

// ---------------------------------------------------------------------------
// Stage-A instance-norm stats (x + pos broadcast), 2048 channels.
// ---------------------------------------------------------------------------
__global__ void k_stats_cm(const float* __restrict__ x0, const float* __restrict__ x1,
                           const float* __restrict__ pos, float* __restrict__ mean,
                           float* __restrict__ rstd) {
    int gc = blockIdx.x;
    const float* src = ((gc < 1024) ? x0 : x1) + (size_t)(gc & 1023) * 4096;
    const float* posr = pos + (size_t)(gc & 127) * 4096;
    float s = 0.f, s2 = 0.f;
    for (int p = threadIdx.x; p < 4096; p += TPB) {
        float v = src[p] + posr[p];
        s += v; s2 += v * v;
    }
#pragma unroll
    for (int m = 32; m; m >>= 1) { s += __shfl_xor(s, m); s2 += __shfl_xor(s2, m); }
    __shared__ float ls[4], ls2[4];
    int w = threadIdx.x >> 6;
    if ((threadIdx.x & 63) == 0) { ls[w] = s; ls2[w] = s2; }
    __syncthreads();
    if (threadIdx.x == 0) {
        s = ls[0] + ls[1] + ls[2] + ls[3];
        s2 = ls2[0] + ls2[1] + ls2[2] + ls2[3];
        float mu = s / 4096.f;
        float var = s2 / 4096.f - mu * mu;
        mean[gc] = mu;
        rstd[gc] = rsqrtf(var + 1e-5f);
    }
}

// ---------------------------------------------------------------------------
// Token-major stats, two-phase.
// ---------------------------------------------------------------------------
__global__ void k_stats_part(const float* __restrict__ z, float* __restrict__ part, int T) {
    int c = blockIdx.x, b = blockIdx.y;
    int tid = threadIdx.x;
    int d = tid & 127, half = tid >> 7;
    const float* base = z + ((size_t)b * T + c * 64) * 128;
    float s = 0.f, s2 = 0.f;
    for (int t = half; t < 64; t += 2) {
        float v = base[t * 128 + d];
        s += v; s2 += v * v;
    }
    __shared__ float ls[256], ls2[256];
    ls[tid] = s; ls2[tid] = s2;
    __syncthreads();
    if (tid < 128) {
        s = ls[tid] + ls[tid + 128];
        s2 = ls2[tid] + ls2[tid + 128];
        float* p = part + ((size_t)(b * gridDim.x + c) * 2) * 128;
        p[d] = s; p[128 + d] = s2;
    }
}

__global__ void k_stats_red(const float* __restrict__ part, float* __restrict__ mean,
                            float* __restrict__ rstd, int nc, int T) {
    int b = blockIdx.x, d = threadIdx.x;
    float s = 0.f, s2 = 0.f;
    for (int c = 0; c < nc; c++) {
        const float* p = part + ((size_t)(b * nc + c) * 2) * 128;
        s += p[d]; s2 += p[128 + d];
    }
    float mu = s / (float)T;
    float var = s2 / (float)T - mu * mu;
    mean[b * 128 + d] = mu;
    rstd[b * 128 + d] = rsqrtf(var + 1e-5f);
}

// both z_cam and z_lid in one launch: grid (32, 8, 2)
__global__ void k_stats_part2(const float* __restrict__ zc, const float* __restrict__ zl,
                              float* __restrict__ part) {
    int c = blockIdx.x, b = blockIdx.y, sel = blockIdx.z;
    int tid = threadIdx.x;
    int d = tid & 127, half = tid >> 7;
    const float* base = (sel ? zl : zc) + ((size_t)b * 2048 + c * 64) * 128;
    float s = 0.f, s2 = 0.f;
    for (int t = half; t < 64; t += 2) {
        float v = base[t * 128 + d];
        s += v; s2 += v * v;
    }
    __shared__ float ls[256], ls2[256];
    ls[tid] = s; ls2[tid] = s2;
    __syncthreads();
    if (tid < 128) {
        s = ls[tid] + ls[tid + 128];
        s2 = ls2[tid] + ls2[tid + 128];
        float* p = part + ((size_t)((sel * 8 + b) * 32 + c) * 2) * 128;
        p[d] = s; p[128 + d] = s2;
    }
}

__global__ void k_stats_red2(const float* __restrict__ part,
                             float* __restrict__ meanC, float* __restrict__ rstdC,
                             float* __restrict__ meanL, float* __restrict__ rstdL) {
    int idx = blockIdx.x, d = threadIdx.x;  // 16 blocks x 128 thr
    int sel = idx >> 3, b = idx & 7;
    float s = 0.f, s2 = 0.f;
    for (int c = 0; c < 32; c++) {
        const float* p = part + ((size_t)((sel * 8 + b) * 32 + c) * 2) * 128;
        s += p[d]; s2 += p[128 + d];
    }
    float mu = s / 2048.f;
    float var = s2 / 2048.f - mu * mu;
    float* mean = sel ? meanL : meanC;
    float* rstd = sel ? rstdL : rstdC;
    mean[b * 128 + d] = mu;
    rstd[b * 128 + d] = rsqrtf(var + 1e-5f);
}

// ---------------------------------------------------------------------------
// Conv prep (cam+lid merged): normalize+ReLU+im2col -> bf16 xcolT[bb][p][512].
// grid (32 h, 16 bb): bb<8 cam else lid.
// ---------------------------------------------------------------------------
__global__ void k_prep(const float* __restrict__ cam, const float* __restrict__ lid,
                       const float* __restrict__ pos, const float* __restrict__ mean,
                       const float* __restrict__ rstd, unsigned short* __restrict__ xcolT) {
    __shared__ unsigned short T[32 * 520];
    int h = blockIdx.x, bb = blockIdx.y;
    int b = bb & 7, so = (bb < 8) ? 0 : 1024;
    const float* x = (bb < 8) ? cam : lid;
    int tid = threadIdx.x;
    for (int i = tid; i < 4096; i += TPB) {
        int c = i >> 5, w = i & 31;
        int ch = b * 128 + c;
        const float* xr = x + (size_t)ch * 4096 + (2 * h) * 64 + 2 * w;
        const float* pr = pos + (size_t)c * 4096 + (2 * h) * 64 + 2 * w;
        float mu = mean[so + ch], rs = rstd[so + ch];
        float2 x0 = *(const float2*)xr;
        float2 x1 = *(const float2*)(xr + 64);
        float2 p0 = *(const float2*)pr;
        float2 p1 = *(const float2*)(pr + 64);
        ushort4 u;
        u.x = f2bf(fmaxf((x0.x + p0.x - mu) * rs, 0.f));
        u.y = f2bf(fmaxf((x0.y + p0.y - mu) * rs, 0.f));
        u.z = f2bf(fmaxf((x1.x + p1.x - mu) * rs, 0.f));
        u.w = f2bf(fmaxf((x1.y + p1.y - mu) * rs, 0.f));
        *(ushort4*)&T[w * 520 + c * 4] = u;
    }
    __syncthreads();
    unsigned short* dst = xcolT + ((size_t)bb * 1024 + h * 32) * 512;
    for (int i = tid; i < 2048; i += TPB) {
        int w = i >> 6, kk = (i & 63) * 8;
        *(bf16x8*)&dst[(size_t)w * 512 + kk] = *(bf16x8*)&T[w * 520 + kk];
    }
}

// ---------------------------------------------------------------------------
// Conv as batched MFMA GEMM (cam+lid merged). grid (16, 1, 16).
// ---------------------------------------------------------------------------
__global__ __launch_bounds__(256, 2) void k_conv_gemm(
        const float* __restrict__ W, const unsigned short* __restrict__ xcolT,
        float* __restrict__ camT, float* __restrict__ lidT) {
    __shared__ __align__(16) unsigned short As[128 * 40];
    __shared__ __align__(16) unsigned short Bs[64 * 40];
    int tid = threadIdx.x, lane = tid & 63, w = tid >> 6;
    int l16 = lane & 15, lhi = lane >> 4;
    int n0 = blockIdx.x * 64, bb = blockIdx.z;
    const unsigned short* BT = xcolT + (size_t)bb * 524288;
    float* eT = ((bb < 8) ? camT : lidT) + (size_t)(bb & 7) * 131072;

    f32x4 acc[2][4];
#pragma unroll
    for (int mi = 0; mi < 2; mi++)
#pragma unroll
        for (int ni = 0; ni < 4; ni++) acc[mi][ni] = (f32x4){0.f, 0.f, 0.f, 0.f};

    for (int k0 = 0; k0 < 512; k0 += 32) {
        for (int i = tid; i < 1024; i += TPB) {
            int row = i >> 3, kc = (i & 7) * 4;
            float4 va = *(const float4*)&W[(size_t)row * 512 + k0 + kc];
            ushort4 u;
            u.x = f2bf(va.x); u.y = f2bf(va.y); u.z = f2bf(va.z); u.w = f2bf(va.w);
            *(ushort4*)&As[row * 40 + kc] = u;
        }
        for (int i = tid; i < 256; i += TPB) {
            int n = i >> 2, kc = (i & 3) * 8;
            *(bf16x8*)&Bs[n * 40 + kc] = *(const bf16x8*)&BT[(size_t)(n0 + n) * 512 + k0 + kc];
        }
        __syncthreads();
        bf16x8 af[2], bfr[4];
#pragma unroll
        for (int mi = 0; mi < 2; mi++)
            af[mi] = *(bf16x8*)&As[(w * 32 + mi * 16 + l16) * 40 + lhi * 8];
#pragma unroll
        for (int ni = 0; ni < 4; ni++)
            bfr[ni] = *(bf16x8*)&Bs[(ni * 16 + l16) * 40 + lhi * 8];
#pragma unroll
        for (int mi = 0; mi < 2; mi++)
#pragma unroll
            for (int ni = 0; ni < 4; ni++)
                acc[mi][ni] = __builtin_amdgcn_mfma_f32_16x16x32_bf16(af[mi], bfr[ni], acc[mi][ni], 0, 0, 0);
        __syncthreads();
    }
#pragma unroll
    for (int mi = 0; mi < 2; mi++)
#pragma unroll
        for (int ni = 0; ni < 4; ni++) {
            int col = n0 + ni * 16 + l16;
            int rowb = w * 32 + mi * 16 + lhi * 4;
            *(float4*)&eT[(size_t)col * 128 + rowb] = *(float4*)&acc[mi][ni];
        }
}

// ---------------------------------------------------------------------------
// K/V LayerNorm: shared stats, two affine outputs. grid 2048.
// ---------------------------------------------------------------------------
__global__ void k_rowln_kv(const float* __restrict__ in, float* __restrict__ outk,
                           float* __restrict__ outv,
                           const float* __restrict__ gk, const float* __restrict__ bk,
                           const float* __restrict__ gv, const float* __restrict__ bv) {
    int r = blockIdx.x * 4 + (threadIdx.x >> 6);
    int lane = threadIdx.x & 63;
    const float* row = in + (size_t)r * 128;
    float v0 = row[lane], v1 = row[lane + 64];
    float s = v0 + v1, s2 = v0 * v0 + v1 * v1;
#pragma unroll
    for (int m = 32; m; m >>= 1) { s += __shfl_xor(s, m); s2 += __shfl_xor(s2, m); }
    float mu = s * (1.f / 128.f);
    float var = s2 * (1.f / 128.f) - mu * mu;
    float rs = rsqrtf(var + 1e-5f);
    float n0 = (v0 - mu) * rs, n1 = (v1 - mu) * rs;
    outk[(size_t)r * 128 + lane]      = n0 * gk[lane] + bk[lane];
    outk[(size_t)r * 128 + lane + 64] = n1 * gk[lane + 64] + bk[lane + 64];
    outv[(size_t)r * 128 + lane]      = n0 * gv[lane] + bv[lane];
    outv[(size_t)r * 128 + lane + 64] = n1 * gv[lane + 64] + bv[lane + 64];
}

// Q-path LN reading the concat [camT | lidT] along tokens. grid 4096.
__global__ void k_rowln2(const float* __restrict__ camT, const float* __restrict__ lidT,
                         float* __restrict__ out, const float* __restrict__ g,
                         const float* __restrict__ bb) {
    int r = blockIdx.x * 4 + (threadIdx.x >> 6);
    int lane = threadIdx.x & 63;
    int b = r >> 11, t = r & 2047;
    const float* row = ((t < 1024) ? camT : lidT) + ((size_t)(b * 1024 + (t & 1023))) * 128;
    float v0 = row[lane], v1 = row[lane + 64];
    float s = v0 + v1, s2 = v0 * v0 + v1 * v1;
#pragma unroll
    for (int m = 32; m; m >>= 1) { s += __shfl_xor(s, m); s2 += __shfl_xor(s2, m); }
    float mu = s * (1.f / 128.f);
    float var = s2 * (1.f / 128.f) - mu * mu;
    float rs = rsqrtf(var + 1e-5f);
    out[(size_t)r * 128 + lane]      = (v0 - mu) * rs * g[lane] + bb[lane];
    out[(size_t)r * 128 + lane + 64] = (v1 - mu) * rs * g[lane + 64] + bb[lane + 64];
}

// ---------------------------------------------------------------------------
// All weight transposes in one launch. 384 blocks.
// ---------------------------------------------------------------------------
__global__ void k_wtrans_all(
        const float* __restrict__ wq, const float* __restrict__ wk,
        const float* __restrict__ wv, const float* __restrict__ proj,
        const float* __restrict__ m1, const float* __restrict__ m2,
        const float* __restrict__ ct,
        unsigned short* wqT, unsigned short* wkT, unsigned short* wvT,
        unsigned short* projT, unsigned short* m1T, unsigned short* m2T,
        unsigned short* ctT) {
    __shared__ float t[32][33];
    int bid = blockIdx.x;
    const float* W; unsigned short* WT; int K, N, ti;
    if (bid < 64)       { W = wq;   WT = wqT;   K = 128; N = 512; ti = bid; }
    else if (bid < 128) { W = wk;   WT = wkT;   K = 128; N = 512; ti = bid - 64; }
    else if (bid < 192) { W = wv;   WT = wvT;   K = 128; N = 512; ti = bid - 128; }
    else if (bid < 256) { W = proj; WT = projT; K = 512; N = 128; ti = bid - 192; }
    else if (bid < 288) { W = m1;   WT = m1T;   K = 128; N = 256; ti = bid - 256; }
    else if (bid < 320) { W = m2;   WT = m2T;   K = 256; N = 128; ti = bid - 288; }
    else                { W = ct;   WT = ctT;   K = 128; N = 512; ti = bid - 320; }
    int tx = N >> 5;
    int n0 = (ti % tx) * 32, k0 = (ti / tx) * 32;
    int tid = threadIdx.x;
    for (int i = tid; i < 1024; i += TPB) {
        int r = i >> 5, c = i & 31;
        t[r][c] = W[(size_t)(k0 + r) * N + n0 + c];
    }
    __syncthreads();
    for (int i = tid; i < 1024; i += TPB) {
        int r = i >> 5, c = i & 31;
        WT[(size_t)(n0 + r) * K + k0 + c] = f2bf(t[c][r]);
    }
}

// ---------------------------------------------------------------------------
// MFMA bf16 GEMM: C = A[M,K](fp32) @ BT[N,K](bf16).
// mode 3: fp32 C = gelu(v + bias); mode 4: bf16 head-major C16 (scaled);
// mode 6: bf16 row-major C16.
// ---------------------------------------------------------------------------
template <int BM, int BN, int WM, int WN>
__global__ __launch_bounds__(256, 2) void k_gemm_mfma(
        const float* __restrict__ A, const unsigned short* __restrict__ BT,
        float* __restrict__ C, unsigned short* __restrict__ C16,
        int M, int N, int K, int mode,
        const float* __restrict__ bias, int sT, float scale) {
    constexpr int MI = BM / WM / 16;
    constexpr int NI = BN / WN / 16;
    __shared__ __align__(16) unsigned short As[BM * 40];
    __shared__ __align__(16) unsigned short Bs[BN * 40];
    int tid = threadIdx.x, lane = tid & 63, w = tid >> 6;
    int l16 = lane & 15, lhi = lane >> 4;
    int wm = w / WN, wn = w % WN;
    int m0 = blockIdx.y * BM, n0 = blockIdx.x * BN;

    f32x4 acc[MI][NI];
#pragma unroll
    for (int mi = 0; mi < MI; mi++)
#pragma unroll
        for (int ni = 0; ni < NI; ni++) acc[mi][ni] = (f32x4){0.f, 0.f, 0.f, 0.f};

    for (int k0 = 0; k0 < K; k0 += 32) {
        for (int i = tid; i < BM * 8; i += TPB) {
            int row = i >> 3, kc = (i & 7) * 4;
            float4 va = *(const float4*)&A[(size_t)(m0 + row) * K + k0 + kc];
            ushort4 u;
            u.x = f2bf(va.x); u.y = f2bf(va.y); u.z = f2bf(va.z); u.w = f2bf(va.w);
            *(ushort4*)&As[row * 40 + kc] = u;
        }
        for (int i = tid; i < BN * 4; i += TPB) {
            int n = i >> 2, kc = (i & 3) * 8;
            *(bf16x8*)&Bs[n * 40 + kc] = *(const bf16x8*)&BT[(size_t)(n0 + n) * K + k0 + kc];
        }
        __syncthreads();
        bf16x8 af[MI], bfr[NI];
#pragma unroll
        for (int mi = 0; mi < MI; mi++)
            af[mi] = *(bf16x8*)&As[(wm * (BM / WM) + mi * 16 + l16) * 40 + lhi * 8];
#pragma unroll
        for (int ni = 0; ni < NI; ni++)
            bfr[ni] = *(bf16x8*)&Bs[(wn * (BN / WN) + ni * 16 + l16) * 40 + lhi * 8];
#pragma unroll
        for (int mi = 0; mi < MI; mi++)
#pragma unroll
            for (int ni = 0; ni < NI; ni++)
                acc[mi][ni] = __builtin_amdgcn_mfma_f32_16x16x32_bf16(af[mi], bfr[ni], acc[mi][ni], 0, 0, 0);
        __syncthreads();
    }
#pragma unroll
    for (int mi = 0; mi < MI; mi++) {
#pragma unroll
        for (int ni = 0; ni < NI; ni++) {
            int col = n0 + wn * (BN / WN) + ni * 16 + l16;
#pragma unroll
            for (int rg = 0; rg < 4; rg++) {
                int row = m0 + wm * (BM / WM) + mi * 16 + lhi * 4 + rg;
                float v = acc[mi][ni][rg];
                if (mode == 4) {
                    int bb = row >> sT, t = row & ((1 << sT) - 1);
                    size_t oa = ((((size_t)bb * 4 + (col >> 7)) << sT) + t) * 128 + (col & 127);
                    C16[oa] = f2bf(v * scale);
                } else if (mode == 6) {
                    C16[(size_t)row * N + col] = f2bf(v);
                } else {  // mode 3
                    C[(size_t)row * N + col] = gelu_exact(v + bias[col]);
                }
            }
        }
    }
}

// ---------------------------------------------------------------------------
// GEMM (BM=64, BN=128=N, WM=1, WN=4) + bias + skip/residual + LayerNorm fused.
// mode 0: skip = width-concat [camT|lidT] (proj); mode 1: skip = aux (mlp2).
// grid (256) 1D.
// ---------------------------------------------------------------------------
__global__ __launch_bounds__(256, 2) void k_gemm_ln(
        const float* __restrict__ A, const unsigned short* __restrict__ BT,
        float* __restrict__ C, int K, int mode,
        const float* __restrict__ bias, const float* __restrict__ aux,
        const float* __restrict__ aux2,
        const float* __restrict__ g, const float* __restrict__ bvec) {
    __shared__ __align__(16) char shm[64 * 132 * 4];
    unsigned short* As = (unsigned short*)shm;      // 64*40
    unsigned short* Bs = As + 64 * 40;              // 128*40
    float* Cs = (float*)shm;                        // 64*132 (aliases staging)
    int tid = threadIdx.x, lane = tid & 63, w = tid >> 6;
    int l16 = lane & 15, lhi = lane >> 4;
    int m0 = blockIdx.x * 64;

    f32x4 acc[4][2];
#pragma unroll
    for (int mi = 0; mi < 4; mi++)
#pragma unroll
        for (int ni = 0; ni < 2; ni++) acc[mi][ni] = (f32x4){0.f, 0.f, 0.f, 0.f};

    for (int k0 = 0; k0 < K; k0 += 32) {
        for (int i = tid; i < 512; i += TPB) {
            int row = i >> 3, kc = (i & 7) * 4;
            float4 va = *(const float4*)&A[(size_t)(m0 + row) * K + k0 + kc];
            ushort4 u;
            u.x = f2bf(va.x); u.y = f2bf(va.y); u.z = f2bf(va.z); u.w = f2bf(va.w);
            *(ushort4*)&As[row * 40 + kc] = u;
        }
        for (int i = tid; i < 512; i += TPB) {
            int n = i >> 2, kc = (i & 3) * 8;
            *(bf16x8*)&Bs[n * 40 + kc] = *(const bf16x8*)&BT[(size_t)n * K + k0 + kc];
        }
        __syncthreads();
        bf16x8 af[4], bfr[2];
#pragma unroll
        for (int mi = 0; mi < 4; mi++)
            af[mi] = *(bf16x8*)&As[(mi * 16 + l16) * 40 + lhi * 8];
#pragma unroll
        for (int ni = 0; ni < 2; ni++)
            bfr[ni] = *(bf16x8*)&Bs[(w * 32 + ni * 16 + l16) * 40 + lhi * 8];
#pragma unroll
        for (int mi = 0; mi < 4; mi++)
#pragma unroll
            for (int ni = 0; ni < 2; ni++)
                acc[mi][ni] = __builtin_amdgcn_mfma_f32_16x16x32_bf16(af[mi], bfr[ni], acc[mi][ni], 0, 0, 0);
        __syncthreads();
    }
    // epilogue part 1: bias + skip, stage to LDS
#pragma unroll
    for (int mi = 0; mi < 4; mi++) {
#pragma unroll
        for (int ni = 0; ni < 2; ni++) {
            int col = w * 32 + ni * 16 + l16;
#pragma unroll
            for (int rg = 0; rg < 4; rg++) {
                int rl = mi * 16 + lhi * 4 + rg;
                int grow = m0 + rl;
                float v = acc[mi][ni][rg] + bias[col];
                if (mode == 0) {
                    int b = grow >> 11, s = grow & 2047;
                    int H = s >> 6, W = s & 63;
                    const float* sp = (W < 32) ? aux : aux2;
                    v += sp[((size_t)(b * 1024 + H * 32 + (W & 31))) * 128 + col];
                } else {
                    v += aux[(size_t)grow * 128 + col];
                }
                Cs[rl * 132 + col] = v;
            }
        }
    }
    __syncthreads();
    // epilogue part 2: per-row LayerNorm (wave w handles rows w*16..+15)
    for (int rr = 0; rr < 16; rr++) {
        int row = w * 16 + rr, grow = m0 + row;
        float x0 = Cs[row * 132 + lane], x1 = Cs[row * 132 + 64 + lane];
        float s = x0 + x1, s2 = x0 * x0 + x1 * x1;
#pragma unroll
        for (int m = 32; m; m >>= 1) { s += __shfl_xor(s, m); s2 += __shfl_xor(s2, m); }
        float mu = s * (1.f / 128.f);
        float var = s2 * (1.f / 128.f) - mu * mu;
        float rs = rsqrtf(var + 1e-5f);
        C[(size_t)grow * 128 + lane]      = (x0 - mu) * rs * g[lane] + bvec[lane];
        C[(size_t)grow * 128 + lane + 64] = (x1 - mu) * rs * g[lane + 64] + bvec[lane + 64];
    }
}

// ---------------------------------------------------------------------------
// ConvTranspose as batched MFMA GEMM with fused instance-norm+ReLU on A.
// ---------------------------------------------------------------------------
__global__ __launch_bounds__(256, 2) void k_convt_gemm(
        const float* __restrict__ src, const float* __restrict__ mean,
        const float* __restrict__ rstd, const unsigned short* __restrict__ ctT,
        float* __restrict__ out, int M, int Hin) {
    __shared__ __align__(16) unsigned short As[128 * 40];
    __shared__ __align__(16) unsigned short Bs[128 * 40];
    int tid = threadIdx.x, lane = tid & 63, w = tid >> 6;
    int l16 = lane & 15, lhi = lane >> 4;
    int wm = w >> 1, wn = w & 1;
    int m0 = blockIdx.y * 128, n0 = blockIdx.x * 128, b = blockIdx.z;
    const float* Ab = src + (size_t)b * M * 128;
    const float* mb = mean + b * 128;
    const float* rb = rstd + b * 128;

    f32x4 acc[4][4];
#pragma unroll
    for (int mi = 0; mi < 4; mi++)
#pragma unroll
        for (int ni = 0; ni < 4; ni++) acc[mi][ni] = (f32x4){0.f, 0.f, 0.f, 0.f};

    for (int k0 = 0; k0 < 128; k0 += 32) {
        for (int i = tid; i < 1024; i += TPB) {
            int row = i >> 3, kc = (i & 7) * 4;
            float4 va = *(const float4*)&Ab[(size_t)(m0 + row) * 128 + k0 + kc];
            float4 mn = *(const float4*)&mb[k0 + kc];
            float4 rs = *(const float4*)&rb[k0 + kc];
            ushort4 u;
            u.x = f2bf(fmaxf((va.x - mn.x) * rs.x, 0.f));
            u.y = f2bf(fmaxf((va.y - mn.y) * rs.y, 0.f));
            u.z = f2bf(fmaxf((va.z - mn.z) * rs.z, 0.f));
            u.w = f2bf(fmaxf((va.w - mn.w) * rs.w, 0.f));
            *(ushort4*)&As[row * 40 + kc] = u;
        }
        for (int i = tid; i < 512; i += TPB) {
            int n = i >> 2, kc = (i & 3) * 8;
            *(bf16x8*)&Bs[n * 40 + kc] = *(const bf16x8*)&ctT[(size_t)(n0 + n) * 128 + k0 + kc];
        }
        __syncthreads();
        bf16x8 af[4], bfr[4];
#pragma unroll
        for (int mi = 0; mi < 4; mi++)
            af[mi] = *(bf16x8*)&As[(wm * 64 + mi * 16 + l16) * 40 + lhi * 8];
#pragma unroll
        for (int ni = 0; ni < 4; ni++)
            bfr[ni] = *(bf16x8*)&Bs[(wn * 64 + ni * 16 + l16) * 40 + lhi * 8];
#pragma unroll
        for (int mi = 0; mi < 4; mi++)
#pragma unroll
            for (int ni = 0; ni < 4; ni++)
                acc[mi][ni] = __builtin_amdgcn_mfma_f32_16x16x32_bf16(af[mi], bfr[ni], acc[mi][ni], 0, 0, 0);
        __syncthreads();
    }
    int Ho = 2 * Hin, Wo = 64;
#pragma unroll
    for (int mi = 0; mi < 4; mi++) {
#pragma unroll
        for (int ni = 0; ni < 4; ni++) {
            int col = n0 + wn * 64 + ni * 16 + l16;
            int oc = col >> 2, aa = (col >> 1) & 1, dd = col & 1;
#pragma unroll
            for (int rg = 0; rg < 4; rg++) {
                int p = m0 + wm * 64 + mi * 16 + lhi * 4 + rg;
                int hin = p >> 5, win = p & 31;
                out[(((size_t)b * 128 + oc) * Ho + 2 * hin + aa) * Wo + 2 * win + dd] =
                    acc[mi][ni][rg];
            }
        }
    }
}

// ---------------------------------------------------------------------------
// V transpose (bf16 in): vbf [8192][512] u16 -> vt [b][h][d][1024] u16.
// grid (16, 4, 8).
// ---------------------------------------------------------------------------
__global__ void k_vtrans(const unsigned short* __restrict__ vbf,
                         unsigned short* __restrict__ vt) {
    __shared__ unsigned short tile[64][140];
    int t0 = blockIdx.x * 64, h = blockIdx.y, b = blockIdx.z;
    int tid = threadIdx.x;
    for (int i = tid; i < 1024; i += TPB) {
        int tt = i >> 4, d8 = (i & 15) * 8;
        *(bf16x8*)&tile[tt][d8] =
            *(const bf16x8*)&vbf[(size_t)(b * 1024 + t0 + tt) * 512 + h * 128 + d8];
    }
    __syncthreads();
    for (int i = tid; i < 8192; i += TPB) {
        int d = i >> 6, tt = i & 63;
        vt[((size_t)(b * 4 + h) * 128 + d) * 1024 + t0 + tt] = tile[tt][d];
    }
}

// ---------------------------------------------------------------------------
// bf16 flash attention, 64-key chunks, slot-swizzled LDS (conflict-free),
// lane-local l, defer-rescale (THR=8). grid (32, 4, 8), 4 blocks/CU.
// ---------------------------------------------------------------------------
__global__ __launch_bounds__(256, 4) void k_attn_bf16(
        const unsigned short* __restrict__ qb, const unsigned short* __restrict__ kb,
        const unsigned short* __restrict__ vt, float* __restrict__ aout) {
    __shared__ __align__(16) unsigned short smem[20480];  // 40 KB
    unsigned short* Ks = smem;            // [64][128], slot^row swizzle
    unsigned short* Vt = smem + 8192;     // [128][64], slot^d swizzle
    unsigned short* Ps = smem + 16384;    // 4 waves x [16][64], slot^row swizzle
    int tid = threadIdx.x;
    int lane = tid & 63, w = tid >> 6;
    int l16 = lane & 15, lhi = lane >> 4;
    int qt = blockIdx.x, h = blockIdx.y, b = blockIdx.z;
    int bh = b * 4 + h;

    const unsigned short* qg = qb + ((size_t)bh * 2048 + qt * 64) * 128;
    bf16x8 qa[4];
    {
        int r = w * 16 + l16;
#pragma unroll
        for (int ks = 0; ks < 4; ks++)
            qa[ks] = *(const bf16x8*)&qg[(size_t)r * 128 + ks * 32 + lhi * 8];
    }

    f32x4 acc[8];
#pragma unroll
    for (int dt = 0; dt < 8; dt++) acc[dt] = (f32x4){0.f, 0.f, 0.f, 0.f};
    float m_r[4], l_r[4];
#pragma unroll
    for (int rg = 0; rg < 4; rg++) { m_r[rg] = -1e30f; l_r[rg] = 0.f; }

    const unsigned short* kg = kb + (size_t)bh * 1024 * 128;
    const unsigned short* vg = vt + (size_t)bh * 128 * 1024;
    unsigned short* Pw = Ps + w * 1024;

    for (int c0 = 0; c0 < 1024; c0 += 64) {
        // stage K: 64 rows x 128, swizzled 16B slots
        for (int i = tid; i < 1024; i += TPB) {
            int row = i >> 4, sl = i & 15;
            *(bf16x8*)&Ks[row * 128 + ((sl ^ (row & 7)) << 3)] =
                *(const bf16x8*)&kg[(size_t)(c0 + row) * 128 + sl * 8];
        }
        // stage V^T: 128 d x 64 keys, swizzled
        for (int i = tid; i < 1024; i += TPB) {
            int d = i >> 3, sl = i & 7;
            *(bf16x8*)&Vt[d * 64 + ((sl ^ (d & 7)) << 3)] =
                *(const bf16x8*)&vg[(size_t)d * 1024 + c0 + sl * 8];
        }
        __syncthreads();

        // QK^T: 16 rows x 64 cols per wave
        f32x4 s[4];
        s[0] = s[1] = s[2] = s[3] = (f32x4){0.f, 0.f, 0.f, 0.f};
#pragma unroll
        for (int nt = 0; nt < 4; nt++) {
            int r = nt * 16 + l16;
#pragma unroll
            for (int ks = 0; ks < 4; ks++) {
                bf16x8 kbf = *(bf16x8*)&Ks[r * 128 + (((ks * 4 + lhi) ^ (r & 7)) << 3)];
                s[nt] = __builtin_amdgcn_mfma_f32_16x16x32_bf16(qa[ks], kbf, s[nt], 0, 0, 0);
            }
        }

        // per-row max (group-uniform) + defer-rescale decision
        float pm[4];
        bool need = false;
#pragma unroll
        for (int rg = 0; rg < 4; rg++) {
            float a = fmaxf(fmaxf(s[0][rg], s[1][rg]), fmaxf(s[2][rg], s[3][rg]));
            a = fmaxf(a, __shfl_xor(a, 1));
            a = fmaxf(a, __shfl_xor(a, 2));
            a = fmaxf(a, __shfl_xor(a, 4));
            a = fmaxf(a, __shfl_xor(a, 8));
            pm[rg] = a;
            need = need || (a > m_r[rg] + 8.f);
        }
        if (__any(need)) {
#pragma unroll
            for (int rg = 0; rg < 4; rg++) {
                float mn = fmaxf(m_r[rg], pm[rg]);
                float f = __expf(m_r[rg] - mn);
                m_r[rg] = mn;
                l_r[rg] *= f;
#pragma unroll
                for (int dt = 0; dt < 8; dt++) acc[dt][rg] *= f;
            }
        }
        // exponentiate, lane-local l, write P (swizzled bf16)
#pragma unroll
        for (int rg = 0; rg < 4; rg++) {
            int row = lhi * 4 + rg;
            float lsum = 0.f;
#pragma unroll
            for (int nt = 0; nt < 4; nt++) {
                float p = __expf(s[nt][rg] - m_r[rg]);
                lsum += p;
                int col = nt * 16 + l16;
                Pw[row * 64 + ((((col >> 3) ^ (row & 7)) << 3) | (col & 7))] = f2bf(p);
            }
            l_r[rg] += lsum;
        }
        asm volatile("s_waitcnt lgkmcnt(0)" ::: "memory");

        // PV: 2 k-halves x 8 d-tiles
        bf16x8 pa0 = *(bf16x8*)&Pw[l16 * 64 + ((lhi ^ (l16 & 7)) << 3)];
        bf16x8 pa1 = *(bf16x8*)&Pw[l16 * 64 + (((4 + lhi) ^ (l16 & 7)) << 3)];
#pragma unroll
        for (int dt = 0; dt < 8; dt++) {
            int d = dt * 16 + l16;
            bf16x8 vb0 = *(bf16x8*)&Vt[d * 64 + ((lhi ^ (d & 7)) << 3)];
            bf16x8 vb1 = *(bf16x8*)&Vt[d * 64 + (((4 + lhi) ^ (d & 7)) << 3)];
            acc[dt] = __builtin_amdgcn_mfma_f32_16x16x32_bf16(pa0, vb0, acc[dt], 0, 0, 0);
            acc[dt] = __builtin_amdgcn_mfma_f32_16x16x32_bf16(pa1, vb1, acc[dt], 0, 0, 0);
        }
        __syncthreads();
    }

#pragma unroll
    for (int rg = 0; rg < 4; rg++) {
        float lt = l_r[rg];
        lt += __shfl_xor(lt, 1);
        lt += __shfl_xor(lt, 2);
        lt += __shfl_xor(lt, 4);
        lt += __shfl_xor(lt, 8);
        float linv = 1.f / lt;
        int qrow = qt * 64 + w * 16 + lhi * 4 + rg;
        float* orow = aout + ((size_t)(b * 2048 + qrow)) * 512 + h * 128;
#pragma unroll
        for (int dt = 0; dt < 8; dt++)
            orow[dt * 16 + l16] = acc[dt][rg] * linv;
    }
}

// ---------------------------------------------------------------------------
// fused_s[b][p][d] = zc[b][p]+zc[b][1024+p]+zl[b][p]+zl[b][1024+p]
// ---------------------------------------------------------------------------
__global__ void k_fused_sum(const float* __restrict__ zc, const float* __restrict__ zl,
                            float* __restrict__ fs) {
    int idx = blockIdx.x * TPB + threadIdx.x;
    int d = idx & 127, p = (idx >> 7) & 1023, b = idx >> 17;
    size_t r0 = ((size_t)b * 2048 + p) * 128 + d;
    size_t r1 = ((size_t)b * 2048 + 1024 + p) * 128 + d;
    fs[((size_t)b * 1024 + p) * 128 + d] = zc[r0] + zc[r1] + zl[r0] + zl[r1];
}

// ---------------------------------------------------------------------------
extern "C" void kernel_launch(void* const* d_in, const int* in_sizes, int n_in,
                              void* d_out, int out_size, void* d_ws, size_t ws_size,
                              hipStream_t stream) {
    const float* cam_feat = (const float*)d_in[0];
    const float* lid_feat = (const float*)d_in[1];
    const float* pos      = (const float*)d_in[2];
    const float* conv_w   = (const float*)d_in[3];
    const float* convT_w  = (const float*)d_in[4];
    const float* lnq_g = (const float*)d_in[5];
    const float* lnq_b = (const float*)d_in[6];
    const float* wq    = (const float*)d_in[7];
    const float* lnk_g = (const float*)d_in[8];
    const float* lnk_b = (const float*)d_in[9];
    const float* wk    = (const float*)d_in[10];
    const float* lnv_g = (const float*)d_in[11];
    const float* lnv_b = (const float*)d_in[12];
    const float* wv    = (const float*)d_in[13];
    const float* proj_w = (const float*)d_in[14];
    const float* proj_b = (const float*)d_in[15];
    const float* pre_g = (const float*)d_in[16];
    const float* pre_b = (const float*)d_in[17];
    const float* mlp_w1 = (const float*)d_in[18];
    const float* mlp_b1 = (const float*)d_in[19];
    const float* mlp_w2 = (const float*)d_in[20];
    const float* mlp_b2 = (const float*)d_in[21];
    const float* post_g = (const float*)d_in[22];
    const float* post_b = (const float*)d_in[23];

    float* ws = (float*)d_ws;
    float* outp = (float*)d_out;

    // persistent buffers (floats)
    float* cam_eT  = ws + 0;               // 1,048,576
    float* lid_eT  = ws + 1048576;         // 1,048,576
    unsigned short* qbf16 = (unsigned short*)(ws + 2097152);   // 4,194,304 f
    float* z_cam   = ws + 6291456;         // 2,097,152
    float* z_lid   = ws + 8388608;         // 2,097,152
    float* fused_s = ws + 10485760;        // 1,048,576
    float* stats   = ws + 11534336;        // 16,384
    unsigned short* wbuf = (unsigned short*)(ws + 11550720);   // 196,608 f
    float* part    = ws + 11747328;        // 131,072
    unsigned short* xcolT = (unsigned short*)(ws + 11878400);  // 4,194,304 f
    float* pool    = ws + 16072704;        // 16,777,216  (total ~131.4 MB)

    unsigned short* wqT   = wbuf + 0;        // 512x128
    unsigned short* wkT   = wbuf + 65536;    // 512x128
    unsigned short* wvT   = wbuf + 131072;   // 512x128
    unsigned short* projT = wbuf + 196608;   // 128x512
    unsigned short* m1T   = wbuf + 262144;   // 256x128
    unsigned short* m2T   = wbuf + 294912;   // 128x256
    unsigned short* ctT   = wbuf + 327680;   // 512x128

    float* meanA = stats + 0,    *rstdA = stats + 2048;
    float* meanF = stats + 4096, *rstdF = stats + 5120;
    float* meanC = stats + 6144, *rstdC = stats + 7168;
    float* meanL = stats + 8192, *rstdL = stats + 9216;

    // pool (timeline-overlapped)
    float* lnqb  = pool + 0;                 // 2,097,152 (dead after Q gemm)
    float* lnkb  = pool + 0;                 // 1,048,576
    float* lnvb  = pool + 1048576;           // 1,048,576
    unsigned short* kbf16 = (unsigned short*)(pool + 2097152); // 2,097,152 f
    unsigned short* vbf   = (unsigned short*)(pool + 4194304); // 2,097,152 f
    unsigned short* vbfT  = (unsigned short*)(pool + 6291456); // 2,097,152 f
    float* abuf  = pool + 8388608;           // 8,388,608
    float* z2    = pool + 0;                 // 2,097,152 (over dead ln bufs)
    float* h1    = pool + 2097152;           // 4,194,304 (over dead kbf16/vbf)

    const float qscale = 0.08838834764831845f;  // 1/sqrt(128)

    // Weight prep (one launch)
    k_wtrans_all<<<384, TPB, 0, stream>>>(wq, wk, wv, proj_w, mlp_w1, mlp_w2, convT_w,
                                          wqT, wkT, wvT, projT, m1T, m2T, ctT);

    // Stage A: stats + conv encoders (cam+lid in single launches)
    k_stats_cm<<<2048, TPB, 0, stream>>>(cam_feat, lid_feat, pos, meanA, rstdA);
    k_prep<<<dim3(32, 16), TPB, 0, stream>>>(cam_feat, lid_feat, pos, meanA, rstdA, xcolT);
    k_conv_gemm<<<dim3(16, 1, 16), TPB, 0, stream>>>(conv_w, xcolT, cam_eT, lid_eT);

    // Shared Q (bf16, head-major, pre-scaled)
    k_rowln2<<<4096, TPB, 0, stream>>>(cam_eT, lid_eT, lnqb, lnq_g, lnq_b);
    k_gemm_mfma<128, 128, 2, 2><<<dim3(4, 128), TPB, 0, stream>>>(
        lnqb, wqT, nullptr, qbf16, 16384, 512, 128, 4, nullptr, 11, qscale);

    for (int cross = 0; cross < 2; cross++) {
        const float* eT = cross ? lid_eT : cam_eT;
        float* zout = cross ? z_lid : z_cam;
        k_rowln_kv<<<2048, TPB, 0, stream>>>(eT, lnkb, lnvb, lnk_g, lnk_b, lnv_g, lnv_b);
        k_gemm_mfma<128, 128, 2, 2><<<dim3(4, 64), TPB, 0, stream>>>(
            lnkb, wkT, nullptr, kbf16, 8192, 512, 128, 4, nullptr, 10, 1.f);
        k_gemm_mfma<128, 128, 2, 2><<<dim3(4, 64), TPB, 0, stream>>>(
            lnvb, wvT, nullptr, vbf, 8192, 512, 128, 6, nullptr, 0, 1.f);
        k_vtrans<<<dim3(16, 4, 8), TPB, 0, stream>>>(vbf, vbfT);
        k_attn_bf16<<<dim3(32, 4, 8), TPB, 0, stream>>>(qbf16, kbf16, vbfT, abuf);
        k_gemm_ln<<<256, TPB, 0, stream>>>(
            abuf, projT, z2, 512, 0, proj_b, cam_eT, lid_eT, pre_g, pre_b);
        k_gemm_mfma<128, 128, 2, 2><<<dim3(2, 128), TPB, 0, stream>>>(
            z2, m1T, h1, nullptr, 16384, 256, 128, 3, mlp_b1, 0, 1.f);
        k_gemm_ln<<<256, TPB, 0, stream>>>(
            h1, m2T, zout, 256, 1, mlp_b2, z2, nullptr, post_g, post_b);
    }

    // Outputs
    k_fused_sum<<<4096, TPB, 0, stream>>>(z_cam, z_lid, fused_s);
    k_stats_part<<<dim3(16, 8), TPB, 0, stream>>>(fused_s, part, 1024);
    k_stats_red<<<8, 128, 0, stream>>>(part, meanF, rstdF, 16, 1024);
    k_stats_part2<<<dim3(32, 8, 2), TPB, 0, stream>>>(z_cam, z_lid, part);
    k_stats_red2<<<16, 128, 0, stream>>>(part, meanC, rstdC, meanL, rstdL);
    k_convt_gemm<<<dim3(4, 8, 8), TPB, 0, stream>>>(fused_s, meanF, rstdF, ctT, outp, 1024, 32);
    k_convt_gemm<<<dim3(4, 16, 8), TPB, 0, stream>>>(z_cam, meanC, rstdC, ctT, outp + 4194304, 2048, 64);
    k_convt_gemm<<<dim3(4, 16, 8), TPB, 0, stream>>>(z_lid, meanL, rstdL, ctT, outp + 12582912, 2048, 64);
}

// Round 7
// 477.413 us; speedup vs baseline: 10.7810x; 1.2681x over previous
//
#include <hip/hip_runtime.h>
#include <math.h>

#define TPB 256

typedef __attribute__((ext_vector_type(8))) short bf16x8;
typedef __attribute__((ext_vector_type(4))) float f32x4;

__device__ __forceinline__ float gelu_exact(float x) {
    return 0.5f * x * (1.0f + erff(x * 0.70710678118654752f));
}

__device__ __forceinline__ unsigned short f2bf(float x) {
    unsigned u = __float_as_uint(x);
    return (unsigned short)((u + 0x7fffu + ((u >> 16) & 1u)) >> 16);
}

// ---------------------------------------------------------------------------
// Stage-A instance-norm stats (x + pos broadcast), 2048 channels.
// ---------------------------------------------------------------------------
__global__ void k_stats_cm(const float* __restrict__ x0, const float* __restrict__ x1,
                           const float* __restrict__ pos, float* __restrict__ mean,
                           float* __restrict__ rstd) {
    int gc = blockIdx.x;
    const float* src = ((gc < 1024) ? x0 : x1) + (size_t)(gc & 1023) * 4096;
    const float* posr = pos + (size_t)(gc & 127) * 4096;
    float s = 0.f, s2 = 0.f;
    for (int p = threadIdx.x; p < 4096; p += TPB) {
        float v = src[p] + posr[p];
        s += v; s2 += v * v;
    }
#pragma unroll
    for (int m = 32; m; m >>= 1) { s += __shfl_xor(s, m); s2 += __shfl_xor(s2, m); }
    __shared__ float ls[4], ls2[4];
    int w = threadIdx.x >> 6;
    if ((threadIdx.x & 63) == 0) { ls[w] = s; ls2[w] = s2; }
    __syncthreads();
    if (threadIdx.x == 0) {
        s = ls[0] + ls[1] + ls[2] + ls[3];
        s2 = ls2[0] + ls2[1] + ls2[2] + ls2[3];
        float mu = s / 4096.f;
        float var = s2 / 4096.f - mu * mu;
        mean[gc] = mu;
        rstd[gc] = rsqrtf(var + 1e-5f);
    }
}

// ---------------------------------------------------------------------------
// Token-major stats, two-phase.
// ---------------------------------------------------------------------------
__global__ void k_stats_part(const float* __restrict__ z, float* __restrict__ part, int T) {
    int c = blockIdx.x, b = blockIdx.y;
    int tid = threadIdx.x;
    int d = tid & 127, half = tid >> 7;
    const float* base = z + ((size_t)b * T + c * 64) * 128;
    float s = 0.f, s2 = 0.f;
    for (int t = half; t < 64; t += 2) {
        float v = base[t * 128 + d];
        s += v; s2 += v * v;
    }
    __shared__ float ls[256], ls2[256];
    ls[tid] = s; ls2[tid] = s2;
    __syncthreads();
    if (tid < 128) {
        s = ls[tid] + ls[tid + 128];
        s2 = ls2[tid] + ls2[tid + 128];
        float* p = part + ((size_t)(b * gridDim.x + c) * 2) * 128;
        p[d] = s; p[128 + d] = s2;
    }
}

__global__ void k_stats_red(const float* __restrict__ part, float* __restrict__ mean,
                            float* __restrict__ rstd, int nc, int T) {
    int b = blockIdx.x, d = threadIdx.x;
    float s = 0.f, s2 = 0.f;
    for (int c = 0; c < nc; c++) {
        const float* p = part + ((size_t)(b * nc + c) * 2) * 128;
        s += p[d]; s2 += p[128 + d];
    }
    float mu = s / (float)T;
    float var = s2 / (float)T - mu * mu;
    mean[b * 128 + d] = mu;
    rstd[b * 128 + d] = rsqrtf(var + 1e-5f);
}

__global__ void k_stats_part2(const float* __restrict__ zc, const float* __restrict__ zl,
                              float* __restrict__ part) {
    int c = blockIdx.x, b = blockIdx.y, sel = blockIdx.z;
    int tid = threadIdx.x;
    int d = tid & 127, half = tid >> 7;
    const float* base = (sel ? zl : zc) + ((size_t)b * 2048 + c * 64) * 128;
    float s = 0.f, s2 = 0.f;
    for (int t = half; t < 64; t += 2) {
        float v = base[t * 128 + d];
        s += v; s2 += v * v;
    }
    __shared__ float ls[256], ls2[256];
    ls[tid] = s; ls2[tid] = s2;
    __syncthreads();
    if (tid < 128) {
        s = ls[tid] + ls[tid + 128];
        s2 = ls2[tid] + ls2[tid + 128];
        float* p = part + ((size_t)((sel * 8 + b) * 32 + c) * 2) * 128;
        p[d] = s; p[128 + d] = s2;
    }
}

__global__ void k_stats_red2(const float* __restrict__ part,
                             float* __restrict__ meanC, float* __restrict__ rstdC,
                             float* __restrict__ meanL, float* __restrict__ rstdL) {
    int idx = blockIdx.x, d = threadIdx.x;
    int sel = idx >> 3, b = idx & 7;
    float s = 0.f, s2 = 0.f;
    for (int c = 0; c < 32; c++) {
        const float* p = part + ((size_t)((sel * 8 + b) * 32 + c) * 2) * 128;
        s += p[d]; s2 += p[128 + d];
    }
    float mu = s / 2048.f;
    float var = s2 / 2048.f - mu * mu;
    float* mean = sel ? meanL : meanC;
    float* rstd = sel ? rstdL : rstdC;
    mean[b * 128 + d] = mu;
    rstd[b * 128 + d] = rsqrtf(var + 1e-5f);
}

// ---------------------------------------------------------------------------
// Conv prep (cam+lid merged): normalize+ReLU+im2col -> bf16 xcolT[bb][p][512].
// ---------------------------------------------------------------------------
__global__ void k_prep(const float* __restrict__ cam, const float* __restrict__ lid,
                       const float* __restrict__ pos, const float* __restrict__ mean,
                       const float* __restrict__ rstd, unsigned short* __restrict__ xcolT) {
    __shared__ unsigned short T[32 * 520];
    int h = blockIdx.x, bb = blockIdx.y;
    int b = bb & 7, so = (bb < 8) ? 0 : 1024;
    const float* x = (bb < 8) ? cam : lid;
    int tid = threadIdx.x;
    for (int i = tid; i < 4096; i += TPB) {
        int c = i >> 5, w = i & 31;
        int ch = b * 128 + c;
        const float* xr = x + (size_t)ch * 4096 + (2 * h) * 64 + 2 * w;
        const float* pr = pos + (size_t)c * 4096 + (2 * h) * 64 + 2 * w;
        float mu = mean[so + ch], rs = rstd[so + ch];
        float2 x0 = *(const float2*)xr;
        float2 x1 = *(const float2*)(xr + 64);
        float2 p0 = *(const float2*)pr;
        float2 p1 = *(const float2*)(pr + 64);
        ushort4 u;
        u.x = f2bf(fmaxf((x0.x + p0.x - mu) * rs, 0.f));
        u.y = f2bf(fmaxf((x0.y + p0.y - mu) * rs, 0.f));
        u.z = f2bf(fmaxf((x1.x + p1.x - mu) * rs, 0.f));
        u.w = f2bf(fmaxf((x1.y + p1.y - mu) * rs, 0.f));
        *(ushort4*)&T[w * 520 + c * 4] = u;
    }
    __syncthreads();
    unsigned short* dst = xcolT + ((size_t)bb * 1024 + h * 32) * 512;
    for (int i = tid; i < 2048; i += TPB) {
        int w = i >> 6, kk = (i & 63) * 8;
        *(bf16x8*)&dst[(size_t)w * 512 + kk] = *(bf16x8*)&T[w * 520 + kk];
    }
}

// ---------------------------------------------------------------------------
// Conv as batched MFMA GEMM (cam+lid merged). grid (16, 1, 16).
// ---------------------------------------------------------------------------
__global__ __launch_bounds__(256, 2) void k_conv_gemm(
        const float* __restrict__ W, const unsigned short* __restrict__ xcolT,
        float* __restrict__ camT, float* __restrict__ lidT) {
    __shared__ __align__(16) unsigned short As[128 * 40];
    __shared__ __align__(16) unsigned short Bs[64 * 40];
    int tid = threadIdx.x, lane = tid & 63, w = tid >> 6;
    int l16 = lane & 15, lhi = lane >> 4;
    int n0 = blockIdx.x * 64, bb = blockIdx.z;
    const unsigned short* BT = xcolT + (size_t)bb * 524288;
    float* eT = ((bb < 8) ? camT : lidT) + (size_t)(bb & 7) * 131072;

    f32x4 acc[2][4];
#pragma unroll
    for (int mi = 0; mi < 2; mi++)
#pragma unroll
        for (int ni = 0; ni < 4; ni++) acc[mi][ni] = (f32x4){0.f, 0.f, 0.f, 0.f};

    for (int k0 = 0; k0 < 512; k0 += 32) {
        for (int i = tid; i < 1024; i += TPB) {
            int row = i >> 3, kc = (i & 7) * 4;
            float4 va = *(const float4*)&W[(size_t)row * 512 + k0 + kc];
            ushort4 u;
            u.x = f2bf(va.x); u.y = f2bf(va.y); u.z = f2bf(va.z); u.w = f2bf(va.w);
            *(ushort4*)&As[row * 40 + kc] = u;
        }
        for (int i = tid; i < 256; i += TPB) {
            int n = i >> 2, kc = (i & 3) * 8;
            *(bf16x8*)&Bs[n * 40 + kc] = *(const bf16x8*)&BT[(size_t)(n0 + n) * 512 + k0 + kc];
        }
        __syncthreads();
        bf16x8 af[2], bfr[4];
#pragma unroll
        for (int mi = 0; mi < 2; mi++)
            af[mi] = *(bf16x8*)&As[(w * 32 + mi * 16 + l16) * 40 + lhi * 8];
#pragma unroll
        for (int ni = 0; ni < 4; ni++)
            bfr[ni] = *(bf16x8*)&Bs[(ni * 16 + l16) * 40 + lhi * 8];
#pragma unroll
        for (int mi = 0; mi < 2; mi++)
#pragma unroll
            for (int ni = 0; ni < 4; ni++)
                acc[mi][ni] = __builtin_amdgcn_mfma_f32_16x16x32_bf16(af[mi], bfr[ni], acc[mi][ni], 0, 0, 0);
        __syncthreads();
    }
#pragma unroll
    for (int mi = 0; mi < 2; mi++)
#pragma unroll
        for (int ni = 0; ni < 4; ni++) {
            int col = n0 + ni * 16 + l16;
            int rowb = w * 32 + mi * 16 + lhi * 4;
            *(float4*)&eT[(size_t)col * 128 + rowb] = *(float4*)&acc[mi][ni];
        }
}

// ---------------------------------------------------------------------------
// K/V LayerNorm, both crosses: grid 4096 (16384 rows).
// ---------------------------------------------------------------------------
__global__ void k_rowln_kv(const float* __restrict__ camT, const float* __restrict__ lidT,
                           float* __restrict__ outk, float* __restrict__ outv,
                           const float* __restrict__ gk, const float* __restrict__ bk,
                           const float* __restrict__ gv, const float* __restrict__ bv) {
    int r = blockIdx.x * 4 + (threadIdx.x >> 6);
    int lane = threadIdx.x & 63;
    const float* row = ((r < 8192) ? camT : lidT) + (size_t)(r & 8191) * 128;
    float v0 = row[lane], v1 = row[lane + 64];
    float s = v0 + v1, s2 = v0 * v0 + v1 * v1;
#pragma unroll
    for (int m = 32; m; m >>= 1) { s += __shfl_xor(s, m); s2 += __shfl_xor(s2, m); }
    float mu = s * (1.f / 128.f);
    float var = s2 * (1.f / 128.f) - mu * mu;
    float rs = rsqrtf(var + 1e-5f);
    float n0 = (v0 - mu) * rs, n1 = (v1 - mu) * rs;
    outk[(size_t)r * 128 + lane]      = n0 * gk[lane] + bk[lane];
    outk[(size_t)r * 128 + lane + 64] = n1 * gk[lane + 64] + bk[lane + 64];
    outv[(size_t)r * 128 + lane]      = n0 * gv[lane] + bv[lane];
    outv[(size_t)r * 128 + lane + 64] = n1 * gv[lane + 64] + bv[lane + 64];
}

// Q-path LN reading the concat [camT | lidT] along tokens. grid 4096.
__global__ void k_rowln2(const float* __restrict__ camT, const float* __restrict__ lidT,
                         float* __restrict__ out, const float* __restrict__ g,
                         const float* __restrict__ bb) {
    int r = blockIdx.x * 4 + (threadIdx.x >> 6);
    int lane = threadIdx.x & 63;
    int b = r >> 11, t = r & 2047;
    const float* row = ((t < 1024) ? camT : lidT) + ((size_t)(b * 1024 + (t & 1023))) * 128;
    float v0 = row[lane], v1 = row[lane + 64];
    float s = v0 + v1, s2 = v0 * v0 + v1 * v1;
#pragma unroll
    for (int m = 32; m; m >>= 1) { s += __shfl_xor(s, m); s2 += __shfl_xor(s2, m); }
    float mu = s * (1.f / 128.f);
    float var = s2 * (1.f / 128.f) - mu * mu;
    float rs = rsqrtf(var + 1e-5f);
    out[(size_t)r * 128 + lane]      = (v0 - mu) * rs * g[lane] + bb[lane];
    out[(size_t)r * 128 + lane + 64] = (v1 - mu) * rs * g[lane + 64] + bb[lane + 64];
}

// ---------------------------------------------------------------------------
// All weight transposes in one launch. 384 blocks.
// ---------------------------------------------------------------------------
__global__ void k_wtrans_all(
        const float* __restrict__ wq, const float* __restrict__ wk,
        const float* __restrict__ wv, const float* __restrict__ proj,
        const float* __restrict__ m1, const float* __restrict__ m2,
        const float* __restrict__ ct,
        unsigned short* wqT, unsigned short* wkT, unsigned short* wvT,
        unsigned short* projT, unsigned short* m1T, unsigned short* m2T,
        unsigned short* ctT) {
    __shared__ float t[32][33];
    int bid = blockIdx.x;
    const float* W; unsigned short* WT; int K, N, ti;
    if (bid < 64)       { W = wq;   WT = wqT;   K = 128; N = 512; ti = bid; }
    else if (bid < 128) { W = wk;   WT = wkT;   K = 128; N = 512; ti = bid - 64; }
    else if (bid < 192) { W = wv;   WT = wvT;   K = 128; N = 512; ti = bid - 128; }
    else if (bid < 256) { W = proj; WT = projT; K = 512; N = 128; ti = bid - 192; }
    else if (bid < 288) { W = m1;   WT = m1T;   K = 128; N = 256; ti = bid - 256; }
    else if (bid < 320) { W = m2;   WT = m2T;   K = 256; N = 128; ti = bid - 288; }
    else                { W = ct;   WT = ctT;   K = 128; N = 512; ti = bid - 320; }
    int tx = N >> 5;
    int n0 = (ti % tx) * 32, k0 = (ti / tx) * 32;
    int tid = threadIdx.x;
    for (int i = tid; i < 1024; i += TPB) {
        int r = i >> 5, c = i & 31;
        t[r][c] = W[(size_t)(k0 + r) * N + n0 + c];
    }
    __syncthreads();
    for (int i = tid; i < 1024; i += TPB) {
        int r = i >> 5, c = i & 31;
        WT[(size_t)(n0 + r) * K + k0 + c] = f2bf(t[c][r]);
    }
}

// ---------------------------------------------------------------------------
// MFMA bf16 GEMM: C = A[M,K](fp32) @ BT[N,K](bf16).
// mode 3: fp32 C = gelu(v + bias); mode 4: bf16 head-major C16 (scaled);
// mode 7: bf16 transposed head-major (V^T): [bh][d][1024].
// ---------------------------------------------------------------------------
template <int BM, int BN, int WM, int WN>
__global__ __launch_bounds__(256, 2) void k_gemm_mfma(
        const float* __restrict__ A, const unsigned short* __restrict__ BT,
        float* __restrict__ C, unsigned short* __restrict__ C16,
        int M, int N, int K, int mode,
        const float* __restrict__ bias, int sT, float scale) {
    constexpr int MI = BM / WM / 16;
    constexpr int NI = BN / WN / 16;
    __shared__ __align__(16) unsigned short As[BM * 40];
    __shared__ __align__(16) unsigned short Bs[BN * 40];
    int tid = threadIdx.x, lane = tid & 63, w = tid >> 6;
    int l16 = lane & 15, lhi = lane >> 4;
    int wm = w / WN, wn = w % WN;
    int m0 = blockIdx.y * BM, n0 = blockIdx.x * BN;

    f32x4 acc[MI][NI];
#pragma unroll
    for (int mi = 0; mi < MI; mi++)
#pragma unroll
        for (int ni = 0; ni < NI; ni++) acc[mi][ni] = (f32x4){0.f, 0.f, 0.f, 0.f};

    for (int k0 = 0; k0 < K; k0 += 32) {
        for (int i = tid; i < BM * 8; i += TPB) {
            int row = i >> 3, kc = (i & 7) * 4;
            float4 va = *(const float4*)&A[(size_t)(m0 + row) * K + k0 + kc];
            ushort4 u;
            u.x = f2bf(va.x); u.y = f2bf(va.y); u.z = f2bf(va.z); u.w = f2bf(va.w);
            *(ushort4*)&As[row * 40 + kc] = u;
        }
        for (int i = tid; i < BN * 4; i += TPB) {
            int n = i >> 2, kc = (i & 3) * 8;
            *(bf16x8*)&Bs[n * 40 + kc] = *(const bf16x8*)&BT[(size_t)(n0 + n) * K + k0 + kc];
        }
        __syncthreads();
        bf16x8 af[MI], bfr[NI];
#pragma unroll
        for (int mi = 0; mi < MI; mi++)
            af[mi] = *(bf16x8*)&As[(wm * (BM / WM) + mi * 16 + l16) * 40 + lhi * 8];
#pragma unroll
        for (int ni = 0; ni < NI; ni++)
            bfr[ni] = *(bf16x8*)&Bs[(wn * (BN / WN) + ni * 16 + l16) * 40 + lhi * 8];
#pragma unroll
        for (int mi = 0; mi < MI; mi++)
#pragma unroll
            for (int ni = 0; ni < NI; ni++)
                acc[mi][ni] = __builtin_amdgcn_mfma_f32_16x16x32_bf16(af[mi], bfr[ni], acc[mi][ni], 0, 0, 0);
        __syncthreads();
    }
#pragma unroll
    for (int mi = 0; mi < MI; mi++) {
#pragma unroll
        for (int ni = 0; ni < NI; ni++) {
            int col = n0 + wn * (BN / WN) + ni * 16 + l16;
            if (mode == 7) {
                int row0 = m0 + wm * (BM / WM) + mi * 16 + lhi * 4;
                int bb = row0 >> 10, t0 = row0 & 1023;
                ushort4 u;
                u.x = f2bf(acc[mi][ni][0]); u.y = f2bf(acc[mi][ni][1]);
                u.z = f2bf(acc[mi][ni][2]); u.w = f2bf(acc[mi][ni][3]);
                *(ushort4*)&C16[(((size_t)(bb * 4 + (col >> 7))) * 128 + (col & 127)) * 1024 + t0] = u;
            } else {
#pragma unroll
                for (int rg = 0; rg < 4; rg++) {
                    int row = m0 + wm * (BM / WM) + mi * 16 + lhi * 4 + rg;
                    float v = acc[mi][ni][rg];
                    if (mode == 4) {
                        int bb = row >> sT, t = row & ((1 << sT) - 1);
                        size_t oa = ((((size_t)bb * 4 + (col >> 7)) << sT) + t) * 128 + (col & 127);
                        C16[oa] = f2bf(v * scale);
                    } else {  // mode 3
                        C[(size_t)row * N + col] = gelu_exact(v + bias[col]);
                    }
                }
            }
        }
    }
}

// ---------------------------------------------------------------------------
// GEMM (BM=64, BN=128=N) + bias + skip/residual + LayerNorm fused.
// A bf16 (ABF=true) or fp32. mode 0: skip = width-concat [camT|lidT] (proj,
// rows 0..32767 = cross-major); mode 1: skip = aux, out split z_cam/z_lid.
// ---------------------------------------------------------------------------
template <bool ABF>
__global__ __launch_bounds__(256, 2) void k_gemm_ln(
        const void* __restrict__ Av, const unsigned short* __restrict__ BT,
        float* __restrict__ C0, float* __restrict__ C1, int K, int mode,
        const float* __restrict__ bias, const float* __restrict__ aux,
        const float* __restrict__ aux2,
        const float* __restrict__ g, const float* __restrict__ bvec) {
    __shared__ __align__(16) char shm[64 * 132 * 4];
    unsigned short* As = (unsigned short*)shm;      // 64*40
    unsigned short* Bs = As + 64 * 40;              // 128*40
    float* Cs = (float*)shm;                        // 64*132 (aliases staging)
    int tid = threadIdx.x, lane = tid & 63, w = tid >> 6;
    int l16 = lane & 15, lhi = lane >> 4;
    int m0 = blockIdx.x * 64;

    f32x4 acc[4][2];
#pragma unroll
    for (int mi = 0; mi < 4; mi++)
#pragma unroll
        for (int ni = 0; ni < 2; ni++) acc[mi][ni] = (f32x4){0.f, 0.f, 0.f, 0.f};

    for (int k0 = 0; k0 < K; k0 += 32) {
        if (ABF) {
            const unsigned short* Ab = (const unsigned short*)Av;
            for (int i = tid; i < 256; i += TPB) {
                int row = i >> 2, kc = (i & 3) * 8;
                *(bf16x8*)&As[row * 40 + kc] =
                    *(const bf16x8*)&Ab[(size_t)(m0 + row) * K + k0 + kc];
            }
        } else {
            const float* Af = (const float*)Av;
            for (int i = tid; i < 512; i += TPB) {
                int row = i >> 3, kc = (i & 7) * 4;
                float4 va = *(const float4*)&Af[(size_t)(m0 + row) * K + k0 + kc];
                ushort4 u;
                u.x = f2bf(va.x); u.y = f2bf(va.y); u.z = f2bf(va.z); u.w = f2bf(va.w);
                *(ushort4*)&As[row * 40 + kc] = u;
            }
        }
        for (int i = tid; i < 512; i += TPB) {
            int n = i >> 2, kc = (i & 3) * 8;
            *(bf16x8*)&Bs[n * 40 + kc] = *(const bf16x8*)&BT[(size_t)n * K + k0 + kc];
        }
        __syncthreads();
        bf16x8 af[4], bfr[2];
#pragma unroll
        for (int mi = 0; mi < 4; mi++)
            af[mi] = *(bf16x8*)&As[(mi * 16 + l16) * 40 + lhi * 8];
#pragma unroll
        for (int ni = 0; ni < 2; ni++)
            bfr[ni] = *(bf16x8*)&Bs[(w * 32 + ni * 16 + l16) * 40 + lhi * 8];
#pragma unroll
        for (int mi = 0; mi < 4; mi++)
#pragma unroll
            for (int ni = 0; ni < 2; ni++)
                acc[mi][ni] = __builtin_amdgcn_mfma_f32_16x16x32_bf16(af[mi], bfr[ni], acc[mi][ni], 0, 0, 0);
        __syncthreads();
    }
    // epilogue part 1: bias + skip, stage to LDS
#pragma unroll
    for (int mi = 0; mi < 4; mi++) {
#pragma unroll
        for (int ni = 0; ni < 2; ni++) {
            int col = w * 32 + ni * 16 + l16;
#pragma unroll
            for (int rg = 0; rg < 4; rg++) {
                int rl = mi * 16 + lhi * 4 + rg;
                int grow = m0 + rl;
                float v = acc[mi][ni][rg] + bias[col];
                if (mode == 0) {
                    int rr = grow & 16383;
                    int b = rr >> 11, s = rr & 2047;
                    int H = s >> 6, W = s & 63;
                    const float* sp = (W < 32) ? aux : aux2;
                    v += sp[((size_t)(b * 1024 + H * 32 + (W & 31))) * 128 + col];
                } else {
                    v += aux[(size_t)grow * 128 + col];
                }
                Cs[rl * 132 + col] = v;
            }
        }
    }
    __syncthreads();
    // epilogue part 2: per-row LayerNorm
    for (int rr = 0; rr < 16; rr++) {
        int row = w * 16 + rr, grow = m0 + row;
        float x0 = Cs[row * 132 + lane], x1 = Cs[row * 132 + 64 + lane];
        float s = x0 + x1, s2 = x0 * x0 + x1 * x1;
#pragma unroll
        for (int m = 32; m; m >>= 1) { s += __shfl_xor(s, m); s2 += __shfl_xor(s2, m); }
        float mu = s * (1.f / 128.f);
        float var = s2 * (1.f / 128.f) - mu * mu;
        float rs = rsqrtf(var + 1e-5f);
        float* Cp;
        size_t ro;
        if (mode == 1) { Cp = (grow < 16384) ? C0 : C1; ro = (size_t)(grow & 16383) * 128; }
        else           { Cp = C0; ro = (size_t)grow * 128; }
        Cp[ro + lane]      = (x0 - mu) * rs * g[lane] + bvec[lane];
        Cp[ro + lane + 64] = (x1 - mu) * rs * g[lane + 64] + bvec[lane + 64];
    }
}

// ---------------------------------------------------------------------------
// ConvTranspose as batched MFMA GEMM with fused instance-norm+ReLU on A.
// ---------------------------------------------------------------------------
__global__ __launch_bounds__(256, 2) void k_convt_gemm(
        const float* __restrict__ src, const float* __restrict__ mean,
        const float* __restrict__ rstd, const unsigned short* __restrict__ ctT,
        float* __restrict__ out, int M, int Hin) {
    __shared__ __align__(16) unsigned short As[128 * 40];
    __shared__ __align__(16) unsigned short Bs[128 * 40];
    int tid = threadIdx.x, lane = tid & 63, w = tid >> 6;
    int l16 = lane & 15, lhi = lane >> 4;
    int wm = w >> 1, wn = w & 1;
    int m0 = blockIdx.y * 128, n0 = blockIdx.x * 128, b = blockIdx.z;
    const float* Ab = src + (size_t)b * M * 128;
    const float* mb = mean + b * 128;
    const float* rb = rstd + b * 128;

    f32x4 acc[4][4];
#pragma unroll
    for (int mi = 0; mi < 4; mi++)
#pragma unroll
        for (int ni = 0; ni < 4; ni++) acc[mi][ni] = (f32x4){0.f, 0.f, 0.f, 0.f};

    for (int k0 = 0; k0 < 128; k0 += 32) {
        for (int i = tid; i < 1024; i += TPB) {
            int row = i >> 3, kc = (i & 7) * 4;
            float4 va = *(const float4*)&Ab[(size_t)(m0 + row) * 128 + k0 + kc];
            float4 mn = *(const float4*)&mb[k0 + kc];
            float4 rs = *(const float4*)&rb[k0 + kc];
            ushort4 u;
            u.x = f2bf(fmaxf((va.x - mn.x) * rs.x, 0.f));
            u.y = f2bf(fmaxf((va.y - mn.y) * rs.y, 0.f));
            u.z = f2bf(fmaxf((va.z - mn.z) * rs.z, 0.f));
            u.w = f2bf(fmaxf((va.w - mn.w) * rs.w, 0.f));
            *(ushort4*)&As[row * 40 + kc] = u;
        }
        for (int i = tid; i < 512; i += TPB) {
            int n = i >> 2, kc = (i & 3) * 8;
            *(bf16x8*)&Bs[n * 40 + kc] = *(const bf16x8*)&ctT[(size_t)(n0 + n) * 128 + k0 + kc];
        }
        __syncthreads();
        bf16x8 af[4], bfr[4];
#pragma unroll
        for (int mi = 0; mi < 4; mi++)
            af[mi] = *(bf16x8*)&As[(wm * 64 + mi * 16 + l16) * 40 + lhi * 8];
#pragma unroll
        for (int ni = 0; ni < 4; ni++)
            bfr[ni] = *(bf16x8*)&Bs[(wn * 64 + ni * 16 + l16) * 40 + lhi * 8];
#pragma unroll
        for (int mi = 0; mi < 4; mi++)
#pragma unroll
            for (int ni = 0; ni < 4; ni++)
                acc[mi][ni] = __builtin_amdgcn_mfma_f32_16x16x32_bf16(af[mi], bfr[ni], acc[mi][ni], 0, 0, 0);
        __syncthreads();
    }
    int Ho = 2 * Hin, Wo = 64;
#pragma unroll
    for (int mi = 0; mi < 4; mi++) {
#pragma unroll
        for (int ni = 0; ni < 4; ni++) {
            int col = n0 + wn * 64 + ni * 16 + l16;
            int oc = col >> 2, aa = (col >> 1) & 1, dd = col & 1;
#pragma unroll
            for (int rg = 0; rg < 4; rg++) {
                int p = m0 + wm * 64 + mi * 16 + lhi * 4 + rg;
                int hin = p >> 5, win = p & 31;
                out[(((size_t)b * 128 + oc) * Ho + 2 * hin + aa) * Wo + 2 * win + dd] =
                    acc[mi][ni][rg];
            }
        }
    }
}

// ---------------------------------------------------------------------------
// bf16 flash attention, both crosses, 2 m-tiles/wave (128 q-rows/block),
// 64-key chunks, swizzled LDS, lane-local l, defer-rescale.
// grid (16, 4, 16): z = cross*8 + b. Output bf16.
// ---------------------------------------------------------------------------
__global__ __launch_bounds__(256, 2) void k_attn_bf16(
        const unsigned short* __restrict__ qb, const unsigned short* __restrict__ kb,
        const unsigned short* __restrict__ vt, unsigned short* __restrict__ aout) {
    __shared__ __align__(16) unsigned short smem[24576];  // 48 KB
    unsigned short* Ks = smem;            // [64][128], slot^row swizzle
    unsigned short* Vt = smem + 8192;     // [128][64], slot^d swizzle
    unsigned short* Ps = smem + 16384;    // 4 waves x [32][64]
    int tid = threadIdx.x;
    int lane = tid & 63, w = tid >> 6;
    int l16 = lane & 15, lhi = lane >> 4;
    int qt = blockIdx.x, h = blockIdx.y, z = blockIdx.z;
    int bh_q = (z & 7) * 4 + h;
    int bh_kv = z * 4 + h;

    const unsigned short* qg = qb + ((size_t)bh_q * 2048 + qt * 128) * 128;
    bf16x8 qa[2][4];
#pragma unroll
    for (int mt = 0; mt < 2; mt++) {
        int r = w * 32 + mt * 16 + l16;
#pragma unroll
        for (int ks = 0; ks < 4; ks++)
            qa[mt][ks] = *(const bf16x8*)&qg[(size_t)r * 128 + ks * 32 + lhi * 8];
    }

    f32x4 acc[2][8];
#pragma unroll
    for (int mt = 0; mt < 2; mt++)
#pragma unroll
        for (int dt = 0; dt < 8; dt++) acc[mt][dt] = (f32x4){0.f, 0.f, 0.f, 0.f};
    float m_r[2][4], l_r[2][4];
#pragma unroll
    for (int mt = 0; mt < 2; mt++)
#pragma unroll
        for (int rg = 0; rg < 4; rg++) { m_r[mt][rg] = -1e30f; l_r[mt][rg] = 0.f; }

    const unsigned short* kg = kb + (size_t)bh_kv * 1024 * 128;
    const unsigned short* vg = vt + (size_t)bh_kv * 128 * 1024;
    unsigned short* Pw = Ps + w * 2048;

    for (int c0 = 0; c0 < 1024; c0 += 64) {
        // stage K: 64 rows x 128, swizzled 16B slots
        for (int i = tid; i < 1024; i += TPB) {
            int row = i >> 4, sl = i & 15;
            *(bf16x8*)&Ks[row * 128 + ((sl ^ (row & 7)) << 3)] =
                *(const bf16x8*)&kg[(size_t)(c0 + row) * 128 + sl * 8];
        }
        // stage V^T: 128 d x 64 keys, swizzled
        for (int i = tid; i < 1024; i += TPB) {
            int d = i >> 3, sl = i & 7;
            *(bf16x8*)&Vt[d * 64 + ((sl ^ (d & 7)) << 3)] =
                *(const bf16x8*)&vg[(size_t)d * 1024 + c0 + sl * 8];
        }
        __syncthreads();

        // QK^T: 32 rows x 64 cols per wave; K-frags shared across m-tiles
        f32x4 s[2][4];
#pragma unroll
        for (int mt = 0; mt < 2; mt++)
#pragma unroll
            for (int nt = 0; nt < 4; nt++) s[mt][nt] = (f32x4){0.f, 0.f, 0.f, 0.f};
#pragma unroll
        for (int nt = 0; nt < 4; nt++) {
            int r = nt * 16 + l16;
#pragma unroll
            for (int ks = 0; ks < 4; ks++) {
                bf16x8 kbf = *(bf16x8*)&Ks[r * 128 + (((ks * 4 + lhi) ^ (r & 7)) << 3)];
                s[0][nt] = __builtin_amdgcn_mfma_f32_16x16x32_bf16(qa[0][ks], kbf, s[0][nt], 0, 0, 0);
                s[1][nt] = __builtin_amdgcn_mfma_f32_16x16x32_bf16(qa[1][ks], kbf, s[1][nt], 0, 0, 0);
            }
        }

        // per-row max + defer-rescale decision
        float pm[2][4];
        bool need = false;
#pragma unroll
        for (int mt = 0; mt < 2; mt++)
#pragma unroll
            for (int rg = 0; rg < 4; rg++) {
                float a = fmaxf(fmaxf(s[mt][0][rg], s[mt][1][rg]),
                                fmaxf(s[mt][2][rg], s[mt][3][rg]));
                a = fmaxf(a, __shfl_xor(a, 1));
                a = fmaxf(a, __shfl_xor(a, 2));
                a = fmaxf(a, __shfl_xor(a, 4));
                a = fmaxf(a, __shfl_xor(a, 8));
                pm[mt][rg] = a;
                need = need || (a > m_r[mt][rg] + 8.f);
            }
        if (__any(need)) {
#pragma unroll
            for (int mt = 0; mt < 2; mt++)
#pragma unroll
                for (int rg = 0; rg < 4; rg++) {
                    float mn = fmaxf(m_r[mt][rg], pm[mt][rg]);
                    float f = __expf(m_r[mt][rg] - mn);
                    m_r[mt][rg] = mn;
                    l_r[mt][rg] *= f;
#pragma unroll
                    for (int dt = 0; dt < 8; dt++) acc[mt][dt][rg] *= f;
                }
        }
        // exponentiate, lane-local l, write P
#pragma unroll
        for (int mt = 0; mt < 2; mt++)
#pragma unroll
            for (int rg = 0; rg < 4; rg++) {
                int row = mt * 16 + lhi * 4 + rg;
                float lsum = 0.f;
#pragma unroll
                for (int nt = 0; nt < 4; nt++) {
                    float p = __expf(s[mt][nt][rg] - m_r[mt][rg]);
                    lsum += p;
                    int col = nt * 16 + l16;
                    Pw[row * 64 + ((((col >> 3) ^ (row & 7)) << 3) | (col & 7))] = f2bf(p);
                }
                l_r[mt][rg] += lsum;
            }
        asm volatile("s_waitcnt lgkmcnt(0)" ::: "memory");

        // PV: V-frags shared across m-tiles
        bf16x8 pa0[2], pa1[2];
#pragma unroll
        for (int mt = 0; mt < 2; mt++) {
            int row = mt * 16 + l16;
            pa0[mt] = *(bf16x8*)&Pw[row * 64 + ((lhi ^ (l16 & 7)) << 3)];
            pa1[mt] = *(bf16x8*)&Pw[row * 64 + (((4 + lhi) ^ (l16 & 7)) << 3)];
        }
#pragma unroll
        for (int dt = 0; dt < 8; dt++) {
            int d = dt * 16 + l16;
            bf16x8 vb0 = *(bf16x8*)&Vt[d * 64 + ((lhi ^ (d & 7)) << 3)];
            bf16x8 vb1 = *(bf16x8*)&Vt[d * 64 + (((4 + lhi) ^ (d & 7)) << 3)];
            acc[0][dt] = __builtin_amdgcn_mfma_f32_16x16x32_bf16(pa0[0], vb0, acc[0][dt], 0, 0, 0);
            acc[0][dt] = __builtin_amdgcn_mfma_f32_16x16x32_bf16(pa1[0], vb1, acc[0][dt], 0, 0, 0);
            acc[1][dt] = __builtin_amdgcn_mfma_f32_16x16x32_bf16(pa0[1], vb0, acc[1][dt], 0, 0, 0);
            acc[1][dt] = __builtin_amdgcn_mfma_f32_16x16x32_bf16(pa1[1], vb1, acc[1][dt], 0, 0, 0);
        }
        __syncthreads();
    }

    size_t obase = (size_t)(z >> 3) * 16384 + (size_t)(z & 7) * 2048;
#pragma unroll
    for (int mt = 0; mt < 2; mt++)
#pragma unroll
        for (int rg = 0; rg < 4; rg++) {
            float lt = l_r[mt][rg];
            lt += __shfl_xor(lt, 1);
            lt += __shfl_xor(lt, 2);
            lt += __shfl_xor(lt, 4);
            lt += __shfl_xor(lt, 8);
            float linv = 1.f / lt;
            int qrow = qt * 128 + w * 32 + mt * 16 + lhi * 4 + rg;
            unsigned short* orow = aout + (obase + qrow) * 512 + h * 128;
#pragma unroll
            for (int dt = 0; dt < 8; dt++)
                orow[dt * 16 + l16] = f2bf(acc[mt][dt][rg] * linv);
        }
}

// ---------------------------------------------------------------------------
// fused_s[b][p][d] = zc[b][p]+zc[b][1024+p]+zl[b][p]+zl[b][1024+p]
// ---------------------------------------------------------------------------
__global__ void k_fused_sum(const float* __restrict__ zc, const float* __restrict__ zl,
                            float* __restrict__ fs) {
    int idx = blockIdx.x * TPB + threadIdx.x;
    int d = idx & 127, p = (idx >> 7) & 1023, b = idx >> 17;
    size_t r0 = ((size_t)b * 2048 + p) * 128 + d;
    size_t r1 = ((size_t)b * 2048 + 1024 + p) * 128 + d;
    fs[((size_t)b * 1024 + p) * 128 + d] = zc[r0] + zc[r1] + zl[r0] + zl[r1];
}

// ---------------------------------------------------------------------------
extern "C" void kernel_launch(void* const* d_in, const int* in_sizes, int n_in,
                              void* d_out, int out_size, void* d_ws, size_t ws_size,
                              hipStream_t stream) {
    const float* cam_feat = (const float*)d_in[0];
    const float* lid_feat = (const float*)d_in[1];
    const float* pos      = (const float*)d_in[2];
    const float* conv_w   = (const float*)d_in[3];
    const float* convT_w  = (const float*)d_in[4];
    const float* lnq_g = (const float*)d_in[5];
    const float* lnq_b = (const float*)d_in[6];
    const float* wq    = (const float*)d_in[7];
    const float* lnk_g = (const float*)d_in[8];
    const float* lnk_b = (const float*)d_in[9];
    const float* wk    = (const float*)d_in[10];
    const float* lnv_g = (const float*)d_in[11];
    const float* lnv_b = (const float*)d_in[12];
    const float* wv    = (const float*)d_in[13];
    const float* proj_w = (const float*)d_in[14];
    const float* proj_b = (const float*)d_in[15];
    const float* pre_g = (const float*)d_in[16];
    const float* pre_b = (const float*)d_in[17];
    const float* mlp_w1 = (const float*)d_in[18];
    const float* mlp_b1 = (const float*)d_in[19];
    const float* mlp_w2 = (const float*)d_in[20];
    const float* mlp_b2 = (const float*)d_in[21];
    const float* post_g = (const float*)d_in[22];
    const float* post_b = (const float*)d_in[23];

    float* ws = (float*)d_ws;
    float* outp = (float*)d_out;

    // persistent buffers (floats)
    float* cam_eT  = ws + 0;               // 1,048,576
    float* lid_eT  = ws + 1048576;         // 1,048,576
    unsigned short* qbf16 = (unsigned short*)(ws + 2097152);   // 4,194,304 f
    float* z_cam   = ws + 6291456;         // 2,097,152
    float* z_lid   = ws + 8388608;         // 2,097,152
    float* fused_s = ws + 10485760;        // 1,048,576
    float* stats   = ws + 11534336;        // 16,384
    unsigned short* wbuf = (unsigned short*)(ws + 11550720);   // 196,608 f
    float* part    = ws + 11747328;        // 131,072
    unsigned short* xcolT = (unsigned short*)(ws + 11878400);  // 4,194,304 f
    float* pool    = ws + 16072704;        // 20,971,520  (total ~148 MB)

    unsigned short* wqT   = wbuf + 0;        // 512x128
    unsigned short* wkT   = wbuf + 65536;    // 512x128
    unsigned short* wvT   = wbuf + 131072;   // 512x128
    unsigned short* projT = wbuf + 196608;   // 128x512
    unsigned short* m1T   = wbuf + 262144;   // 256x128
    unsigned short* m2T   = wbuf + 294912;   // 128x256
    unsigned short* ctT   = wbuf + 327680;   // 512x128

    float* meanA = stats + 0,    *rstdA = stats + 2048;
    float* meanF = stats + 4096, *rstdF = stats + 5120;
    float* meanC = stats + 6144, *rstdC = stats + 7168;
    float* meanL = stats + 8192, *rstdL = stats + 9216;

    // pool (timeline-overlapped)
    float* lnqb  = pool + 0;                                    // 2,097,152
    float* lnkb  = pool + 0;                                    // 2,097,152
    float* lnvb  = pool + 2097152;                              // 2,097,152
    unsigned short* kbf16 = (unsigned short*)(pool + 4194304);  // 4,194,304 f
    unsigned short* vbfT  = (unsigned short*)(pool + 8388608);  // 4,194,304 f
    unsigned short* abuf  = (unsigned short*)(pool + 12582912); // 8,388,608 f
    float* z2    = pool + 0;                                    // 4,194,304
    float* h1    = pool + 4194304;                              // 8,388,608

    const float qscale = 0.08838834764831845f;  // 1/sqrt(128)

    // Weight prep (one launch)
    k_wtrans_all<<<384, TPB, 0, stream>>>(wq, wk, wv, proj_w, mlp_w1, mlp_w2, convT_w,
                                          wqT, wkT, wvT, projT, m1T, m2T, ctT);

    // Stage A: stats + conv encoders
    k_stats_cm<<<2048, TPB, 0, stream>>>(cam_feat, lid_feat, pos, meanA, rstdA);
    k_prep<<<dim3(32, 16), TPB, 0, stream>>>(cam_feat, lid_feat, pos, meanA, rstdA, xcolT);
    k_conv_gemm<<<dim3(16, 1, 16), TPB, 0, stream>>>(conv_w, xcolT, cam_eT, lid_eT);

    // Shared Q (bf16, head-major, pre-scaled)
    k_rowln2<<<4096, TPB, 0, stream>>>(cam_eT, lid_eT, lnqb, lnq_g, lnq_b);
    k_gemm_mfma<128, 128, 2, 2><<<dim3(4, 128), TPB, 0, stream>>>(
        lnqb, wqT, nullptr, qbf16, 16384, 512, 128, 4, nullptr, 11, qscale);

    // K/V for BOTH crosses, then one attention + one tail pipeline
    k_rowln_kv<<<4096, TPB, 0, stream>>>(cam_eT, lid_eT, lnkb, lnvb,
                                         lnk_g, lnk_b, lnv_g, lnv_b);
    k_gemm_mfma<128, 128, 2, 2><<<dim3(4, 128), TPB, 0, stream>>>(
        lnkb, wkT, nullptr, kbf16, 16384, 512, 128, 4, nullptr, 10, 1.f);
    k_gemm_mfma<128, 128, 2, 2><<<dim3(4, 128), TPB, 0, stream>>>(
        lnvb, wvT, nullptr, vbfT, 16384, 512, 128, 7, nullptr, 0, 1.f);
    k_attn_bf16<<<dim3(16, 4, 16), TPB, 0, stream>>>(qbf16, kbf16, vbfT, abuf);
    k_gemm_ln<true><<<512, TPB, 0, stream>>>(
        abuf, projT, z2, nullptr, 512, 0, proj_b, cam_eT, lid_eT, pre_g, pre_b);
    k_gemm_mfma<128, 128, 2, 2><<<dim3(2, 256), TPB, 0, stream>>>(
        z2, m1T, h1, nullptr, 32768, 256, 128, 3, mlp_b1, 0, 1.f);
    k_gemm_ln<false><<<512, TPB, 0, stream>>>(
        h1, m2T, z_cam, z_lid, 256, 1, mlp_b2, z2, nullptr, post_g, post_b);

    // Outputs
    k_fused_sum<<<4096, TPB, 0, stream>>>(z_cam, z_lid, fused_s);
    k_stats_part<<<dim3(16, 8), TPB, 0, stream>>>(fused_s, part, 1024);
    k_stats_red<<<8, 128, 0, stream>>>(part, meanF, rstdF, 16, 1024);
    k_stats_part2<<<dim3(32, 8, 2), TPB, 0, stream>>>(z_cam, z_lid, part);
    k_stats_red2<<<16, 128, 0, stream>>>(part, meanC, rstdC, meanL, rstdL);
    k_convt_gemm<<<dim3(4, 8, 8), TPB, 0, stream>>>(fused_s, meanF, rstdF, ctT, outp, 1024, 32);
    k_convt_gemm<<<dim3(4, 16, 8), TPB, 0, stream>>>(z_cam, meanC, rstdC, ctT, outp + 4194304, 2048, 64);
    k_convt_gemm<<<dim3(4, 16, 8), TPB, 0, stream>>>(z_lid, meanL, rstdL, ctT, outp + 12582912, 2048, 64);
}

// Round 8
// 395.460 us; speedup vs baseline: 13.0152x; 1.2072x over previous
//
#include <hip/hip_runtime.h>
#include <math.h>

#define TPB 256

typedef __attribute__((ext_vector_type(8))) short bf16x8;
typedef __attribute__((ext_vector_type(4))) float f32x4;

__device__ __forceinline__ float gelu_exact(float x) {
    return 0.5f * x * (1.0f + erff(x * 0.70710678118654752f));
}

__device__ __forceinline__ unsigned short f2bf(float x) {
    unsigned u = __float_as_uint(x);
    return (unsigned short)((u + 0x7fffu + ((u >> 16) & 1u)) >> 16);
}

// ---------------------------------------------------------------------------
// Stage-A instance-norm stats (x + pos broadcast), 2048 channels.
// ---------------------------------------------------------------------------
__global__ void k_stats_cm(const float* __restrict__ x0, const float* __restrict__ x1,
                           const float* __restrict__ pos, float* __restrict__ mean,
                           float* __restrict__ rstd) {
    int gc = blockIdx.x;
    const float* src = ((gc < 1024) ? x0 : x1) + (size_t)(gc & 1023) * 4096;
    const float* posr = pos + (size_t)(gc & 127) * 4096;
    float s = 0.f, s2 = 0.f;
    for (int p = threadIdx.x; p < 4096; p += TPB) {
        float v = src[p] + posr[p];
        s += v; s2 += v * v;
    }
#pragma unroll
    for (int m = 32; m; m >>= 1) { s += __shfl_xor(s, m); s2 += __shfl_xor(s2, m); }
    __shared__ float ls[4], ls2[4];
    int w = threadIdx.x >> 6;
    if ((threadIdx.x & 63) == 0) { ls[w] = s; ls2[w] = s2; }
    __syncthreads();
    if (threadIdx.x == 0) {
        s = ls[0] + ls[1] + ls[2] + ls[3];
        s2 = ls2[0] + ls2[1] + ls2[2] + ls2[3];
        float mu = s / 4096.f;
        float var = s2 / 4096.f - mu * mu;
        mean[gc] = mu;
        rstd[gc] = rsqrtf(var + 1e-5f);
    }
}

// ---------------------------------------------------------------------------
// Token-major stats, two-phase.
// ---------------------------------------------------------------------------
__global__ void k_stats_part(const float* __restrict__ z, float* __restrict__ part, int T) {
    int c = blockIdx.x, b = blockIdx.y;
    int tid = threadIdx.x;
    int d = tid & 127, half = tid >> 7;
    const float* base = z + ((size_t)b * T + c * 64) * 128;
    float s = 0.f, s2 = 0.f;
    for (int t = half; t < 64; t += 2) {
        float v = base[t * 128 + d];
        s += v; s2 += v * v;
    }
    __shared__ float ls[256], ls2[256];
    ls[tid] = s; ls2[tid] = s2;
    __syncthreads();
    if (tid < 128) {
        s = ls[tid] + ls[tid + 128];
        s2 = ls2[tid] + ls2[tid + 128];
        float* p = part + ((size_t)(b * gridDim.x + c) * 2) * 128;
        p[d] = s; p[128 + d] = s2;
    }
}

__global__ void k_stats_red(const float* __restrict__ part, float* __restrict__ mean,
                            float* __restrict__ rstd, int nc, int T) {
    int b = blockIdx.x, d = threadIdx.x;
    float s = 0.f, s2 = 0.f;
    for (int c = 0; c < nc; c++) {
        const float* p = part + ((size_t)(b * nc + c) * 2) * 128;
        s += p[d]; s2 += p[128 + d];
    }
    float mu = s / (float)T;
    float var = s2 / (float)T - mu * mu;
    mean[b * 128 + d] = mu;
    rstd[b * 128 + d] = rsqrtf(var + 1e-5f);
}

__global__ void k_stats_part2(const float* __restrict__ zc, const float* __restrict__ zl,
                              float* __restrict__ part) {
    int c = blockIdx.x, b = blockIdx.y, sel = blockIdx.z;
    int tid = threadIdx.x;
    int d = tid & 127, half = tid >> 7;
    const float* base = (sel ? zl : zc) + ((size_t)b * 2048 + c * 64) * 128;
    float s = 0.f, s2 = 0.f;
    for (int t = half; t < 64; t += 2) {
        float v = base[t * 128 + d];
        s += v; s2 += v * v;
    }
    __shared__ float ls[256], ls2[256];
    ls[tid] = s; ls2[tid] = s2;
    __syncthreads();
    if (tid < 128) {
        s = ls[tid] + ls[tid + 128];
        s2 = ls2[tid] + ls2[tid + 128];
        float* p = part + ((size_t)((sel * 8 + b) * 32 + c) * 2) * 128;
        p[d] = s; p[128 + d] = s2;
    }
}

__global__ void k_stats_red2(const float* __restrict__ part,
                             float* __restrict__ meanC, float* __restrict__ rstdC,
                             float* __restrict__ meanL, float* __restrict__ rstdL) {
    int idx = blockIdx.x, d = threadIdx.x;
    int sel = idx >> 3, b = idx & 7;
    float s = 0.f, s2 = 0.f;
    for (int c = 0; c < 32; c++) {
        const float* p = part + ((size_t)((sel * 8 + b) * 32 + c) * 2) * 128;
        s += p[d]; s2 += p[128 + d];
    }
    float mu = s / 2048.f;
    float var = s2 / 2048.f - mu * mu;
    float* mean = sel ? meanL : meanC;
    float* rstd = sel ? rstdL : rstdC;
    mean[b * 128 + d] = mu;
    rstd[b * 128 + d] = rsqrtf(var + 1e-5f);
}

// ---------------------------------------------------------------------------
// Conv prep (cam+lid merged): normalize+ReLU+im2col -> bf16 xcolT[bb][p][512].
// ---------------------------------------------------------------------------
__global__ void k_prep(const float* __restrict__ cam, const float* __restrict__ lid,
                       const float* __restrict__ pos, const float* __restrict__ mean,
                       const float* __restrict__ rstd, unsigned short* __restrict__ xcolT) {
    __shared__ unsigned short T[32 * 520];
    int h = blockIdx.x, bb = blockIdx.y;
    int b = bb & 7, so = (bb < 8) ? 0 : 1024;
    const float* x = (bb < 8) ? cam : lid;
    int tid = threadIdx.x;
    for (int i = tid; i < 4096; i += TPB) {
        int c = i >> 5, w = i & 31;
        int ch = b * 128 + c;
        const float* xr = x + (size_t)ch * 4096 + (2 * h) * 64 + 2 * w;
        const float* pr = pos + (size_t)c * 4096 + (2 * h) * 64 + 2 * w;
        float mu = mean[so + ch], rs = rstd[so + ch];
        float2 x0 = *(const float2*)xr;
        float2 x1 = *(const float2*)(xr + 64);
        float2 p0 = *(const float2*)pr;
        float2 p1 = *(const float2*)(pr + 64);
        ushort4 u;
        u.x = f2bf(fmaxf((x0.x + p0.x - mu) * rs, 0.f));
        u.y = f2bf(fmaxf((x0.y + p0.y - mu) * rs, 0.f));
        u.z = f2bf(fmaxf((x1.x + p1.x - mu) * rs, 0.f));
        u.w = f2bf(fmaxf((x1.y + p1.y - mu) * rs, 0.f));
        *(ushort4*)&T[w * 520 + c * 4] = u;
    }
    __syncthreads();
    unsigned short* dst = xcolT + ((size_t)bb * 1024 + h * 32) * 512;
    for (int i = tid; i < 2048; i += TPB) {
        int w = i >> 6, kk = (i & 63) * 8;
        *(bf16x8*)&dst[(size_t)w * 512 + kk] = *(bf16x8*)&T[w * 520 + kk];
    }
}

// ---------------------------------------------------------------------------
// Conv as batched MFMA GEMM (cam+lid merged). grid (16, 1, 16).
// ---------------------------------------------------------------------------
__global__ __launch_bounds__(256, 2) void k_conv_gemm(
        const float* __restrict__ W, const unsigned short* __restrict__ xcolT,
        float* __restrict__ camT, float* __restrict__ lidT) {
    __shared__ __align__(16) unsigned short As[128 * 40];
    __shared__ __align__(16) unsigned short Bs[64 * 40];
    int tid = threadIdx.x, lane = tid & 63, w = tid >> 6;
    int l16 = lane & 15, lhi = lane >> 4;
    int n0 = blockIdx.x * 64, bb = blockIdx.z;
    const unsigned short* BT = xcolT + (size_t)bb * 524288;
    float* eT = ((bb < 8) ? camT : lidT) + (size_t)(bb & 7) * 131072;

    f32x4 acc[2][4];
#pragma unroll
    for (int mi = 0; mi < 2; mi++)
#pragma unroll
        for (int ni = 0; ni < 4; ni++) acc[mi][ni] = (f32x4){0.f, 0.f, 0.f, 0.f};

    for (int k0 = 0; k0 < 512; k0 += 32) {
        for (int i = tid; i < 1024; i += TPB) {
            int row = i >> 3, kc = (i & 7) * 4;
            float4 va = *(const float4*)&W[(size_t)row * 512 + k0 + kc];
            ushort4 u;
            u.x = f2bf(va.x); u.y = f2bf(va.y); u.z = f2bf(va.z); u.w = f2bf(va.w);
            *(ushort4*)&As[row * 40 + kc] = u;
        }
        for (int i = tid; i < 256; i += TPB) {
            int n = i >> 2, kc = (i & 3) * 8;
            *(bf16x8*)&Bs[n * 40 + kc] = *(const bf16x8*)&BT[(size_t)(n0 + n) * 512 + k0 + kc];
        }
        __syncthreads();
        bf16x8 af[2], bfr[4];
#pragma unroll
        for (int mi = 0; mi < 2; mi++)
            af[mi] = *(bf16x8*)&As[(w * 32 + mi * 16 + l16) * 40 + lhi * 8];
#pragma unroll
        for (int ni = 0; ni < 4; ni++)
            bfr[ni] = *(bf16x8*)&Bs[(ni * 16 + l16) * 40 + lhi * 8];
#pragma unroll
        for (int mi = 0; mi < 2; mi++)
#pragma unroll
            for (int ni = 0; ni < 4; ni++)
                acc[mi][ni] = __builtin_amdgcn_mfma_f32_16x16x32_bf16(af[mi], bfr[ni], acc[mi][ni], 0, 0, 0);
        __syncthreads();
    }
#pragma unroll
    for (int mi = 0; mi < 2; mi++)
#pragma unroll
        for (int ni = 0; ni < 4; ni++) {
            int col = n0 + ni * 16 + l16;
            int rowb = w * 32 + mi * 16 + lhi * 4;
            *(float4*)&eT[(size_t)col * 128 + rowb] = *(float4*)&acc[mi][ni];
        }
}

// ---------------------------------------------------------------------------
// K/V LayerNorm, both crosses: grid 4096 (16384 rows).
// ---------------------------------------------------------------------------
__global__ void k_rowln_kv(const float* __restrict__ camT, const float* __restrict__ lidT,
                           float* __restrict__ outk, float* __restrict__ outv,
                           const float* __restrict__ gk, const float* __restrict__ bk,
                           const float* __restrict__ gv, const float* __restrict__ bv) {
    int r = blockIdx.x * 4 + (threadIdx.x >> 6);
    int lane = threadIdx.x & 63;
    const float* row = ((r < 8192) ? camT : lidT) + (size_t)(r & 8191) * 128;
    float v0 = row[lane], v1 = row[lane + 64];
    float s = v0 + v1, s2 = v0 * v0 + v1 * v1;
#pragma unroll
    for (int m = 32; m; m >>= 1) { s += __shfl_xor(s, m); s2 += __shfl_xor(s2, m); }
    float mu = s * (1.f / 128.f);
    float var = s2 * (1.f / 128.f) - mu * mu;
    float rs = rsqrtf(var + 1e-5f);
    float n0 = (v0 - mu) * rs, n1 = (v1 - mu) * rs;
    outk[(size_t)r * 128 + lane]      = n0 * gk[lane] + bk[lane];
    outk[(size_t)r * 128 + lane + 64] = n1 * gk[lane + 64] + bk[lane + 64];
    outv[(size_t)r * 128 + lane]      = n0 * gv[lane] + bv[lane];
    outv[(size_t)r * 128 + lane + 64] = n1 * gv[lane + 64] + bv[lane + 64];
}

// Q-path LN reading the concat [camT | lidT] along tokens. grid 4096.
__global__ void k_rowln2(const float* __restrict__ camT, const float* __restrict__ lidT,
                         float* __restrict__ out, const float* __restrict__ g,
                         const float* __restrict__ bb) {
    int r = blockIdx.x * 4 + (threadIdx.x >> 6);
    int lane = threadIdx.x & 63;
    int b = r >> 11, t = r & 2047;
    const float* row = ((t < 1024) ? camT : lidT) + ((size_t)(b * 1024 + (t & 1023))) * 128;
    float v0 = row[lane], v1 = row[lane + 64];
    float s = v0 + v1, s2 = v0 * v0 + v1 * v1;
#pragma unroll
    for (int m = 32; m; m >>= 1) { s += __shfl_xor(s, m); s2 += __shfl_xor(s2, m); }
    float mu = s * (1.f / 128.f);
    float var = s2 * (1.f / 128.f) - mu * mu;
    float rs = rsqrtf(var + 1e-5f);
    out[(size_t)r * 128 + lane]      = (v0 - mu) * rs * g[lane] + bb[lane];
    out[(size_t)r * 128 + lane + 64] = (v1 - mu) * rs * g[lane + 64] + bb[lane + 64];
}

// ---------------------------------------------------------------------------
// All weight transposes in one launch. 384 blocks.
// ---------------------------------------------------------------------------
__global__ void k_wtrans_all(
        const float* __restrict__ wq, const float* __restrict__ wk,
        const float* __restrict__ wv, const float* __restrict__ proj,
        const float* __restrict__ m1, const float* __restrict__ m2,
        const float* __restrict__ ct,
        unsigned short* wqT, unsigned short* wkT, unsigned short* wvT,
        unsigned short* projT, unsigned short* m1T, unsigned short* m2T,
        unsigned short* ctT) {
    __shared__ float t[32][33];
    int bid = blockIdx.x;
    const float* W; unsigned short* WT; int K, N, ti;
    if (bid < 64)       { W = wq;   WT = wqT;   K = 128; N = 512; ti = bid; }
    else if (bid < 128) { W = wk;   WT = wkT;   K = 128; N = 512; ti = bid - 64; }
    else if (bid < 192) { W = wv;   WT = wvT;   K = 128; N = 512; ti = bid - 128; }
    else if (bid < 256) { W = proj; WT = projT; K = 512; N = 128; ti = bid - 192; }
    else if (bid < 288) { W = m1;   WT = m1T;   K = 128; N = 256; ti = bid - 256; }
    else if (bid < 320) { W = m2;   WT = m2T;   K = 256; N = 128; ti = bid - 288; }
    else                { W = ct;   WT = ctT;   K = 128; N = 512; ti = bid - 320; }
    int tx = N >> 5;
    int n0 = (ti % tx) * 32, k0 = (ti / tx) * 32;
    int tid = threadIdx.x;
    for (int i = tid; i < 1024; i += TPB) {
        int r = i >> 5, c = i & 31;
        t[r][c] = W[(size_t)(k0 + r) * N + n0 + c];
    }
    __syncthreads();
    for (int i = tid; i < 1024; i += TPB) {
        int r = i >> 5, c = i & 31;
        WT[(size_t)(n0 + r) * K + k0 + c] = f2bf(t[c][r]);
    }
}

// ---------------------------------------------------------------------------
// MFMA bf16 GEMM: C = A[M,K](fp32) @ BT[N,K](bf16).
// mode 3: fp32 C = gelu(v + bias); mode 4: bf16 head-major C16 (scaled);
// mode 7: bf16 transposed head-major (V^T): [bh][d][1024].
// ---------------------------------------------------------------------------
template <int BM, int BN, int WM, int WN>
__global__ __launch_bounds__(256, 2) void k_gemm_mfma(
        const float* __restrict__ A, const unsigned short* __restrict__ BT,
        float* __restrict__ C, unsigned short* __restrict__ C16,
        int M, int N, int K, int mode,
        const float* __restrict__ bias, int sT, float scale) {
    constexpr int MI = BM / WM / 16;
    constexpr int NI = BN / WN / 16;
    __shared__ __align__(16) unsigned short As[BM * 40];
    __shared__ __align__(16) unsigned short Bs[BN * 40];
    int tid = threadIdx.x, lane = tid & 63, w = tid >> 6;
    int l16 = lane & 15, lhi = lane >> 4;
    int wm = w / WN, wn = w % WN;
    int m0 = blockIdx.y * BM, n0 = blockIdx.x * BN;

    f32x4 acc[MI][NI];
#pragma unroll
    for (int mi = 0; mi < MI; mi++)
#pragma unroll
        for (int ni = 0; ni < NI; ni++) acc[mi][ni] = (f32x4){0.f, 0.f, 0.f, 0.f};

    for (int k0 = 0; k0 < K; k0 += 32) {
        for (int i = tid; i < BM * 8; i += TPB) {
            int row = i >> 3, kc = (i & 7) * 4;
            float4 va = *(const float4*)&A[(size_t)(m0 + row) * K + k0 + kc];
            ushort4 u;
            u.x = f2bf(va.x); u.y = f2bf(va.y); u.z = f2bf(va.z); u.w = f2bf(va.w);
            *(ushort4*)&As[row * 40 + kc] = u;
        }
        for (int i = tid; i < BN * 4; i += TPB) {
            int n = i >> 2, kc = (i & 3) * 8;
            *(bf16x8*)&Bs[n * 40 + kc] = *(const bf16x8*)&BT[(size_t)(n0 + n) * K + k0 + kc];
        }
        __syncthreads();
        bf16x8 af[MI], bfr[NI];
#pragma unroll
        for (int mi = 0; mi < MI; mi++)
            af[mi] = *(bf16x8*)&As[(wm * (BM / WM) + mi * 16 + l16) * 40 + lhi * 8];
#pragma unroll
        for (int ni = 0; ni < NI; ni++)
            bfr[ni] = *(bf16x8*)&Bs[(wn * (BN / WN) + ni * 16 + l16) * 40 + lhi * 8];
#pragma unroll
        for (int mi = 0; mi < MI; mi++)
#pragma unroll
            for (int ni = 0; ni < NI; ni++)
                acc[mi][ni] = __builtin_amdgcn_mfma_f32_16x16x32_bf16(af[mi], bfr[ni], acc[mi][ni], 0, 0, 0);
        __syncthreads();
    }
#pragma unroll
    for (int mi = 0; mi < MI; mi++) {
#pragma unroll
        for (int ni = 0; ni < NI; ni++) {
            int col = n0 + wn * (BN / WN) + ni * 16 + l16;
            if (mode == 7) {
                int row0 = m0 + wm * (BM / WM) + mi * 16 + lhi * 4;
                int bb = row0 >> 10, t0 = row0 & 1023;
                ushort4 u;
                u.x = f2bf(acc[mi][ni][0]); u.y = f2bf(acc[mi][ni][1]);
                u.z = f2bf(acc[mi][ni][2]); u.w = f2bf(acc[mi][ni][3]);
                *(ushort4*)&C16[(((size_t)(bb * 4 + (col >> 7))) * 128 + (col & 127)) * 1024 + t0] = u;
            } else {
#pragma unroll
                for (int rg = 0; rg < 4; rg++) {
                    int row = m0 + wm * (BM / WM) + mi * 16 + lhi * 4 + rg;
                    float v = acc[mi][ni][rg];
                    if (mode == 4) {
                        int bb = row >> sT, t = row & ((1 << sT) - 1);
                        size_t oa = ((((size_t)bb * 4 + (col >> 7)) << sT) + t) * 128 + (col & 127);
                        C16[oa] = f2bf(v * scale);
                    } else {  // mode 3
                        C[(size_t)row * N + col] = gelu_exact(v + bias[col]);
                    }
                }
            }
        }
    }
}

// ---------------------------------------------------------------------------
// GEMM (BM=64, BN=128=N) + bias + skip/residual + LayerNorm fused.
// ---------------------------------------------------------------------------
template <bool ABF>
__global__ __launch_bounds__(256, 2) void k_gemm_ln(
        const void* __restrict__ Av, const unsigned short* __restrict__ BT,
        float* __restrict__ C0, float* __restrict__ C1, int K, int mode,
        const float* __restrict__ bias, const float* __restrict__ aux,
        const float* __restrict__ aux2,
        const float* __restrict__ g, const float* __restrict__ bvec) {
    __shared__ __align__(16) char shm[64 * 132 * 4];
    unsigned short* As = (unsigned short*)shm;      // 64*40
    unsigned short* Bs = As + 64 * 40;              // 128*40
    float* Cs = (float*)shm;                        // 64*132 (aliases staging)
    int tid = threadIdx.x, lane = tid & 63, w = tid >> 6;
    int l16 = lane & 15, lhi = lane >> 4;
    int m0 = blockIdx.x * 64;

    f32x4 acc[4][2];
#pragma unroll
    for (int mi = 0; mi < 4; mi++)
#pragma unroll
        for (int ni = 0; ni < 2; ni++) acc[mi][ni] = (f32x4){0.f, 0.f, 0.f, 0.f};

    for (int k0 = 0; k0 < K; k0 += 32) {
        if (ABF) {
            const unsigned short* Ab = (const unsigned short*)Av;
            for (int i = tid; i < 256; i += TPB) {
                int row = i >> 2, kc = (i & 3) * 8;
                *(bf16x8*)&As[row * 40 + kc] =
                    *(const bf16x8*)&Ab[(size_t)(m0 + row) * K + k0 + kc];
            }
        } else {
            const float* Af = (const float*)Av;
            for (int i = tid; i < 512; i += TPB) {
                int row = i >> 3, kc = (i & 7) * 4;
                float4 va = *(const float4*)&Af[(size_t)(m0 + row) * K + k0 + kc];
                ushort4 u;
                u.x = f2bf(va.x); u.y = f2bf(va.y); u.z = f2bf(va.z); u.w = f2bf(va.w);
                *(ushort4*)&As[row * 40 + kc] = u;
            }
        }
        for (int i = tid; i < 512; i += TPB) {
            int n = i >> 2, kc = (i & 3) * 8;
            *(bf16x8*)&Bs[n * 40 + kc] = *(const bf16x8*)&BT[(size_t)n * K + k0 + kc];
        }
        __syncthreads();
        bf16x8 af[4], bfr[2];
#pragma unroll
        for (int mi = 0; mi < 4; mi++)
            af[mi] = *(bf16x8*)&As[(mi * 16 + l16) * 40 + lhi * 8];
#pragma unroll
        for (int ni = 0; ni < 2; ni++)
            bfr[ni] = *(bf16x8*)&Bs[(w * 32 + ni * 16 + l16) * 40 + lhi * 8];
#pragma unroll
        for (int mi = 0; mi < 4; mi++)
#pragma unroll
            for (int ni = 0; ni < 2; ni++)
                acc[mi][ni] = __builtin_amdgcn_mfma_f32_16x16x32_bf16(af[mi], bfr[ni], acc[mi][ni], 0, 0, 0);
        __syncthreads();
    }
#pragma unroll
    for (int mi = 0; mi < 4; mi++) {
#pragma unroll
        for (int ni = 0; ni < 2; ni++) {
            int col = w * 32 + ni * 16 + l16;
#pragma unroll
            for (int rg = 0; rg < 4; rg++) {
                int rl = mi * 16 + lhi * 4 + rg;
                int grow = m0 + rl;
                float v = acc[mi][ni][rg] + bias[col];
                if (mode == 0) {
                    int rr = grow & 16383;
                    int b = rr >> 11, s = rr & 2047;
                    int H = s >> 6, W = s & 63;
                    const float* sp = (W < 32) ? aux : aux2;
                    v += sp[((size_t)(b * 1024 + H * 32 + (W & 31))) * 128 + col];
                } else {
                    v += aux[(size_t)grow * 128 + col];
                }
                Cs[rl * 132 + col] = v;
            }
        }
    }
    __syncthreads();
    for (int rr = 0; rr < 16; rr++) {
        int row = w * 16 + rr, grow = m0 + row;
        float x0 = Cs[row * 132 + lane], x1 = Cs[row * 132 + 64 + lane];
        float s = x0 + x1, s2 = x0 * x0 + x1 * x1;
#pragma unroll
        for (int m = 32; m; m >>= 1) { s += __shfl_xor(s, m); s2 += __shfl_xor(s2, m); }
        float mu = s * (1.f / 128.f);
        float var = s2 * (1.f / 128.f) - mu * mu;
        float rs = rsqrtf(var + 1e-5f);
        float* Cp;
        size_t ro;
        if (mode == 1) { Cp = (grow < 16384) ? C0 : C1; ro = (size_t)(grow & 16383) * 128; }
        else           { Cp = C0; ro = (size_t)grow * 128; }
        Cp[ro + lane]      = (x0 - mu) * rs * g[lane] + bvec[lane];
        Cp[ro + lane + 64] = (x1 - mu) * rs * g[lane + 64] + bvec[lane + 64];
    }
}

// ---------------------------------------------------------------------------
// ConvTranspose as batched MFMA GEMM with fused instance-norm+ReLU on A.
// ---------------------------------------------------------------------------
__global__ __launch_bounds__(256, 2) void k_convt_gemm(
        const float* __restrict__ src, const float* __restrict__ mean,
        const float* __restrict__ rstd, const unsigned short* __restrict__ ctT,
        float* __restrict__ out, int M, int Hin) {
    __shared__ __align__(16) unsigned short As[128 * 40];
    __shared__ __align__(16) unsigned short Bs[128 * 40];
    int tid = threadIdx.x, lane = tid & 63, w = tid >> 6;
    int l16 = lane & 15, lhi = lane >> 4;
    int wm = w >> 1, wn = w & 1;
    int m0 = blockIdx.y * 128, n0 = blockIdx.x * 128, b = blockIdx.z;
    const float* Ab = src + (size_t)b * M * 128;
    const float* mb = mean + b * 128;
    const float* rb = rstd + b * 128;

    f32x4 acc[4][4];
#pragma unroll
    for (int mi = 0; mi < 4; mi++)
#pragma unroll
        for (int ni = 0; ni < 4; ni++) acc[mi][ni] = (f32x4){0.f, 0.f, 0.f, 0.f};

    for (int k0 = 0; k0 < 128; k0 += 32) {
        for (int i = tid; i < 1024; i += TPB) {
            int row = i >> 3, kc = (i & 7) * 4;
            float4 va = *(const float4*)&Ab[(size_t)(m0 + row) * 128 + k0 + kc];
            float4 mn = *(const float4*)&mb[k0 + kc];
            float4 rs = *(const float4*)&rb[k0 + kc];
            ushort4 u;
            u.x = f2bf(fmaxf((va.x - mn.x) * rs.x, 0.f));
            u.y = f2bf(fmaxf((va.y - mn.y) * rs.y, 0.f));
            u.z = f2bf(fmaxf((va.z - mn.z) * rs.z, 0.f));
            u.w = f2bf(fmaxf((va.w - mn.w) * rs.w, 0.f));
            *(ushort4*)&As[row * 40 + kc] = u;
        }
        for (int i = tid; i < 512; i += TPB) {
            int n = i >> 2, kc = (i & 3) * 8;
            *(bf16x8*)&Bs[n * 40 + kc] = *(const bf16x8*)&ctT[(size_t)(n0 + n) * 128 + k0 + kc];
        }
        __syncthreads();
        bf16x8 af[4], bfr[4];
#pragma unroll
        for (int mi = 0; mi < 4; mi++)
            af[mi] = *(bf16x8*)&As[(wm * 64 + mi * 16 + l16) * 40 + lhi * 8];
#pragma unroll
        for (int ni = 0; ni < 4; ni++)
            bfr[ni] = *(bf16x8*)&Bs[(wn * 64 + ni * 16 + l16) * 40 + lhi * 8];
#pragma unroll
        for (int mi = 0; mi < 4; mi++)
#pragma unroll
            for (int ni = 0; ni < 4; ni++)
                acc[mi][ni] = __builtin_amdgcn_mfma_f32_16x16x32_bf16(af[mi], bfr[ni], acc[mi][ni], 0, 0, 0);
        __syncthreads();
    }
    int Ho = 2 * Hin, Wo = 64;
#pragma unroll
    for (int mi = 0; mi < 4; mi++) {
#pragma unroll
        for (int ni = 0; ni < 4; ni++) {
            int col = n0 + wn * 64 + ni * 16 + l16;
            int oc = col >> 2, aa = (col >> 1) & 1, dd = col & 1;
#pragma unroll
            for (int rg = 0; rg < 4; rg++) {
                int p = m0 + wm * 64 + mi * 16 + lhi * 4 + rg;
                int hin = p >> 5, win = p & 31;
                out[(((size_t)b * 128 + oc) * Ho + 2 * hin + aa) * Wo + 2 * win + dd] =
                    acc[mi][ni][rg];
            }
        }
    }
}

// ---------------------------------------------------------------------------
// bf16 flash attention, swapped-QK^T softmax (S^T: keys in registers),
// exp2 domain (Q pre-scaled by log2e/sqrt(d)), cvt_pk bf16 packing,
// async-stage prefetch (T14). 128 q-rows/block, 64-key chunks.
// grid (16, 4, 16): z = cross*8 + b. Output bf16.
// ---------------------------------------------------------------------------
__global__ __launch_bounds__(256, 2) void k_attn_bf16(
        const unsigned short* __restrict__ qb, const unsigned short* __restrict__ kb,
        const unsigned short* __restrict__ vt, unsigned short* __restrict__ aout) {
    __shared__ __align__(16) unsigned short smem[24576];  // 48 KB
    unsigned short* Ks = smem;            // [64][128], 16B-slot ^row swizzle
    unsigned short* Vt = smem + 8192;     // [128][64], ^d swizzle
    unsigned short* Ps = smem + 16384;    // 4 waves x [32][64], ^row swizzle
    int tid = threadIdx.x;
    int lane = tid & 63, w = tid >> 6;
    int l16 = lane & 15, lhi = lane >> 4;
    int qt = blockIdx.x, h = blockIdx.y, z = blockIdx.z;
    int bh_q = (z & 7) * 4 + h;
    int bh_kv = z * 4 + h;

    const unsigned short* qg = qb + ((size_t)bh_q * 2048 + qt * 128) * 128;
    bf16x8 qa[2][4];
#pragma unroll
    for (int mt = 0; mt < 2; mt++) {
        int r = w * 32 + mt * 16 + l16;
#pragma unroll
        for (int ks = 0; ks < 4; ks++)
            qa[mt][ks] = *(const bf16x8*)&qg[(size_t)r * 128 + ks * 32 + lhi * 8];
    }

    f32x4 acc[2][8];
#pragma unroll
    for (int mt = 0; mt < 2; mt++)
#pragma unroll
        for (int dt = 0; dt < 8; dt++) acc[mt][dt] = (f32x4){0.f, 0.f, 0.f, 0.f};
    float m_r[2] = {-1e30f, -1e30f};
    float l_r[2] = {0.f, 0.f};

    const unsigned short* kg = kb + (size_t)bh_kv * 131072;
    const unsigned short* vg = vt + (size_t)bh_kv * 131072;
    unsigned short* Pw = Ps + w * 2048;

    // per-thread staging coordinates (identical for every chunk)
    int krow = tid >> 4, kcol = (tid & 15) * 8;
    int kls = ((tid & 15) ^ (krow & 7)) << 3;
    int vrow = tid >> 3, vcol = (tid & 7) * 8;
    int vls = ((tid & 7) ^ (vrow & 7)) << 3;

    // prologue: stage chunk 0 directly
#pragma unroll
    for (int j = 0; j < 4; j++) {
        int r = krow + j * 16;
        *(bf16x8*)&Ks[r * 128 + kls] = *(const bf16x8*)&kg[(size_t)r * 128 + kcol];
        int d = vrow + j * 32;
        *(bf16x8*)&Vt[d * 64 + vls] = *(const bf16x8*)&vg[(size_t)d * 1024 + vcol];
    }
    __syncthreads();

    for (int c = 0; c < 16; c++) {
        // issue next-chunk loads early (latency hides under compute)
        bf16x8 kpre[4], vpre[4];
        if (c < 15) {
            int c0 = (c + 1) * 64;
#pragma unroll
            for (int j = 0; j < 4; j++) {
                kpre[j] = *(const bf16x8*)&kg[(size_t)(c0 + krow + j * 16) * 128 + kcol];
                vpre[j] = *(const bf16x8*)&vg[(size_t)(vrow + j * 32) * 1024 + c0 + vcol];
            }
        }

        // QK^T swapped: S^T[key][q]; K-frags shared across m-tiles
        f32x4 s[2][4];
#pragma unroll
        for (int mt = 0; mt < 2; mt++)
#pragma unroll
            for (int kt = 0; kt < 4; kt++) s[mt][kt] = (f32x4){0.f, 0.f, 0.f, 0.f};
#pragma unroll
        for (int kt = 0; kt < 4; kt++) {
            int r = kt * 16 + l16;
#pragma unroll
            for (int ks = 0; ks < 4; ks++) {
                bf16x8 kf = *(bf16x8*)&Ks[r * 128 + (((ks * 4 + lhi) ^ (r & 7)) << 3)];
                s[0][kt] = __builtin_amdgcn_mfma_f32_16x16x32_bf16(kf, qa[0][ks], s[0][kt], 0, 0, 0);
                s[1][kt] = __builtin_amdgcn_mfma_f32_16x16x32_bf16(kf, qa[1][ks], s[1][kt], 0, 0, 0);
            }
        }

        // row max: 15 in-register fmax + 2 cross-lhi shfl per m-tile
        float pm[2];
#pragma unroll
        for (int mt = 0; mt < 2; mt++) {
            float a = s[mt][0][0];
#pragma unroll
            for (int kt = 0; kt < 4; kt++)
#pragma unroll
                for (int rg = 0; rg < 4; rg++) a = fmaxf(a, s[mt][kt][rg]);
            a = fmaxf(a, __shfl_xor(a, 16));
            a = fmaxf(a, __shfl_xor(a, 32));
            pm[mt] = a;
        }
        bool need = (pm[0] > m_r[0] + 8.f) || (pm[1] > m_r[1] + 8.f);
        if (__any(need)) {
#pragma unroll
            for (int mt = 0; mt < 2; mt++) {
                float mn = fmaxf(m_r[mt], pm[mt]);
                float f = __builtin_amdgcn_exp2f(m_r[mt] - mn);
                m_r[mt] = mn;
                l_r[mt] *= f;
#pragma unroll
                for (int rg = 0; rg < 4; rg++) {
                    float ft = __shfl(f, lhi * 4 + rg);
#pragma unroll
                    for (int dt = 0; dt < 8; dt++) acc[mt][dt][rg] *= ft;
                }
            }
        }

        // p = exp2(s-m); lane-local l; pack pairs via v_cvt_pk_bf16_f32
#pragma unroll
        for (int mt = 0; mt < 2; mt++) {
            int row = mt * 16 + l16;
            int rsw = row & 7;
            float ls = 0.f;
#pragma unroll
            for (int kt = 0; kt < 4; kt++) {
                float p0 = __builtin_amdgcn_exp2f(s[mt][kt][0] - m_r[mt]);
                float p1 = __builtin_amdgcn_exp2f(s[mt][kt][1] - m_r[mt]);
                float p2 = __builtin_amdgcn_exp2f(s[mt][kt][2] - m_r[mt]);
                float p3 = __builtin_amdgcn_exp2f(s[mt][kt][3] - m_r[mt]);
                ls += (p0 + p1) + (p2 + p3);
                unsigned u01, u23;
                asm("v_cvt_pk_bf16_f32 %0, %1, %2" : "=v"(u01) : "v"(p0), "v"(p1));
                asm("v_cvt_pk_bf16_f32 %0, %1, %2" : "=v"(u23) : "v"(p2), "v"(p3));
                int slot = kt * 2 + (lhi >> 1);
                int base = row * 64 + ((slot ^ rsw) << 3) + (lhi & 1) * 4;
                *(unsigned*)&Pw[base] = u01;
                *(unsigned*)&Pw[base + 2] = u23;
            }
            l_r[mt] += ls;
        }
        asm volatile("s_waitcnt lgkmcnt(0)" ::: "memory");

        // PV: V-frags shared across m-tiles
        bf16x8 pa0[2], pa1[2];
#pragma unroll
        for (int mt = 0; mt < 2; mt++) {
            int row = mt * 16 + l16;
            pa0[mt] = *(bf16x8*)&Pw[row * 64 + ((lhi ^ (row & 7)) << 3)];
            pa1[mt] = *(bf16x8*)&Pw[row * 64 + (((4 + lhi) ^ (row & 7)) << 3)];
        }
#pragma unroll
        for (int dt = 0; dt < 8; dt++) {
            int d = dt * 16 + l16;
            bf16x8 vb0 = *(bf16x8*)&Vt[d * 64 + ((lhi ^ (d & 7)) << 3)];
            bf16x8 vb1 = *(bf16x8*)&Vt[d * 64 + (((4 + lhi) ^ (d & 7)) << 3)];
            acc[0][dt] = __builtin_amdgcn_mfma_f32_16x16x32_bf16(pa0[0], vb0, acc[0][dt], 0, 0, 0);
            acc[0][dt] = __builtin_amdgcn_mfma_f32_16x16x32_bf16(pa1[0], vb1, acc[0][dt], 0, 0, 0);
            acc[1][dt] = __builtin_amdgcn_mfma_f32_16x16x32_bf16(pa0[1], vb0, acc[1][dt], 0, 0, 0);
            acc[1][dt] = __builtin_amdgcn_mfma_f32_16x16x32_bf16(pa1[1], vb1, acc[1][dt], 0, 0, 0);
        }
        __syncthreads();

        // write prefetched chunk to LDS (global latency already absorbed)
        if (c < 15) {
#pragma unroll
            for (int j = 0; j < 4; j++) {
                *(bf16x8*)&Ks[(krow + j * 16) * 128 + kls] = kpre[j];
                *(bf16x8*)&Vt[(vrow + j * 32) * 64 + vls] = vpre[j];
            }
            __syncthreads();
        }
    }

    // epilogue: reduce l across lhi, transpose via shfl, write O (bf16)
#pragma unroll
    for (int mt = 0; mt < 2; mt++) {
        float lt = l_r[mt];
        lt += __shfl_xor(lt, 16);
        lt += __shfl_xor(lt, 32);
        l_r[mt] = lt;
    }
    size_t obase = (size_t)(z >> 3) * 16384 + (size_t)(z & 7) * 2048;
#pragma unroll
    for (int mt = 0; mt < 2; mt++)
#pragma unroll
        for (int rg = 0; rg < 4; rg++) {
            float linv = 1.f / __shfl(l_r[mt], lhi * 4 + rg);
            int qrow = qt * 128 + w * 32 + mt * 16 + lhi * 4 + rg;
            unsigned short* orow = aout + (obase + qrow) * 512 + h * 128;
#pragma unroll
            for (int dt = 0; dt < 8; dt++)
                orow[dt * 16 + l16] = f2bf(acc[mt][dt][rg] * linv);
        }
}

// ---------------------------------------------------------------------------
// fused_s[b][p][d] = zc[b][p]+zc[b][1024+p]+zl[b][p]+zl[b][1024+p]
// ---------------------------------------------------------------------------
__global__ void k_fused_sum(const float* __restrict__ zc, const float* __restrict__ zl,
                            float* __restrict__ fs) {
    int idx = blockIdx.x * TPB + threadIdx.x;
    int d = idx & 127, p = (idx >> 7) & 1023, b = idx >> 17;
    size_t r0 = ((size_t)b * 2048 + p) * 128 + d;
    size_t r1 = ((size_t)b * 2048 + 1024 + p) * 128 + d;
    fs[((size_t)b * 1024 + p) * 128 + d] = zc[r0] + zc[r1] + zl[r0] + zl[r1];
}

// ---------------------------------------------------------------------------
extern "C" void kernel_launch(void* const* d_in, const int* in_sizes, int n_in,
                              void* d_out, int out_size, void* d_ws, size_t ws_size,
                              hipStream_t stream) {
    const float* cam_feat = (const float*)d_in[0];
    const float* lid_feat = (const float*)d_in[1];
    const float* pos      = (const float*)d_in[2];
    const float* conv_w   = (const float*)d_in[3];
    const float* convT_w  = (const float*)d_in[4];
    const float* lnq_g = (const float*)d_in[5];
    const float* lnq_b = (const float*)d_in[6];
    const float* wq    = (const float*)d_in[7];
    const float* lnk_g = (const float*)d_in[8];
    const float* lnk_b = (const float*)d_in[9];
    const float* wk    = (const float*)d_in[10];
    const float* lnv_g = (const float*)d_in[11];
    const float* lnv_b = (const float*)d_in[12];
    const float* wv    = (const float*)d_in[13];
    const float* proj_w = (const float*)d_in[14];
    const float* proj_b = (const float*)d_in[15];
    const float* pre_g = (const float*)d_in[16];
    const float* pre_b = (const float*)d_in[17];
    const float* mlp_w1 = (const float*)d_in[18];
    const float* mlp_b1 = (const float*)d_in[19];
    const float* mlp_w2 = (const float*)d_in[20];
    const float* mlp_b2 = (const float*)d_in[21];
    const float* post_g = (const float*)d_in[22];
    const float* post_b = (const float*)d_in[23];

    float* ws = (float*)d_ws;
    float* outp = (float*)d_out;

    // persistent buffers (floats)
    float* cam_eT  = ws + 0;               // 1,048,576
    float* lid_eT  = ws + 1048576;         // 1,048,576
    unsigned short* qbf16 = (unsigned short*)(ws + 2097152);   // 4,194,304 f
    float* z_cam   = ws + 6291456;         // 2,097,152
    float* z_lid   = ws + 8388608;         // 2,097,152
    float* fused_s = ws + 10485760;        // 1,048,576
    float* stats   = ws + 11534336;        // 16,384
    unsigned short* wbuf = (unsigned short*)(ws + 11550720);   // 196,608 f
    float* part    = ws + 11747328;        // 131,072
    unsigned short* xcolT = (unsigned short*)(ws + 11878400);  // 4,194,304 f
    float* pool    = ws + 16072704;        // 20,971,520  (total ~148 MB)

    unsigned short* wqT   = wbuf + 0;        // 512x128
    unsigned short* wkT   = wbuf + 65536;    // 512x128
    unsigned short* wvT   = wbuf + 131072;   // 512x128
    unsigned short* projT = wbuf + 196608;   // 128x512
    unsigned short* m1T   = wbuf + 262144;   // 256x128
    unsigned short* m2T   = wbuf + 294912;   // 128x256
    unsigned short* ctT   = wbuf + 327680;   // 512x128

    float* meanA = stats + 0,    *rstdA = stats + 2048;
    float* meanF = stats + 4096, *rstdF = stats + 5120;
    float* meanC = stats + 6144, *rstdC = stats + 7168;
    float* meanL = stats + 8192, *rstdL = stats + 9216;

    // pool (timeline-overlapped)
    float* lnqb  = pool + 0;                                    // 2,097,152
    float* lnkb  = pool + 0;                                    // 2,097,152
    float* lnvb  = pool + 2097152;                              // 2,097,152
    unsigned short* kbf16 = (unsigned short*)(pool + 4194304);  // 4,194,304 f
    unsigned short* vbfT  = (unsigned short*)(pool + 8388608);  // 4,194,304 f
    unsigned short* abuf  = (unsigned short*)(pool + 12582912); // 8,388,608 f
    float* z2    = pool + 0;                                    // 4,194,304
    float* h1    = pool + 4194304;                              // 8,388,608

    // 1/sqrt(128) * log2(e): attention runs softmax in the exp2 domain
    const float qscale = 0.12751744436f;

    // Weight prep (one launch)
    k_wtrans_all<<<384, TPB, 0, stream>>>(wq, wk, wv, proj_w, mlp_w1, mlp_w2, convT_w,
                                          wqT, wkT, wvT, projT, m1T, m2T, ctT);

    // Stage A: stats + conv encoders
    k_stats_cm<<<2048, TPB, 0, stream>>>(cam_feat, lid_feat, pos, meanA, rstdA);
    k_prep<<<dim3(32, 16), TPB, 0, stream>>>(cam_feat, lid_feat, pos, meanA, rstdA, xcolT);
    k_conv_gemm<<<dim3(16, 1, 16), TPB, 0, stream>>>(conv_w, xcolT, cam_eT, lid_eT);

    // Shared Q (bf16, head-major, pre-scaled into log2 domain)
    k_rowln2<<<4096, TPB, 0, stream>>>(cam_eT, lid_eT, lnqb, lnq_g, lnq_b);
    k_gemm_mfma<128, 128, 2, 2><<<dim3(4, 128), TPB, 0, stream>>>(
        lnqb, wqT, nullptr, qbf16, 16384, 512, 128, 4, nullptr, 11, qscale);

    // K/V for BOTH crosses, then one attention + one tail pipeline
    k_rowln_kv<<<4096, TPB, 0, stream>>>(cam_eT, lid_eT, lnkb, lnvb,
                                         lnk_g, lnk_b, lnv_g, lnv_b);
    k_gemm_mfma<128, 128, 2, 2><<<dim3(4, 128), TPB, 0, stream>>>(
        lnkb, wkT, nullptr, kbf16, 16384, 512, 128, 4, nullptr, 10, 1.f);
    k_gemm_mfma<128, 128, 2, 2><<<dim3(4, 128), TPB, 0, stream>>>(
        lnvb, wvT, nullptr, vbfT, 16384, 512, 128, 7, nullptr, 0, 1.f);
    k_attn_bf16<<<dim3(16, 4, 16), TPB, 0, stream>>>(qbf16, kbf16, vbfT, abuf);
    k_gemm_ln<true><<<512, TPB, 0, stream>>>(
        abuf, projT, z2, nullptr, 512, 0, proj_b, cam_eT, lid_eT, pre_g, pre_b);
    k_gemm_mfma<128, 128, 2, 2><<<dim3(2, 256), TPB, 0, stream>>>(
        z2, m1T, h1, nullptr, 32768, 256, 128, 3, mlp_b1, 0, 1.f);
    k_gemm_ln<false><<<512, TPB, 0, stream>>>(
        h1, m2T, z_cam, z_lid, 256, 1, mlp_b2, z2, nullptr, post_g, post_b);

    // Outputs
    k_fused_sum<<<4096, TPB, 0, stream>>>(z_cam, z_lid, fused_s);
    k_stats_part<<<dim3(16, 8), TPB, 0, stream>>>(fused_s, part, 1024);
    k_stats_red<<<8, 128, 0, stream>>>(part, meanF, rstdF, 16, 1024);
    k_stats_part2<<<dim3(32, 8, 2), TPB, 0, stream>>>(z_cam, z_lid, part);
    k_stats_red2<<<16, 128, 0, stream>>>(part, meanC, rstdC, meanL, rstdL);
    k_convt_gemm<<<dim3(4, 8, 8), TPB, 0, stream>>>(fused_s, meanF, rstdF, ctT, outp, 1024, 32);
    k_convt_gemm<<<dim3(4, 16, 8), TPB, 0, stream>>>(z_cam, meanC, rstdC, ctT, outp + 4194304, 2048, 64);
    k_convt_gemm<<<dim3(4, 16, 8), TPB, 0, stream>>>(z_lid, meanL, rstdL, ctT, outp + 12582912, 2048, 64);
}

// Round 9
// 365.198 us; speedup vs baseline: 14.0937x; 1.0829x over previous
//
#include <hip/hip_runtime.h>
#include <math.h>

#define TPB 256

typedef __attribute__((ext_vector_type(8))) short bf16x8;
typedef __attribute__((ext_vector_type(4))) float f32x4;

__device__ __forceinline__ float gelu_exact(float x) {
    return 0.5f * x * (1.0f + erff(x * 0.70710678118654752f));
}

__device__ __forceinline__ unsigned short f2bf(float x) {
    unsigned u = __float_as_uint(x);
    return (unsigned short)((u + 0x7fffu + ((u >> 16) & 1u)) >> 16);
}

// ---------------------------------------------------------------------------
// Stage-A instance-norm stats (x + pos broadcast), 2048 channels.
// ---------------------------------------------------------------------------
__global__ void k_stats_cm(const float* __restrict__ x0, const float* __restrict__ x1,
                           const float* __restrict__ pos, float* __restrict__ mean,
                           float* __restrict__ rstd) {
    int gc = blockIdx.x;
    const float* src = ((gc < 1024) ? x0 : x1) + (size_t)(gc & 1023) * 4096;
    const float* posr = pos + (size_t)(gc & 127) * 4096;
    float s = 0.f, s2 = 0.f;
    for (int p = threadIdx.x; p < 4096; p += TPB) {
        float v = src[p] + posr[p];
        s += v; s2 += v * v;
    }
#pragma unroll
    for (int m = 32; m; m >>= 1) { s += __shfl_xor(s, m); s2 += __shfl_xor(s2, m); }
    __shared__ float ls[4], ls2[4];
    int w = threadIdx.x >> 6;
    if ((threadIdx.x & 63) == 0) { ls[w] = s; ls2[w] = s2; }
    __syncthreads();
    if (threadIdx.x == 0) {
        s = ls[0] + ls[1] + ls[2] + ls[3];
        s2 = ls2[0] + ls2[1] + ls2[2] + ls2[3];
        float mu = s / 4096.f;
        float var = s2 / 4096.f - mu * mu;
        mean[gc] = mu;
        rstd[gc] = rsqrtf(var + 1e-5f);
    }
}

// ---------------------------------------------------------------------------
// Token-major stats, two-phase.
// ---------------------------------------------------------------------------
__global__ void k_stats_part(const float* __restrict__ z, float* __restrict__ part, int T) {
    int c = blockIdx.x, b = blockIdx.y;
    int tid = threadIdx.x;
    int d = tid & 127, half = tid >> 7;
    const float* base = z + ((size_t)b * T + c * 64) * 128;
    float s = 0.f, s2 = 0.f;
    for (int t = half; t < 64; t += 2) {
        float v = base[t * 128 + d];
        s += v; s2 += v * v;
    }
    __shared__ float ls[256], ls2[256];
    ls[tid] = s; ls2[tid] = s2;
    __syncthreads();
    if (tid < 128) {
        s = ls[tid] + ls[tid + 128];
        s2 = ls2[tid] + ls2[tid + 128];
        float* p = part + ((size_t)(b * gridDim.x + c) * 2) * 128;
        p[d] = s; p[128 + d] = s2;
    }
}

__global__ void k_stats_red(const float* __restrict__ part, float* __restrict__ mean,
                            float* __restrict__ rstd, int nc, int T) {
    int b = blockIdx.x, d = threadIdx.x;
    float s = 0.f, s2 = 0.f;
    for (int c = 0; c < nc; c++) {
        const float* p = part + ((size_t)(b * nc + c) * 2) * 128;
        s += p[d]; s2 += p[128 + d];
    }
    float mu = s / (float)T;
    float var = s2 / (float)T - mu * mu;
    mean[b * 128 + d] = mu;
    rstd[b * 128 + d] = rsqrtf(var + 1e-5f);
}

__global__ void k_stats_part2(const float* __restrict__ zc, const float* __restrict__ zl,
                              float* __restrict__ part) {
    int c = blockIdx.x, b = blockIdx.y, sel = blockIdx.z;
    int tid = threadIdx.x;
    int d = tid & 127, half = tid >> 7;
    const float* base = (sel ? zl : zc) + ((size_t)b * 2048 + c * 64) * 128;
    float s = 0.f, s2 = 0.f;
    for (int t = half; t < 64; t += 2) {
        float v = base[t * 128 + d];
        s += v; s2 += v * v;
    }
    __shared__ float ls[256], ls2[256];
    ls[tid] = s; ls2[tid] = s2;
    __syncthreads();
    if (tid < 128) {
        s = ls[tid] + ls[tid + 128];
        s2 = ls2[tid] + ls2[tid + 128];
        float* p = part + ((size_t)((sel * 8 + b) * 32 + c) * 2) * 128;
        p[d] = s; p[128 + d] = s2;
    }
}

__global__ void k_stats_red2(const float* __restrict__ part,
                             float* __restrict__ meanC, float* __restrict__ rstdC,
                             float* __restrict__ meanL, float* __restrict__ rstdL) {
    int idx = blockIdx.x, d = threadIdx.x;
    int sel = idx >> 3, b = idx & 7;
    float s = 0.f, s2 = 0.f;
    for (int c = 0; c < 32; c++) {
        const float* p = part + ((size_t)((sel * 8 + b) * 32 + c) * 2) * 128;
        s += p[d]; s2 += p[128 + d];
    }
    float mu = s / 2048.f;
    float var = s2 / 2048.f - mu * mu;
    float* mean = sel ? meanL : meanC;
    float* rstd = sel ? rstdL : rstdC;
    mean[b * 128 + d] = mu;
    rstd[b * 128 + d] = rsqrtf(var + 1e-5f);
}

// ---------------------------------------------------------------------------
// Conv prep (cam+lid merged): normalize+ReLU+im2col -> bf16 xcolT[bb][p][512].
// ---------------------------------------------------------------------------
__global__ void k_prep(const float* __restrict__ cam, const float* __restrict__ lid,
                       const float* __restrict__ pos, const float* __restrict__ mean,
                       const float* __restrict__ rstd, unsigned short* __restrict__ xcolT) {
    __shared__ unsigned short T[32 * 520];
    int h = blockIdx.x, bb = blockIdx.y;
    int b = bb & 7, so = (bb < 8) ? 0 : 1024;
    const float* x = (bb < 8) ? cam : lid;
    int tid = threadIdx.x;
    for (int i = tid; i < 4096; i += TPB) {
        int c = i >> 5, w = i & 31;
        int ch = b * 128 + c;
        const float* xr = x + (size_t)ch * 4096 + (2 * h) * 64 + 2 * w;
        const float* pr = pos + (size_t)c * 4096 + (2 * h) * 64 + 2 * w;
        float mu = mean[so + ch], rs = rstd[so + ch];
        float2 x0 = *(const float2*)xr;
        float2 x1 = *(const float2*)(xr + 64);
        float2 p0 = *(const float2*)pr;
        float2 p1 = *(const float2*)(pr + 64);
        ushort4 u;
        u.x = f2bf(fmaxf((x0.x + p0.x - mu) * rs, 0.f));
        u.y = f2bf(fmaxf((x0.y + p0.y - mu) * rs, 0.f));
        u.z = f2bf(fmaxf((x1.x + p1.x - mu) * rs, 0.f));
        u.w = f2bf(fmaxf((x1.y + p1.y - mu) * rs, 0.f));
        *(ushort4*)&T[w * 520 + c * 4] = u;
    }
    __syncthreads();
    unsigned short* dst = xcolT + ((size_t)bb * 1024 + h * 32) * 512;
    for (int i = tid; i < 2048; i += TPB) {
        int w = i >> 6, kk = (i & 63) * 8;
        *(bf16x8*)&dst[(size_t)w * 512 + kk] = *(bf16x8*)&T[w * 520 + kk];
    }
}

// ---------------------------------------------------------------------------
// Conv as batched MFMA GEMM (cam+lid merged) + per-token LN stats epilogue.
// Block covers ALL 128 out-channels for 64 tokens -> can emit mean/rstd.
// grid (16, 1, 16).
// ---------------------------------------------------------------------------
__global__ __launch_bounds__(256, 2) void k_conv_gemm(
        const float* __restrict__ W, const unsigned short* __restrict__ xcolT,
        float* __restrict__ camT, float* __restrict__ lidT,
        float* __restrict__ mean_e, float* __restrict__ rstd_e) {
    __shared__ __align__(16) unsigned short As[128 * 40];
    __shared__ __align__(16) unsigned short Bs[64 * 40];
    __shared__ float red[2048];  // [2][4 ni][16 l16][16 w*4+lhi]
    int tid = threadIdx.x, lane = tid & 63, w = tid >> 6;
    int l16 = lane & 15, lhi = lane >> 4;
    int n0 = blockIdx.x * 64, bb = blockIdx.z;
    const unsigned short* BT = xcolT + (size_t)bb * 524288;
    float* eT = ((bb < 8) ? camT : lidT) + (size_t)(bb & 7) * 131072;

    f32x4 acc[2][4];
#pragma unroll
    for (int mi = 0; mi < 2; mi++)
#pragma unroll
        for (int ni = 0; ni < 4; ni++) acc[mi][ni] = (f32x4){0.f, 0.f, 0.f, 0.f};

    for (int k0 = 0; k0 < 512; k0 += 32) {
        for (int i = tid; i < 1024; i += TPB) {
            int row = i >> 3, kc = (i & 7) * 4;
            float4 va = *(const float4*)&W[(size_t)row * 512 + k0 + kc];
            ushort4 u;
            u.x = f2bf(va.x); u.y = f2bf(va.y); u.z = f2bf(va.z); u.w = f2bf(va.w);
            *(ushort4*)&As[row * 40 + kc] = u;
        }
        for (int i = tid; i < 256; i += TPB) {
            int n = i >> 2, kc = (i & 3) * 8;
            *(bf16x8*)&Bs[n * 40 + kc] = *(const bf16x8*)&BT[(size_t)(n0 + n) * 512 + k0 + kc];
        }
        __syncthreads();
        bf16x8 af[2], bfr[4];
#pragma unroll
        for (int mi = 0; mi < 2; mi++)
            af[mi] = *(bf16x8*)&As[(w * 32 + mi * 16 + l16) * 40 + lhi * 8];
#pragma unroll
        for (int ni = 0; ni < 4; ni++)
            bfr[ni] = *(bf16x8*)&Bs[(ni * 16 + l16) * 40 + lhi * 8];
#pragma unroll
        for (int mi = 0; mi < 2; mi++)
#pragma unroll
            for (int ni = 0; ni < 4; ni++)
                acc[mi][ni] = __builtin_amdgcn_mfma_f32_16x16x32_bf16(af[mi], bfr[ni], acc[mi][ni], 0, 0, 0);
        __syncthreads();
    }
#pragma unroll
    for (int mi = 0; mi < 2; mi++)
#pragma unroll
        for (int ni = 0; ni < 4; ni++) {
            int col = n0 + ni * 16 + l16;
            int rowb = w * 32 + mi * 16 + lhi * 4;
            *(float4*)&eT[(size_t)col * 128 + rowb] = *(float4*)&acc[mi][ni];
        }
    // per-token LN stats: reduce 128 channels per col
#pragma unroll
    for (int ni = 0; ni < 4; ni++) {
        float s = 0.f, s2 = 0.f;
#pragma unroll
        for (int mi = 0; mi < 2; mi++)
#pragma unroll
            for (int rg = 0; rg < 4; rg++) {
                float v = acc[mi][ni][rg];
                s += v; s2 += v * v;
            }
        int idx = (ni * 16 + l16) * 16 + w * 4 + lhi;
        red[idx] = s;
        red[1024 + idx] = s2;
    }
    __syncthreads();
    if (tid < 64) {
        int ni = tid >> 4, c16 = tid & 15;
        float s = 0.f, s2 = 0.f;
#pragma unroll
        for (int j = 0; j < 16; j++) {
            s += red[(ni * 16 + c16) * 16 + j];
            s2 += red[1024 + (ni * 16 + c16) * 16 + j];
        }
        int col = n0 + ni * 16 + c16;
        int tok = bb * 1024 + col;
        float mu = s * (1.f / 128.f);
        float var = s2 * (1.f / 128.f) - mu * mu;
        mean_e[tok] = mu;
        rstd_e[tok] = rsqrtf(var + 1e-5f);
    }
}

// ---------------------------------------------------------------------------
// All weight transposes in one launch; Q/K/V weights pre-scaled by LN gamma.
// ---------------------------------------------------------------------------
__global__ void k_wtrans_all(
        const float* __restrict__ wq, const float* __restrict__ wk,
        const float* __restrict__ wv, const float* __restrict__ proj,
        const float* __restrict__ m1, const float* __restrict__ m2,
        const float* __restrict__ ct,
        const float* __restrict__ gq, const float* __restrict__ gk,
        const float* __restrict__ gv,
        unsigned short* wqT, unsigned short* wkT, unsigned short* wvT,
        unsigned short* projT, unsigned short* m1T, unsigned short* m2T,
        unsigned short* ctT) {
    __shared__ float t[32][33];
    int bid = blockIdx.x;
    const float* W; unsigned short* WT; const float* sc = nullptr; int K, N, ti;
    if (bid < 64)       { W = wq;   WT = wqT;   sc = gq; K = 128; N = 512; ti = bid; }
    else if (bid < 128) { W = wk;   WT = wkT;   sc = gk; K = 128; N = 512; ti = bid - 64; }
    else if (bid < 192) { W = wv;   WT = wvT;   sc = gv; K = 128; N = 512; ti = bid - 128; }
    else if (bid < 256) { W = proj; WT = projT; K = 512; N = 128; ti = bid - 192; }
    else if (bid < 288) { W = m1;   WT = m1T;   K = 128; N = 256; ti = bid - 256; }
    else if (bid < 320) { W = m2;   WT = m2T;   K = 256; N = 128; ti = bid - 288; }
    else                { W = ct;   WT = ctT;   K = 128; N = 512; ti = bid - 320; }
    int tx = N >> 5;
    int n0 = (ti % tx) * 32, k0 = (ti / tx) * 32;
    int tid = threadIdx.x;
    for (int i = tid; i < 1024; i += TPB) {
        int r = i >> 5, c = i & 31;
        float v = W[(size_t)(k0 + r) * N + n0 + c];
        if (sc) v *= sc[k0 + r];
        t[r][c] = v;
    }
    __syncthreads();
    for (int i = tid; i < 1024; i += TPB) {
        int r = i >> 5, c = i & 31;
        WT[(size_t)(n0 + r) * K + k0 + c] = f2bf(t[c][r]);
    }
}

// ---------------------------------------------------------------------------
// Bias vectors: bX[n] = sum_k lnX_b[k] * wX[k][n]. grid(6), 256 thr.
// bout layout: [bq(512) | bk(512) | bv(512)]
// ---------------------------------------------------------------------------
__global__ void k_bias_vec(const float* __restrict__ wq, const float* __restrict__ wk,
                           const float* __restrict__ wv,
                           const float* __restrict__ bq, const float* __restrict__ bk,
                           const float* __restrict__ bv, float* __restrict__ bout) {
    int i = blockIdx.x;
    int which = i >> 1, half = i & 1;
    const float* W = (which == 0) ? wq : (which == 1) ? wk : wv;
    const float* bb = (which == 0) ? bq : (which == 1) ? bk : bv;
    int n = half * 256 + threadIdx.x;
    float s = 0.f;
    for (int k = 0; k < 128; k++) s += bb[k] * W[(size_t)k * 512 + n];
    bout[which * 512 + n] = s;
}

// ---------------------------------------------------------------------------
// MFMA bf16 GEMM with fused LN on A (ASRC 1: Q token-concat; 2: K/V cross-
// concat; 0: plain fp32). Outputs bf16 only:
// mode 4: head-major C16, (v+bias)*scale; mode 7: V^T head-major, v+bias;
// mode 8: row-major C16 = gelu(v+bias).
// ---------------------------------------------------------------------------
template <int BM, int BN, int WM, int WN, int ASRC>
__global__ __launch_bounds__(256, 2) void k_gemm_mfma(
        const float* __restrict__ A0, const float* __restrict__ A1,
        const float* __restrict__ me, const float* __restrict__ re,
        const unsigned short* __restrict__ BT, unsigned short* __restrict__ C16,
        int M, int N, int K, int mode,
        const float* __restrict__ bias, int sT, float scale) {
    constexpr int MI = BM / WM / 16;
    constexpr int NI = BN / WN / 16;
    __shared__ __align__(16) unsigned short As[BM * 40];
    __shared__ __align__(16) unsigned short Bs[BN * 40];
    int tid = threadIdx.x, lane = tid & 63, w = tid >> 6;
    int l16 = lane & 15, lhi = lane >> 4;
    int wm = w / WN, wn = w % WN;
    int m0 = blockIdx.y * BM, n0 = blockIdx.x * BN;

    f32x4 acc[MI][NI];
#pragma unroll
    for (int mi = 0; mi < MI; mi++)
#pragma unroll
        for (int ni = 0; ni < NI; ni++) acc[mi][ni] = (f32x4){0.f, 0.f, 0.f, 0.f};

    for (int k0 = 0; k0 < K; k0 += 32) {
        for (int i = tid; i < BM * 8; i += TPB) {
            int row = i >> 3, kc = (i & 7) * 4;
            int r = m0 + row;
            const float* srow;
            float mu = 0.f, rs = 1.f;
            if (ASRC == 0) {
                srow = A0 + (size_t)r * K;
            } else if (ASRC == 1) {
                int b = r >> 11, t = r & 2047;
                bool cam = t < 1024;
                int tok = (cam ? b : 8 + b) * 1024 + (t & 1023);
                srow = (cam ? A0 : A1) + (size_t)(b * 1024 + (t & 1023)) * 128;
                mu = me[tok]; rs = re[tok];
            } else {
                srow = ((r < 8192) ? A0 : A1) + (size_t)(r & 8191) * 128;
                mu = me[r]; rs = re[r];
            }
            float4 va = *(const float4*)&srow[k0 + kc];
            ushort4 u;
            u.x = f2bf((va.x - mu) * rs); u.y = f2bf((va.y - mu) * rs);
            u.z = f2bf((va.z - mu) * rs); u.w = f2bf((va.w - mu) * rs);
            *(ushort4*)&As[row * 40 + kc] = u;
        }
        for (int i = tid; i < BN * 4; i += TPB) {
            int n = i >> 2, kc = (i & 3) * 8;
            *(bf16x8*)&Bs[n * 40 + kc] = *(const bf16x8*)&BT[(size_t)(n0 + n) * K + k0 + kc];
        }
        __syncthreads();
        bf16x8 af[MI], bfr[NI];
#pragma unroll
        for (int mi = 0; mi < MI; mi++)
            af[mi] = *(bf16x8*)&As[(wm * (BM / WM) + mi * 16 + l16) * 40 + lhi * 8];
#pragma unroll
        for (int ni = 0; ni < NI; ni++)
            bfr[ni] = *(bf16x8*)&Bs[(wn * (BN / WN) + ni * 16 + l16) * 40 + lhi * 8];
#pragma unroll
        for (int mi = 0; mi < MI; mi++)
#pragma unroll
            for (int ni = 0; ni < NI; ni++)
                acc[mi][ni] = __builtin_amdgcn_mfma_f32_16x16x32_bf16(af[mi], bfr[ni], acc[mi][ni], 0, 0, 0);
        __syncthreads();
    }
#pragma unroll
    for (int mi = 0; mi < MI; mi++) {
#pragma unroll
        for (int ni = 0; ni < NI; ni++) {
            int col = n0 + wn * (BN / WN) + ni * 16 + l16;
            float bc = bias[col];
            if (mode == 7) {
                int row0 = m0 + wm * (BM / WM) + mi * 16 + lhi * 4;
                int bb = row0 >> 10, t0 = row0 & 1023;
                ushort4 u;
                u.x = f2bf(acc[mi][ni][0] + bc); u.y = f2bf(acc[mi][ni][1] + bc);
                u.z = f2bf(acc[mi][ni][2] + bc); u.w = f2bf(acc[mi][ni][3] + bc);
                *(ushort4*)&C16[(((size_t)(bb * 4 + (col >> 7))) * 128 + (col & 127)) * 1024 + t0] = u;
            } else {
#pragma unroll
                for (int rg = 0; rg < 4; rg++) {
                    int row = m0 + wm * (BM / WM) + mi * 16 + lhi * 4 + rg;
                    float v = acc[mi][ni][rg];
                    if (mode == 4) {
                        int bb = row >> sT, t = row & ((1 << sT) - 1);
                        size_t oa = ((((size_t)bb * 4 + (col >> 7)) << sT) + t) * 128 + (col & 127);
                        C16[oa] = f2bf((v + bc) * scale);
                    } else {  // mode 8
                        C16[(size_t)row * N + col] = f2bf(gelu_exact(v + bc));
                    }
                }
            }
        }
    }
}

// ---------------------------------------------------------------------------
// GEMM (BM=64, BN=128=N) + bias + skip/residual + LayerNorm fused. A is bf16.
// mode 0: skip = width-concat [camT|lidT] (proj); mode 1: skip = aux,
// out split z_cam/z_lid.
// ---------------------------------------------------------------------------
__global__ __launch_bounds__(256, 2) void k_gemm_ln(
        const unsigned short* __restrict__ Ab, const unsigned short* __restrict__ BT,
        float* __restrict__ C0, float* __restrict__ C1, int K, int mode,
        const float* __restrict__ bias, const float* __restrict__ aux,
        const float* __restrict__ aux2,
        const float* __restrict__ g, const float* __restrict__ bvec) {
    __shared__ __align__(16) char shm[64 * 132 * 4];
    unsigned short* As = (unsigned short*)shm;      // 64*40
    unsigned short* Bs = As + 64 * 40;              // 128*40
    float* Cs = (float*)shm;                        // 64*132 (aliases staging)
    int tid = threadIdx.x, lane = tid & 63, w = tid >> 6;
    int l16 = lane & 15, lhi = lane >> 4;
    int m0 = blockIdx.x * 64;

    f32x4 acc[4][2];
#pragma unroll
    for (int mi = 0; mi < 4; mi++)
#pragma unroll
        for (int ni = 0; ni < 2; ni++) acc[mi][ni] = (f32x4){0.f, 0.f, 0.f, 0.f};

    for (int k0 = 0; k0 < K; k0 += 32) {
        for (int i = tid; i < 256; i += TPB) {
            int row = i >> 2, kc = (i & 3) * 8;
            *(bf16x8*)&As[row * 40 + kc] =
                *(const bf16x8*)&Ab[(size_t)(m0 + row) * K + k0 + kc];
        }
        for (int i = tid; i < 512; i += TPB) {
            int n = i >> 2, kc = (i & 3) * 8;
            *(bf16x8*)&Bs[n * 40 + kc] = *(const bf16x8*)&BT[(size_t)n * K + k0 + kc];
        }
        __syncthreads();
        bf16x8 af[4], bfr[2];
#pragma unroll
        for (int mi = 0; mi < 4; mi++)
            af[mi] = *(bf16x8*)&As[(mi * 16 + l16) * 40 + lhi * 8];
#pragma unroll
        for (int ni = 0; ni < 2; ni++)
            bfr[ni] = *(bf16x8*)&Bs[(w * 32 + ni * 16 + l16) * 40 + lhi * 8];
#pragma unroll
        for (int mi = 0; mi < 4; mi++)
#pragma unroll
            for (int ni = 0; ni < 2; ni++)
                acc[mi][ni] = __builtin_amdgcn_mfma_f32_16x16x32_bf16(af[mi], bfr[ni], acc[mi][ni], 0, 0, 0);
        __syncthreads();
    }
#pragma unroll
    for (int mi = 0; mi < 4; mi++) {
#pragma unroll
        for (int ni = 0; ni < 2; ni++) {
            int col = w * 32 + ni * 16 + l16;
#pragma unroll
            for (int rg = 0; rg < 4; rg++) {
                int rl = mi * 16 + lhi * 4 + rg;
                int grow = m0 + rl;
                float v = acc[mi][ni][rg] + bias[col];
                if (mode == 0) {
                    int rr = grow & 16383;
                    int b = rr >> 11, s = rr & 2047;
                    int H = s >> 6, W = s & 63;
                    const float* sp = (W < 32) ? aux : aux2;
                    v += sp[((size_t)(b * 1024 + H * 32 + (W & 31))) * 128 + col];
                } else {
                    v += aux[(size_t)grow * 128 + col];
                }
                Cs[rl * 132 + col] = v;
            }
        }
    }
    __syncthreads();
    for (int rr = 0; rr < 16; rr++) {
        int row = w * 16 + rr, grow = m0 + row;
        float x0 = Cs[row * 132 + lane], x1 = Cs[row * 132 + 64 + lane];
        float s = x0 + x1, s2 = x0 * x0 + x1 * x1;
#pragma unroll
        for (int m = 32; m; m >>= 1) { s += __shfl_xor(s, m); s2 += __shfl_xor(s2, m); }
        float mu = s * (1.f / 128.f);
        float var = s2 * (1.f / 128.f) - mu * mu;
        float rs = rsqrtf(var + 1e-5f);
        float* Cp;
        size_t ro;
        if (mode == 1) { Cp = (grow < 16384) ? C0 : C1; ro = (size_t)(grow & 16383) * 128; }
        else           { Cp = C0; ro = (size_t)grow * 128; }
        Cp[ro + lane]      = (x0 - mu) * rs * g[lane] + bvec[lane];
        Cp[ro + lane + 64] = (x1 - mu) * rs * g[lane + 64] + bvec[lane + 64];
    }
}

// ---------------------------------------------------------------------------
// ConvTranspose as batched MFMA GEMM, fused instance-norm+ReLU on A,
// pair-shfl float4 coalesced output writes.
// ---------------------------------------------------------------------------
__global__ __launch_bounds__(256, 2) void k_convt_gemm(
        const float* __restrict__ src, const float* __restrict__ mean,
        const float* __restrict__ rstd, const unsigned short* __restrict__ ctT,
        float* __restrict__ out, int M, int Hin) {
    __shared__ __align__(16) unsigned short As[128 * 40];
    __shared__ __align__(16) unsigned short Bs[128 * 40];
    int tid = threadIdx.x, lane = tid & 63, w = tid >> 6;
    int l16 = lane & 15, lhi = lane >> 4;
    int wm = w >> 1, wn = w & 1;
    int m0 = blockIdx.y * 128, n0 = blockIdx.x * 128, b = blockIdx.z;
    const float* Ab = src + (size_t)b * M * 128;
    const float* mb = mean + b * 128;
    const float* rb = rstd + b * 128;

    f32x4 acc[4][4];
#pragma unroll
    for (int mi = 0; mi < 4; mi++)
#pragma unroll
        for (int ni = 0; ni < 4; ni++) acc[mi][ni] = (f32x4){0.f, 0.f, 0.f, 0.f};

    for (int k0 = 0; k0 < 128; k0 += 32) {
        for (int i = tid; i < 1024; i += TPB) {
            int row = i >> 3, kc = (i & 7) * 4;
            float4 va = *(const float4*)&Ab[(size_t)(m0 + row) * 128 + k0 + kc];
            float4 mn = *(const float4*)&mb[k0 + kc];
            float4 rs = *(const float4*)&rb[k0 + kc];
            ushort4 u;
            u.x = f2bf(fmaxf((va.x - mn.x) * rs.x, 0.f));
            u.y = f2bf(fmaxf((va.y - mn.y) * rs.y, 0.f));
            u.z = f2bf(fmaxf((va.z - mn.z) * rs.z, 0.f));
            u.w = f2bf(fmaxf((va.w - mn.w) * rs.w, 0.f));
            *(ushort4*)&As[row * 40 + kc] = u;
        }
        for (int i = tid; i < 512; i += TPB) {
            int n = i >> 2, kc = (i & 3) * 8;
            *(bf16x8*)&Bs[n * 40 + kc] = *(const bf16x8*)&ctT[(size_t)(n0 + n) * 128 + k0 + kc];
        }
        __syncthreads();
        bf16x8 af[4], bfr[4];
#pragma unroll
        for (int mi = 0; mi < 4; mi++)
            af[mi] = *(bf16x8*)&As[(wm * 64 + mi * 16 + l16) * 40 + lhi * 8];
#pragma unroll
        for (int ni = 0; ni < 4; ni++)
            bfr[ni] = *(bf16x8*)&Bs[(wn * 64 + ni * 16 + l16) * 40 + lhi * 8];
#pragma unroll
        for (int mi = 0; mi < 4; mi++)
#pragma unroll
            for (int ni = 0; ni < 4; ni++)
                acc[mi][ni] = __builtin_amdgcn_mfma_f32_16x16x32_bf16(af[mi], bfr[ni], acc[mi][ni], 0, 0, 0);
        __syncthreads();
    }
    int Ho = 2 * Hin, Wo = 64;
#pragma unroll
    for (int mi = 0; mi < 4; mi++) {
#pragma unroll
        for (int ni = 0; ni < 4; ni++) {
            int col = n0 + wn * 64 + ni * 16 + l16;
            int oc = col >> 2, aa = (col >> 1) & 1, dd = col & 1;
            int p0 = m0 + wm * 64 + mi * 16 + lhi * 4;
            int hin = p0 >> 5, win0 = p0 & 31;
            // lane pair (dd=0, dd=1) interleaves into one contiguous float4
            float s0 = __shfl_xor(acc[mi][ni][0], 1);
            float s1 = __shfl_xor(acc[mi][ni][1], 1);
            float s2 = __shfl_xor(acc[mi][ni][2], 1);
            float s3 = __shfl_xor(acc[mi][ni][3], 1);
            float4 o;
            if (!dd) o = make_float4(acc[mi][ni][0], s0, acc[mi][ni][1], s1);
            else     o = make_float4(s2, acc[mi][ni][2], s3, acc[mi][ni][3]);
            size_t addr = (((size_t)b * 128 + oc) * Ho + 2 * hin + aa) * Wo
                        + 2 * win0 + (dd ? 4 : 0);
            *(float4*)&out[addr] = o;
        }
    }
}

// ---------------------------------------------------------------------------
// bf16 flash attention: swapped-QK^T softmax, exp2 domain, cvt_pk packing,
// async-stage prefetch, P-scratch ALIASED onto Ks (32 KB LDS -> 4 blocks/CU).
// grid (16, 4, 16): z = cross*8 + b. Output bf16.
// ---------------------------------------------------------------------------
__global__ __launch_bounds__(256, 2) void k_attn_bf16(
        const unsigned short* __restrict__ qb, const unsigned short* __restrict__ kb,
        const unsigned short* __restrict__ vt, unsigned short* __restrict__ aout) {
    __shared__ __align__(16) unsigned short smem[16384];  // 32 KB
    unsigned short* Ks = smem;            // [64][128], 16B-slot ^row swizzle
    unsigned short* Vt = smem + 8192;     // [128][64], ^d swizzle
    int tid = threadIdx.x;
    int lane = tid & 63, w = tid >> 6;
    int l16 = lane & 15, lhi = lane >> 4;
    int qt = blockIdx.x, h = blockIdx.y, z = blockIdx.z;
    int bh_q = (z & 7) * 4 + h;
    int bh_kv = z * 4 + h;
    unsigned short* Pw = smem + w * 2048;  // aliases Ks (dead after QK^T)

    const unsigned short* qg = qb + ((size_t)bh_q * 2048 + qt * 128) * 128;
    bf16x8 qa[2][4];
#pragma unroll
    for (int mt = 0; mt < 2; mt++) {
        int r = w * 32 + mt * 16 + l16;
#pragma unroll
        for (int ks = 0; ks < 4; ks++)
            qa[mt][ks] = *(const bf16x8*)&qg[(size_t)r * 128 + ks * 32 + lhi * 8];
    }

    f32x4 acc[2][8];
#pragma unroll
    for (int mt = 0; mt < 2; mt++)
#pragma unroll
        for (int dt = 0; dt < 8; dt++) acc[mt][dt] = (f32x4){0.f, 0.f, 0.f, 0.f};
    float m_r[2] = {-1e30f, -1e30f};
    float l_r[2] = {0.f, 0.f};

    const unsigned short* kg = kb + (size_t)bh_kv * 131072;
    const unsigned short* vg = vt + (size_t)bh_kv * 131072;

    int krow = tid >> 4, kcol = (tid & 15) * 8;
    int kls = ((tid & 15) ^ (krow & 7)) << 3;
    int vrow = tid >> 3, vcol = (tid & 7) * 8;
    int vls = ((tid & 7) ^ (vrow & 7)) << 3;

    // prologue: stage chunk 0
#pragma unroll
    for (int j = 0; j < 4; j++) {
        int r = krow + j * 16;
        *(bf16x8*)&Ks[r * 128 + kls] = *(const bf16x8*)&kg[(size_t)r * 128 + kcol];
        int d = vrow + j * 32;
        *(bf16x8*)&Vt[d * 64 + vls] = *(const bf16x8*)&vg[(size_t)d * 1024 + vcol];
    }
    __syncthreads();

    for (int c = 0; c < 16; c++) {
        bf16x8 kpre[4], vpre[4];
        if (c < 15) {
            int c0 = (c + 1) * 64;
#pragma unroll
            for (int j = 0; j < 4; j++) {
                kpre[j] = *(const bf16x8*)&kg[(size_t)(c0 + krow + j * 16) * 128 + kcol];
                vpre[j] = *(const bf16x8*)&vg[(size_t)(vrow + j * 32) * 1024 + c0 + vcol];
            }
        }

        // QK^T swapped: S^T[key][q]
        f32x4 s[2][4];
#pragma unroll
        for (int mt = 0; mt < 2; mt++)
#pragma unroll
            for (int kt = 0; kt < 4; kt++) s[mt][kt] = (f32x4){0.f, 0.f, 0.f, 0.f};
#pragma unroll
        for (int kt = 0; kt < 4; kt++) {
            int r = kt * 16 + l16;
#pragma unroll
            for (int ks = 0; ks < 4; ks++) {
                bf16x8 kf = *(bf16x8*)&Ks[r * 128 + (((ks * 4 + lhi) ^ (r & 7)) << 3)];
                s[0][kt] = __builtin_amdgcn_mfma_f32_16x16x32_bf16(kf, qa[0][ks], s[0][kt], 0, 0, 0);
                s[1][kt] = __builtin_amdgcn_mfma_f32_16x16x32_bf16(kf, qa[1][ks], s[1][kt], 0, 0, 0);
            }
        }
        __syncthreads();  // Ks fully consumed; Pw may now overwrite it

        float pm[2];
#pragma unroll
        for (int mt = 0; mt < 2; mt++) {
            float a = s[mt][0][0];
#pragma unroll
            for (int kt = 0; kt < 4; kt++)
#pragma unroll
                for (int rg = 0; rg < 4; rg++) a = fmaxf(a, s[mt][kt][rg]);
            a = fmaxf(a, __shfl_xor(a, 16));
            a = fmaxf(a, __shfl_xor(a, 32));
            pm[mt] = a;
        }
        bool need = (pm[0] > m_r[0] + 8.f) || (pm[1] > m_r[1] + 8.f);
        if (__any(need)) {
#pragma unroll
            for (int mt = 0; mt < 2; mt++) {
                float mn = fmaxf(m_r[mt], pm[mt]);
                float f = __builtin_amdgcn_exp2f(m_r[mt] - mn);
                m_r[mt] = mn;
                l_r[mt] *= f;
#pragma unroll
                for (int rg = 0; rg < 4; rg++) {
                    float ft = __shfl(f, lhi * 4 + rg);
#pragma unroll
                    for (int dt = 0; dt < 8; dt++) acc[mt][dt][rg] *= ft;
                }
            }
        }

#pragma unroll
        for (int mt = 0; mt < 2; mt++) {
            int row = mt * 16 + l16;
            int rsw = row & 7;
            float ls = 0.f;
#pragma unroll
            for (int kt = 0; kt < 4; kt++) {
                float p0 = __builtin_amdgcn_exp2f(s[mt][kt][0] - m_r[mt]);
                float p1 = __builtin_amdgcn_exp2f(s[mt][kt][1] - m_r[mt]);
                float p2 = __builtin_amdgcn_exp2f(s[mt][kt][2] - m_r[mt]);
                float p3 = __builtin_amdgcn_exp2f(s[mt][kt][3] - m_r[mt]);
                ls += (p0 + p1) + (p2 + p3);
                unsigned u01, u23;
                asm("v_cvt_pk_bf16_f32 %0, %1, %2" : "=v"(u01) : "v"(p0), "v"(p1));
                asm("v_cvt_pk_bf16_f32 %0, %1, %2" : "=v"(u23) : "v"(p2), "v"(p3));
                int slot = kt * 2 + (lhi >> 1);
                int base = row * 64 + ((slot ^ rsw) << 3) + (lhi & 1) * 4;
                *(unsigned*)&Pw[base] = u01;
                *(unsigned*)&Pw[base + 2] = u23;
            }
            l_r[mt] += ls;
        }
        asm volatile("s_waitcnt lgkmcnt(0)" ::: "memory");

        bf16x8 pa0[2], pa1[2];
#pragma unroll
        for (int mt = 0; mt < 2; mt++) {
            int row = mt * 16 + l16;
            pa0[mt] = *(bf16x8*)&Pw[row * 64 + ((lhi ^ (row & 7)) << 3)];
            pa1[mt] = *(bf16x8*)&Pw[row * 64 + (((4 + lhi) ^ (row & 7)) << 3)];
        }
#pragma unroll
        for (int dt = 0; dt < 8; dt++) {
            int d = dt * 16 + l16;
            bf16x8 vb0 = *(bf16x8*)&Vt[d * 64 + ((lhi ^ (d & 7)) << 3)];
            bf16x8 vb1 = *(bf16x8*)&Vt[d * 64 + (((4 + lhi) ^ (d & 7)) << 3)];
            acc[0][dt] = __builtin_amdgcn_mfma_f32_16x16x32_bf16(pa0[0], vb0, acc[0][dt], 0, 0, 0);
            acc[0][dt] = __builtin_amdgcn_mfma_f32_16x16x32_bf16(pa1[0], vb1, acc[0][dt], 0, 0, 0);
            acc[1][dt] = __builtin_amdgcn_mfma_f32_16x16x32_bf16(pa0[1], vb0, acc[1][dt], 0, 0, 0);
            acc[1][dt] = __builtin_amdgcn_mfma_f32_16x16x32_bf16(pa1[1], vb1, acc[1][dt], 0, 0, 0);
        }
        __syncthreads();  // Pw + Vt consumed

        if (c < 15) {
#pragma unroll
            for (int j = 0; j < 4; j++) {
                *(bf16x8*)&Ks[(krow + j * 16) * 128 + kls] = kpre[j];
                *(bf16x8*)&Vt[(vrow + j * 32) * 64 + vls] = vpre[j];
            }
            __syncthreads();
        }
    }

#pragma unroll
    for (int mt = 0; mt < 2; mt++) {
        float lt = l_r[mt];
        lt += __shfl_xor(lt, 16);
        lt += __shfl_xor(lt, 32);
        l_r[mt] = lt;
    }
    size_t obase = (size_t)(z >> 3) * 16384 + (size_t)(z & 7) * 2048;
#pragma unroll
    for (int mt = 0; mt < 2; mt++)
#pragma unroll
        for (int rg = 0; rg < 4; rg++) {
            float linv = 1.f / __shfl(l_r[mt], lhi * 4 + rg);
            int qrow = qt * 128 + w * 32 + mt * 16 + lhi * 4 + rg;
            unsigned short* orow = aout + (obase + qrow) * 512 + h * 128;
#pragma unroll
            for (int dt = 0; dt < 8; dt++)
                orow[dt * 16 + l16] = f2bf(acc[mt][dt][rg] * linv);
        }
}

// ---------------------------------------------------------------------------
// fused_s[b][p][d] = zc[b][p]+zc[b][1024+p]+zl[b][p]+zl[b][1024+p]
// ---------------------------------------------------------------------------
__global__ void k_fused_sum(const float* __restrict__ zc, const float* __restrict__ zl,
                            float* __restrict__ fs) {
    int idx = blockIdx.x * TPB + threadIdx.x;
    int d = idx & 127, p = (idx >> 7) & 1023, b = idx >> 17;
    size_t r0 = ((size_t)b * 2048 + p) * 128 + d;
    size_t r1 = ((size_t)b * 2048 + 1024 + p) * 128 + d;
    fs[((size_t)b * 1024 + p) * 128 + d] = zc[r0] + zc[r1] + zl[r0] + zl[r1];
}

// ---------------------------------------------------------------------------
extern "C" void kernel_launch(void* const* d_in, const int* in_sizes, int n_in,
                              void* d_out, int out_size, void* d_ws, size_t ws_size,
                              hipStream_t stream) {
    const float* cam_feat = (const float*)d_in[0];
    const float* lid_feat = (const float*)d_in[1];
    const float* pos      = (const float*)d_in[2];
    const float* conv_w   = (const float*)d_in[3];
    const float* convT_w  = (const float*)d_in[4];
    const float* lnq_g = (const float*)d_in[5];
    const float* lnq_b = (const float*)d_in[6];
    const float* wq    = (const float*)d_in[7];
    const float* lnk_g = (const float*)d_in[8];
    const float* lnk_b = (const float*)d_in[9];
    const float* wk    = (const float*)d_in[10];
    const float* lnv_g = (const float*)d_in[11];
    const float* lnv_b = (const float*)d_in[12];
    const float* wv    = (const float*)d_in[13];
    const float* proj_w = (const float*)d_in[14];
    const float* proj_b = (const float*)d_in[15];
    const float* pre_g = (const float*)d_in[16];
    const float* pre_b = (const float*)d_in[17];
    const float* mlp_w1 = (const float*)d_in[18];
    const float* mlp_b1 = (const float*)d_in[19];
    const float* mlp_w2 = (const float*)d_in[20];
    const float* mlp_b2 = (const float*)d_in[21];
    const float* post_g = (const float*)d_in[22];
    const float* post_b = (const float*)d_in[23];

    float* ws = (float*)d_ws;
    float* outp = (float*)d_out;

    // persistent buffers (floats)
    float* cam_eT  = ws + 0;               // 1,048,576
    float* lid_eT  = ws + 1048576;         // 1,048,576
    unsigned short* qbf16 = (unsigned short*)(ws + 2097152);   // 4,194,304 f
    float* z_cam   = ws + 6291456;         // 2,097,152
    float* z_lid   = ws + 8388608;         // 2,097,152
    float* fused_s = ws + 10485760;        // 1,048,576
    float* stats   = ws + 11534336;        // 16,384
    unsigned short* wbuf = (unsigned short*)(ws + 11550720);   // 196,608 f
    float* part    = ws + 11747328;        // 131,072
    float* mean_e  = ws + 11878400;        // 16,384
    float* rstd_e  = ws + 11894784;        // 16,384
    float* bvecs   = ws + 11911168;        // 1,536
    unsigned short* xcolT = (unsigned short*)(ws + 11912704);  // 4,194,304 f
    float* pool    = ws + 16107008;        // 16,777,216  (total ~131.5 MB)

    unsigned short* wqT   = wbuf + 0;        // 512x128
    unsigned short* wkT   = wbuf + 65536;    // 512x128
    unsigned short* wvT   = wbuf + 131072;   // 512x128
    unsigned short* projT = wbuf + 196608;   // 128x512
    unsigned short* m1T   = wbuf + 262144;   // 256x128
    unsigned short* m2T   = wbuf + 294912;   // 128x256
    unsigned short* ctT   = wbuf + 327680;   // 512x128

    float* meanA = stats + 0,    *rstdA = stats + 2048;
    float* meanF = stats + 4096, *rstdF = stats + 5120;
    float* meanC = stats + 6144, *rstdC = stats + 7168;
    float* meanL = stats + 8192, *rstdL = stats + 9216;
    float* bq = bvecs, *bk = bvecs + 512, *bv = bvecs + 1024;

    // pool (timeline-overlapped)
    unsigned short* kbf16 = (unsigned short*)(pool + 0);        // 4,194,304 f
    unsigned short* vbfT  = (unsigned short*)(pool + 4194304);  // 4,194,304 f
    unsigned short* abuf  = (unsigned short*)(pool + 8388608);  // 8,388,608 f
    float* z2 = pool + 0;                                       // 4,194,304 (over dead kbf16)
    unsigned short* h1 = (unsigned short*)(pool + 4194304);     // 4,194,304 f (over dead vbfT)

    // 1/sqrt(128) * log2(e): attention softmax runs in the exp2 domain
    const float qscale = 0.12751744436f;

    // Weight prep + bias vectors
    k_wtrans_all<<<384, TPB, 0, stream>>>(wq, wk, wv, proj_w, mlp_w1, mlp_w2, convT_w,
                                          lnq_g, lnk_g, lnv_g,
                                          wqT, wkT, wvT, projT, m1T, m2T, ctT);
    k_bias_vec<<<6, TPB, 0, stream>>>(wq, wk, wv, lnq_b, lnk_b, lnv_b, bvecs);

    // Stage A: stats + conv encoders (conv epilogue emits per-token LN stats)
    k_stats_cm<<<2048, TPB, 0, stream>>>(cam_feat, lid_feat, pos, meanA, rstdA);
    k_prep<<<dim3(32, 16), TPB, 0, stream>>>(cam_feat, lid_feat, pos, meanA, rstdA, xcolT);
    k_conv_gemm<<<dim3(16, 1, 16), TPB, 0, stream>>>(conv_w, xcolT, cam_eT, lid_eT,
                                                     mean_e, rstd_e);

    // Q/K/V GEMMs with LN folded into A-staging (gamma in weights, beta@W bias)
    k_gemm_mfma<128, 128, 2, 2, 1><<<dim3(4, 128), TPB, 0, stream>>>(
        cam_eT, lid_eT, mean_e, rstd_e, wqT, qbf16, 16384, 512, 128, 4, bq, 11, qscale);
    k_gemm_mfma<128, 128, 2, 2, 2><<<dim3(4, 128), TPB, 0, stream>>>(
        cam_eT, lid_eT, mean_e, rstd_e, wkT, kbf16, 16384, 512, 128, 4, bk, 10, 1.f);
    k_gemm_mfma<128, 128, 2, 2, 2><<<dim3(4, 128), TPB, 0, stream>>>(
        cam_eT, lid_eT, mean_e, rstd_e, wvT, vbfT, 16384, 512, 128, 7, bv, 0, 1.f);
    k_attn_bf16<<<dim3(16, 4, 16), TPB, 0, stream>>>(qbf16, kbf16, vbfT, abuf);
    k_gemm_ln<<<512, TPB, 0, stream>>>(
        abuf, projT, z2, nullptr, 512, 0, proj_b, cam_eT, lid_eT, pre_g, pre_b);
    k_gemm_mfma<128, 128, 2, 2, 0><<<dim3(2, 256), TPB, 0, stream>>>(
        z2, nullptr, nullptr, nullptr, m1T, h1, 32768, 256, 128, 8, mlp_b1, 0, 1.f);
    k_gemm_ln<<<512, TPB, 0, stream>>>(
        h1, m2T, z_cam, z_lid, 256, 1, mlp_b2, z2, nullptr, post_g, post_b);

    // Outputs
    k_fused_sum<<<4096, TPB, 0, stream>>>(z_cam, z_lid, fused_s);
    k_stats_part<<<dim3(16, 8), TPB, 0, stream>>>(fused_s, part, 1024);
    k_stats_red<<<8, 128, 0, stream>>>(part, meanF, rstdF, 16, 1024);
    k_stats_part2<<<dim3(32, 8, 2), TPB, 0, stream>>>(z_cam, z_lid, part);
    k_stats_red2<<<16, 128, 0, stream>>>(part, meanC, rstdC, meanL, rstdL);
    k_convt_gemm<<<dim3(4, 8, 8), TPB, 0, stream>>>(fused_s, meanF, rstdF, ctT, outp, 1024, 32);
    k_convt_gemm<<<dim3(4, 16, 8), TPB, 0, stream>>>(z_cam, meanC, rstdC, ctT, outp + 4194304, 2048, 64);
    k_convt_gemm<<<dim3(4, 16, 8), TPB, 0, stream>>>(z_lid, meanL, rstdL, ctT, outp + 12582912, 2048, 64);
}

// Round 10
// 339.174 us; speedup vs baseline: 15.1750x; 1.0767x over previous
//
#include <hip/hip_runtime.h>
#include <math.h>

#define TPB 256

typedef __attribute__((ext_vector_type(8))) short bf16x8;
typedef __attribute__((ext_vector_type(4))) float f32x4;

__device__ __forceinline__ float gelu_exact(float x) {
    return 0.5f * x * (1.0f + erff(x * 0.70710678118654752f));
}

__device__ __forceinline__ unsigned short f2bf(float x) {
    unsigned u = __float_as_uint(x);
    return (unsigned short)((u + 0x7fffu + ((u >> 16) & 1u)) >> 16);
}

// ---------------------------------------------------------------------------
// Stage-A instance-norm stats (x + pos broadcast), 2048 channels.
// ---------------------------------------------------------------------------
__global__ void k_stats_cm(const float* __restrict__ x0, const float* __restrict__ x1,
                           const float* __restrict__ pos, float* __restrict__ mean,
                           float* __restrict__ rstd) {
    int gc = blockIdx.x;
    const float* src = ((gc < 1024) ? x0 : x1) + (size_t)(gc & 1023) * 4096;
    const float* posr = pos + (size_t)(gc & 127) * 4096;
    float s = 0.f, s2 = 0.f;
    for (int p = threadIdx.x; p < 4096; p += TPB) {
        float v = src[p] + posr[p];
        s += v; s2 += v * v;
    }
#pragma unroll
    for (int m = 32; m; m >>= 1) { s += __shfl_xor(s, m); s2 += __shfl_xor(s2, m); }
    __shared__ float ls[4], ls2[4];
    int w = threadIdx.x >> 6;
    if ((threadIdx.x & 63) == 0) { ls[w] = s; ls2[w] = s2; }
    __syncthreads();
    if (threadIdx.x == 0) {
        s = ls[0] + ls[1] + ls[2] + ls[3];
        s2 = ls2[0] + ls2[1] + ls2[2] + ls2[3];
        float mu = s / 4096.f;
        float var = s2 / 4096.f - mu * mu;
        mean[gc] = mu;
        rstd[gc] = rsqrtf(var + 1e-5f);
    }
}

// ---------------------------------------------------------------------------
// Token-major stats reduce.
// ---------------------------------------------------------------------------
__global__ void k_stats_red(const float* __restrict__ part, float* __restrict__ mean,
                            float* __restrict__ rstd, int nc, int T) {
    int b = blockIdx.x, d = threadIdx.x;
    float s = 0.f, s2 = 0.f;
    for (int c = 0; c < nc; c++) {
        const float* p = part + ((size_t)(b * nc + c) * 2) * 128;
        s += p[d]; s2 += p[128 + d];
    }
    float mu = s / (float)T;
    float var = s2 / (float)T - mu * mu;
    mean[b * 128 + d] = mu;
    rstd[b * 128 + d] = rsqrtf(var + 1e-5f);
}

__global__ void k_stats_part2(const float* __restrict__ zc, const float* __restrict__ zl,
                              float* __restrict__ part) {
    int c = blockIdx.x, b = blockIdx.y, sel = blockIdx.z;
    int tid = threadIdx.x;
    int d = tid & 127, half = tid >> 7;
    const float* base = (sel ? zl : zc) + ((size_t)b * 2048 + c * 64) * 128;
    float s = 0.f, s2 = 0.f;
    for (int t = half; t < 64; t += 2) {
        float v = base[t * 128 + d];
        s += v; s2 += v * v;
    }
    __shared__ float ls[256], ls2[256];
    ls[tid] = s; ls2[tid] = s2;
    __syncthreads();
    if (tid < 128) {
        s = ls[tid] + ls[tid + 128];
        s2 = ls2[tid] + ls2[tid + 128];
        float* p = part + ((size_t)((sel * 8 + b) * 32 + c) * 2) * 128;
        p[d] = s; p[128 + d] = s2;
    }
}

__global__ void k_stats_red2(const float* __restrict__ part,
                             float* __restrict__ meanC, float* __restrict__ rstdC,
                             float* __restrict__ meanL, float* __restrict__ rstdL) {
    int idx = blockIdx.x, d = threadIdx.x;
    int sel = idx >> 3, b = idx & 7;
    float s = 0.f, s2 = 0.f;
    for (int c = 0; c < 32; c++) {
        const float* p = part + ((size_t)((sel * 8 + b) * 32 + c) * 2) * 128;
        s += p[d]; s2 += p[128 + d];
    }
    float mu = s / 2048.f;
    float var = s2 / 2048.f - mu * mu;
    float* mean = sel ? meanL : meanC;
    float* rstd = sel ? rstdL : rstdC;
    mean[b * 128 + d] = mu;
    rstd[b * 128 + d] = rsqrtf(var + 1e-5f);
}

// ---------------------------------------------------------------------------
// Conv prep (cam+lid merged): normalize+ReLU+im2col -> bf16 xcolT[bb][p][512].
// ---------------------------------------------------------------------------
__global__ void k_prep(const float* __restrict__ cam, const float* __restrict__ lid,
                       const float* __restrict__ pos, const float* __restrict__ mean,
                       const float* __restrict__ rstd, unsigned short* __restrict__ xcolT) {
    __shared__ unsigned short T[32 * 520];
    int h = blockIdx.x, bb = blockIdx.y;
    int b = bb & 7, so = (bb < 8) ? 0 : 1024;
    const float* x = (bb < 8) ? cam : lid;
    int tid = threadIdx.x;
    for (int i = tid; i < 4096; i += TPB) {
        int c = i >> 5, w = i & 31;
        int ch = b * 128 + c;
        const float* xr = x + (size_t)ch * 4096 + (2 * h) * 64 + 2 * w;
        const float* pr = pos + (size_t)c * 4096 + (2 * h) * 64 + 2 * w;
        float mu = mean[so + ch], rs = rstd[so + ch];
        float2 x0 = *(const float2*)xr;
        float2 x1 = *(const float2*)(xr + 64);
        float2 p0 = *(const float2*)pr;
        float2 p1 = *(const float2*)(pr + 64);
        ushort4 u;
        u.x = f2bf(fmaxf((x0.x + p0.x - mu) * rs, 0.f));
        u.y = f2bf(fmaxf((x0.y + p0.y - mu) * rs, 0.f));
        u.z = f2bf(fmaxf((x1.x + p1.x - mu) * rs, 0.f));
        u.w = f2bf(fmaxf((x1.y + p1.y - mu) * rs, 0.f));
        *(ushort4*)&T[w * 520 + c * 4] = u;
    }
    __syncthreads();
    unsigned short* dst = xcolT + ((size_t)bb * 1024 + h * 32) * 512;
    for (int i = tid; i < 2048; i += TPB) {
        int w = i >> 6, kk = (i & 63) * 8;
        *(bf16x8*)&dst[(size_t)w * 512 + kk] = *(bf16x8*)&T[w * 520 + kk];
    }
}

// ---------------------------------------------------------------------------
// Conv as batched MFMA GEMM (cam+lid merged) + per-token LN stats epilogue.
// grid (16, 1, 16).
// ---------------------------------------------------------------------------
__global__ __launch_bounds__(256, 2) void k_conv_gemm(
        const float* __restrict__ W, const unsigned short* __restrict__ xcolT,
        float* __restrict__ camT, float* __restrict__ lidT,
        float* __restrict__ mean_e, float* __restrict__ rstd_e) {
    __shared__ __align__(16) unsigned short As[128 * 40];
    __shared__ __align__(16) unsigned short Bs[64 * 40];
    __shared__ float red[2048];
    int tid = threadIdx.x, lane = tid & 63, w = tid >> 6;
    int l16 = lane & 15, lhi = lane >> 4;
    int n0 = blockIdx.x * 64, bb = blockIdx.z;
    const unsigned short* BT = xcolT + (size_t)bb * 524288;
    float* eT = ((bb < 8) ? camT : lidT) + (size_t)(bb & 7) * 131072;

    f32x4 acc[2][4];
#pragma unroll
    for (int mi = 0; mi < 2; mi++)
#pragma unroll
        for (int ni = 0; ni < 4; ni++) acc[mi][ni] = (f32x4){0.f, 0.f, 0.f, 0.f};

    for (int k0 = 0; k0 < 512; k0 += 32) {
        for (int i = tid; i < 1024; i += TPB) {
            int row = i >> 3, kc = (i & 7) * 4;
            float4 va = *(const float4*)&W[(size_t)row * 512 + k0 + kc];
            ushort4 u;
            u.x = f2bf(va.x); u.y = f2bf(va.y); u.z = f2bf(va.z); u.w = f2bf(va.w);
            *(ushort4*)&As[row * 40 + kc] = u;
        }
        for (int i = tid; i < 256; i += TPB) {
            int n = i >> 2, kc = (i & 3) * 8;
            *(bf16x8*)&Bs[n * 40 + kc] = *(const bf16x8*)&BT[(size_t)(n0 + n) * 512 + k0 + kc];
        }
        __syncthreads();
        bf16x8 af[2], bfr[4];
#pragma unroll
        for (int mi = 0; mi < 2; mi++)
            af[mi] = *(bf16x8*)&As[(w * 32 + mi * 16 + l16) * 40 + lhi * 8];
#pragma unroll
        for (int ni = 0; ni < 4; ni++)
            bfr[ni] = *(bf16x8*)&Bs[(ni * 16 + l16) * 40 + lhi * 8];
#pragma unroll
        for (int mi = 0; mi < 2; mi++)
#pragma unroll
            for (int ni = 0; ni < 4; ni++)
                acc[mi][ni] = __builtin_amdgcn_mfma_f32_16x16x32_bf16(af[mi], bfr[ni], acc[mi][ni], 0, 0, 0);
        __syncthreads();
    }
#pragma unroll
    for (int mi = 0; mi < 2; mi++)
#pragma unroll
        for (int ni = 0; ni < 4; ni++) {
            int col = n0 + ni * 16 + l16;
            int rowb = w * 32 + mi * 16 + lhi * 4;
            *(float4*)&eT[(size_t)col * 128 + rowb] = *(float4*)&acc[mi][ni];
        }
#pragma unroll
    for (int ni = 0; ni < 4; ni++) {
        float s = 0.f, s2 = 0.f;
#pragma unroll
        for (int mi = 0; mi < 2; mi++)
#pragma unroll
            for (int rg = 0; rg < 4; rg++) {
                float v = acc[mi][ni][rg];
                s += v; s2 += v * v;
            }
        int idx = (ni * 16 + l16) * 16 + w * 4 + lhi;
        red[idx] = s;
        red[1024 + idx] = s2;
    }
    __syncthreads();
    if (tid < 64) {
        int ni = tid >> 4, c16 = tid & 15;
        float s = 0.f, s2 = 0.f;
#pragma unroll
        for (int j = 0; j < 16; j++) {
            s += red[(ni * 16 + c16) * 16 + j];
            s2 += red[1024 + (ni * 16 + c16) * 16 + j];
        }
        int col = n0 + ni * 16 + c16;
        int tok = bb * 1024 + col;
        float mu = s * (1.f / 128.f);
        float var = s2 * (1.f / 128.f) - mu * mu;
        mean_e[tok] = mu;
        rstd_e[tok] = rsqrtf(var + 1e-5f);
    }
}

// ---------------------------------------------------------------------------
// All weight transposes in one launch; Q/K/V weights pre-scaled by LN gamma.
// ---------------------------------------------------------------------------
__global__ void k_wtrans_all(
        const float* __restrict__ wq, const float* __restrict__ wk,
        const float* __restrict__ wv, const float* __restrict__ proj,
        const float* __restrict__ m1, const float* __restrict__ m2,
        const float* __restrict__ ct,
        const float* __restrict__ gq, const float* __restrict__ gk,
        const float* __restrict__ gv,
        unsigned short* wqT, unsigned short* wkT, unsigned short* wvT,
        unsigned short* projT, unsigned short* m1T, unsigned short* m2T,
        unsigned short* ctT) {
    __shared__ float t[32][33];
    int bid = blockIdx.x;
    const float* W; unsigned short* WT; const float* sc = nullptr; int K, N, ti;
    if (bid < 64)       { W = wq;   WT = wqT;   sc = gq; K = 128; N = 512; ti = bid; }
    else if (bid < 128) { W = wk;   WT = wkT;   sc = gk; K = 128; N = 512; ti = bid - 64; }
    else if (bid < 192) { W = wv;   WT = wvT;   sc = gv; K = 128; N = 512; ti = bid - 128; }
    else if (bid < 256) { W = proj; WT = projT; K = 512; N = 128; ti = bid - 192; }
    else if (bid < 288) { W = m1;   WT = m1T;   K = 128; N = 256; ti = bid - 256; }
    else if (bid < 320) { W = m2;   WT = m2T;   K = 256; N = 128; ti = bid - 288; }
    else                { W = ct;   WT = ctT;   K = 128; N = 512; ti = bid - 320; }
    int tx = N >> 5;
    int n0 = (ti % tx) * 32, k0 = (ti / tx) * 32;
    int tid = threadIdx.x;
    for (int i = tid; i < 1024; i += TPB) {
        int r = i >> 5, c = i & 31;
        float v = W[(size_t)(k0 + r) * N + n0 + c];
        if (sc) v *= sc[k0 + r];
        t[r][c] = v;
    }
    __syncthreads();
    for (int i = tid; i < 1024; i += TPB) {
        int r = i >> 5, c = i & 31;
        WT[(size_t)(n0 + r) * K + k0 + c] = f2bf(t[c][r]);
    }
}

// ---------------------------------------------------------------------------
// Bias vectors: bX[n] = sum_k lnX_b[k] * wX[k][n]. grid(6), 256 thr.
// ---------------------------------------------------------------------------
__global__ void k_bias_vec(const float* __restrict__ wq, const float* __restrict__ wk,
                           const float* __restrict__ wv,
                           const float* __restrict__ bq, const float* __restrict__ bk,
                           const float* __restrict__ bv, float* __restrict__ bout) {
    int i = blockIdx.x;
    int which = i >> 1, half = i & 1;
    const float* W = (which == 0) ? wq : (which == 1) ? wk : wv;
    const float* bb = (which == 0) ? bq : (which == 1) ? bk : bv;
    int n = half * 256 + threadIdx.x;
    float s = 0.f;
    for (int k = 0; k < 128; k++) s += bb[k] * W[(size_t)k * 512 + n];
    bout[which * 512 + n] = s;
}

// ---------------------------------------------------------------------------
// MFMA bf16 GEMM with fused LN on A (ASRC 1: Q token-concat; 2: K/V cross-
// concat; 0: plain fp32). mode 4: head-major C16, (v+bias)*scale;
// mode 7: V^T head-major, v+bias; mode 8: row-major C16 = gelu(v+bias).
// ---------------------------------------------------------------------------
template <int BM, int BN, int WM, int WN, int ASRC>
__global__ __launch_bounds__(256, 2) void k_gemm_mfma(
        const float* __restrict__ A0, const float* __restrict__ A1,
        const float* __restrict__ me, const float* __restrict__ re,
        const unsigned short* __restrict__ BT, unsigned short* __restrict__ C16,
        int M, int N, int K, int mode,
        const float* __restrict__ bias, int sT, float scale) {
    constexpr int MI = BM / WM / 16;
    constexpr int NI = BN / WN / 16;
    __shared__ __align__(16) unsigned short As[BM * 40];
    __shared__ __align__(16) unsigned short Bs[BN * 40];
    int tid = threadIdx.x, lane = tid & 63, w = tid >> 6;
    int l16 = lane & 15, lhi = lane >> 4;
    int wm = w / WN, wn = w % WN;
    int m0 = blockIdx.y * BM, n0 = blockIdx.x * BN;

    f32x4 acc[MI][NI];
#pragma unroll
    for (int mi = 0; mi < MI; mi++)
#pragma unroll
        for (int ni = 0; ni < NI; ni++) acc[mi][ni] = (f32x4){0.f, 0.f, 0.f, 0.f};

    for (int k0 = 0; k0 < K; k0 += 32) {
        for (int i = tid; i < BM * 8; i += TPB) {
            int row = i >> 3, kc = (i & 7) * 4;
            int r = m0 + row;
            const float* srow;
            float mu = 0.f, rs = 1.f;
            if (ASRC == 0) {
                srow = A0 + (size_t)r * K;
            } else if (ASRC == 1) {
                int b = r >> 11, t = r & 2047;
                bool cam = t < 1024;
                int tok = (cam ? b : 8 + b) * 1024 + (t & 1023);
                srow = (cam ? A0 : A1) + (size_t)(b * 1024 + (t & 1023)) * 128;
                mu = me[tok]; rs = re[tok];
            } else {
                srow = ((r < 8192) ? A0 : A1) + (size_t)(r & 8191) * 128;
                mu = me[r]; rs = re[r];
            }
            float4 va = *(const float4*)&srow[k0 + kc];
            ushort4 u;
            u.x = f2bf((va.x - mu) * rs); u.y = f2bf((va.y - mu) * rs);
            u.z = f2bf((va.z - mu) * rs); u.w = f2bf((va.w - mu) * rs);
            *(ushort4*)&As[row * 40 + kc] = u;
        }
        for (int i = tid; i < BN * 4; i += TPB) {
            int n = i >> 2, kc = (i & 3) * 8;
            *(bf16x8*)&Bs[n * 40 + kc] = *(const bf16x8*)&BT[(size_t)(n0 + n) * K + k0 + kc];
        }
        __syncthreads();
        bf16x8 af[MI], bfr[NI];
#pragma unroll
        for (int mi = 0; mi < MI; mi++)
            af[mi] = *(bf16x8*)&As[(wm * (BM / WM) + mi * 16 + l16) * 40 + lhi * 8];
#pragma unroll
        for (int ni = 0; ni < NI; ni++)
            bfr[ni] = *(bf16x8*)&Bs[(wn * (BN / WN) + ni * 16 + l16) * 40 + lhi * 8];
#pragma unroll
        for (int mi = 0; mi < MI; mi++)
#pragma unroll
            for (int ni = 0; ni < NI; ni++)
                acc[mi][ni] = __builtin_amdgcn_mfma_f32_16x16x32_bf16(af[mi], bfr[ni], acc[mi][ni], 0, 0, 0);
        __syncthreads();
    }
#pragma unroll
    for (int mi = 0; mi < MI; mi++) {
#pragma unroll
        for (int ni = 0; ni < NI; ni++) {
            int col = n0 + wn * (BN / WN) + ni * 16 + l16;
            float bc = bias[col];
            if (mode == 7) {
                int row0 = m0 + wm * (BM / WM) + mi * 16 + lhi * 4;
                int bb = row0 >> 10, t0 = row0 & 1023;
                ushort4 u;
                u.x = f2bf(acc[mi][ni][0] + bc); u.y = f2bf(acc[mi][ni][1] + bc);
                u.z = f2bf(acc[mi][ni][2] + bc); u.w = f2bf(acc[mi][ni][3] + bc);
                *(ushort4*)&C16[(((size_t)(bb * 4 + (col >> 7))) * 128 + (col & 127)) * 1024 + t0] = u;
            } else {
#pragma unroll
                for (int rg = 0; rg < 4; rg++) {
                    int row = m0 + wm * (BM / WM) + mi * 16 + lhi * 4 + rg;
                    float v = acc[mi][ni][rg];
                    if (mode == 4) {
                        int bb = row >> sT, t = row & ((1 << sT) - 1);
                        size_t oa = ((((size_t)bb * 4 + (col >> 7)) << sT) + t) * 128 + (col & 127);
                        C16[oa] = f2bf((v + bc) * scale);
                    } else {  // mode 8
                        C16[(size_t)row * N + col] = f2bf(gelu_exact(v + bc));
                    }
                }
            }
        }
    }
}

// ---------------------------------------------------------------------------
// GEMM (BM=64, BN=128=N) + bias + skip/residual + LayerNorm fused. A is bf16.
// ---------------------------------------------------------------------------
__global__ __launch_bounds__(256, 2) void k_gemm_ln(
        const unsigned short* __restrict__ Ab, const unsigned short* __restrict__ BT,
        float* __restrict__ C0, float* __restrict__ C1, int K, int mode,
        const float* __restrict__ bias, const float* __restrict__ aux,
        const float* __restrict__ aux2,
        const float* __restrict__ g, const float* __restrict__ bvec) {
    __shared__ __align__(16) char shm[64 * 132 * 4];
    unsigned short* As = (unsigned short*)shm;
    unsigned short* Bs = As + 64 * 40;
    float* Cs = (float*)shm;
    int tid = threadIdx.x, lane = tid & 63, w = tid >> 6;
    int l16 = lane & 15, lhi = lane >> 4;
    int m0 = blockIdx.x * 64;

    f32x4 acc[4][2];
#pragma unroll
    for (int mi = 0; mi < 4; mi++)
#pragma unroll
        for (int ni = 0; ni < 2; ni++) acc[mi][ni] = (f32x4){0.f, 0.f, 0.f, 0.f};

    for (int k0 = 0; k0 < K; k0 += 32) {
        for (int i = tid; i < 256; i += TPB) {
            int row = i >> 2, kc = (i & 3) * 8;
            *(bf16x8*)&As[row * 40 + kc] =
                *(const bf16x8*)&Ab[(size_t)(m0 + row) * K + k0 + kc];
        }
        for (int i = tid; i < 512; i += TPB) {
            int n = i >> 2, kc = (i & 3) * 8;
            *(bf16x8*)&Bs[n * 40 + kc] = *(const bf16x8*)&BT[(size_t)n * K + k0 + kc];
        }
        __syncthreads();
        bf16x8 af[4], bfr[2];
#pragma unroll
        for (int mi = 0; mi < 4; mi++)
            af[mi] = *(bf16x8*)&As[(mi * 16 + l16) * 40 + lhi * 8];
#pragma unroll
        for (int ni = 0; ni < 2; ni++)
            bfr[ni] = *(bf16x8*)&Bs[(w * 32 + ni * 16 + l16) * 40 + lhi * 8];
#pragma unroll
        for (int mi = 0; mi < 4; mi++)
#pragma unroll
            for (int ni = 0; ni < 2; ni++)
                acc[mi][ni] = __builtin_amdgcn_mfma_f32_16x16x32_bf16(af[mi], bfr[ni], acc[mi][ni], 0, 0, 0);
        __syncthreads();
    }
#pragma unroll
    for (int mi = 0; mi < 4; mi++) {
#pragma unroll
        for (int ni = 0; ni < 2; ni++) {
            int col = w * 32 + ni * 16 + l16;
#pragma unroll
            for (int rg = 0; rg < 4; rg++) {
                int rl = mi * 16 + lhi * 4 + rg;
                int grow = m0 + rl;
                float v = acc[mi][ni][rg] + bias[col];
                if (mode == 0) {
                    int rr = grow & 16383;
                    int b = rr >> 11, s = rr & 2047;
                    int H = s >> 6, W = s & 63;
                    const float* sp = (W < 32) ? aux : aux2;
                    v += sp[((size_t)(b * 1024 + H * 32 + (W & 31))) * 128 + col];
                } else {
                    v += aux[(size_t)grow * 128 + col];
                }
                Cs[rl * 132 + col] = v;
            }
        }
    }
    __syncthreads();
    for (int rr = 0; rr < 16; rr++) {
        int row = w * 16 + rr, grow = m0 + row;
        float x0 = Cs[row * 132 + lane], x1 = Cs[row * 132 + 64 + lane];
        float s = x0 + x1, s2 = x0 * x0 + x1 * x1;
#pragma unroll
        for (int m = 32; m; m >>= 1) { s += __shfl_xor(s, m); s2 += __shfl_xor(s2, m); }
        float mu = s * (1.f / 128.f);
        float var = s2 * (1.f / 128.f) - mu * mu;
        float rs = rsqrtf(var + 1e-5f);
        float* Cp;
        size_t ro;
        if (mode == 1) { Cp = (grow < 16384) ? C0 : C1; ro = (size_t)(grow & 16383) * 128; }
        else           { Cp = C0; ro = (size_t)grow * 128; }
        Cp[ro + lane]      = (x0 - mu) * rs * g[lane] + bvec[lane];
        Cp[ro + lane + 64] = (x1 - mu) * rs * g[lane + 64] + bvec[lane + 64];
    }
}

// ---------------------------------------------------------------------------
// ConvTranspose, ALL THREE outputs in one launch. grid (4, 40, 8):
// y 0..7 -> fused (M=1024,Hin=32); 8..23 -> cam; 24..39 -> lid (M=2048,Hin=64).
// Fused instance-norm+ReLU on A; pair-shfl float4 coalesced writes.
// ---------------------------------------------------------------------------
__global__ __launch_bounds__(256, 2) void k_convt_gemm(
        const float* __restrict__ srcF, const float* __restrict__ srcC,
        const float* __restrict__ srcL, const float* __restrict__ stats,
        const unsigned short* __restrict__ ctT, float* __restrict__ outp) {
    __shared__ __align__(16) unsigned short As[128 * 40];
    __shared__ __align__(16) unsigned short Bs[128 * 40];
    int tid = threadIdx.x, lane = tid & 63, w = tid >> 6;
    int l16 = lane & 15, lhi = lane >> 4;
    int wm = w >> 1, wn = w & 1;
    int my = blockIdx.y, n0 = blockIdx.x * 128, b = blockIdx.z;
    const float* src; const float* mean; const float* rstd; float* out;
    int M, Hin, m0;
    if (my < 8)       { src = srcF; mean = stats + 4096; rstd = stats + 5120;
                        out = outp;            M = 1024; Hin = 32; m0 = my * 128; }
    else if (my < 24) { src = srcC; mean = stats + 6144; rstd = stats + 7168;
                        out = outp + 4194304;  M = 2048; Hin = 64; m0 = (my - 8) * 128; }
    else              { src = srcL; mean = stats + 8192; rstd = stats + 9216;
                        out = outp + 12582912; M = 2048; Hin = 64; m0 = (my - 24) * 128; }
    const float* Ab = src + (size_t)b * M * 128;
    const float* mb = mean + b * 128;
    const float* rb = rstd + b * 128;

    f32x4 acc[4][4];
#pragma unroll
    for (int mi = 0; mi < 4; mi++)
#pragma unroll
        for (int ni = 0; ni < 4; ni++) acc[mi][ni] = (f32x4){0.f, 0.f, 0.f, 0.f};

    for (int k0 = 0; k0 < 128; k0 += 32) {
        for (int i = tid; i < 1024; i += TPB) {
            int row = i >> 3, kc = (i & 7) * 4;
            float4 va = *(const float4*)&Ab[(size_t)(m0 + row) * 128 + k0 + kc];
            float4 mn = *(const float4*)&mb[k0 + kc];
            float4 rs = *(const float4*)&rb[k0 + kc];
            ushort4 u;
            u.x = f2bf(fmaxf((va.x - mn.x) * rs.x, 0.f));
            u.y = f2bf(fmaxf((va.y - mn.y) * rs.y, 0.f));
            u.z = f2bf(fmaxf((va.z - mn.z) * rs.z, 0.f));
            u.w = f2bf(fmaxf((va.w - mn.w) * rs.w, 0.f));
            *(ushort4*)&As[row * 40 + kc] = u;
        }
        for (int i = tid; i < 512; i += TPB) {
            int n = i >> 2, kc = (i & 3) * 8;
            *(bf16x8*)&Bs[n * 40 + kc] = *(const bf16x8*)&ctT[(size_t)(n0 + n) * 128 + k0 + kc];
        }
        __syncthreads();
        bf16x8 af[4], bfr[4];
#pragma unroll
        for (int mi = 0; mi < 4; mi++)
            af[mi] = *(bf16x8*)&As[(wm * 64 + mi * 16 + l16) * 40 + lhi * 8];
#pragma unroll
        for (int ni = 0; ni < 4; ni++)
            bfr[ni] = *(bf16x8*)&Bs[(wn * 64 + ni * 16 + l16) * 40 + lhi * 8];
#pragma unroll
        for (int mi = 0; mi < 4; mi++)
#pragma unroll
            for (int ni = 0; ni < 4; ni++)
                acc[mi][ni] = __builtin_amdgcn_mfma_f32_16x16x32_bf16(af[mi], bfr[ni], acc[mi][ni], 0, 0, 0);
        __syncthreads();
    }
    int Ho = 2 * Hin, Wo = 64;
#pragma unroll
    for (int mi = 0; mi < 4; mi++) {
#pragma unroll
        for (int ni = 0; ni < 4; ni++) {
            int col = n0 + wn * 64 + ni * 16 + l16;
            int oc = col >> 2, aa = (col >> 1) & 1, dd = col & 1;
            int p0 = m0 + wm * 64 + mi * 16 + lhi * 4;
            int hin = p0 >> 5, win0 = p0 & 31;
            float s0 = __shfl_xor(acc[mi][ni][0], 1);
            float s1 = __shfl_xor(acc[mi][ni][1], 1);
            float s2 = __shfl_xor(acc[mi][ni][2], 1);
            float s3 = __shfl_xor(acc[mi][ni][3], 1);
            float4 o;
            if (!dd) o = make_float4(acc[mi][ni][0], s0, acc[mi][ni][1], s1);
            else     o = make_float4(s2, acc[mi][ni][2], s3, acc[mi][ni][3]);
            size_t addr = (((size_t)b * 128 + oc) * Ho + 2 * hin + aa) * Wo
                        + 2 * win0 + (dd ? 4 : 0);
            *(float4*)&out[addr] = o;
        }
    }
}

// ---------------------------------------------------------------------------
// bf16 flash attention: swapped-QK^T, exp2 domain, cvt_pk packing, async-stage
// prefetch, XCD-aware 1D grid (each XCD owns 8 (h,z) pairs -> K/V L2-resident).
// 1024 blocks, 128 q-rows each, 64-key chunks, 48 KB LDS, 2 barriers/chunk.
// ---------------------------------------------------------------------------
__global__ __launch_bounds__(256, 2) void k_attn_bf16(
        const unsigned short* __restrict__ qb, const unsigned short* __restrict__ kb,
        const unsigned short* __restrict__ vt, unsigned short* __restrict__ aout) {
    __shared__ __align__(16) unsigned short smem[24576];  // 48 KB
    unsigned short* Ks = smem;            // [64][128], 16B-slot ^row swizzle
    unsigned short* Vt = smem + 8192;     // [128][64], ^d swizzle
    unsigned short* Ps = smem + 16384;    // 4 waves x [32][64]
    int tid = threadIdx.x;
    int lane = tid & 63, w = tid >> 6;
    int l16 = lane & 15, lhi = lane >> 4;
    // XCD-aware decode: XCD = bid&7 owns hz in [8*XCD, 8*XCD+8)
    int bid = blockIdx.x;
    int xcd = bid & 7, j = bid >> 3;
    int hz = xcd * 8 + (j >> 4);
    int qt = j & 15;
    int h = hz & 3, z = hz >> 2;
    int bh_q = (z & 7) * 4 + h;
    int bh_kv = z * 4 + h;
    unsigned short* Pw = Ps + w * 2048;

    const unsigned short* qg = qb + ((size_t)bh_q * 2048 + qt * 128) * 128;
    bf16x8 qa[2][4];
#pragma unroll
    for (int mt = 0; mt < 2; mt++) {
        int r = w * 32 + mt * 16 + l16;
#pragma unroll
        for (int ks = 0; ks < 4; ks++)
            qa[mt][ks] = *(const bf16x8*)&qg[(size_t)r * 128 + ks * 32 + lhi * 8];
    }

    f32x4 acc[2][8];
#pragma unroll
    for (int mt = 0; mt < 2; mt++)
#pragma unroll
        for (int dt = 0; dt < 8; dt++) acc[mt][dt] = (f32x4){0.f, 0.f, 0.f, 0.f};
    float m_r[2] = {-1e30f, -1e30f};
    float l_r[2] = {0.f, 0.f};

    const unsigned short* kg = kb + (size_t)bh_kv * 131072;
    const unsigned short* vg = vt + (size_t)bh_kv * 131072;

    int krow = tid >> 4, kcol = (tid & 15) * 8;
    int kls = ((tid & 15) ^ (krow & 7)) << 3;
    int vrow = tid >> 3, vcol = (tid & 7) * 8;
    int vls = ((tid & 7) ^ (vrow & 7)) << 3;

#pragma unroll
    for (int jj = 0; jj < 4; jj++) {
        int r = krow + jj * 16;
        *(bf16x8*)&Ks[r * 128 + kls] = *(const bf16x8*)&kg[(size_t)r * 128 + kcol];
        int d = vrow + jj * 32;
        *(bf16x8*)&Vt[d * 64 + vls] = *(const bf16x8*)&vg[(size_t)d * 1024 + vcol];
    }
    __syncthreads();

    for (int c = 0; c < 16; c++) {
        bf16x8 kpre[4], vpre[4];
        if (c < 15) {
            int c0 = (c + 1) * 64;
#pragma unroll
            for (int jj = 0; jj < 4; jj++) {
                kpre[jj] = *(const bf16x8*)&kg[(size_t)(c0 + krow + jj * 16) * 128 + kcol];
                vpre[jj] = *(const bf16x8*)&vg[(size_t)(vrow + jj * 32) * 1024 + c0 + vcol];
            }
        }

        // QK^T swapped: S^T[key][q]
        f32x4 s[2][4];
#pragma unroll
        for (int mt = 0; mt < 2; mt++)
#pragma unroll
            for (int kt = 0; kt < 4; kt++) s[mt][kt] = (f32x4){0.f, 0.f, 0.f, 0.f};
#pragma unroll
        for (int kt = 0; kt < 4; kt++) {
            int r = kt * 16 + l16;
#pragma unroll
            for (int ks = 0; ks < 4; ks++) {
                bf16x8 kf = *(bf16x8*)&Ks[r * 128 + (((ks * 4 + lhi) ^ (r & 7)) << 3)];
                s[0][kt] = __builtin_amdgcn_mfma_f32_16x16x32_bf16(kf, qa[0][ks], s[0][kt], 0, 0, 0);
                s[1][kt] = __builtin_amdgcn_mfma_f32_16x16x32_bf16(kf, qa[1][ks], s[1][kt], 0, 0, 0);
            }
        }

        float pm[2];
#pragma unroll
        for (int mt = 0; mt < 2; mt++) {
            float a = s[mt][0][0];
#pragma unroll
            for (int kt = 0; kt < 4; kt++)
#pragma unroll
                for (int rg = 0; rg < 4; rg++) a = fmaxf(a, s[mt][kt][rg]);
            a = fmaxf(a, __shfl_xor(a, 16));
            a = fmaxf(a, __shfl_xor(a, 32));
            pm[mt] = a;
        }
        bool need = (pm[0] > m_r[0] + 8.f) || (pm[1] > m_r[1] + 8.f);
        if (__any(need)) {
#pragma unroll
            for (int mt = 0; mt < 2; mt++) {
                float mn = fmaxf(m_r[mt], pm[mt]);
                float f = __builtin_amdgcn_exp2f(m_r[mt] - mn);
                m_r[mt] = mn;
                l_r[mt] *= f;
#pragma unroll
                for (int rg = 0; rg < 4; rg++) {
                    float ft = __shfl(f, lhi * 4 + rg);
#pragma unroll
                    for (int dt = 0; dt < 8; dt++) acc[mt][dt][rg] *= ft;
                }
            }
        }

#pragma unroll
        for (int mt = 0; mt < 2; mt++) {
            int row = mt * 16 + l16;
            int rsw = row & 7;
            float ls = 0.f;
#pragma unroll
            for (int kt = 0; kt < 4; kt++) {
                float p0 = __builtin_amdgcn_exp2f(s[mt][kt][0] - m_r[mt]);
                float p1 = __builtin_amdgcn_exp2f(s[mt][kt][1] - m_r[mt]);
                float p2 = __builtin_amdgcn_exp2f(s[mt][kt][2] - m_r[mt]);
                float p3 = __builtin_amdgcn_exp2f(s[mt][kt][3] - m_r[mt]);
                ls += (p0 + p1) + (p2 + p3);
                unsigned u01, u23;
                asm("v_cvt_pk_bf16_f32 %0, %1, %2" : "=v"(u01) : "v"(p0), "v"(p1));
                asm("v_cvt_pk_bf16_f32 %0, %1, %2" : "=v"(u23) : "v"(p2), "v"(p3));
                int slot = kt * 2 + (lhi >> 1);
                int base = row * 64 + ((slot ^ rsw) << 3) + (lhi & 1) * 4;
                *(unsigned*)&Pw[base] = u01;
                *(unsigned*)&Pw[base + 2] = u23;
            }
            l_r[mt] += ls;
        }
        asm volatile("s_waitcnt lgkmcnt(0)" ::: "memory");

        bf16x8 pa0[2], pa1[2];
#pragma unroll
        for (int mt = 0; mt < 2; mt++) {
            int row = mt * 16 + l16;
            pa0[mt] = *(bf16x8*)&Pw[row * 64 + ((lhi ^ (row & 7)) << 3)];
            pa1[mt] = *(bf16x8*)&Pw[row * 64 + (((4 + lhi) ^ (row & 7)) << 3)];
        }
#pragma unroll
        for (int dt = 0; dt < 8; dt++) {
            int d = dt * 16 + l16;
            bf16x8 vb0 = *(bf16x8*)&Vt[d * 64 + ((lhi ^ (d & 7)) << 3)];
            bf16x8 vb1 = *(bf16x8*)&Vt[d * 64 + (((4 + lhi) ^ (d & 7)) << 3)];
            acc[0][dt] = __builtin_amdgcn_mfma_f32_16x16x32_bf16(pa0[0], vb0, acc[0][dt], 0, 0, 0);
            acc[0][dt] = __builtin_amdgcn_mfma_f32_16x16x32_bf16(pa1[0], vb1, acc[0][dt], 0, 0, 0);
            acc[1][dt] = __builtin_amdgcn_mfma_f32_16x16x32_bf16(pa0[1], vb0, acc[1][dt], 0, 0, 0);
            acc[1][dt] = __builtin_amdgcn_mfma_f32_16x16x32_bf16(pa1[1], vb1, acc[1][dt], 0, 0, 0);
        }
        __syncthreads();

        if (c < 15) {
#pragma unroll
            for (int jj = 0; jj < 4; jj++) {
                *(bf16x8*)&Ks[(krow + jj * 16) * 128 + kls] = kpre[jj];
                *(bf16x8*)&Vt[(vrow + jj * 32) * 64 + vls] = vpre[jj];
            }
            __syncthreads();
        }
    }

#pragma unroll
    for (int mt = 0; mt < 2; mt++) {
        float lt = l_r[mt];
        lt += __shfl_xor(lt, 16);
        lt += __shfl_xor(lt, 32);
        l_r[mt] = lt;
    }
    size_t obase = (size_t)(z >> 3) * 16384 + (size_t)(z & 7) * 2048;
#pragma unroll
    for (int mt = 0; mt < 2; mt++)
#pragma unroll
        for (int rg = 0; rg < 4; rg++) {
            float linv = 1.f / __shfl(l_r[mt], lhi * 4 + rg);
            int qrow = qt * 128 + w * 32 + mt * 16 + lhi * 4 + rg;
            unsigned short* orow = aout + (obase + qrow) * 512 + h * 128;
#pragma unroll
            for (int dt = 0; dt < 8; dt++)
                orow[dt * 16 + l16] = f2bf(acc[mt][dt][rg] * linv);
        }
}

// ---------------------------------------------------------------------------
// fused_s write + stats partials in one pass. grid (16, 8).
// ---------------------------------------------------------------------------
__global__ void k_fused_stats(const float* __restrict__ zc, const float* __restrict__ zl,
                              float* __restrict__ fs, float* __restrict__ part) {
    int c = blockIdx.x, b = blockIdx.y;
    int tid = threadIdx.x;
    int d = tid & 127, half = tid >> 7;
    size_t base0 = ((size_t)b * 2048 + c * 64) * 128;
    size_t base1 = ((size_t)b * 2048 + 1024 + c * 64) * 128;
    float s = 0.f, s2 = 0.f;
    for (int t = half; t < 64; t += 2) {
        float v = zc[base0 + t * 128 + d] + zc[base1 + t * 128 + d]
                + zl[base0 + t * 128 + d] + zl[base1 + t * 128 + d];
        fs[((size_t)b * 1024 + c * 64 + t) * 128 + d] = v;
        s += v; s2 += v * v;
    }
    __shared__ float ls[256], ls2[256];
    ls[tid] = s; ls2[tid] = s2;
    __syncthreads();
    if (tid < 128) {
        s = ls[tid] + ls[tid + 128];
        s2 = ls2[tid] + ls2[tid + 128];
        float* p = part + ((size_t)(b * 16 + c) * 2) * 128;
        p[d] = s; p[128 + d] = s2;
    }
}

// ---------------------------------------------------------------------------
extern "C" void kernel_launch(void* const* d_in, const int* in_sizes, int n_in,
                              void* d_out, int out_size, void* d_ws, size_t ws_size,
                              hipStream_t stream) {
    const float* cam_feat = (const float*)d_in[0];
    const float* lid_feat = (const float*)d_in[1];
    const float* pos      = (const float*)d_in[2];
    const float* conv_w   = (const float*)d_in[3];
    const float* convT_w  = (const float*)d_in[4];
    const float* lnq_g = (const float*)d_in[5];
    const float* lnq_b = (const float*)d_in[6];
    const float* wq    = (const float*)d_in[7];
    const float* lnk_g = (const float*)d_in[8];
    const float* lnk_b = (const float*)d_in[9];
    const float* wk    = (const float*)d_in[10];
    const float* lnv_g = (const float*)d_in[11];
    const float* lnv_b = (const float*)d_in[12];
    const float* wv    = (const float*)d_in[13];
    const float* proj_w = (const float*)d_in[14];
    const float* proj_b = (const float*)d_in[15];
    const float* pre_g = (const float*)d_in[16];
    const float* pre_b = (const float*)d_in[17];
    const float* mlp_w1 = (const float*)d_in[18];
    const float* mlp_b1 = (const float*)d_in[19];
    const float* mlp_w2 = (const float*)d_in[20];
    const float* mlp_b2 = (const float*)d_in[21];
    const float* post_g = (const float*)d_in[22];
    const float* post_b = (const float*)d_in[23];

    float* ws = (float*)d_ws;
    float* outp = (float*)d_out;

    // persistent buffers (floats)
    float* cam_eT  = ws + 0;               // 1,048,576
    float* lid_eT  = ws + 1048576;         // 1,048,576
    unsigned short* qbf16 = (unsigned short*)(ws + 2097152);   // 4,194,304 f
    float* z_cam   = ws + 6291456;         // 2,097,152
    float* z_lid   = ws + 8388608;         // 2,097,152
    float* fused_s = ws + 10485760;        // 1,048,576
    float* stats   = ws + 11534336;        // 16,384
    unsigned short* wbuf = (unsigned short*)(ws + 11550720);   // 196,608 f
    float* part    = ws + 11747328;        // 131,072
    float* mean_e  = ws + 11878400;        // 16,384
    float* rstd_e  = ws + 11894784;        // 16,384
    float* bvecs   = ws + 11911168;        // 1,536
    unsigned short* xcolT = (unsigned short*)(ws + 11912704);  // 4,194,304 f
    float* pool    = ws + 16107008;        // 16,777,216

    unsigned short* wqT   = wbuf + 0;
    unsigned short* wkT   = wbuf + 65536;
    unsigned short* wvT   = wbuf + 131072;
    unsigned short* projT = wbuf + 196608;
    unsigned short* m1T   = wbuf + 262144;
    unsigned short* m2T   = wbuf + 294912;
    unsigned short* ctT   = wbuf + 327680;

    float* meanA = stats + 0,    *rstdA = stats + 2048;
    float* meanF = stats + 4096, *rstdF = stats + 5120;
    float* meanC = stats + 6144, *rstdC = stats + 7168;
    float* meanL = stats + 8192, *rstdL = stats + 9216;
    float* bq = bvecs, *bk = bvecs + 512, *bv = bvecs + 1024;

    // pool (timeline-overlapped)
    unsigned short* kbf16 = (unsigned short*)(pool + 0);        // 4,194,304 f
    unsigned short* vbfT  = (unsigned short*)(pool + 4194304);  // 4,194,304 f
    unsigned short* abuf  = (unsigned short*)(pool + 8388608);  // 8,388,608 f
    float* z2 = pool + 0;                                       // over dead kbf16
    unsigned short* h1 = (unsigned short*)(pool + 4194304);     // over dead vbfT

    // 1/sqrt(128) * log2(e): attention softmax runs in the exp2 domain
    const float qscale = 0.12751744436f;

    // Weight prep + bias vectors
    k_wtrans_all<<<384, TPB, 0, stream>>>(wq, wk, wv, proj_w, mlp_w1, mlp_w2, convT_w,
                                          lnq_g, lnk_g, lnv_g,
                                          wqT, wkT, wvT, projT, m1T, m2T, ctT);
    k_bias_vec<<<6, TPB, 0, stream>>>(wq, wk, wv, lnq_b, lnk_b, lnv_b, bvecs);

    // Stage A: stats + conv encoders (conv epilogue emits per-token LN stats)
    k_stats_cm<<<2048, TPB, 0, stream>>>(cam_feat, lid_feat, pos, meanA, rstdA);
    k_prep<<<dim3(32, 16), TPB, 0, stream>>>(cam_feat, lid_feat, pos, meanA, rstdA, xcolT);
    k_conv_gemm<<<dim3(16, 1, 16), TPB, 0, stream>>>(conv_w, xcolT, cam_eT, lid_eT,
                                                     mean_e, rstd_e);

    // Q/K/V GEMMs with LN folded in; attention; tail
    k_gemm_mfma<128, 128, 2, 2, 1><<<dim3(4, 128), TPB, 0, stream>>>(
        cam_eT, lid_eT, mean_e, rstd_e, wqT, qbf16, 16384, 512, 128, 4, bq, 11, qscale);
    k_gemm_mfma<128, 128, 2, 2, 2><<<dim3(4, 128), TPB, 0, stream>>>(
        cam_eT, lid_eT, mean_e, rstd_e, wkT, kbf16, 16384, 512, 128, 4, bk, 10, 1.f);
    k_gemm_mfma<128, 128, 2, 2, 2><<<dim3(4, 128), TPB, 0, stream>>>(
        cam_eT, lid_eT, mean_e, rstd_e, wvT, vbfT, 16384, 512, 128, 7, bv, 0, 1.f);
    k_attn_bf16<<<1024, TPB, 0, stream>>>(qbf16, kbf16, vbfT, abuf);
    k_gemm_ln<<<512, TPB, 0, stream>>>(
        abuf, projT, z2, nullptr, 512, 0, proj_b, cam_eT, lid_eT, pre_g, pre_b);
    k_gemm_mfma<128, 128, 2, 2, 0><<<dim3(2, 256), TPB, 0, stream>>>(
        z2, nullptr, nullptr, nullptr, m1T, h1, 32768, 256, 128, 8, mlp_b1, 0, 1.f);
    k_gemm_ln<<<512, TPB, 0, stream>>>(
        h1, m2T, z_cam, z_lid, 256, 1, mlp_b2, z2, nullptr, post_g, post_b);

    // Outputs
    k_fused_stats<<<dim3(16, 8), TPB, 0, stream>>>(z_cam, z_lid, fused_s, part);
    k_stats_red<<<8, 128, 0, stream>>>(part, meanF, rstdF, 16, 1024);
    k_stats_part2<<<dim3(32, 8, 2), TPB, 0, stream>>>(z_cam, z_lid, part);
    k_stats_red2<<<16, 128, 0, stream>>>(part, meanC, rstdC, meanL, rstdL);
    k_convt_gemm<<<dim3(4, 40, 8), TPB, 0, stream>>>(fused_s, z_cam, z_lid, stats,
                                                     ctT, outp);
}

// Round 11
// 298.196 us; speedup vs baseline: 17.2604x; 1.1374x over previous
//
#include <hip/hip_runtime.h>
#include <math.h>

#define TPB 256

typedef __attribute__((ext_vector_type(8))) short bf16x8;
typedef __attribute__((ext_vector_type(4))) float f32x4;

__device__ __forceinline__ float gelu_exact(float x) {
    return 0.5f * x * (1.0f + erff(x * 0.70710678118654752f));
}

__device__ __forceinline__ unsigned short f2bf(float x) {
    unsigned u = __float_as_uint(x);
    return (unsigned short)((u + 0x7fffu + ((u >> 16) & 1u)) >> 16);
}

// ---------------------------------------------------------------------------
// Stage-A instance-norm stats (x + pos broadcast), 2048 channels.
// ---------------------------------------------------------------------------
__global__ void k_stats_cm(const float* __restrict__ x0, const float* __restrict__ x1,
                           const float* __restrict__ pos, float* __restrict__ mean,
                           float* __restrict__ rstd) {
    int gc = blockIdx.x;
    const float* src = ((gc < 1024) ? x0 : x1) + (size_t)(gc & 1023) * 4096;
    const float* posr = pos + (size_t)(gc & 127) * 4096;
    float s = 0.f, s2 = 0.f;
    for (int p = threadIdx.x; p < 4096; p += TPB) {
        float v = src[p] + posr[p];
        s += v; s2 += v * v;
    }
#pragma unroll
    for (int m = 32; m; m >>= 1) { s += __shfl_xor(s, m); s2 += __shfl_xor(s2, m); }
    __shared__ float ls[4], ls2[4];
    int w = threadIdx.x >> 6;
    if ((threadIdx.x & 63) == 0) { ls[w] = s; ls2[w] = s2; }
    __syncthreads();
    if (threadIdx.x == 0) {
        s = ls[0] + ls[1] + ls[2] + ls[3];
        s2 = ls2[0] + ls2[1] + ls2[2] + ls2[3];
        float mu = s / 4096.f;
        float var = s2 / 4096.f - mu * mu;
        mean[gc] = mu;
        rstd[gc] = rsqrtf(var + 1e-5f);
    }
}

// ---------------------------------------------------------------------------
// Token-major stats reduces.
// ---------------------------------------------------------------------------
__global__ void k_stats_red(const float* __restrict__ part, float* __restrict__ mean,
                            float* __restrict__ rstd, int nc, int T) {
    int b = blockIdx.x, d = threadIdx.x;
    float s = 0.f, s2 = 0.f;
    for (int c = 0; c < nc; c++) {
        const float* p = part + ((size_t)(b * nc + c) * 2) * 128;
        s += p[d]; s2 += p[128 + d];
    }
    float mu = s / (float)T;
    float var = s2 / (float)T - mu * mu;
    mean[b * 128 + d] = mu;
    rstd[b * 128 + d] = rsqrtf(var + 1e-5f);
}

__global__ void k_stats_red2(const float* __restrict__ part,
                             float* __restrict__ meanC, float* __restrict__ rstdC,
                             float* __restrict__ meanL, float* __restrict__ rstdL) {
    int idx = blockIdx.x, d = threadIdx.x;
    int sel = idx >> 3, b = idx & 7;
    float s = 0.f, s2 = 0.f;
    for (int c = 0; c < 32; c++) {
        const float* p = part + ((size_t)((sel * 8 + b) * 32 + c) * 2) * 128;
        s += p[d]; s2 += p[128 + d];
    }
    float mu = s / 2048.f;
    float var = s2 / 2048.f - mu * mu;
    float* mean = sel ? meanL : meanC;
    float* rstd = sel ? rstdL : rstdC;
    mean[b * 128 + d] = mu;
    rstd[b * 128 + d] = rsqrtf(var + 1e-5f);
}

// ---------------------------------------------------------------------------
// Conv prep (cam+lid merged): normalize+ReLU+im2col -> bf16 xcolT[bb][p][512].
// ---------------------------------------------------------------------------
__global__ void k_prep(const float* __restrict__ cam, const float* __restrict__ lid,
                       const float* __restrict__ pos, const float* __restrict__ mean,
                       const float* __restrict__ rstd, unsigned short* __restrict__ xcolT) {
    __shared__ unsigned short T[32 * 520];
    int h = blockIdx.x, bb = blockIdx.y;
    int b = bb & 7, so = (bb < 8) ? 0 : 1024;
    const float* x = (bb < 8) ? cam : lid;
    int tid = threadIdx.x;
    for (int i = tid; i < 4096; i += TPB) {
        int c = i >> 5, w = i & 31;
        int ch = b * 128 + c;
        const float* xr = x + (size_t)ch * 4096 + (2 * h) * 64 + 2 * w;
        const float* pr = pos + (size_t)c * 4096 + (2 * h) * 64 + 2 * w;
        float mu = mean[so + ch], rs = rstd[so + ch];
        float2 x0 = *(const float2*)xr;
        float2 x1 = *(const float2*)(xr + 64);
        float2 p0 = *(const float2*)pr;
        float2 p1 = *(const float2*)(pr + 64);
        ushort4 u;
        u.x = f2bf(fmaxf((x0.x + p0.x - mu) * rs, 0.f));
        u.y = f2bf(fmaxf((x0.y + p0.y - mu) * rs, 0.f));
        u.z = f2bf(fmaxf((x1.x + p1.x - mu) * rs, 0.f));
        u.w = f2bf(fmaxf((x1.y + p1.y - mu) * rs, 0.f));
        *(ushort4*)&T[w * 520 + c * 4] = u;
    }
    __syncthreads();
    unsigned short* dst = xcolT + ((size_t)bb * 1024 + h * 32) * 512;
    for (int i = tid; i < 2048; i += TPB) {
        int w = i >> 6, kk = (i & 63) * 8;
        *(bf16x8*)&dst[(size_t)w * 512 + kk] = *(bf16x8*)&T[w * 520 + kk];
    }
}

// ---------------------------------------------------------------------------
// Conv as batched MFMA GEMM (cam+lid merged) + per-token LN stats epilogue.
// grid (16, 1, 16).
// ---------------------------------------------------------------------------
__global__ __launch_bounds__(256, 2) void k_conv_gemm(
        const float* __restrict__ W, const unsigned short* __restrict__ xcolT,
        float* __restrict__ camT, float* __restrict__ lidT,
        float* __restrict__ mean_e, float* __restrict__ rstd_e) {
    __shared__ __align__(16) unsigned short As[128 * 40];
    __shared__ __align__(16) unsigned short Bs[64 * 40];
    __shared__ float red[2048];
    int tid = threadIdx.x, lane = tid & 63, w = tid >> 6;
    int l16 = lane & 15, lhi = lane >> 4;
    int n0 = blockIdx.x * 64, bb = blockIdx.z;
    const unsigned short* BT = xcolT + (size_t)bb * 524288;
    float* eT = ((bb < 8) ? camT : lidT) + (size_t)(bb & 7) * 131072;

    f32x4 acc[2][4];
#pragma unroll
    for (int mi = 0; mi < 2; mi++)
#pragma unroll
        for (int ni = 0; ni < 4; ni++) acc[mi][ni] = (f32x4){0.f, 0.f, 0.f, 0.f};

    for (int k0 = 0; k0 < 512; k0 += 32) {
        for (int i = tid; i < 1024; i += TPB) {
            int row = i >> 3, kc = (i & 7) * 4;
            float4 va = *(const float4*)&W[(size_t)row * 512 + k0 + kc];
            ushort4 u;
            u.x = f2bf(va.x); u.y = f2bf(va.y); u.z = f2bf(va.z); u.w = f2bf(va.w);
            *(ushort4*)&As[row * 40 + kc] = u;
        }
        for (int i = tid; i < 256; i += TPB) {
            int n = i >> 2, kc = (i & 3) * 8;
            *(bf16x8*)&Bs[n * 40 + kc] = *(const bf16x8*)&BT[(size_t)(n0 + n) * 512 + k0 + kc];
        }
        __syncthreads();
        bf16x8 af[2], bfr[4];
#pragma unroll
        for (int mi = 0; mi < 2; mi++)
            af[mi] = *(bf16x8*)&As[(w * 32 + mi * 16 + l16) * 40 + lhi * 8];
#pragma unroll
        for (int ni = 0; ni < 4; ni++)
            bfr[ni] = *(bf16x8*)&Bs[(ni * 16 + l16) * 40 + lhi * 8];
#pragma unroll
        for (int mi = 0; mi < 2; mi++)
#pragma unroll
            for (int ni = 0; ni < 4; ni++)
                acc[mi][ni] = __builtin_amdgcn_mfma_f32_16x16x32_bf16(af[mi], bfr[ni], acc[mi][ni], 0, 0, 0);
        __syncthreads();
    }
#pragma unroll
    for (int mi = 0; mi < 2; mi++)
#pragma unroll
        for (int ni = 0; ni < 4; ni++) {
            int col = n0 + ni * 16 + l16;
            int rowb = w * 32 + mi * 16 + lhi * 4;
            *(float4*)&eT[(size_t)col * 128 + rowb] = *(float4*)&acc[mi][ni];
        }
#pragma unroll
    for (int ni = 0; ni < 4; ni++) {
        float s = 0.f, s2 = 0.f;
#pragma unroll
        for (int mi = 0; mi < 2; mi++)
#pragma unroll
            for (int rg = 0; rg < 4; rg++) {
                float v = acc[mi][ni][rg];
                s += v; s2 += v * v;
            }
        int idx = (ni * 16 + l16) * 16 + w * 4 + lhi;
        red[idx] = s;
        red[1024 + idx] = s2;
    }
    __syncthreads();
    if (tid < 64) {
        int ni = tid >> 4, c16 = tid & 15;
        float s = 0.f, s2 = 0.f;
#pragma unroll
        for (int j = 0; j < 16; j++) {
            s += red[(ni * 16 + c16) * 16 + j];
            s2 += red[1024 + (ni * 16 + c16) * 16 + j];
        }
        int col = n0 + ni * 16 + c16;
        int tok = bb * 1024 + col;
        float mu = s * (1.f / 128.f);
        float var = s2 * (1.f / 128.f) - mu * mu;
        mean_e[tok] = mu;
        rstd_e[tok] = rsqrtf(var + 1e-5f);
    }
}

// ---------------------------------------------------------------------------
// Weight transposes (bid<384, gamma-prescaled Q/K/V) + beta@W bias vectors
// (bid 384..389) in ONE launch. grid 390.
// ---------------------------------------------------------------------------
__global__ void k_wtrans_all(
        const float* __restrict__ wq, const float* __restrict__ wk,
        const float* __restrict__ wv, const float* __restrict__ proj,
        const float* __restrict__ m1, const float* __restrict__ m2,
        const float* __restrict__ ct,
        const float* __restrict__ gq, const float* __restrict__ gk,
        const float* __restrict__ gv,
        const float* __restrict__ bq_in, const float* __restrict__ bk_in,
        const float* __restrict__ bv_in,
        unsigned short* wqT, unsigned short* wkT, unsigned short* wvT,
        unsigned short* projT, unsigned short* m1T, unsigned short* m2T,
        unsigned short* ctT, float* __restrict__ bout) {
    __shared__ float t[32][33];
    int bid = blockIdx.x;
    int tid = threadIdx.x;
    if (bid >= 384) {  // bias vectors: bX[n] = sum_k lnX_b[k]*wX[k][n]
        int i = bid - 384;
        int which = i >> 1, half = i & 1;
        const float* W = (which == 0) ? wq : (which == 1) ? wk : wv;
        const float* bb = (which == 0) ? bq_in : (which == 1) ? bk_in : bv_in;
        int n = half * 256 + tid;
        float s = 0.f;
        for (int k = 0; k < 128; k++) s += bb[k] * W[(size_t)k * 512 + n];
        bout[which * 512 + n] = s;
        return;
    }
    const float* W; unsigned short* WT; const float* sc = nullptr; int K, N, ti;
    if (bid < 64)       { W = wq;   WT = wqT;   sc = gq; K = 128; N = 512; ti = bid; }
    else if (bid < 128) { W = wk;   WT = wkT;   sc = gk; K = 128; N = 512; ti = bid - 64; }
    else if (bid < 192) { W = wv;   WT = wvT;   sc = gv; K = 128; N = 512; ti = bid - 128; }
    else if (bid < 256) { W = proj; WT = projT; K = 512; N = 128; ti = bid - 192; }
    else if (bid < 288) { W = m1;   WT = m1T;   K = 128; N = 256; ti = bid - 256; }
    else if (bid < 320) { W = m2;   WT = m2T;   K = 256; N = 128; ti = bid - 288; }
    else                { W = ct;   WT = ctT;   K = 128; N = 512; ti = bid - 320; }
    int tx = N >> 5;
    int n0 = (ti % tx) * 32, k0 = (ti / tx) * 32;
    for (int i = tid; i < 1024; i += TPB) {
        int r = i >> 5, c = i & 31;
        float v = W[(size_t)(k0 + r) * N + n0 + c];
        if (sc) v *= sc[k0 + r];
        t[r][c] = v;
    }
    __syncthreads();
    for (int i = tid; i < 1024; i += TPB) {
        int r = i >> 5, c = i & 31;
        WT[(size_t)(n0 + r) * K + k0 + c] = f2bf(t[c][r]);
    }
}

// ---------------------------------------------------------------------------
// Merged Q/K/V projection GEMM with fused LN on A. grid (12, 128):
// which = x>>2 (0=Q,1=K,2=V), n0 = (x&3)*128. Q: token-concat row map +
// head-major scaled bf16 out; K: cross-concat + head-major out; V: cross-
// concat + transposed head-major (V^T) out.
// ---------------------------------------------------------------------------
__global__ __launch_bounds__(256, 2) void k_qkv_gemm(
        const float* __restrict__ camT, const float* __restrict__ lidT,
        const float* __restrict__ me, const float* __restrict__ re,
        const unsigned short* __restrict__ wqT, const unsigned short* __restrict__ wkT,
        const unsigned short* __restrict__ wvT,
        unsigned short* __restrict__ qout, unsigned short* __restrict__ kout,
        unsigned short* __restrict__ vout,
        const float* __restrict__ bvecs, float qscale) {
    __shared__ __align__(16) unsigned short As[128 * 40];
    __shared__ __align__(16) unsigned short Bs[128 * 40];
    int tid = threadIdx.x, lane = tid & 63, w = tid >> 6;
    int l16 = lane & 15, lhi = lane >> 4;
    int wm = w >> 1, wn = w & 1;
    int which = blockIdx.x >> 2;
    int n0 = (blockIdx.x & 3) * 128;
    int m0 = blockIdx.y * 128;
    const unsigned short* BT = (which == 0) ? wqT : (which == 1) ? wkT : wvT;
    const float* bias = bvecs + which * 512;

    f32x4 acc[4][4];
#pragma unroll
    for (int mi = 0; mi < 4; mi++)
#pragma unroll
        for (int ni = 0; ni < 4; ni++) acc[mi][ni] = (f32x4){0.f, 0.f, 0.f, 0.f};

    for (int k0 = 0; k0 < 128; k0 += 32) {
        for (int i = tid; i < 1024; i += TPB) {
            int row = i >> 3, kc = (i & 7) * 4;
            int r = m0 + row;
            const float* srow;
            int tok;
            if (which == 0) {
                int b = r >> 11, t = r & 2047;
                bool cam = t < 1024;
                tok = (cam ? b : 8 + b) * 1024 + (t & 1023);
                srow = (cam ? camT : lidT) + (size_t)(b * 1024 + (t & 1023)) * 128;
            } else {
                tok = r;
                srow = ((r < 8192) ? camT : lidT) + (size_t)(r & 8191) * 128;
            }
            float mu = me[tok], rs = re[tok];
            float4 va = *(const float4*)&srow[k0 + kc];
            ushort4 u;
            u.x = f2bf((va.x - mu) * rs); u.y = f2bf((va.y - mu) * rs);
            u.z = f2bf((va.z - mu) * rs); u.w = f2bf((va.w - mu) * rs);
            *(ushort4*)&As[row * 40 + kc] = u;
        }
        for (int i = tid; i < 512; i += TPB) {
            int n = i >> 2, kc = (i & 3) * 8;
            *(bf16x8*)&Bs[n * 40 + kc] = *(const bf16x8*)&BT[(size_t)(n0 + n) * 128 + k0 + kc];
        }
        __syncthreads();
        bf16x8 af[4], bfr[4];
#pragma unroll
        for (int mi = 0; mi < 4; mi++)
            af[mi] = *(bf16x8*)&As[(wm * 64 + mi * 16 + l16) * 40 + lhi * 8];
#pragma unroll
        for (int ni = 0; ni < 4; ni++)
            bfr[ni] = *(bf16x8*)&Bs[(wn * 64 + ni * 16 + l16) * 40 + lhi * 8];
#pragma unroll
        for (int mi = 0; mi < 4; mi++)
#pragma unroll
            for (int ni = 0; ni < 4; ni++)
                acc[mi][ni] = __builtin_amdgcn_mfma_f32_16x16x32_bf16(af[mi], bfr[ni], acc[mi][ni], 0, 0, 0);
        __syncthreads();
    }
#pragma unroll
    for (int mi = 0; mi < 4; mi++) {
#pragma unroll
        for (int ni = 0; ni < 4; ni++) {
            int col = n0 + wn * 64 + ni * 16 + l16;
            float bc = bias[col];
            if (which == 2) {  // V^T head-major: [bh][d][1024]
                int row0 = m0 + wm * 64 + mi * 16 + lhi * 4;
                int bb = row0 >> 10, t0 = row0 & 1023;
                ushort4 u;
                u.x = f2bf(acc[mi][ni][0] + bc); u.y = f2bf(acc[mi][ni][1] + bc);
                u.z = f2bf(acc[mi][ni][2] + bc); u.w = f2bf(acc[mi][ni][3] + bc);
                *(ushort4*)&vout[(((size_t)(bb * 4 + (col >> 7))) * 128 + (col & 127)) * 1024 + t0] = u;
            } else {
                int sT = (which == 0) ? 11 : 10;
                float sc = (which == 0) ? qscale : 1.f;
                unsigned short* C16 = (which == 0) ? qout : kout;
#pragma unroll
                for (int rg = 0; rg < 4; rg++) {
                    int row = m0 + wm * 64 + mi * 16 + lhi * 4 + rg;
                    int bb = row >> sT, t = row & ((1 << sT) - 1);
                    size_t oa = ((((size_t)bb * 4 + (col >> 7)) << sT) + t) * 128 + (col & 127);
                    C16[oa] = f2bf((acc[mi][ni][rg] + bc) * sc);
                }
            }
        }
    }
}

// ---------------------------------------------------------------------------
// MFMA bf16 GEMM, plain fp32 A, bf16 gelu output (mlp1). grid (2, 256).
// ---------------------------------------------------------------------------
__global__ __launch_bounds__(256, 2) void k_gemm_gelu(
        const float* __restrict__ A, const unsigned short* __restrict__ BT,
        unsigned short* __restrict__ C16, int N, int K,
        const float* __restrict__ bias) {
    __shared__ __align__(16) unsigned short As[128 * 40];
    __shared__ __align__(16) unsigned short Bs[128 * 40];
    int tid = threadIdx.x, lane = tid & 63, w = tid >> 6;
    int l16 = lane & 15, lhi = lane >> 4;
    int wm = w >> 1, wn = w & 1;
    int m0 = blockIdx.y * 128, n0 = blockIdx.x * 128;

    f32x4 acc[4][4];
#pragma unroll
    for (int mi = 0; mi < 4; mi++)
#pragma unroll
        for (int ni = 0; ni < 4; ni++) acc[mi][ni] = (f32x4){0.f, 0.f, 0.f, 0.f};

    for (int k0 = 0; k0 < K; k0 += 32) {
        for (int i = tid; i < 1024; i += TPB) {
            int row = i >> 3, kc = (i & 7) * 4;
            float4 va = *(const float4*)&A[(size_t)(m0 + row) * K + k0 + kc];
            ushort4 u;
            u.x = f2bf(va.x); u.y = f2bf(va.y); u.z = f2bf(va.z); u.w = f2bf(va.w);
            *(ushort4*)&As[row * 40 + kc] = u;
        }
        for (int i = tid; i < 512; i += TPB) {
            int n = i >> 2, kc = (i & 3) * 8;
            *(bf16x8*)&Bs[n * 40 + kc] = *(const bf16x8*)&BT[(size_t)(n0 + n) * K + k0 + kc];
        }
        __syncthreads();
        bf16x8 af[4], bfr[4];
#pragma unroll
        for (int mi = 0; mi < 4; mi++)
            af[mi] = *(bf16x8*)&As[(wm * 64 + mi * 16 + l16) * 40 + lhi * 8];
#pragma unroll
        for (int ni = 0; ni < 4; ni++)
            bfr[ni] = *(bf16x8*)&Bs[(wn * 64 + ni * 16 + l16) * 40 + lhi * 8];
#pragma unroll
        for (int mi = 0; mi < 4; mi++)
#pragma unroll
            for (int ni = 0; ni < 4; ni++)
                acc[mi][ni] = __builtin_amdgcn_mfma_f32_16x16x32_bf16(af[mi], bfr[ni], acc[mi][ni], 0, 0, 0);
        __syncthreads();
    }
#pragma unroll
    for (int mi = 0; mi < 4; mi++)
#pragma unroll
        for (int ni = 0; ni < 4; ni++) {
            int col = n0 + wn * 64 + ni * 16 + l16;
            float bc = bias[col];
#pragma unroll
            for (int rg = 0; rg < 4; rg++) {
                int row = m0 + wm * 64 + mi * 16 + lhi * 4 + rg;
                C16[(size_t)row * N + col] = f2bf(gelu_exact(acc[mi][ni][rg] + bc));
            }
        }
}

// ---------------------------------------------------------------------------
// GEMM (BM=64, BN=128=N) + bias + skip/residual + LayerNorm fused. A is bf16.
// mode 0: skip = width-concat [camT|lidT] (proj); mode 1: skip = aux, out
// split z_cam/z_lid, AND emits per-block stats partials (same layout as the
// old k_stats_part2) into `part`.
// ---------------------------------------------------------------------------
__global__ __launch_bounds__(256, 2) void k_gemm_ln(
        const unsigned short* __restrict__ Ab, const unsigned short* __restrict__ BT,
        float* __restrict__ C0, float* __restrict__ C1, int K, int mode,
        const float* __restrict__ bias, const float* __restrict__ aux,
        const float* __restrict__ aux2,
        const float* __restrict__ g, const float* __restrict__ bvec,
        float* __restrict__ part) {
    __shared__ __align__(16) char shm[64 * 132 * 4];
    unsigned short* As = (unsigned short*)shm;
    unsigned short* Bs = As + 64 * 40;
    float* Cs = (float*)shm;
    int tid = threadIdx.x, lane = tid & 63, w = tid >> 6;
    int l16 = lane & 15, lhi = lane >> 4;
    int m0 = blockIdx.x * 64;

    f32x4 acc[4][2];
#pragma unroll
    for (int mi = 0; mi < 4; mi++)
#pragma unroll
        for (int ni = 0; ni < 2; ni++) acc[mi][ni] = (f32x4){0.f, 0.f, 0.f, 0.f};

    for (int k0 = 0; k0 < K; k0 += 32) {
        for (int i = tid; i < 256; i += TPB) {
            int row = i >> 2, kc = (i & 3) * 8;
            *(bf16x8*)&As[row * 40 + kc] =
                *(const bf16x8*)&Ab[(size_t)(m0 + row) * K + k0 + kc];
        }
        for (int i = tid; i < 512; i += TPB) {
            int n = i >> 2, kc = (i & 3) * 8;
            *(bf16x8*)&Bs[n * 40 + kc] = *(const bf16x8*)&BT[(size_t)n * K + k0 + kc];
        }
        __syncthreads();
        bf16x8 af[4], bfr[2];
#pragma unroll
        for (int mi = 0; mi < 4; mi++)
            af[mi] = *(bf16x8*)&As[(mi * 16 + l16) * 40 + lhi * 8];
#pragma unroll
        for (int ni = 0; ni < 2; ni++)
            bfr[ni] = *(bf16x8*)&Bs[(w * 32 + ni * 16 + l16) * 40 + lhi * 8];
#pragma unroll
        for (int mi = 0; mi < 4; mi++)
#pragma unroll
            for (int ni = 0; ni < 2; ni++)
                acc[mi][ni] = __builtin_amdgcn_mfma_f32_16x16x32_bf16(af[mi], bfr[ni], acc[mi][ni], 0, 0, 0);
        __syncthreads();
    }
#pragma unroll
    for (int mi = 0; mi < 4; mi++) {
#pragma unroll
        for (int ni = 0; ni < 2; ni++) {
            int col = w * 32 + ni * 16 + l16;
#pragma unroll
            for (int rg = 0; rg < 4; rg++) {
                int rl = mi * 16 + lhi * 4 + rg;
                int grow = m0 + rl;
                float v = acc[mi][ni][rg] + bias[col];
                if (mode == 0) {
                    int rr = grow & 16383;
                    int b = rr >> 11, s = rr & 2047;
                    int H = s >> 6, W = s & 63;
                    const float* sp = (W < 32) ? aux : aux2;
                    v += sp[((size_t)(b * 1024 + H * 32 + (W & 31))) * 128 + col];
                } else {
                    v += aux[(size_t)grow * 128 + col];
                }
                Cs[rl * 132 + col] = v;
            }
        }
    }
    __syncthreads();
    float sl = 0.f, sl2 = 0.f, sh = 0.f, sh2 = 0.f;
    for (int rr = 0; rr < 16; rr++) {
        int row = w * 16 + rr, grow = m0 + row;
        float x0 = Cs[row * 132 + lane], x1 = Cs[row * 132 + 64 + lane];
        float s = x0 + x1, s2 = x0 * x0 + x1 * x1;
#pragma unroll
        for (int m = 32; m; m >>= 1) { s += __shfl_xor(s, m); s2 += __shfl_xor(s2, m); }
        float mu = s * (1.f / 128.f);
        float var = s2 * (1.f / 128.f) - mu * mu;
        float rs = rsqrtf(var + 1e-5f);
        float o0 = (x0 - mu) * rs * g[lane] + bvec[lane];
        float o1 = (x1 - mu) * rs * g[lane + 64] + bvec[lane + 64];
        float* Cp;
        size_t ro;
        if (mode == 1) { Cp = (grow < 16384) ? C0 : C1; ro = (size_t)(grow & 16383) * 128; }
        else           { Cp = C0; ro = (size_t)grow * 128; }
        Cp[ro + lane]      = o0;
        Cp[ro + lane + 64] = o1;
        sl += o0; sl2 += o0 * o0; sh += o1; sh2 += o1 * o1;
    }
    if (mode == 1) {
        // per-block stats partials (block spans one (sel,b,64-token chunk))
        __syncthreads();
        float* redS = Cs;            // reuse shm: [4][128] sums then [4][128] sq
        redS[w * 128 + lane] = sl;
        redS[w * 128 + 64 + lane] = sh;
        redS[512 + w * 128 + lane] = sl2;
        redS[512 + w * 128 + 64 + lane] = sh2;
        __syncthreads();
        if (tid < 128) {
            int d = tid;
            float S = 0.f, S2 = 0.f;
#pragma unroll
            for (int j = 0; j < 4; j++) {
                S += redS[j * 128 + d];
                S2 += redS[512 + j * 128 + d];
            }
            int sel = (m0 >= 16384) ? 1 : 0;
            int rrg = m0 & 16383;
            int b = rrg >> 11, c = (rrg >> 6) & 31;
            float* p = part + ((size_t)((sel * 8 + b) * 32 + c) * 2) * 128;
            p[d] = S; p[128 + d] = S2;
        }
    }
}

// ---------------------------------------------------------------------------
// ConvTranspose, ALL THREE outputs in one launch. grid (4, 40, 8).
// ---------------------------------------------------------------------------
__global__ __launch_bounds__(256, 2) void k_convt_gemm(
        const float* __restrict__ srcF, const float* __restrict__ srcC,
        const float* __restrict__ srcL, const float* __restrict__ stats,
        const unsigned short* __restrict__ ctT, float* __restrict__ outp) {
    __shared__ __align__(16) unsigned short As[128 * 40];
    __shared__ __align__(16) unsigned short Bs[128 * 40];
    int tid = threadIdx.x, lane = tid & 63, w = tid >> 6;
    int l16 = lane & 15, lhi = lane >> 4;
    int wm = w >> 1, wn = w & 1;
    int my = blockIdx.y, n0 = blockIdx.x * 128, b = blockIdx.z;
    const float* src; const float* mean; const float* rstd; float* out;
    int M, Hin, m0;
    if (my < 8)       { src = srcF; mean = stats + 4096; rstd = stats + 5120;
                        out = outp;            M = 1024; Hin = 32; m0 = my * 128; }
    else if (my < 24) { src = srcC; mean = stats + 6144; rstd = stats + 7168;
                        out = outp + 4194304;  M = 2048; Hin = 64; m0 = (my - 8) * 128; }
    else              { src = srcL; mean = stats + 8192; rstd = stats + 9216;
                        out = outp + 12582912; M = 2048; Hin = 64; m0 = (my - 24) * 128; }
    const float* Ab = src + (size_t)b * M * 128;
    const float* mb = mean + b * 128;
    const float* rb = rstd + b * 128;

    f32x4 acc[4][4];
#pragma unroll
    for (int mi = 0; mi < 4; mi++)
#pragma unroll
        for (int ni = 0; ni < 4; ni++) acc[mi][ni] = (f32x4){0.f, 0.f, 0.f, 0.f};

    for (int k0 = 0; k0 < 128; k0 += 32) {
        for (int i = tid; i < 1024; i += TPB) {
            int row = i >> 3, kc = (i & 7) * 4;
            float4 va = *(const float4*)&Ab[(size_t)(m0 + row) * 128 + k0 + kc];
            float4 mn = *(const float4*)&mb[k0 + kc];
            float4 rs = *(const float4*)&rb[k0 + kc];
            ushort4 u;
            u.x = f2bf(fmaxf((va.x - mn.x) * rs.x, 0.f));
            u.y = f2bf(fmaxf((va.y - mn.y) * rs.y, 0.f));
            u.z = f2bf(fmaxf((va.z - mn.z) * rs.z, 0.f));
            u.w = f2bf(fmaxf((va.w - mn.w) * rs.w, 0.f));
            *(ushort4*)&As[row * 40 + kc] = u;
        }
        for (int i = tid; i < 512; i += TPB) {
            int n = i >> 2, kc = (i & 3) * 8;
            *(bf16x8*)&Bs[n * 40 + kc] = *(const bf16x8*)&ctT[(size_t)(n0 + n) * 128 + k0 + kc];
        }
        __syncthreads();
        bf16x8 af[4], bfr[4];
#pragma unroll
        for (int mi = 0; mi < 4; mi++)
            af[mi] = *(bf16x8*)&As[(wm * 64 + mi * 16 + l16) * 40 + lhi * 8];
#pragma unroll
        for (int ni = 0; ni < 4; ni++)
            bfr[ni] = *(bf16x8*)&Bs[(wn * 64 + ni * 16 + l16) * 40 + lhi * 8];
#pragma unroll
        for (int mi = 0; mi < 4; mi++)
#pragma unroll
            for (int ni = 0; ni < 4; ni++)
                acc[mi][ni] = __builtin_amdgcn_mfma_f32_16x16x32_bf16(af[mi], bfr[ni], acc[mi][ni], 0, 0, 0);
        __syncthreads();
    }
    int Ho = 2 * Hin, Wo = 64;
#pragma unroll
    for (int mi = 0; mi < 4; mi++) {
#pragma unroll
        for (int ni = 0; ni < 4; ni++) {
            int col = n0 + wn * 64 + ni * 16 + l16;
            int oc = col >> 2, aa = (col >> 1) & 1, dd = col & 1;
            int p0 = m0 + wm * 64 + mi * 16 + lhi * 4;
            int hin = p0 >> 5, win0 = p0 & 31;
            float s0 = __shfl_xor(acc[mi][ni][0], 1);
            float s1 = __shfl_xor(acc[mi][ni][1], 1);
            float s2 = __shfl_xor(acc[mi][ni][2], 1);
            float s3 = __shfl_xor(acc[mi][ni][3], 1);
            float4 o;
            if (!dd) o = make_float4(acc[mi][ni][0], s0, acc[mi][ni][1], s1);
            else     o = make_float4(s2, acc[mi][ni][2], s3, acc[mi][ni][3]);
            size_t addr = (((size_t)b * 128 + oc) * Ho + 2 * hin + aa) * Wo
                        + 2 * win0 + (dd ? 4 : 0);
            *(float4*)&out[addr] = o;
        }
    }
}

// ---------------------------------------------------------------------------
// bf16 flash attention: swapped-QK^T, exp2 domain, cvt_pk packing, async-stage
// prefetch, XCD-aware 1D grid, setprio around MFMA clusters (T5).
// ---------------------------------------------------------------------------
__global__ __launch_bounds__(256, 2) void k_attn_bf16(
        const unsigned short* __restrict__ qb, const unsigned short* __restrict__ kb,
        const unsigned short* __restrict__ vt, unsigned short* __restrict__ aout) {
    __shared__ __align__(16) unsigned short smem[24576];  // 48 KB
    unsigned short* Ks = smem;            // [64][128], 16B-slot ^row swizzle
    unsigned short* Vt = smem + 8192;     // [128][64], ^d swizzle
    unsigned short* Ps = smem + 16384;    // 4 waves x [32][64]
    int tid = threadIdx.x;
    int lane = tid & 63, w = tid >> 6;
    int l16 = lane & 15, lhi = lane >> 4;
    int bid = blockIdx.x;
    int xcd = bid & 7, j = bid >> 3;
    int hz = xcd * 8 + (j >> 4);
    int qt = j & 15;
    int h = hz & 3, z = hz >> 2;
    int bh_q = (z & 7) * 4 + h;
    int bh_kv = z * 4 + h;
    unsigned short* Pw = Ps + w * 2048;

    const unsigned short* qg = qb + ((size_t)bh_q * 2048 + qt * 128) * 128;
    bf16x8 qa[2][4];
#pragma unroll
    for (int mt = 0; mt < 2; mt++) {
        int r = w * 32 + mt * 16 + l16;
#pragma unroll
        for (int ks = 0; ks < 4; ks++)
            qa[mt][ks] = *(const bf16x8*)&qg[(size_t)r * 128 + ks * 32 + lhi * 8];
    }

    f32x4 acc[2][8];
#pragma unroll
    for (int mt = 0; mt < 2; mt++)
#pragma unroll
        for (int dt = 0; dt < 8; dt++) acc[mt][dt] = (f32x4){0.f, 0.f, 0.f, 0.f};
    float m_r[2] = {-1e30f, -1e30f};
    float l_r[2] = {0.f, 0.f};

    const unsigned short* kg = kb + (size_t)bh_kv * 131072;
    const unsigned short* vg = vt + (size_t)bh_kv * 131072;

    int krow = tid >> 4, kcol = (tid & 15) * 8;
    int kls = ((tid & 15) ^ (krow & 7)) << 3;
    int vrow = tid >> 3, vcol = (tid & 7) * 8;
    int vls = ((tid & 7) ^ (vrow & 7)) << 3;

#pragma unroll
    for (int jj = 0; jj < 4; jj++) {
        int r = krow + jj * 16;
        *(bf16x8*)&Ks[r * 128 + kls] = *(const bf16x8*)&kg[(size_t)r * 128 + kcol];
        int d = vrow + jj * 32;
        *(bf16x8*)&Vt[d * 64 + vls] = *(const bf16x8*)&vg[(size_t)d * 1024 + vcol];
    }
    __syncthreads();

    for (int c = 0; c < 16; c++) {
        bf16x8 kpre[4], vpre[4];
        if (c < 15) {
            int c0 = (c + 1) * 64;
#pragma unroll
            for (int jj = 0; jj < 4; jj++) {
                kpre[jj] = *(const bf16x8*)&kg[(size_t)(c0 + krow + jj * 16) * 128 + kcol];
                vpre[jj] = *(const bf16x8*)&vg[(size_t)(vrow + jj * 32) * 1024 + c0 + vcol];
            }
        }

        // QK^T swapped: S^T[key][q]
        f32x4 s[2][4];
#pragma unroll
        for (int mt = 0; mt < 2; mt++)
#pragma unroll
            for (int kt = 0; kt < 4; kt++) s[mt][kt] = (f32x4){0.f, 0.f, 0.f, 0.f};
        __builtin_amdgcn_s_setprio(1);
#pragma unroll
        for (int kt = 0; kt < 4; kt++) {
            int r = kt * 16 + l16;
#pragma unroll
            for (int ks = 0; ks < 4; ks++) {
                bf16x8 kf = *(bf16x8*)&Ks[r * 128 + (((ks * 4 + lhi) ^ (r & 7)) << 3)];
                s[0][kt] = __builtin_amdgcn_mfma_f32_16x16x32_bf16(kf, qa[0][ks], s[0][kt], 0, 0, 0);
                s[1][kt] = __builtin_amdgcn_mfma_f32_16x16x32_bf16(kf, qa[1][ks], s[1][kt], 0, 0, 0);
            }
        }
        __builtin_amdgcn_s_setprio(0);

        float pm[2];
#pragma unroll
        for (int mt = 0; mt < 2; mt++) {
            float a = s[mt][0][0];
#pragma unroll
            for (int kt = 0; kt < 4; kt++)
#pragma unroll
                for (int rg = 0; rg < 4; rg++) a = fmaxf(a, s[mt][kt][rg]);
            a = fmaxf(a, __shfl_xor(a, 16));
            a = fmaxf(a, __shfl_xor(a, 32));
            pm[mt] = a;
        }
        bool need = (pm[0] > m_r[0] + 8.f) || (pm[1] > m_r[1] + 8.f);
        if (__any(need)) {
#pragma unroll
            for (int mt = 0; mt < 2; mt++) {
                float mn = fmaxf(m_r[mt], pm[mt]);
                float f = __builtin_amdgcn_exp2f(m_r[mt] - mn);
                m_r[mt] = mn;
                l_r[mt] *= f;
#pragma unroll
                for (int rg = 0; rg < 4; rg++) {
                    float ft = __shfl(f, lhi * 4 + rg);
#pragma unroll
                    for (int dt = 0; dt < 8; dt++) acc[mt][dt][rg] *= ft;
                }
            }
        }

#pragma unroll
        for (int mt = 0; mt < 2; mt++) {
            int row = mt * 16 + l16;
            int rsw = row & 7;
            float ls = 0.f;
#pragma unroll
            for (int kt = 0; kt < 4; kt++) {
                float p0 = __builtin_amdgcn_exp2f(s[mt][kt][0] - m_r[mt]);
                float p1 = __builtin_amdgcn_exp2f(s[mt][kt][1] - m_r[mt]);
                float p2 = __builtin_amdgcn_exp2f(s[mt][kt][2] - m_r[mt]);
                float p3 = __builtin_amdgcn_exp2f(s[mt][kt][3] - m_r[mt]);
                ls += (p0 + p1) + (p2 + p3);
                unsigned u01, u23;
                asm("v_cvt_pk_bf16_f32 %0, %1, %2" : "=v"(u01) : "v"(p0), "v"(p1));
                asm("v_cvt_pk_bf16_f32 %0, %1, %2" : "=v"(u23) : "v"(p2), "v"(p3));
                int slot = kt * 2 + (lhi >> 1);
                int base = row * 64 + ((slot ^ rsw) << 3) + (lhi & 1) * 4;
                *(unsigned*)&Pw[base] = u01;
                *(unsigned*)&Pw[base + 2] = u23;
            }
            l_r[mt] += ls;
        }
        asm volatile("s_waitcnt lgkmcnt(0)" ::: "memory");

        bf16x8 pa0[2], pa1[2];
#pragma unroll
        for (int mt = 0; mt < 2; mt++) {
            int row = mt * 16 + l16;
            pa0[mt] = *(bf16x8*)&Pw[row * 64 + ((lhi ^ (row & 7)) << 3)];
            pa1[mt] = *(bf16x8*)&Pw[row * 64 + (((4 + lhi) ^ (row & 7)) << 3)];
        }
        __builtin_amdgcn_s_setprio(1);
#pragma unroll
        for (int dt = 0; dt < 8; dt++) {
            int d = dt * 16 + l16;
            bf16x8 vb0 = *(bf16x8*)&Vt[d * 64 + ((lhi ^ (d & 7)) << 3)];
            bf16x8 vb1 = *(bf16x8*)&Vt[d * 64 + (((4 + lhi) ^ (d & 7)) << 3)];
            acc[0][dt] = __builtin_amdgcn_mfma_f32_16x16x32_bf16(pa0[0], vb0, acc[0][dt], 0, 0, 0);
            acc[0][dt] = __builtin_amdgcn_mfma_f32_16x16x32_bf16(pa1[0], vb1, acc[0][dt], 0, 0, 0);
            acc[1][dt] = __builtin_amdgcn_mfma_f32_16x16x32_bf16(pa0[1], vb0, acc[1][dt], 0, 0, 0);
            acc[1][dt] = __builtin_amdgcn_mfma_f32_16x16x32_bf16(pa1[1], vb1, acc[1][dt], 0, 0, 0);
        }
        __builtin_amdgcn_s_setprio(0);
        __syncthreads();

        if (c < 15) {
#pragma unroll
            for (int jj = 0; jj < 4; jj++) {
                *(bf16x8*)&Ks[(krow + jj * 16) * 128 + kls] = kpre[jj];
                *(bf16x8*)&Vt[(vrow + jj * 32) * 64 + vls] = vpre[jj];
            }
            __syncthreads();
        }
    }

#pragma unroll
    for (int mt = 0; mt < 2; mt++) {
        float lt = l_r[mt];
        lt += __shfl_xor(lt, 16);
        lt += __shfl_xor(lt, 32);
        l_r[mt] = lt;
    }
    size_t obase = (size_t)(z >> 3) * 16384 + (size_t)(z & 7) * 2048;
#pragma unroll
    for (int mt = 0; mt < 2; mt++)
#pragma unroll
        for (int rg = 0; rg < 4; rg++) {
            float linv = 1.f / __shfl(l_r[mt], lhi * 4 + rg);
            int qrow = qt * 128 + w * 32 + mt * 16 + lhi * 4 + rg;
            unsigned short* orow = aout + (obase + qrow) * 512 + h * 128;
#pragma unroll
            for (int dt = 0; dt < 8; dt++)
                orow[dt * 16 + l16] = f2bf(acc[mt][dt][rg] * linv);
        }
}

// ---------------------------------------------------------------------------
// fused_s write + stats partials in one pass. grid (16, 8).
// ---------------------------------------------------------------------------
__global__ void k_fused_stats(const float* __restrict__ zc, const float* __restrict__ zl,
                              float* __restrict__ fs, float* __restrict__ part) {
    int c = blockIdx.x, b = blockIdx.y;
    int tid = threadIdx.x;
    int d = tid & 127, half = tid >> 7;
    size_t base0 = ((size_t)b * 2048 + c * 64) * 128;
    size_t base1 = ((size_t)b * 2048 + 1024 + c * 64) * 128;
    float s = 0.f, s2 = 0.f;
    for (int t = half; t < 64; t += 2) {
        float v = zc[base0 + t * 128 + d] + zc[base1 + t * 128 + d]
                + zl[base0 + t * 128 + d] + zl[base1 + t * 128 + d];
        fs[((size_t)b * 1024 + c * 64 + t) * 128 + d] = v;
        s += v; s2 += v * v;
    }
    __shared__ float ls[256], ls2[256];
    ls[tid] = s; ls2[tid] = s2;
    __syncthreads();
    if (tid < 128) {
        s = ls[tid] + ls[tid + 128];
        s2 = ls2[tid] + ls2[tid + 128];
        float* p = part + ((size_t)(b * 16 + c) * 2) * 128;
        p[d] = s; p[128 + d] = s2;
    }
}

// ---------------------------------------------------------------------------
extern "C" void kernel_launch(void* const* d_in, const int* in_sizes, int n_in,
                              void* d_out, int out_size, void* d_ws, size_t ws_size,
                              hipStream_t stream) {
    const float* cam_feat = (const float*)d_in[0];
    const float* lid_feat = (const float*)d_in[1];
    const float* pos      = (const float*)d_in[2];
    const float* conv_w   = (const float*)d_in[3];
    const float* convT_w  = (const float*)d_in[4];
    const float* lnq_g = (const float*)d_in[5];
    const float* lnq_b = (const float*)d_in[6];
    const float* wq    = (const float*)d_in[7];
    const float* lnk_g = (const float*)d_in[8];
    const float* lnk_b = (const float*)d_in[9];
    const float* wk    = (const float*)d_in[10];
    const float* lnv_g = (const float*)d_in[11];
    const float* lnv_b = (const float*)d_in[12];
    const float* wv    = (const float*)d_in[13];
    const float* proj_w = (const float*)d_in[14];
    const float* proj_b = (const float*)d_in[15];
    const float* pre_g = (const float*)d_in[16];
    const float* pre_b = (const float*)d_in[17];
    const float* mlp_w1 = (const float*)d_in[18];
    const float* mlp_b1 = (const float*)d_in[19];
    const float* mlp_w2 = (const float*)d_in[20];
    const float* mlp_b2 = (const float*)d_in[21];
    const float* post_g = (const float*)d_in[22];
    const float* post_b = (const float*)d_in[23];

    float* ws = (float*)d_ws;
    float* outp = (float*)d_out;

    // persistent buffers (floats)
    float* cam_eT  = ws + 0;               // 1,048,576
    float* lid_eT  = ws + 1048576;         // 1,048,576
    unsigned short* qbf16 = (unsigned short*)(ws + 2097152);   // 4,194,304 f
    float* z_cam   = ws + 6291456;         // 2,097,152
    float* z_lid   = ws + 8388608;         // 2,097,152
    float* fused_s = ws + 10485760;        // 1,048,576
    float* stats   = ws + 11534336;        // 16,384
    unsigned short* wbuf = (unsigned short*)(ws + 11550720);   // 196,608 f
    float* part    = ws + 11747328;        // 131,072
    float* mean_e  = ws + 11878400;        // 16,384
    float* rstd_e  = ws + 11894784;        // 16,384
    float* bvecs   = ws + 11911168;        // 1,536
    unsigned short* xcolT = (unsigned short*)(ws + 11912704);  // 4,194,304 f
    float* pool    = ws + 16107008;        // 16,777,216

    unsigned short* wqT   = wbuf + 0;
    unsigned short* wkT   = wbuf + 65536;
    unsigned short* wvT   = wbuf + 131072;
    unsigned short* projT = wbuf + 196608;
    unsigned short* m1T   = wbuf + 262144;
    unsigned short* m2T   = wbuf + 294912;
    unsigned short* ctT   = wbuf + 327680;

    float* meanA = stats + 0,    *rstdA = stats + 2048;
    float* meanF = stats + 4096, *rstdF = stats + 5120;

    // pool (timeline-overlapped)
    unsigned short* kbf16 = (unsigned short*)(pool + 0);        // 4,194,304 f
    unsigned short* vbfT  = (unsigned short*)(pool + 4194304);  // 4,194,304 f
    unsigned short* abuf  = (unsigned short*)(pool + 8388608);  // 8,388,608 f
    float* z2 = pool + 0;                                       // over dead kbf16
    unsigned short* h1 = (unsigned short*)(pool + 4194304);     // over dead vbfT

    // 1/sqrt(128) * log2(e): attention softmax runs in the exp2 domain
    const float qscale = 0.12751744436f;

    // Weight prep + bias vectors (one launch)
    k_wtrans_all<<<390, TPB, 0, stream>>>(wq, wk, wv, proj_w, mlp_w1, mlp_w2, convT_w,
                                          lnq_g, lnk_g, lnv_g, lnq_b, lnk_b, lnv_b,
                                          wqT, wkT, wvT, projT, m1T, m2T, ctT, bvecs);

    // Stage A: stats + conv encoders (conv epilogue emits per-token LN stats)
    k_stats_cm<<<2048, TPB, 0, stream>>>(cam_feat, lid_feat, pos, meanA, rstdA);
    k_prep<<<dim3(32, 16), TPB, 0, stream>>>(cam_feat, lid_feat, pos, meanA, rstdA, xcolT);
    k_conv_gemm<<<dim3(16, 1, 16), TPB, 0, stream>>>(conv_w, xcolT, cam_eT, lid_eT,
                                                     mean_e, rstd_e);

    // Merged Q/K/V projection; attention; tail
    k_qkv_gemm<<<dim3(12, 128), TPB, 0, stream>>>(
        cam_eT, lid_eT, mean_e, rstd_e, wqT, wkT, wvT, qbf16, kbf16, vbfT,
        bvecs, qscale);
    k_attn_bf16<<<1024, TPB, 0, stream>>>(qbf16, kbf16, vbfT, abuf);
    k_gemm_ln<<<512, TPB, 0, stream>>>(
        abuf, projT, z2, nullptr, 512, 0, proj_b, cam_eT, lid_eT, pre_g, pre_b, nullptr);
    k_gemm_gelu<<<dim3(2, 256), TPB, 0, stream>>>(z2, m1T, h1, 256, 128, mlp_b1);
    k_gemm_ln<<<512, TPB, 0, stream>>>(
        h1, m2T, z_cam, z_lid, 256, 1, mlp_b2, z2, nullptr, post_g, post_b, part);

    // Outputs
    k_stats_red2<<<16, 128, 0, stream>>>(part, stats + 6144, stats + 7168,
                                         stats + 8192, stats + 9216);
    k_fused_stats<<<dim3(16, 8), TPB, 0, stream>>>(z_cam, z_lid, fused_s, part + 65536);
    k_stats_red<<<8, 128, 0, stream>>>(part + 65536, meanF, rstdF, 16, 1024);
    k_convt_gemm<<<dim3(4, 40, 8), TPB, 0, stream>>>(fused_s, z_cam, z_lid, stats,
                                                     ctT, outp);
}